// Round 11
// baseline (720.234 us; speedup 1.0000x reference)
//
#include <hip/hip_runtime.h>
#include <hip/hip_bf16.h>
#include <math.h>

#define DIMC 512
#define HEADS 8
#define HD 64
#define BB 4
#define HWX 1024
#define TXT 77
#define LATC 512
#define NE 8
#define HIDC 2048
#define NTOK 4096
#define MAXT 40

typedef __attribute__((ext_vector_type(8))) short bf16x8;
typedef __attribute__((ext_vector_type(4))) float f32x4;
typedef __hip_bfloat16 bf16;

__device__ __forceinline__ void split2(float v, bf16& h, bf16& l) {
    h = __float2bfloat16(v);
    l = __float2bfloat16(v - __bfloat162float(h));
}
__device__ __forceinline__ void split2s(float v, short& h, short& l) {
    bf16 hb, lb; split2(v, hb, lb);
    h = *(short*)&hb; l = *(short*)&lb;
}

// ---------------- style = w @ mod_w.T + mod_b ----------------
__global__ void style_kernel(const float* __restrict__ w, const float* __restrict__ mod_w,
                             const float* __restrict__ mod_b, float* __restrict__ style) {
    int t = blockIdx.x * blockDim.x + threadIdx.x;
    if (t >= BB * DIMC) return;
    int b = t / DIMC, i = t % DIMC;
    const float* wr = w + (long)b * LATC;
    const float* mr = mod_w + (long)i * LATC;
    float s = 0.f;
    #pragma unroll 8
    for (int l = 0; l < LATC; l++) s += wr[l] * mr[l];
    style[t] = s + mod_b[i];
}

// ------- wtmod[b,o,i] -> bf16 hi/lo (demodulated per-sample weight) -------
__global__ void wtmod_kernel(const float* __restrict__ weight, const float* __restrict__ style,
                             bf16* __restrict__ wh, bf16* __restrict__ wl) {
    int bo = blockIdx.x;
    int b = bo / DIMC, o = bo % DIMC;
    const float* wr = weight + (long)o * DIMC;
    const float* sr = style + (long)b * DIMC;
    int t = threadIdx.x;
    float vals[2]; float part = 0.f;
    for (int j = 0; j < 2; j++) {
        int i = t + j * 256;
        float v = wr[i] * sr[i];
        vals[j] = v; part += v * v;
    }
    __shared__ float red[256];
    red[t] = part; __syncthreads();
    for (int s = 128; s > 0; s >>= 1) { if (t < s) red[t] += red[t + s]; __syncthreads(); }
    float d = rsqrtf(red[0] + 1e-8f);
    for (int j = 0; j < 2; j++) {
        int i = t + j * 256;
        bf16 h, l; split2(vals[j] * d, h, l);
        wh[(long)bo * DIMC + i] = h; wl[(long)bo * DIMC + i] = l;
    }
}

// ---------------- fp32 -> bf16 hi/lo convert (flat) ----------------
__global__ void cvt2_kernel(const float* __restrict__ in, bf16* __restrict__ hi,
                            bf16* __restrict__ lo, int n) {
    int i = (blockIdx.x * blockDim.x + threadIdx.x) * 4;
    if (i >= n) return;
    float4 v = *(const float4*)(in + i);
    float a[4] = {v.x, v.y, v.z, v.w};
    #pragma unroll
    for (int j = 0; j < 4; j++) { bf16 h, l; split2(a[j], h, l); hi[i + j] = h; lo[i + j] = l; }
}

// ---------------- fp32 [R][C] -> bf16 [C][R] transpose hi/lo ----------------
__global__ void trcvt2_kernel(const float* __restrict__ in, bf16* __restrict__ hi,
                              bf16* __restrict__ lo, int R, int C, long in_bat, long out_bat) {
    __shared__ float tile[32][33];
    in += (long)blockIdx.z * in_bat; hi += (long)blockIdx.z * out_bat; lo += (long)blockIdx.z * out_bat;
    int c0 = blockIdx.x * 32, r0 = blockIdx.y * 32;
    int tc = threadIdx.x & 31, tr = threadIdx.x >> 5;
    #pragma unroll
    for (int i = 0; i < 4; i++) {
        int r = tr + i * 8;
        tile[r][tc] = in[(long)(r0 + r) * C + c0 + tc];
    }
    __syncthreads();
    #pragma unroll
    for (int i = 0; i < 4; i++) {
        int r = tr + i * 8;
        bf16 h, l; split2(tile[tc][r], h, l);
        hi[(long)(c0 + r) * R + r0 + tc] = h;
        lo[(long)(c0 + r) * R + r0 + tc] = l;
    }
}

// ---------------- fp32 [R][C] -> bf16 [C][R] transpose (single) ----------------
__global__ void trcvt_kernel(const float* __restrict__ in, bf16* __restrict__ out,
                             int R, int C, long in_bat, long out_bat) {
    __shared__ float tile[32][33];
    in += (long)blockIdx.z * in_bat; out += (long)blockIdx.z * out_bat;
    int c0 = blockIdx.x * 32, r0 = blockIdx.y * 32;
    int tc = threadIdx.x & 31, tr = threadIdx.x >> 5;
    #pragma unroll
    for (int i = 0; i < 4; i++) {
        int r = tr + i * 8;
        tile[r][tc] = in[(long)(r0 + r) * C + c0 + tc];
    }
    __syncthreads();
    #pragma unroll
    for (int i = 0; i < 4; i++) {
        int r = tr + i * 8;
        out[(long)(c0 + r) * R + r0 + tc] = __float2bfloat16(tile[tc][r]);
    }
}

// ---- split-precision bf16 MFMA GEMM, dbuf + post-barrier prefetch ----
__global__ __launch_bounds__(256) void mgemm_kernel(
    const bf16* __restrict__ Ah, const bf16* __restrict__ Al,
    const bf16* __restrict__ Bh, const bf16* __restrict__ Bl,
    const float* __restrict__ bias, const float* __restrict__ resid, float* __restrict__ C,
    bf16* __restrict__ Oh, bf16* __restrict__ Ol,
    int M, int N, int K, long a_bat, long b_bat, long c_bat, int cs_m, int cs_n) {
    __shared__ short AsH[2 * 4096];
    __shared__ short AsL[2 * 4096];
    __shared__ short BsH[2 * 4096];
    __shared__ short BsL[2 * 4096];
    int bat = blockIdx.z;
    const short* AbH = (const short*)(Ah + (long)bat * a_bat);
    const short* AbL = (const short*)(Al + (long)bat * a_bat);
    const short* BbH = (const short*)(Bh + (long)bat * b_bat);
    const short* BbL = (const short*)(Bl + (long)bat * b_bat);
    float* Cb = C + (long)bat * c_bat;
    const float* Rb = resid ? resid + (long)bat * c_bat : nullptr;
    int bm = blockIdx.y * 128, bn = blockIdx.x * 128;
    int t = threadIdx.x, lane = t & 63, w = t >> 6;
    int wm = (w >> 1) * 64, wn = (w & 1) * 64;
    int p0 = t, p1 = t + 256;
    int r0 = p0 >> 2, k0s = (p0 & 3) ^ ((r0 >> 1) & 3);
    int r1 = p1 >> 2, k1s = (p1 & 3) ^ ((r1 >> 1) & 3);
    int ar0 = bm + r0; if (ar0 > M - 1) ar0 = M - 1;
    int ar1 = bm + r1; if (ar1 > M - 1) ar1 = M - 1;
    long aoff0 = (long)ar0 * K + k0s * 8, aoff1 = (long)ar1 * K + k1s * 8;
    long boff0 = (long)(bn + r0) * K + k0s * 8, boff1 = (long)(bn + r1) * K + k1s * 8;
    int fr = lane & 15, fq = lane >> 4;
    int aOff[4], bOff[4];
    #pragma unroll
    for (int i = 0; i < 4; i++) {
        int row = wm + i * 16 + fr;
        aOff[i] = row * 32 + ((fq ^ ((row >> 1) & 3)) * 8);
        int col = wn + i * 16 + fr;
        bOff[i] = col * 32 + ((fq ^ ((col >> 1) & 3)) * 8);
    }
    f32x4 acc[4][4] = {};
    // prologue loads (kk = 0)
    bf16x8 vah0 = *(const bf16x8*)(AbH + aoff0);
    bf16x8 vah1 = *(const bf16x8*)(AbH + aoff1);
    bf16x8 val0 = *(const bf16x8*)(AbL + aoff0);
    bf16x8 val1 = *(const bf16x8*)(AbL + aoff1);
    bf16x8 vbh0 = *(const bf16x8*)(BbH + boff0);
    bf16x8 vbh1 = *(const bf16x8*)(BbH + boff1);
    bf16x8 vbl0 = *(const bf16x8*)(BbL + boff0);
    bf16x8 vbl1 = *(const bf16x8*)(BbL + boff1);
    int bufo = 0;
    for (int kk = 0; kk < K; kk += 32) {
        // write current tile to LDS (waits on in-flight loads here, not at barrier)
        *(bf16x8*)&AsH[bufo + p0 * 8] = vah0;  *(bf16x8*)&AsH[bufo + p1 * 8] = vah1;
        *(bf16x8*)&AsL[bufo + p0 * 8] = val0;  *(bf16x8*)&AsL[bufo + p1 * 8] = val1;
        *(bf16x8*)&BsH[bufo + p0 * 8] = vbh0;  *(bf16x8*)&BsH[bufo + p1 * 8] = vbh1;
        *(bf16x8*)&BsL[bufo + p0 * 8] = vbl0;  *(bf16x8*)&BsL[bufo + p1 * 8] = vbl1;
        __syncthreads();           // vmcnt already 0 -> no drain stall
        // prefetch next K-tile AFTER the barrier: stays in flight across MFMA phase
        int kn = (kk + 32 < K) ? kk + 32 : kk;
        bf16x8 nah0 = *(const bf16x8*)(AbH + aoff0 + kn);
        bf16x8 nah1 = *(const bf16x8*)(AbH + aoff1 + kn);
        bf16x8 nal0 = *(const bf16x8*)(AbL + aoff0 + kn);
        bf16x8 nal1 = *(const bf16x8*)(AbL + aoff1 + kn);
        bf16x8 nbh0 = *(const bf16x8*)(BbH + boff0 + kn);
        bf16x8 nbh1 = *(const bf16x8*)(BbH + boff1 + kn);
        bf16x8 nbl0 = *(const bf16x8*)(BbL + boff0 + kn);
        bf16x8 nbl1 = *(const bf16x8*)(BbL + boff1 + kn);
        bf16x8 aH[4], aL[4], bH[4], bL[4];
        #pragma unroll
        for (int i = 0; i < 4; i++) {
            aH[i] = *(const bf16x8*)&AsH[bufo + aOff[i]];
            aL[i] = *(const bf16x8*)&AsL[bufo + aOff[i]];
            bH[i] = *(const bf16x8*)&BsH[bufo + bOff[i]];
            bL[i] = *(const bf16x8*)&BsL[bufo + bOff[i]];
        }
        #pragma unroll
        for (int i = 0; i < 4; i++)
        #pragma unroll
        for (int j = 0; j < 4; j++) {
            acc[i][j] = __builtin_amdgcn_mfma_f32_16x16x32_bf16(aH[i], bH[j], acc[i][j], 0, 0, 0);
            acc[i][j] = __builtin_amdgcn_mfma_f32_16x16x32_bf16(aH[i], bL[j], acc[i][j], 0, 0, 0);
            acc[i][j] = __builtin_amdgcn_mfma_f32_16x16x32_bf16(aL[i], bH[j], acc[i][j], 0, 0, 0);
        }
        vah0 = nah0; vah1 = nah1; val0 = nal0; val1 = nal1;
        vbh0 = nbh0; vbh1 = nbh1; vbl0 = nbl0; vbl1 = nbl1;
        bufo ^= 4096;
    }
    #pragma unroll
    for (int i = 0; i < 4; i++)
    #pragma unroll
    for (int j = 0; j < 4; j++)
    #pragma unroll
    for (int r = 0; r < 4; r++) {
        int row = bm + wm + i * 16 + fq * 4 + r;
        int col = bn + wn + j * 16 + fr;
        if (row < M) {
            long off = (long)row * cs_m + (long)col * cs_n;
            float v = acc[i][j][r];
            if (bias) v += bias[col];
            if (Oh) {
                bf16 hh, ll; split2(v, hh, ll);
                Oh[off] = hh; Ol[off] = ll;
            } else {
                if (Rb) v += Rb[off];
                Cb[off] = v;
            }
        }
    }
}

// ---- split-precision MFMA flash SA: dbuf + post-barrier prefetch + setprio ----
__global__ __launch_bounds__(256) void sa_mfma_kernel(
    const bf16* __restrict__ qh, const bf16* __restrict__ ql,
    bf16* __restrict__ oh, bf16* __restrict__ ol) {
    int qt = blockIdx.x, h = blockIdx.y, b = blockIdx.z;
    __shared__ short KsH[2 * 4096], KsL[2 * 4096];   // [kv][d], swz: col ^ ((kv&7)<<3)
    __shared__ short VtH[2 * 4096], VtL[2 * 4096];   // [d][kv], swz: col ^ (((d>>3)&7)<<3)
    __shared__ short PHs[4][1024], PLs[4][1024];     // per-wave P (intra-wave only)
    int t = threadIdx.x, lane = t & 63, w = t >> 6;
    int fr = lane & 15, fq = lane >> 4;
    const short* QH = (const short*)qh;
    const short* QL = (const short*)ql;
    long qrow = (long)(b * 1024 + qt * 64 + w * 16 + fr) * 1536 + h * 64;
    bf16x8 Qh2[2], Ql2[2];
    Qh2[0] = *(const bf16x8*)(QH + qrow + fq * 8);
    Qh2[1] = *(const bf16x8*)(QH + qrow + 32 + fq * 8);
    Ql2[0] = *(const bf16x8*)(QL + qrow + fq * 8);
    Ql2[1] = *(const bf16x8*)(QL + qrow + 32 + fq * 8);
    float m_i[4], l_i[4];
    f32x4 o_acc[4] = {};
    #pragma unroll
    for (int i = 0; i < 4; i++) { m_i[i] = -1e30f; l_i[i] = 0.f; }
    int c0 = t, c1 = t + 256;
    int r0 = c0 >> 3, g0 = c0 & 7;
    int r1 = c1 >> 3, g1 = c1 & 7;
    int kd0 = r0 * 64 + ((g0 * 8) ^ ((r0 & 7) << 3));
    int kd1 = r1 * 64 + ((g1 * 8) ^ ((r1 & 7) << 3));
    long kb = (long)(b * 1024) * 1536 + 512 + h * 64;
    long vb = kb + 512;
    long lo0 = (long)r0 * 1536 + g0 * 8, lo1 = (long)r1 * 1536 + g1 * 8;
    short* ph = PHs[w]; short* pl = PLs[w];
    // prologue loads (kt = 0)
    bf16x8 kh0 = *(const bf16x8*)(QH + kb + lo0);
    bf16x8 kh1 = *(const bf16x8*)(QH + kb + lo1);
    bf16x8 kl0 = *(const bf16x8*)(QL + kb + lo0);
    bf16x8 kl1 = *(const bf16x8*)(QL + kb + lo1);
    bf16x8 vh0 = *(const bf16x8*)(QH + vb + lo0);
    bf16x8 vh1 = *(const bf16x8*)(QH + vb + lo1);
    bf16x8 vl0 = *(const bf16x8*)(QL + vb + lo0);
    bf16x8 vl1 = *(const bf16x8*)(QL + vb + lo1);
    int bufo = 0;
    for (int kt = 0; kt < 16; kt++) {
        // stage current tile into buf[bufo]
        *(bf16x8*)&KsH[bufo + kd0] = kh0;  *(bf16x8*)&KsH[bufo + kd1] = kh1;
        *(bf16x8*)&KsL[bufo + kd0] = kl0;  *(bf16x8*)&KsL[bufo + kd1] = kl1;
        #pragma unroll
        for (int j = 0; j < 8; j++) {
            int d0 = g0 * 8 + j;
            int i0 = bufo + d0 * 64 + (r0 ^ (((d0 >> 3) & 7) << 3));
            VtH[i0] = ((short*)&vh0)[j];  VtL[i0] = ((short*)&vl0)[j];
            int d1 = g1 * 8 + j;
            int i1 = bufo + d1 * 64 + (r1 ^ (((d1 >> 3) & 7) << 3));
            VtH[i1] = ((short*)&vh1)[j];  VtL[i1] = ((short*)&vl1)[j];
        }
        __syncthreads();          // vmcnt already 0 here -> no drain stall
        // prefetch next KV tile AFTER the barrier (overlaps QK+softmax+PV)
        int ktn = (kt + 1 < 16) ? kt + 1 : kt;
        long ko = kb + (long)(ktn * 64) * 1536;
        long vo = vb + (long)(ktn * 64) * 1536;
        bf16x8 nkh0 = *(const bf16x8*)(QH + ko + lo0);
        bf16x8 nkh1 = *(const bf16x8*)(QH + ko + lo1);
        bf16x8 nkl0 = *(const bf16x8*)(QL + ko + lo0);
        bf16x8 nkl1 = *(const bf16x8*)(QL + ko + lo1);
        bf16x8 nvh0 = *(const bf16x8*)(QH + vo + lo0);
        bf16x8 nvh1 = *(const bf16x8*)(QH + vo + lo1);
        bf16x8 nvl0 = *(const bf16x8*)(QL + vo + lo0);
        bf16x8 nvl1 = *(const bf16x8*)(QL + vo + lo1);
        __builtin_amdgcn_s_setprio(1);
        f32x4 s[4] = {};
        #pragma unroll
        for (int cf = 0; cf < 4; cf++) {
            int kvrow = cf * 16 + fr;
            #pragma unroll
            for (int kf = 0; kf < 2; kf++) {
                int idx = bufo + kvrow * 64 + ((kf * 32 + fq * 8) ^ ((kvrow & 7) << 3));
                bf16x8 Bh2 = *(const bf16x8*)&KsH[idx];
                bf16x8 Bl2 = *(const bf16x8*)&KsL[idx];
                s[cf] = __builtin_amdgcn_mfma_f32_16x16x32_bf16(Qh2[kf], Bh2, s[cf], 0, 0, 0);
                s[cf] = __builtin_amdgcn_mfma_f32_16x16x32_bf16(Qh2[kf], Bl2, s[cf], 0, 0, 0);
                s[cf] = __builtin_amdgcn_mfma_f32_16x16x32_bf16(Ql2[kf], Bh2, s[cf], 0, 0, 0);
            }
        }
        __builtin_amdgcn_s_setprio(0);
        #pragma unroll
        for (int cf = 0; cf < 4; cf++)
        #pragma unroll
        for (int reg = 0; reg < 4; reg++) s[cf][reg] *= 0.125f;
        float sc_[4];
        #pragma unroll
        for (int reg = 0; reg < 4; reg++) {
            float mx = fmaxf(fmaxf(s[0][reg], s[1][reg]), fmaxf(s[2][reg], s[3][reg]));
            mx = fmaxf(mx, __shfl_xor(mx, 1));
            mx = fmaxf(mx, __shfl_xor(mx, 2));
            mx = fmaxf(mx, __shfl_xor(mx, 4));
            mx = fmaxf(mx, __shfl_xor(mx, 8));
            float mn = fmaxf(m_i[reg], mx);
            sc_[reg] = __expf(m_i[reg] - mn);
            m_i[reg] = mn;
            float rs = 0.f;
            #pragma unroll
            for (int cf = 0; cf < 4; cf++) { s[cf][reg] = __expf(s[cf][reg] - mn); rs += s[cf][reg]; }
            rs += __shfl_xor(rs, 1);
            rs += __shfl_xor(rs, 2);
            rs += __shfl_xor(rs, 4);
            rs += __shfl_xor(rs, 8);
            l_i[reg] = l_i[reg] * sc_[reg] + rs;
        }
        #pragma unroll
        for (int cf = 0; cf < 4; cf++)
        #pragma unroll
        for (int reg = 0; reg < 4; reg++) o_acc[cf][reg] *= sc_[reg];
        #pragma unroll
        for (int cf = 0; cf < 4; cf++)
        #pragma unroll
        for (int reg = 0; reg < 4; reg++) {
            int q = fq * 4 + reg, kv = cf * 16 + fr;
            int idx = q * 64 + (kv ^ ((q & 7) << 3));
            split2s(s[cf][reg], ph[idx], pl[idx]);
        }
        // P is per-wave LDS: intra-wave ordering only
        asm volatile("s_waitcnt lgkmcnt(0)" ::: "memory");
        __builtin_amdgcn_sched_barrier(0);
        __builtin_amdgcn_s_setprio(1);
        bf16x8 Pf_h[2], Pf_l[2];
        #pragma unroll
        for (int kf = 0; kf < 2; kf++) {
            int idx = fr * 64 + ((kf * 32 + fq * 8) ^ ((fr & 7) << 3));
            Pf_h[kf] = *(const bf16x8*)&ph[idx];
            Pf_l[kf] = *(const bf16x8*)&pl[idx];
        }
        #pragma unroll
        for (int cf = 0; cf < 4; cf++) {
            int d = cf * 16 + fr;
            #pragma unroll
            for (int kf = 0; kf < 2; kf++) {
                int idx = bufo + d * 64 + ((kf * 32 + fq * 8) ^ (((d >> 3) & 7) << 3));
                bf16x8 Vh2 = *(const bf16x8*)&VtH[idx];
                bf16x8 Vl2 = *(const bf16x8*)&VtL[idx];
                o_acc[cf] = __builtin_amdgcn_mfma_f32_16x16x32_bf16(Pf_h[kf], Vh2, o_acc[cf], 0, 0, 0);
                o_acc[cf] = __builtin_amdgcn_mfma_f32_16x16x32_bf16(Pf_h[kf], Vl2, o_acc[cf], 0, 0, 0);
                o_acc[cf] = __builtin_amdgcn_mfma_f32_16x16x32_bf16(Pf_l[kf], Vh2, o_acc[cf], 0, 0, 0);
            }
        }
        __builtin_amdgcn_s_setprio(0);
        kh0 = nkh0; kh1 = nkh1; kl0 = nkl0; kl1 = nkl1;
        vh0 = nvh0; vh1 = nvh1; vl0 = nvl0; vl1 = nvl1;
        bufo ^= 4096;
    }
    #pragma unroll
    for (int reg = 0; reg < 4; reg++) {
        float inv = 1.f / l_i[reg];
        long m = (long)(b * 1024 + qt * 64 + w * 16 + fq * 4 + reg);
        #pragma unroll
        for (int cf = 0; cf < 4; cf++) {
            float v = o_acc[cf][reg] * inv;
            bf16 hh, ll; split2(v, hh, ll);
            long off = m * DIMC + h * 64 + cf * 16 + fr;
            oh[off] = hh; ol[off] = ll;
        }
    }
}

// ---- split-precision MFMA cross-attention: 77 keys padded to 96, single tile ----
__global__ __launch_bounds__(256) void ca_mfma_kernel(
    const bf16* __restrict__ qh, const bf16* __restrict__ ql,
    const bf16* __restrict__ kvh, const bf16* __restrict__ kvl,
    bf16* __restrict__ oh, bf16* __restrict__ ol) {
    int qt = blockIdx.x, h = blockIdx.y, b = blockIdx.z;
    __shared__ short UH[8192], UL[8192];
    __shared__ short PHs[4][2048], PLs[4][2048];
    int t = threadIdx.x, lane = t & 63, w = t >> 6;
    int fr = lane & 15, fq = lane >> 4;
    const short* QH = (const short*)qh;
    const short* QL = (const short*)ql;
    const short* KVH = (const short*)kvh;
    const short* KVL = (const short*)kvl;
    long qrow = (long)(b * 1024 + qt * 64 + w * 16 + fr) * DIMC + h * 64;
    bf16x8 Qh2[2], Ql2[2];
    Qh2[0] = *(const bf16x8*)(QH + qrow + fq * 8);
    Qh2[1] = *(const bf16x8*)(QH + qrow + 32 + fq * 8);
    Ql2[0] = *(const bf16x8*)(QL + qrow + fq * 8);
    Ql2[1] = *(const bf16x8*)(QL + qrow + 32 + fq * 8);
    for (int c = t; c < 768; c += 256) {
        int r = c >> 3, g = c & 7;
        int idx = r * 64 + ((g * 8) ^ ((r & 7) << 3));
        bf16x8 vh = {}, vl = {};
        if (r < 77) {
            long src = (long)(b * 77 + r) * 1024 + h * 64 + g * 8;
            vh = *(const bf16x8*)(KVH + src);
            vl = *(const bf16x8*)(KVL + src);
        }
        *(bf16x8*)&UH[idx] = vh;
        *(bf16x8*)&UL[idx] = vl;
    }
    __syncthreads();
    f32x4 s[5] = {};
    #pragma unroll
    for (int cf = 0; cf < 5; cf++) {
        int kvrow = cf * 16 + fr;
        #pragma unroll
        for (int kf = 0; kf < 2; kf++) {
            int idx = kvrow * 64 + ((kf * 32 + fq * 8) ^ ((kvrow & 7) << 3));
            bf16x8 Bh2 = *(const bf16x8*)&UH[idx];
            bf16x8 Bl2 = *(const bf16x8*)&UL[idx];
            s[cf] = __builtin_amdgcn_mfma_f32_16x16x32_bf16(Qh2[kf], Bh2, s[cf], 0, 0, 0);
            s[cf] = __builtin_amdgcn_mfma_f32_16x16x32_bf16(Qh2[kf], Bl2, s[cf], 0, 0, 0);
            s[cf] = __builtin_amdgcn_mfma_f32_16x16x32_bf16(Ql2[kf], Bh2, s[cf], 0, 0, 0);
        }
    }
    #pragma unroll
    for (int cf = 0; cf < 5; cf++) {
        int kv = cf * 16 + fr;
        #pragma unroll
        for (int reg = 0; reg < 4; reg++)
            s[cf][reg] = (kv < 77) ? s[cf][reg] * 0.125f : -1e30f;
    }
    float inv[4];
    #pragma unroll
    for (int reg = 0; reg < 4; reg++) {
        float mx = s[0][reg];
        #pragma unroll
        for (int cf = 1; cf < 5; cf++) mx = fmaxf(mx, s[cf][reg]);
        mx = fmaxf(mx, __shfl_xor(mx, 1));
        mx = fmaxf(mx, __shfl_xor(mx, 2));
        mx = fmaxf(mx, __shfl_xor(mx, 4));
        mx = fmaxf(mx, __shfl_xor(mx, 8));
        float rs = 0.f;
        #pragma unroll
        for (int cf = 0; cf < 5; cf++) { s[cf][reg] = __expf(s[cf][reg] - mx); rs += s[cf][reg]; }
        rs += __shfl_xor(rs, 1);
        rs += __shfl_xor(rs, 2);
        rs += __shfl_xor(rs, 4);
        rs += __shfl_xor(rs, 8);
        inv[reg] = 1.f / rs;
    }
    short* ph = PHs[w]; short* pl = PLs[w];
    #pragma unroll
    for (int cf = 0; cf < 6; cf++)
    #pragma unroll
    for (int reg = 0; reg < 4; reg++) {
        int q = fq * 4 + reg, kv = cf * 16 + fr;
        int idx = q * 128 + (kv ^ ((q & 7) << 3));
        float pv = (cf < 5) ? s[cf][reg] * inv[reg] : 0.f;
        split2s(pv, ph[idx], pl[idx]);
    }
    __syncthreads();
    for (int c = t; c < 768; c += 256) {
        int r = c >> 3, g = c & 7;
        bf16x8 vh = {}, vl = {};
        if (r < 77) {
            long src = (long)(b * 77 + r) * 1024 + 512 + h * 64 + g * 8;
            vh = *(const bf16x8*)(KVH + src);
            vl = *(const bf16x8*)(KVL + src);
        }
        #pragma unroll
        for (int j = 0; j < 8; j++) {
            int d = g * 8 + j;
            int idx = d * 128 + (r ^ (((d >> 3) & 7) << 3));
            UH[idx] = ((short*)&vh)[j];
            UL[idx] = ((short*)&vl)[j];
        }
    }
    __syncthreads();
    f32x4 o_acc[4] = {};
    bf16x8 Pf_h[3], Pf_l[3];
    #pragma unroll
    for (int kf = 0; kf < 3; kf++) {
        int idx = fr * 128 + ((kf * 32 + fq * 8) ^ ((fr & 7) << 3));
        Pf_h[kf] = *(const bf16x8*)&ph[idx];
        Pf_l[kf] = *(const bf16x8*)&pl[idx];
    }
    #pragma unroll
    for (int cf = 0; cf < 4; cf++) {
        int d = cf * 16 + fr;
        #pragma unroll
        for (int kf = 0; kf < 3; kf++) {
            int idx = d * 128 + ((kf * 32 + fq * 8) ^ (((d >> 3) & 7) << 3));
            bf16x8 Vh2 = *(const bf16x8*)&UH[idx];
            bf16x8 Vl2 = *(const bf16x8*)&UL[idx];
            o_acc[cf] = __builtin_amdgcn_mfma_f32_16x16x32_bf16(Pf_h[kf], Vh2, o_acc[cf], 0, 0, 0);
            o_acc[cf] = __builtin_amdgcn_mfma_f32_16x16x32_bf16(Pf_h[kf], Vl2, o_acc[cf], 0, 0, 0);
            o_acc[cf] = __builtin_amdgcn_mfma_f32_16x16x32_bf16(Pf_l[kf], Vh2, o_acc[cf], 0, 0, 0);
        }
    }
    #pragma unroll
    for (int reg = 0; reg < 4; reg++) {
        long m = (long)(b * 1024 + qt * 64 + w * 16 + fq * 4 + reg);
        #pragma unroll
        for (int cf = 0; cf < 4; cf++) {
            bf16 hh, ll; split2(o_acc[cf][reg], hh, ll);
            long off = m * DIMC + h * 64 + cf * 16 + fr;
            oh[off] = hh; ol[off] = ll;
        }
    }
}

// ---- MoE grouped MFMA GEMM1 (dbuf + post-barrier prefetch) ----
__global__ __launch_bounds__(256) void moe_mfma1_kernel(
    const bf16* __restrict__ xn_b, const bf16* __restrict__ e1T, const float* __restrict__ e_b1,
    const int* __restrict__ table, const int* __restrict__ ntiles, const int* __restrict__ perm,
    bf16* __restrict__ hid_b) {
    if (blockIdx.y >= ntiles[0]) return;
    int e = table[2 * blockIdx.y], row0 = table[2 * blockIdx.y + 1];
    int bn = blockIdx.x * 128;
    __shared__ short As[2 * 4096];
    __shared__ short Bs[2 * 4096];
    __shared__ int rowsS[128];
    int t = threadIdx.x, lane = t & 63, w = t >> 6;
    if (t < 128) rowsS[t] = perm[row0 + t];
    __syncthreads();
    int wm = (w >> 1) * 64, wn = (w & 1) * 64;
    int p0 = t, p1 = t + 256;
    int r0 = p0 >> 2, k0s = (p0 & 3) ^ ((r0 >> 1) & 3);
    int r1 = p1 >> 2, k1s = (p1 & 3) ^ ((r1 >> 1) & 3);
    int tok0 = rowsS[r0]; if (tok0 < 0) tok0 = 0;
    int tok1 = rowsS[r1]; if (tok1 < 0) tok1 = 0;
    const short* Xs = (const short*)xn_b;
    const short* Ws = (const short*)(e1T + (long)e * HIDC * DIMC);
    const short* a0 = Xs + (long)tok0 * DIMC + k0s * 8;
    const short* a1 = Xs + (long)tok1 * DIMC + k1s * 8;
    const short* b0 = Ws + (long)(bn + r0) * DIMC + k0s * 8;
    const short* b1 = Ws + (long)(bn + r1) * DIMC + k1s * 8;
    int fr = lane & 15, fq = lane >> 4;
    int aOff[4], bOff[4];
    #pragma unroll
    for (int i = 0; i < 4; i++) {
        int row = wm + i * 16 + fr;
        aOff[i] = row * 32 + ((fq ^ ((row >> 1) & 3)) * 8);
        int col = wn + i * 16 + fr;
        bOff[i] = col * 32 + ((fq ^ ((col >> 1) & 3)) * 8);
    }
    f32x4 acc[4][4] = {};
    bf16x8 va0 = *(const bf16x8*)(a0);
    bf16x8 va1 = *(const bf16x8*)(a1);
    bf16x8 vb0 = *(const bf16x8*)(b0);
    bf16x8 vb1 = *(const bf16x8*)(b1);
    int bufo = 0;
    for (int kk = 0; kk < DIMC; kk += 32) {
        *(bf16x8*)&As[bufo + p0 * 8] = va0;  *(bf16x8*)&As[bufo + p1 * 8] = va1;
        *(bf16x8*)&Bs[bufo + p0 * 8] = vb0;  *(bf16x8*)&Bs[bufo + p1 * 8] = vb1;
        __syncthreads();
        int kn = (kk + 32 < DIMC) ? kk + 32 : kk;
        bf16x8 na0 = *(const bf16x8*)(a0 + kn);
        bf16x8 na1 = *(const bf16x8*)(a1 + kn);
        bf16x8 nb0 = *(const bf16x8*)(b0 + kn);
        bf16x8 nb1 = *(const bf16x8*)(b1 + kn);
        bf16x8 aF[4], bF[4];
        #pragma unroll
        for (int i = 0; i < 4; i++) {
            aF[i] = *(const bf16x8*)&As[bufo + aOff[i]];
            bF[i] = *(const bf16x8*)&Bs[bufo + bOff[i]];
        }
        #pragma unroll
        for (int i = 0; i < 4; i++)
        #pragma unroll
        for (int j = 0; j < 4; j++)
            acc[i][j] = __builtin_amdgcn_mfma_f32_16x16x32_bf16(aF[i], bF[j], acc[i][j], 0, 0, 0);
        va0 = na0; va1 = na1; vb0 = nb0; vb1 = nb1;
        bufo ^= 4096;
    }
    const float* bb = e_b1 + (long)e * HIDC;
    #pragma unroll
    for (int i = 0; i < 4; i++)
    #pragma unroll
    for (int r = 0; r < 4; r++) {
        int tok = rowsS[wm + i * 16 + fq * 4 + r];
        if (tok < 0) continue;
        #pragma unroll
        for (int j = 0; j < 4; j++) {
            int col = bn + wn + j * 16 + fr;
            float v = acc[i][j][r] + bb[col];
            v = 0.5f * v * (1.f + erff(v * 0.70710678f));
            hid_b[(long)tok * HIDC + col] = __float2bfloat16(v);
        }
    }
}

// ---- MoE grouped MFMA GEMM2 (dbuf + post-barrier prefetch) ----
__global__ __launch_bounds__(256) void moe_mfma2_kernel(
    const bf16* __restrict__ hid_b, const bf16* __restrict__ e2T, const float* __restrict__ e_b2,
    const int* __restrict__ table, const int* __restrict__ ntiles, const int* __restrict__ perm,
    float* __restrict__ x_flat) {
    if (blockIdx.y >= ntiles[0]) return;
    int e = table[2 * blockIdx.y], row0 = table[2 * blockIdx.y + 1];
    int bn = blockIdx.x * 128;
    __shared__ short As[2 * 4096];
    __shared__ short Bs[2 * 4096];
    __shared__ int rowsS[128];
    int t = threadIdx.x, lane = t & 63, w = t >> 6;
    if (t < 128) rowsS[t] = perm[row0 + t];
    __syncthreads();
    int wm = (w >> 1) * 64, wn = (w & 1) * 64;
    int p0 = t, p1 = t + 256;
    int r0 = p0 >> 2, k0s = (p0 & 3) ^ ((r0 >> 1) & 3);
    int r1 = p1 >> 2, k1s = (p1 & 3) ^ ((r1 >> 1) & 3);
    int tok0 = rowsS[r0]; if (tok0 < 0) tok0 = 0;
    int tok1 = rowsS[r1]; if (tok1 < 0) tok1 = 0;
    const short* Hs = (const short*)hid_b;
    const short* Ws = (const short*)(e2T + (long)e * DIMC * HIDC);
    const short* a0 = Hs + (long)tok0 * HIDC + k0s * 8;
    const short* a1 = Hs + (long)tok1 * HIDC + k1s * 8;
    const short* b0 = Ws + (long)(bn + r0) * HIDC + k0s * 8;
    const short* b1 = Ws + (long)(bn + r1) * HIDC + k1s * 8;
    int fr = lane & 15, fq = lane >> 4;
    int aOff[4], bOff[4];
    #pragma unroll
    for (int i = 0; i < 4; i++) {
        int row = wm + i * 16 + fr;
        aOff[i] = row * 32 + ((fq ^ ((row >> 1) & 3)) * 8);
        int col = wn + i * 16 + fr;
        bOff[i] = col * 32 + ((fq ^ ((col >> 1) & 3)) * 8);
    }
    f32x4 acc[4][4] = {};
    bf16x8 va0 = *(const bf16x8*)(a0);
    bf16x8 va1 = *(const bf16x8*)(a1);
    bf16x8 vb0 = *(const bf16x8*)(b0);
    bf16x8 vb1 = *(const bf16x8*)(b1);
    int bufo = 0;
    for (int kk = 0; kk < HIDC; kk += 32) {
        *(bf16x8*)&As[bufo + p0 * 8] = va0;  *(bf16x8*)&As[bufo + p1 * 8] = va1;
        *(bf16x8*)&Bs[bufo + p0 * 8] = vb0;  *(bf16x8*)&Bs[bufo + p1 * 8] = vb1;
        __syncthreads();
        int kn = (kk + 32 < HIDC) ? kk + 32 : kk;
        bf16x8 na0 = *(const bf16x8*)(a0 + kn);
        bf16x8 na1 = *(const bf16x8*)(a1 + kn);
        bf16x8 nb0 = *(const bf16x8*)(b0 + kn);
        bf16x8 nb1 = *(const bf16x8*)(b1 + kn);
        bf16x8 aF[4], bF[4];
        #pragma unroll
        for (int i = 0; i < 4; i++) {
            aF[i] = *(const bf16x8*)&As[bufo + aOff[i]];
            bF[i] = *(const bf16x8*)&Bs[bufo + bOff[i]];
        }
        #pragma unroll
        for (int i = 0; i < 4; i++)
        #pragma unroll
        for (int j = 0; j < 4; j++)
            acc[i][j] = __builtin_amdgcn_mfma_f32_16x16x32_bf16(aF[i], bF[j], acc[i][j], 0, 0, 0);
        va0 = na0; va1 = na1; vb0 = nb0; vb1 = nb1;
        bufo ^= 4096;
    }
    const float* bb = e_b2 + (long)e * DIMC;
    #pragma unroll
    for (int i = 0; i < 4; i++)
    #pragma unroll
    for (int r = 0; r < 4; r++) {
        int tok = rowsS[wm + i * 16 + fq * 4 + r];
        if (tok < 0) continue;
        #pragma unroll
        for (int j = 0; j < 4; j++) {
            int col = bn + wn + j * 16 + fr;
            x_flat[(long)tok * DIMC + col] += acc[i][j][r] + bb[col];
        }
    }
}

// ---------------- LayerNorm: optional fp32 + bf16 hi/lo outputs ----------------
__global__ void ln_kernel(const float* __restrict__ x, const float* __restrict__ g,
                          const float* __restrict__ b, float* __restrict__ y,
                          bf16* __restrict__ yh, bf16* __restrict__ yl) {
    int tok = blockIdx.x;
    int t = threadIdx.x;
    const float* xr = x + (long)tok * DIMC;
    float v0 = xr[t], v1 = xr[t + 256];
    __shared__ float red[256];
    red[t] = v0 + v1; __syncthreads();
    for (int s = 128; s > 0; s >>= 1) { if (t < s) red[t] += red[t + s]; __syncthreads(); }
    float mu = red[0] * (1.f / DIMC);
    __syncthreads();
    float d0 = v0 - mu, d1 = v1 - mu;
    red[t] = d0 * d0 + d1 * d1; __syncthreads();
    for (int s = 128; s > 0; s >>= 1) { if (t < s) red[t] += red[t + s]; __syncthreads(); }
    float rs = rsqrtf(red[0] * (1.f / DIMC) + 1e-5f);
    float o0 = d0 * rs * g[t] + b[t];
    float o1 = d1 * rs * g[t + 256] + b[t + 256];
    if (y) { y[(long)tok * DIMC + t] = o0; y[(long)tok * DIMC + t + 256] = o1; }
    bf16 h, l;
    split2(o0, h, l); yh[(long)tok * DIMC + t] = h;       yl[(long)tok * DIMC + t] = l;
    split2(o1, h, l); yh[(long)tok * DIMC + t + 256] = h; yl[(long)tok * DIMC + t + 256] = l;
}

// ---------------- router text part ----------------
__global__ void textpart_kernel(const float* __restrict__ w, const float* __restrict__ r_text_mu,
                                const float* __restrict__ r_comb_mu, float* __restrict__ tp) {
    __shared__ float tw[4][128];
    int t = threadIdx.x;
    for (int j = 0; j < 2; j++) {
        int idx = t + j * 256; int b = idx >> 7, c = idx & 127;
        const float* wr = w + (long)b * LATC;
        float s = 0.f;
        for (int k = 0; k < LATC; k++) s += wr[k] * r_text_mu[(long)k * 128 + c];
        tw[b][c] = s;
    }
    __syncthreads();
    if (t < 32) {
        int b = t >> 3, e = t & 7;
        float s = 0.f;
        for (int c = 0; c < 128; c++) s += tw[b][c] * r_comb_mu[(long)(128 + c) * 8 + e];
        tp[t] = s;
    }
}

// ---------------- MoE meta ----------------
__global__ void moe_init_kernel(int* __restrict__ cnt, int* __restrict__ perm) {
    int g = blockIdx.x * blockDim.x + threadIdx.x;
    if (g < MAXT * 128) perm[g] = -1;
    if (g < NE) cnt[g] = 0;
}

__global__ void route_kernel(const float* __restrict__ feat, const float* __restrict__ tp,
                             const float* __restrict__ r_comb_mu, const float* __restrict__ r_temp,
                             float* __restrict__ onehot, int* __restrict__ idx, int* __restrict__ cnt) {
    int n = blockIdx.x * blockDim.x + threadIdx.x;
    if (n >= NTOK) return;
    int b = n >> 10;
    float tmp = fmaxf(r_temp[0], 0.1f);
    float invt = 1.f / tmp;
    const float* fr = feat + (long)n * 128;
    float lg[8];
    for (int e = 0; e < 8; e++) {
        float s = 0.f;
        for (int c = 0; c < 128; c++) s += fr[c] * r_comb_mu[(long)c * 8 + e];
        lg[e] = (s + tp[b * 8 + e]) * invt;
    }
    float best = lg[0]; int bi = 0;
    for (int e = 1; e < 8; e++) { if (lg[e] > best) { best = lg[e]; bi = e; } }
    for (int e = 0; e < 8; e++) onehot[(long)n * 8 + e] = (e == bi) ? 1.f : 0.f;
    idx[n] = bi;
    atomicAdd(&cnt[bi], 1);
}

__global__ void offsets_kernel(const int* __restrict__ cnt, int* __restrict__ cursor,
                               int* __restrict__ ntiles, int* __restrict__ table) {
    if (threadIdx.x != 0) return;
    int po = 0, nt = 0;
    for (int e = 0; e < NE; e++) {
        cursor[e] = po;
        int tiles = (cnt[e] + 127) >> 7;
        for (int j = 0; j < tiles; j++) { table[2 * nt] = e; table[2 * nt + 1] = po + j * 128; nt++; }
        po += tiles * 128;
    }
    ntiles[0] = nt;
}

__global__ void scatter_kernel(const int* __restrict__ idx, int* __restrict__ cursor,
                               int* __restrict__ perm) {
    int n = blockIdx.x * blockDim.x + threadIdx.x;
    if (n >= NTOK) return;
    int e = idx[n];
    int pos = atomicAdd(&cursor[e], 1);
    perm[pos] = n;
}

extern "C" void kernel_launch(void* const* d_in, const int* in_sizes, int n_in,
                              void* d_out, int out_size, void* d_ws, size_t ws_size,
                              hipStream_t stream) {
    const float* x        = (const float*)d_in[0];
    const float* w        = (const float*)d_in[1];
    const float* text     = (const float*)d_in[2];
    const float* pin_w    = (const float*)d_in[3];
    const float* pin_mw   = (const float*)d_in[4];
    const float* pin_mb   = (const float*)d_in[5];
    const float* pout_w   = (const float*)d_in[6];
    const float* pout_mw  = (const float*)d_in[7];
    const float* pout_mb  = (const float*)d_in[8];
    const float* ln1g     = (const float*)d_in[9];
    const float* ln1b     = (const float*)d_in[10];
    const float* ln2g     = (const float*)d_in[11];
    const float* ln2b     = (const float*)d_in[12];
    const float* ln3g     = (const float*)d_in[13];
    const float* ln3b     = (const float*)d_in[14];
    const float* sa_in_w  = (const float*)d_in[15];
    const float* sa_in_b  = (const float*)d_in[16];
    const float* sa_out_w = (const float*)d_in[17];
    const float* sa_out_b = (const float*)d_in[18];
    const float* ca_in_w  = (const float*)d_in[19];
    const float* ca_in_b  = (const float*)d_in[20];
    const float* ca_out_w = (const float*)d_in[21];
    const float* ca_out_b = (const float*)d_in[22];
    const float* r_feat   = (const float*)d_in[23];
    const float* r_text   = (const float*)d_in[24];
    const float* r_comb   = (const float*)d_in[25];
    const float* r_temp   = (const float*)d_in[26];
    const float* e_w1     = (const float*)d_in[27];
    const float* e_b1     = (const float*)d_in[28];
    const float* e_w2     = (const float*)d_in[29];
    const float* e_b2     = (const float*)d_in[30];

    float* out    = (float*)d_out;               // [B, DIM, H, W]
    float* onehot = out + (long)BB * DIMC * HWX; // [4096, 8]

    // ---------------- workspace: fp32 pool ----------------
    float* f32p = (float*)d_ws;
    float* style_in  = f32p;                 // 2048
    float* style_out = f32p + 2048;          // 2048
    float* tp        = f32p + 4096;          // 32
    int*   idx       = (int*)(f32p + 4128);  // 4096
    int*   cnt       = (int*)(f32p + 8224);  // 8
    int*   cursor    = (int*)(f32p + 8232);  // 8
    int*   ntiles    = (int*)(f32p + 8240);  // 8
    int*   table     = (int*)(f32p + 8248);  // 128
    int*   perm      = (int*)(f32p + 8376);  // 5120 -> ends 13496
    float* x_flat    = f32p + 13496;         // 2097152
    float* xn        = x_flat + 2097152;     // 2097152 (dead fp32; kept for layout stability)
    float* qkv       = xn + 2097152;         // 6291456 (SA q split / CA q split home)
    float* spill     = qkv + 6291456;        // 2097152 (e2T tail)

    // ---------------- bf16 pool (phase-aliased) ----------------
    bf16* bp = (bf16*)(f32p + 12596408);
    bf16* R1 = bp;                           // 6291456 elems, 3 phases
    bf16* xT_h  = R1;
    bf16* xT_l  = R1 + 2097152;
    bf16* wtA_h = R1 + 4194304;
    bf16* wtA_l = R1 + 5242880;
    bf16* obuf_h = R1;
    bf16* obuf_l = R1 + 2097152;
    bf16* kvt_h  = R1 + 4194304;                       // [308][1024] split
    bf16* kvt_l  = kvt_h + 315392;
    float* feat  = (float*)(kvt_l + 315392);           // 524288 fp32
    bf16* wtC_h = R1;
    bf16* wtC_l = R1 + 1048576;
    bf16* xn_h = R1 + 6291456;               // 2097152
    bf16* xn_l = xn_h + 2097152;             // 2097152
    bf16* WB   = xn_l + 2097152;             // 8388608: weights (early) / hid_b (late)
    bf16* text_h   = WB;
    bf16* text_l   = text_h + 157696;
    bf16* sawin_h  = text_l + 157696;
    bf16* sawin_l  = sawin_h + 786432;
    bf16* sawout_h = sawin_l + 786432;
    bf16* sawout_l = sawout_h + 262144;
    bf16* caw_h    = sawout_l + 262144;
    bf16* caw_l    = caw_h + 786432;
    bf16* cawout_h = caw_l + 786432;
    bf16* cawout_l = cawout_h + 262144;
    bf16* rfT_h    = cawout_l + 262144;      // [128][512] split r_feat^T
    bf16* rfT_l    = rfT_h + 65536;
    bf16* hid_b    = WB;                     // overlays weights after ca_out
    bf16* e1T = (bf16*)qkv;                  // [8][2048][512] in qkv+spill
    bf16* e2T = e1T + 8388608;
    bf16* xfl_h = xn_h;
    bf16* xfl_l = xn_l;
    bf16* q_h = (bf16*)qkv;                  // [4096][1536]
    bf16* q_l = q_h + 6291456;
    bf16* ca_qh = (bf16*)qkv;                // [4096][512]
    bf16* ca_ql = ca_qh + 2097152;
    (void)ws_size; (void)spill; (void)xn;

    auto mg = [&](const bf16* Ah, const bf16* Al, const bf16* Bh, const bf16* Bl,
                  const float* bias, const float* resid, float* C, bf16* Oh, bf16* Ol,
                  int M, int N, int K, long ab, long bb, long cb, int csm, int csn, int nb) {
        dim3 g(N / 128, (M + 127) / 128, nb);
        hipLaunchKernelGGL(mgemm_kernel, g, dim3(256), 0, stream,
                           Ah, Al, Bh, Bl, bias, resid, C, Oh, Ol, M, N, K, ab, bb, cb, csm, csn);
    };
    auto cvt2 = [&](const float* in, bf16* h2, bf16* l2, int n) {
        hipLaunchKernelGGL(cvt2_kernel, dim3((n / 4 + 255) / 256), dim3(256), 0, stream, in, h2, l2, n);
    };

    // ---- input conversions (hi/lo) ----
    cvt2(sa_in_w, sawin_h, sawin_l, 1536 * 512);
    cvt2(sa_out_w, sawout_h, sawout_l, 512 * 512);
    cvt2(ca_in_w, caw_h, caw_l, 1536 * 512);
    cvt2(ca_out_w, cawout_h, cawout_l, 512 * 512);
    cvt2(text, text_h, text_l, BB * TXT * 512);
    hipLaunchKernelGGL(trcvt2_kernel, dim3(32, 16, BB), dim3(256), 0, stream,
                       x, xT_h, xT_l, 512, 1024, (long)512 * 1024, (long)1024 * 512);
    hipLaunchKernelGGL(trcvt2_kernel, dim3(4, 16, 1), dim3(256), 0, stream,
                       r_feat, rfT_h, rfT_l, 512, 128, 0L, 0L);

    // ---- modconv in ----
    hipLaunchKernelGGL(style_kernel, dim3(8), dim3(256), 0, stream, w, pin_mw, pin_mb, style_in);
    hipLaunchKernelGGL(wtmod_kernel, dim3(BB * DIMC), dim3(256), 0, stream, pin_w, style_in, wtA_h, wtA_l);
    mg(xT_h, xT_l, wtA_h, wtA_l, nullptr, nullptr, x_flat, nullptr, nullptr,
       HWX, DIMC, DIMC, (long)HWX * DIMC, (long)DIMC * DIMC, (long)HWX * DIMC, DIMC, 1, BB);

    // ---- LN1 + self-attention (split MFMA) ----
    hipLaunchKernelGGL(ln_kernel, dim3(NTOK), dim3(256), 0, stream, x_flat, ln1g, ln1b,
                       (float*)nullptr, xn_h, xn_l);
    mg(xn_h, xn_l, sawin_h, sawin_l, sa_in_b, nullptr, nullptr, q_h, q_l,
       NTOK, 1536, 512, 0, 0, 0, 1536, 1, 1);
    hipLaunchKernelGGL(sa_mfma_kernel, dim3(16, HEADS, BB), dim3(256), 0, stream,
                       q_h, q_l, obuf_h, obuf_l);
    mg(obuf_h, obuf_l, sawout_h, sawout_l, sa_out_b, x_flat, x_flat, nullptr, nullptr,
       NTOK, 512, 512, 0, 0, 0, 512, 1, 1);

    // ---- LN2 + cross-attention (split MFMA) ----
    hipLaunchKernelGGL(ln_kernel, dim3(NTOK), dim3(256), 0, stream, x_flat, ln2g, ln2b,
                       (float*)nullptr, xn_h, xn_l);
    mg(xn_h, xn_l, caw_h, caw_l, ca_in_b, nullptr, nullptr, ca_qh, ca_ql,
       NTOK, 512, 512, 0, 0, 0, 512, 1, 1);
    mg(text_h, text_l, caw_h + 512 * 512, caw_l + 512 * 512, ca_in_b + 512, nullptr, nullptr,
       kvt_h, kvt_l, BB * TXT, 1024, 512, 0, 0, 0, 1024, 1, 1);
    hipLaunchKernelGGL(ca_mfma_kernel, dim3(16, HEADS, BB), dim3(256), 0, stream,
                       ca_qh, ca_ql, kvt_h, kvt_l, obuf_h, obuf_l);
    hipLaunchKernelGGL(trcvt_kernel, dim3(64, 16, NE), dim3(256), 0, stream,
                       e_w1, e1T, 512, 2048, (long)512 * 2048, (long)2048 * 512);
    hipLaunchKernelGGL(trcvt_kernel, dim3(16, 64, NE), dim3(256), 0, stream,
                       e_w2, e2T, 2048, 512, (long)2048 * 512, (long)512 * 2048);
    mg(obuf_h, obuf_l, cawout_h, cawout_l, ca_out_b, x_flat, x_flat, nullptr, nullptr,
       NTOK, 512, 512, 0, 0, 0, 512, 1, 1);

    // ---- LN3 + router (feat via split MFMA) ----
    hipLaunchKernelGGL(ln_kernel, dim3(NTOK), dim3(256), 0, stream, x_flat, ln3g, ln3b,
                       (float*)nullptr, xn_h, xn_l);
    mg(xn_h, xn_l, rfT_h, rfT_l, nullptr, nullptr, feat, nullptr, nullptr,
       NTOK, 128, 512, 0, 0, 0, 128, 1, 1);
    hipLaunchKernelGGL(textpart_kernel, dim3(1), dim3(256), 0, stream, w, r_text, r_comb, tp);
    hipLaunchKernelGGL(moe_init_kernel, dim3((MAXT * 128 + 255) / 256), dim3(256), 0, stream, cnt, perm);
    hipLaunchKernelGGL(route_kernel, dim3(16), dim3(256), 0, stream, feat, tp, r_comb, r_temp, onehot, idx, cnt);
    hipLaunchKernelGGL(offsets_kernel, dim3(1), dim3(64), 0, stream, cnt, cursor, ntiles, table);
    hipLaunchKernelGGL(scatter_kernel, dim3(16), dim3(256), 0, stream, idx, cursor, perm);

    // ---- MoE grouped MFMA GEMMs ----
    hipLaunchKernelGGL(moe_mfma1_kernel, dim3(HIDC / 128, MAXT), dim3(256), 0, stream,
                       xn_h, e1T, e_b1, table, ntiles, perm, hid_b);
    hipLaunchKernelGGL(moe_mfma2_kernel, dim3(DIMC / 128, MAXT), dim3(256), 0, stream,
                       hid_b, e2T, e_b2, table, ntiles, perm, x_flat);

    // ---- modconv out (split both sides) ----
    cvt2(x_flat, xfl_h, xfl_l, NTOK * DIMC);
    hipLaunchKernelGGL(style_kernel, dim3(8), dim3(256), 0, stream, w, pout_mw, pout_mb, style_out);
    hipLaunchKernelGGL(wtmod_kernel, dim3(BB * DIMC), dim3(256), 0, stream, pout_w, style_out, wtC_h, wtC_l);
    mg(wtC_h, wtC_l, xfl_h, xfl_l, nullptr, nullptr, out, nullptr, nullptr,
       DIMC, HWX, DIMC, (long)DIMC * DIMC, (long)HWX * DIMC, (long)DIMC * HWX, HWX, 1, BB);
}

// Round 12
// 598.314 us; speedup vs baseline: 1.2038x; 1.2038x over previous
//
#include <hip/hip_runtime.h>
#include <hip/hip_bf16.h>
#include <math.h>

#define DIMC 512
#define HEADS 8
#define HD 64
#define BB 4
#define HWX 1024
#define TXT 77
#define LATC 512
#define NE 8
#define HIDC 2048
#define NTOK 4096
#define MAXT 40

typedef __attribute__((ext_vector_type(8))) short bf16x8;
typedef __attribute__((ext_vector_type(4))) float f32x4;
typedef __hip_bfloat16 bf16;

__device__ __forceinline__ void split2(float v, bf16& h, bf16& l) {
    h = __float2bfloat16(v);
    l = __float2bfloat16(v - __bfloat162float(h));
}
__device__ __forceinline__ void split2s(float v, short& h, short& l) {
    bf16 hb, lb; split2(v, hb, lb);
    h = *(short*)&hb; l = *(short*)&lb;
}

// ---------------- style = w @ mod_w.T + mod_b ----------------
__global__ void style_kernel(const float* __restrict__ w, const float* __restrict__ mod_w,
                             const float* __restrict__ mod_b, float* __restrict__ style) {
    int t = blockIdx.x * blockDim.x + threadIdx.x;
    if (t >= BB * DIMC) return;
    int b = t / DIMC, i = t % DIMC;
    const float* wr = w + (long)b * LATC;
    const float* mr = mod_w + (long)i * LATC;
    float s = 0.f;
    #pragma unroll 8
    for (int l = 0; l < LATC; l++) s += wr[l] * mr[l];
    style[t] = s + mod_b[i];
}

// ------- wtmod[b,o,i] -> bf16 hi/lo (demodulated per-sample weight) -------
__global__ void wtmod_kernel(const float* __restrict__ weight, const float* __restrict__ style,
                             bf16* __restrict__ wh, bf16* __restrict__ wl) {
    int bo = blockIdx.x;
    int b = bo / DIMC, o = bo % DIMC;
    const float* wr = weight + (long)o * DIMC;
    const float* sr = style + (long)b * DIMC;
    int t = threadIdx.x;
    float vals[2]; float part = 0.f;
    for (int j = 0; j < 2; j++) {
        int i = t + j * 256;
        float v = wr[i] * sr[i];
        vals[j] = v; part += v * v;
    }
    __shared__ float red[256];
    red[t] = part; __syncthreads();
    for (int s = 128; s > 0; s >>= 1) { if (t < s) red[t] += red[t + s]; __syncthreads(); }
    float d = rsqrtf(red[0] + 1e-8f);
    for (int j = 0; j < 2; j++) {
        int i = t + j * 256;
        bf16 h, l; split2(vals[j] * d, h, l);
        wh[(long)bo * DIMC + i] = h; wl[(long)bo * DIMC + i] = l;
    }
}

// ---------------- fp32 -> bf16 hi/lo convert (flat) ----------------
__global__ void cvt2_kernel(const float* __restrict__ in, bf16* __restrict__ hi,
                            bf16* __restrict__ lo, int n) {
    int i = (blockIdx.x * blockDim.x + threadIdx.x) * 4;
    if (i >= n) return;
    float4 v = *(const float4*)(in + i);
    float a[4] = {v.x, v.y, v.z, v.w};
    #pragma unroll
    for (int j = 0; j < 4; j++) { bf16 h, l; split2(a[j], h, l); hi[i + j] = h; lo[i + j] = l; }
}

// ---------------- fp32 [R][C] -> bf16 [C][R] transpose hi/lo ----------------
__global__ void trcvt2_kernel(const float* __restrict__ in, bf16* __restrict__ hi,
                              bf16* __restrict__ lo, int R, int C, long in_bat, long out_bat) {
    __shared__ float tile[32][33];
    in += (long)blockIdx.z * in_bat; hi += (long)blockIdx.z * out_bat; lo += (long)blockIdx.z * out_bat;
    int c0 = blockIdx.x * 32, r0 = blockIdx.y * 32;
    int tc = threadIdx.x & 31, tr = threadIdx.x >> 5;
    #pragma unroll
    for (int i = 0; i < 4; i++) {
        int r = tr + i * 8;
        tile[r][tc] = in[(long)(r0 + r) * C + c0 + tc];
    }
    __syncthreads();
    #pragma unroll
    for (int i = 0; i < 4; i++) {
        int r = tr + i * 8;
        bf16 h, l; split2(tile[tc][r], h, l);
        hi[(long)(c0 + r) * R + r0 + tc] = h;
        lo[(long)(c0 + r) * R + r0 + tc] = l;
    }
}

// ---------------- fp32 [R][C] -> bf16 [C][R] transpose (single) ----------------
__global__ void trcvt_kernel(const float* __restrict__ in, bf16* __restrict__ out,
                             int R, int C, long in_bat, long out_bat) {
    __shared__ float tile[32][33];
    in += (long)blockIdx.z * in_bat; out += (long)blockIdx.z * out_bat;
    int c0 = blockIdx.x * 32, r0 = blockIdx.y * 32;
    int tc = threadIdx.x & 31, tr = threadIdx.x >> 5;
    #pragma unroll
    for (int i = 0; i < 4; i++) {
        int r = tr + i * 8;
        tile[r][tc] = in[(long)(r0 + r) * C + c0 + tc];
    }
    __syncthreads();
    #pragma unroll
    for (int i = 0; i < 4; i++) {
        int r = tr + i * 8;
        out[(long)(c0 + r) * R + r0 + tc] = __float2bfloat16(tile[tc][r]);
    }
}

// ---- split-precision bf16 MFMA GEMM, 64x64 tile (high machine fill) ----
// 4 waves in 2x2 quadrants, each 32x32 (2x2 frags). BK=32, dbuf, post-barrier prefetch.
__global__ __launch_bounds__(256) void mgemm64_kernel(
    const bf16* __restrict__ Ah, const bf16* __restrict__ Al,
    const bf16* __restrict__ Bh, const bf16* __restrict__ Bl,
    const float* __restrict__ bias, const float* __restrict__ resid, float* __restrict__ C,
    bf16* __restrict__ Oh, bf16* __restrict__ Ol,
    int M, int N, int K, long a_bat, long b_bat, long c_bat, int cs_m, int cs_n) {
    __shared__ short AsH[2 * 2048];
    __shared__ short AsL[2 * 2048];
    __shared__ short BsH[2 * 2048];
    __shared__ short BsL[2 * 2048];
    int bat = blockIdx.z;
    const short* AbH = (const short*)(Ah + (long)bat * a_bat);
    const short* AbL = (const short*)(Al + (long)bat * a_bat);
    const short* BbH = (const short*)(Bh + (long)bat * b_bat);
    const short* BbL = (const short*)(Bl + (long)bat * b_bat);
    float* Cb = C + (long)bat * c_bat;
    const float* Rb = resid ? resid + (long)bat * c_bat : nullptr;
    int bm = blockIdx.y * 64, bn = blockIdx.x * 64;
    int t = threadIdx.x, lane = t & 63, w = t >> 6;
    int wm = (w >> 1) * 32, wn = (w & 1) * 32;
    int r0 = t >> 2, k0s = (t & 3) ^ ((r0 >> 1) & 3);
    int ar0 = bm + r0; if (ar0 > M - 1) ar0 = M - 1;
    long aoff = (long)ar0 * K + k0s * 8;
    long boff = (long)(bn + r0) * K + k0s * 8;
    int fr = lane & 15, fq = lane >> 4;
    int aOff[2], bOff[2];
    #pragma unroll
    for (int i = 0; i < 2; i++) {
        int row = wm + i * 16 + fr;
        aOff[i] = row * 32 + ((fq ^ ((row >> 1) & 3)) * 8);
        int col = wn + i * 16 + fr;
        bOff[i] = col * 32 + ((fq ^ ((col >> 1) & 3)) * 8);
    }
    f32x4 acc[2][2] = {};
    // prologue loads (kk = 0)
    bf16x8 vah = *(const bf16x8*)(AbH + aoff);
    bf16x8 val = *(const bf16x8*)(AbL + aoff);
    bf16x8 vbh = *(const bf16x8*)(BbH + boff);
    bf16x8 vbl = *(const bf16x8*)(BbL + boff);
    int bufo = 0;
    for (int kk = 0; kk < K; kk += 32) {
        *(bf16x8*)&AsH[bufo + t * 8] = vah;
        *(bf16x8*)&AsL[bufo + t * 8] = val;
        *(bf16x8*)&BsH[bufo + t * 8] = vbh;
        *(bf16x8*)&BsL[bufo + t * 8] = vbl;
        __syncthreads();
        int kn = (kk + 32 < K) ? kk + 32 : kk;
        bf16x8 nah = *(const bf16x8*)(AbH + aoff + kn);
        bf16x8 nal = *(const bf16x8*)(AbL + aoff + kn);
        bf16x8 nbh = *(const bf16x8*)(BbH + boff + kn);
        bf16x8 nbl = *(const bf16x8*)(BbL + boff + kn);
        bf16x8 aH[2], aL[2], bH[2], bL[2];
        #pragma unroll
        for (int i = 0; i < 2; i++) {
            aH[i] = *(const bf16x8*)&AsH[bufo + aOff[i]];
            aL[i] = *(const bf16x8*)&AsL[bufo + aOff[i]];
            bH[i] = *(const bf16x8*)&BsH[bufo + bOff[i]];
            bL[i] = *(const bf16x8*)&BsL[bufo + bOff[i]];
        }
        #pragma unroll
        for (int i = 0; i < 2; i++)
        #pragma unroll
        for (int j = 0; j < 2; j++) {
            acc[i][j] = __builtin_amdgcn_mfma_f32_16x16x32_bf16(aH[i], bH[j], acc[i][j], 0, 0, 0);
            acc[i][j] = __builtin_amdgcn_mfma_f32_16x16x32_bf16(aH[i], bL[j], acc[i][j], 0, 0, 0);
            acc[i][j] = __builtin_amdgcn_mfma_f32_16x16x32_bf16(aL[i], bH[j], acc[i][j], 0, 0, 0);
        }
        vah = nah; val = nal; vbh = nbh; vbl = nbl;
        bufo ^= 2048;
    }
    #pragma unroll
    for (int i = 0; i < 2; i++)
    #pragma unroll
    for (int j = 0; j < 2; j++)
    #pragma unroll
    for (int r = 0; r < 4; r++) {
        int row = bm + wm + i * 16 + fq * 4 + r;
        int col = bn + wn + j * 16 + fr;
        if (row < M) {
            long off = (long)row * cs_m + (long)col * cs_n;
            float v = acc[i][j][r];
            if (bias) v += bias[col];
            if (Oh) {
                bf16 hh, ll; split2(v, hh, ll);
                Oh[off] = hh; Ol[off] = ll;
            } else {
                if (Rb) v += Rb[off];
                Cb[off] = v;
            }
        }
    }
}

// ---- split-precision MFMA flash SA: dbuf + post-barrier prefetch + setprio ----
__global__ __launch_bounds__(256) void sa_mfma_kernel(
    const bf16* __restrict__ qh, const bf16* __restrict__ ql,
    bf16* __restrict__ oh, bf16* __restrict__ ol) {
    int qt = blockIdx.x, h = blockIdx.y, b = blockIdx.z;
    __shared__ short KsH[2 * 4096], KsL[2 * 4096];   // [kv][d], swz: col ^ ((kv&7)<<3)
    __shared__ short VtH[2 * 4096], VtL[2 * 4096];   // [d][kv], swz: col ^ (((d>>3)&7)<<3)
    __shared__ short PHs[4][1024], PLs[4][1024];     // per-wave P (intra-wave only)
    int t = threadIdx.x, lane = t & 63, w = t >> 6;
    int fr = lane & 15, fq = lane >> 4;
    const short* QH = (const short*)qh;
    const short* QL = (const short*)ql;
    long qrow = (long)(b * 1024 + qt * 64 + w * 16 + fr) * 1536 + h * 64;
    bf16x8 Qh2[2], Ql2[2];
    Qh2[0] = *(const bf16x8*)(QH + qrow + fq * 8);
    Qh2[1] = *(const bf16x8*)(QH + qrow + 32 + fq * 8);
    Ql2[0] = *(const bf16x8*)(QL + qrow + fq * 8);
    Ql2[1] = *(const bf16x8*)(QL + qrow + 32 + fq * 8);
    float m_i[4], l_i[4];
    f32x4 o_acc[4] = {};
    #pragma unroll
    for (int i = 0; i < 4; i++) { m_i[i] = -1e30f; l_i[i] = 0.f; }
    int c0 = t, c1 = t + 256;
    int r0 = c0 >> 3, g0 = c0 & 7;
    int r1 = c1 >> 3, g1 = c1 & 7;
    int kd0 = r0 * 64 + ((g0 * 8) ^ ((r0 & 7) << 3));
    int kd1 = r1 * 64 + ((g1 * 8) ^ ((r1 & 7) << 3));
    long kb = (long)(b * 1024) * 1536 + 512 + h * 64;
    long vb = kb + 512;
    long lo0 = (long)r0 * 1536 + g0 * 8, lo1 = (long)r1 * 1536 + g1 * 8;
    short* ph = PHs[w]; short* pl = PLs[w];
    bf16x8 kh0 = *(const bf16x8*)(QH + kb + lo0);
    bf16x8 kh1 = *(const bf16x8*)(QH + kb + lo1);
    bf16x8 kl0 = *(const bf16x8*)(QL + kb + lo0);
    bf16x8 kl1 = *(const bf16x8*)(QL + kb + lo1);
    bf16x8 vh0 = *(const bf16x8*)(QH + vb + lo0);
    bf16x8 vh1 = *(const bf16x8*)(QH + vb + lo1);
    bf16x8 vl0 = *(const bf16x8*)(QL + vb + lo0);
    bf16x8 vl1 = *(const bf16x8*)(QL + vb + lo1);
    int bufo = 0;
    for (int kt = 0; kt < 16; kt++) {
        *(bf16x8*)&KsH[bufo + kd0] = kh0;  *(bf16x8*)&KsH[bufo + kd1] = kh1;
        *(bf16x8*)&KsL[bufo + kd0] = kl0;  *(bf16x8*)&KsL[bufo + kd1] = kl1;
        #pragma unroll
        for (int j = 0; j < 8; j++) {
            int d0 = g0 * 8 + j;
            int i0 = bufo + d0 * 64 + (r0 ^ (((d0 >> 3) & 7) << 3));
            VtH[i0] = ((short*)&vh0)[j];  VtL[i0] = ((short*)&vl0)[j];
            int d1 = g1 * 8 + j;
            int i1 = bufo + d1 * 64 + (r1 ^ (((d1 >> 3) & 7) << 3));
            VtH[i1] = ((short*)&vh1)[j];  VtL[i1] = ((short*)&vl1)[j];
        }
        __syncthreads();
        int ktn = (kt + 1 < 16) ? kt + 1 : kt;
        long ko = kb + (long)(ktn * 64) * 1536;
        long vo = vb + (long)(ktn * 64) * 1536;
        bf16x8 nkh0 = *(const bf16x8*)(QH + ko + lo0);
        bf16x8 nkh1 = *(const bf16x8*)(QH + ko + lo1);
        bf16x8 nkl0 = *(const bf16x8*)(QL + ko + lo0);
        bf16x8 nkl1 = *(const bf16x8*)(QL + ko + lo1);
        bf16x8 nvh0 = *(const bf16x8*)(QH + vo + lo0);
        bf16x8 nvh1 = *(const bf16x8*)(QH + vo + lo1);
        bf16x8 nvl0 = *(const bf16x8*)(QL + vo + lo0);
        bf16x8 nvl1 = *(const bf16x8*)(QL + vo + lo1);
        __builtin_amdgcn_s_setprio(1);
        f32x4 s[4] = {};
        #pragma unroll
        for (int cf = 0; cf < 4; cf++) {
            int kvrow = cf * 16 + fr;
            #pragma unroll
            for (int kf = 0; kf < 2; kf++) {
                int idx = bufo + kvrow * 64 + ((kf * 32 + fq * 8) ^ ((kvrow & 7) << 3));
                bf16x8 Bh2 = *(const bf16x8*)&KsH[idx];
                bf16x8 Bl2 = *(const bf16x8*)&KsL[idx];
                s[cf] = __builtin_amdgcn_mfma_f32_16x16x32_bf16(Qh2[kf], Bh2, s[cf], 0, 0, 0);
                s[cf] = __builtin_amdgcn_mfma_f32_16x16x32_bf16(Qh2[kf], Bl2, s[cf], 0, 0, 0);
                s[cf] = __builtin_amdgcn_mfma_f32_16x16x32_bf16(Ql2[kf], Bh2, s[cf], 0, 0, 0);
            }
        }
        __builtin_amdgcn_s_setprio(0);
        #pragma unroll
        for (int cf = 0; cf < 4; cf++)
        #pragma unroll
        for (int reg = 0; reg < 4; reg++) s[cf][reg] *= 0.125f;
        float sc_[4];
        #pragma unroll
        for (int reg = 0; reg < 4; reg++) {
            float mx = fmaxf(fmaxf(s[0][reg], s[1][reg]), fmaxf(s[2][reg], s[3][reg]));
            mx = fmaxf(mx, __shfl_xor(mx, 1));
            mx = fmaxf(mx, __shfl_xor(mx, 2));
            mx = fmaxf(mx, __shfl_xor(mx, 4));
            mx = fmaxf(mx, __shfl_xor(mx, 8));
            float mn = fmaxf(m_i[reg], mx);
            sc_[reg] = __expf(m_i[reg] - mn);
            m_i[reg] = mn;
            float rs = 0.f;
            #pragma unroll
            for (int cf = 0; cf < 4; cf++) { s[cf][reg] = __expf(s[cf][reg] - mn); rs += s[cf][reg]; }
            rs += __shfl_xor(rs, 1);
            rs += __shfl_xor(rs, 2);
            rs += __shfl_xor(rs, 4);
            rs += __shfl_xor(rs, 8);
            l_i[reg] = l_i[reg] * sc_[reg] + rs;
        }
        #pragma unroll
        for (int cf = 0; cf < 4; cf++)
        #pragma unroll
        for (int reg = 0; reg < 4; reg++) o_acc[cf][reg] *= sc_[reg];
        #pragma unroll
        for (int cf = 0; cf < 4; cf++)
        #pragma unroll
        for (int reg = 0; reg < 4; reg++) {
            int q = fq * 4 + reg, kv = cf * 16 + fr;
            int idx = q * 64 + (kv ^ ((q & 7) << 3));
            split2s(s[cf][reg], ph[idx], pl[idx]);
        }
        asm volatile("s_waitcnt lgkmcnt(0)" ::: "memory");
        __builtin_amdgcn_sched_barrier(0);
        __builtin_amdgcn_s_setprio(1);
        bf16x8 Pf_h[2], Pf_l[2];
        #pragma unroll
        for (int kf = 0; kf < 2; kf++) {
            int idx = fr * 64 + ((kf * 32 + fq * 8) ^ ((fr & 7) << 3));
            Pf_h[kf] = *(const bf16x8*)&ph[idx];
            Pf_l[kf] = *(const bf16x8*)&pl[idx];
        }
        #pragma unroll
        for (int cf = 0; cf < 4; cf++) {
            int d = cf * 16 + fr;
            #pragma unroll
            for (int kf = 0; kf < 2; kf++) {
                int idx = bufo + d * 64 + ((kf * 32 + fq * 8) ^ (((d >> 3) & 7) << 3));
                bf16x8 Vh2 = *(const bf16x8*)&VtH[idx];
                bf16x8 Vl2 = *(const bf16x8*)&VtL[idx];
                o_acc[cf] = __builtin_amdgcn_mfma_f32_16x16x32_bf16(Pf_h[kf], Vh2, o_acc[cf], 0, 0, 0);
                o_acc[cf] = __builtin_amdgcn_mfma_f32_16x16x32_bf16(Pf_h[kf], Vl2, o_acc[cf], 0, 0, 0);
                o_acc[cf] = __builtin_amdgcn_mfma_f32_16x16x32_bf16(Pf_l[kf], Vh2, o_acc[cf], 0, 0, 0);
            }
        }
        __builtin_amdgcn_s_setprio(0);
        kh0 = nkh0; kh1 = nkh1; kl0 = nkl0; kl1 = nkl1;
        vh0 = nvh0; vh1 = nvh1; vl0 = nvl0; vl1 = nvl1;
        bufo ^= 4096;
    }
    #pragma unroll
    for (int reg = 0; reg < 4; reg++) {
        float inv = 1.f / l_i[reg];
        long m = (long)(b * 1024 + qt * 64 + w * 16 + fq * 4 + reg);
        #pragma unroll
        for (int cf = 0; cf < 4; cf++) {
            float v = o_acc[cf][reg] * inv;
            bf16 hh, ll; split2(v, hh, ll);
            long off = m * DIMC + h * 64 + cf * 16 + fr;
            oh[off] = hh; ol[off] = ll;
        }
    }
}

// ---- split-precision MFMA cross-attention: 77 keys padded to 96, single tile ----
__global__ __launch_bounds__(256) void ca_mfma_kernel(
    const bf16* __restrict__ qh, const bf16* __restrict__ ql,
    const bf16* __restrict__ kvh, const bf16* __restrict__ kvl,
    bf16* __restrict__ oh, bf16* __restrict__ ol) {
    int qt = blockIdx.x, h = blockIdx.y, b = blockIdx.z;
    __shared__ short UH[8192], UL[8192];
    __shared__ short PHs[4][2048], PLs[4][2048];
    int t = threadIdx.x, lane = t & 63, w = t >> 6;
    int fr = lane & 15, fq = lane >> 4;
    const short* QH = (const short*)qh;
    const short* QL = (const short*)ql;
    const short* KVH = (const short*)kvh;
    const short* KVL = (const short*)kvl;
    long qrow = (long)(b * 1024 + qt * 64 + w * 16 + fr) * DIMC + h * 64;
    bf16x8 Qh2[2], Ql2[2];
    Qh2[0] = *(const bf16x8*)(QH + qrow + fq * 8);
    Qh2[1] = *(const bf16x8*)(QH + qrow + 32 + fq * 8);
    Ql2[0] = *(const bf16x8*)(QL + qrow + fq * 8);
    Ql2[1] = *(const bf16x8*)(QL + qrow + 32 + fq * 8);
    for (int c = t; c < 768; c += 256) {
        int r = c >> 3, g = c & 7;
        int idx = r * 64 + ((g * 8) ^ ((r & 7) << 3));
        bf16x8 vh = {}, vl = {};
        if (r < 77) {
            long src = (long)(b * 77 + r) * 1024 + h * 64 + g * 8;
            vh = *(const bf16x8*)(KVH + src);
            vl = *(const bf16x8*)(KVL + src);
        }
        *(bf16x8*)&UH[idx] = vh;
        *(bf16x8*)&UL[idx] = vl;
    }
    __syncthreads();
    f32x4 s[5] = {};
    #pragma unroll
    for (int cf = 0; cf < 5; cf++) {
        int kvrow = cf * 16 + fr;
        #pragma unroll
        for (int kf = 0; kf < 2; kf++) {
            int idx = kvrow * 64 + ((kf * 32 + fq * 8) ^ ((kvrow & 7) << 3));
            bf16x8 Bh2 = *(const bf16x8*)&UH[idx];
            bf16x8 Bl2 = *(const bf16x8*)&UL[idx];
            s[cf] = __builtin_amdgcn_mfma_f32_16x16x32_bf16(Qh2[kf], Bh2, s[cf], 0, 0, 0);
            s[cf] = __builtin_amdgcn_mfma_f32_16x16x32_bf16(Qh2[kf], Bl2, s[cf], 0, 0, 0);
            s[cf] = __builtin_amdgcn_mfma_f32_16x16x32_bf16(Ql2[kf], Bh2, s[cf], 0, 0, 0);
        }
    }
    #pragma unroll
    for (int cf = 0; cf < 5; cf++) {
        int kv = cf * 16 + fr;
        #pragma unroll
        for (int reg = 0; reg < 4; reg++)
            s[cf][reg] = (kv < 77) ? s[cf][reg] * 0.125f : -1e30f;
    }
    float inv[4];
    #pragma unroll
    for (int reg = 0; reg < 4; reg++) {
        float mx = s[0][reg];
        #pragma unroll
        for (int cf = 1; cf < 5; cf++) mx = fmaxf(mx, s[cf][reg]);
        mx = fmaxf(mx, __shfl_xor(mx, 1));
        mx = fmaxf(mx, __shfl_xor(mx, 2));
        mx = fmaxf(mx, __shfl_xor(mx, 4));
        mx = fmaxf(mx, __shfl_xor(mx, 8));
        float rs = 0.f;
        #pragma unroll
        for (int cf = 0; cf < 5; cf++) { s[cf][reg] = __expf(s[cf][reg] - mx); rs += s[cf][reg]; }
        rs += __shfl_xor(rs, 1);
        rs += __shfl_xor(rs, 2);
        rs += __shfl_xor(rs, 4);
        rs += __shfl_xor(rs, 8);
        inv[reg] = 1.f / rs;
    }
    short* ph = PHs[w]; short* pl = PLs[w];
    #pragma unroll
    for (int cf = 0; cf < 6; cf++)
    #pragma unroll
    for (int reg = 0; reg < 4; reg++) {
        int q = fq * 4 + reg, kv = cf * 16 + fr;
        int idx = q * 128 + (kv ^ ((q & 7) << 3));
        float pv = (cf < 5) ? s[cf][reg] * inv[reg] : 0.f;
        split2s(pv, ph[idx], pl[idx]);
    }
    __syncthreads();
    for (int c = t; c < 768; c += 256) {
        int r = c >> 3, g = c & 7;
        bf16x8 vh = {}, vl = {};
        if (r < 77) {
            long src = (long)(b * 77 + r) * 1024 + 512 + h * 64 + g * 8;
            vh = *(const bf16x8*)(KVH + src);
            vl = *(const bf16x8*)(KVL + src);
        }
        #pragma unroll
        for (int j = 0; j < 8; j++) {
            int d = g * 8 + j;
            int idx = d * 128 + (r ^ (((d >> 3) & 7) << 3));
            UH[idx] = ((short*)&vh)[j];
            UL[idx] = ((short*)&vl)[j];
        }
    }
    __syncthreads();
    f32x4 o_acc[4] = {};
    bf16x8 Pf_h[3], Pf_l[3];
    #pragma unroll
    for (int kf = 0; kf < 3; kf++) {
        int idx = fr * 128 + ((kf * 32 + fq * 8) ^ ((fr & 7) << 3));
        Pf_h[kf] = *(const bf16x8*)&ph[idx];
        Pf_l[kf] = *(const bf16x8*)&pl[idx];
    }
    #pragma unroll
    for (int cf = 0; cf < 4; cf++) {
        int d = cf * 16 + fr;
        #pragma unroll
        for (int kf = 0; kf < 3; kf++) {
            int idx = d * 128 + ((kf * 32 + fq * 8) ^ (((d >> 3) & 7) << 3));
            bf16x8 Vh2 = *(const bf16x8*)&UH[idx];
            bf16x8 Vl2 = *(const bf16x8*)&UL[idx];
            o_acc[cf] = __builtin_amdgcn_mfma_f32_16x16x32_bf16(Pf_h[kf], Vh2, o_acc[cf], 0, 0, 0);
            o_acc[cf] = __builtin_amdgcn_mfma_f32_16x16x32_bf16(Pf_h[kf], Vl2, o_acc[cf], 0, 0, 0);
            o_acc[cf] = __builtin_amdgcn_mfma_f32_16x16x32_bf16(Pf_l[kf], Vh2, o_acc[cf], 0, 0, 0);
        }
    }
    #pragma unroll
    for (int reg = 0; reg < 4; reg++) {
        long m = (long)(b * 1024 + qt * 64 + w * 16 + fq * 4 + reg);
        #pragma unroll
        for (int cf = 0; cf < 4; cf++) {
            bf16 hh, ll; split2(o_acc[cf][reg], hh, ll);
            long off = m * DIMC + h * 64 + cf * 16 + fr;
            oh[off] = hh; ol[off] = ll;
        }
    }
}

// ---- MoE grouped MFMA GEMM1 (dbuf + post-barrier prefetch) ----
__global__ __launch_bounds__(256) void moe_mfma1_kernel(
    const bf16* __restrict__ xn_b, const bf16* __restrict__ e1T, const float* __restrict__ e_b1,
    const int* __restrict__ table, const int* __restrict__ ntiles, const int* __restrict__ perm,
    bf16* __restrict__ hid_b) {
    if (blockIdx.y >= ntiles[0]) return;
    int e = table[2 * blockIdx.y], row0 = table[2 * blockIdx.y + 1];
    int bn = blockIdx.x * 128;
    __shared__ short As[2 * 4096];
    __shared__ short Bs[2 * 4096];
    __shared__ int rowsS[128];
    int t = threadIdx.x, lane = t & 63, w = t >> 6;
    if (t < 128) rowsS[t] = perm[row0 + t];
    __syncthreads();
    int wm = (w >> 1) * 64, wn = (w & 1) * 64;
    int p0 = t, p1 = t + 256;
    int r0 = p0 >> 2, k0s = (p0 & 3) ^ ((r0 >> 1) & 3);
    int r1 = p1 >> 2, k1s = (p1 & 3) ^ ((r1 >> 1) & 3);
    int tok0 = rowsS[r0]; if (tok0 < 0) tok0 = 0;
    int tok1 = rowsS[r1]; if (tok1 < 0) tok1 = 0;
    const short* Xs = (const short*)xn_b;
    const short* Ws = (const short*)(e1T + (long)e * HIDC * DIMC);
    const short* a0 = Xs + (long)tok0 * DIMC + k0s * 8;
    const short* a1 = Xs + (long)tok1 * DIMC + k1s * 8;
    const short* b0 = Ws + (long)(bn + r0) * DIMC + k0s * 8;
    const short* b1 = Ws + (long)(bn + r1) * DIMC + k1s * 8;
    int fr = lane & 15, fq = lane >> 4;
    int aOff[4], bOff[4];
    #pragma unroll
    for (int i = 0; i < 4; i++) {
        int row = wm + i * 16 + fr;
        aOff[i] = row * 32 + ((fq ^ ((row >> 1) & 3)) * 8);
        int col = wn + i * 16 + fr;
        bOff[i] = col * 32 + ((fq ^ ((col >> 1) & 3)) * 8);
    }
    f32x4 acc[4][4] = {};
    bf16x8 va0 = *(const bf16x8*)(a0);
    bf16x8 va1 = *(const bf16x8*)(a1);
    bf16x8 vb0 = *(const bf16x8*)(b0);
    bf16x8 vb1 = *(const bf16x8*)(b1);
    int bufo = 0;
    for (int kk = 0; kk < DIMC; kk += 32) {
        *(bf16x8*)&As[bufo + p0 * 8] = va0;  *(bf16x8*)&As[bufo + p1 * 8] = va1;
        *(bf16x8*)&Bs[bufo + p0 * 8] = vb0;  *(bf16x8*)&Bs[bufo + p1 * 8] = vb1;
        __syncthreads();
        int kn = (kk + 32 < DIMC) ? kk + 32 : kk;
        bf16x8 na0 = *(const bf16x8*)(a0 + kn);
        bf16x8 na1 = *(const bf16x8*)(a1 + kn);
        bf16x8 nb0 = *(const bf16x8*)(b0 + kn);
        bf16x8 nb1 = *(const bf16x8*)(b1 + kn);
        bf16x8 aF[4], bF[4];
        #pragma unroll
        for (int i = 0; i < 4; i++) {
            aF[i] = *(const bf16x8*)&As[bufo + aOff[i]];
            bF[i] = *(const bf16x8*)&Bs[bufo + bOff[i]];
        }
        #pragma unroll
        for (int i = 0; i < 4; i++)
        #pragma unroll
        for (int j = 0; j < 4; j++)
            acc[i][j] = __builtin_amdgcn_mfma_f32_16x16x32_bf16(aF[i], bF[j], acc[i][j], 0, 0, 0);
        va0 = na0; va1 = na1; vb0 = nb0; vb1 = nb1;
        bufo ^= 4096;
    }
    const float* bb = e_b1 + (long)e * HIDC;
    #pragma unroll
    for (int i = 0; i < 4; i++)
    #pragma unroll
    for (int r = 0; r < 4; r++) {
        int tok = rowsS[wm + i * 16 + fq * 4 + r];
        if (tok < 0) continue;
        #pragma unroll
        for (int j = 0; j < 4; j++) {
            int col = bn + wn + j * 16 + fr;
            float v = acc[i][j][r] + bb[col];
            v = 0.5f * v * (1.f + erff(v * 0.70710678f));
            hid_b[(long)tok * HIDC + col] = __float2bfloat16(v);
        }
    }
}

// ---- MoE grouped MFMA GEMM2 (dbuf + post-barrier prefetch) ----
__global__ __launch_bounds__(256) void moe_mfma2_kernel(
    const bf16* __restrict__ hid_b, const bf16* __restrict__ e2T, const float* __restrict__ e_b2,
    const int* __restrict__ table, const int* __restrict__ ntiles, const int* __restrict__ perm,
    float* __restrict__ x_flat) {
    if (blockIdx.y >= ntiles[0]) return;
    int e = table[2 * blockIdx.y], row0 = table[2 * blockIdx.y + 1];
    int bn = blockIdx.x * 128;
    __shared__ short As[2 * 4096];
    __shared__ short Bs[2 * 4096];
    __shared__ int rowsS[128];
    int t = threadIdx.x, lane = t & 63, w = t >> 6;
    if (t < 128) rowsS[t] = perm[row0 + t];
    __syncthreads();
    int wm = (w >> 1) * 64, wn = (w & 1) * 64;
    int p0 = t, p1 = t + 256;
    int r0 = p0 >> 2, k0s = (p0 & 3) ^ ((r0 >> 1) & 3);
    int r1 = p1 >> 2, k1s = (p1 & 3) ^ ((r1 >> 1) & 3);
    int tok0 = rowsS[r0]; if (tok0 < 0) tok0 = 0;
    int tok1 = rowsS[r1]; if (tok1 < 0) tok1 = 0;
    const short* Hs = (const short*)hid_b;
    const short* Ws = (const short*)(e2T + (long)e * DIMC * HIDC);
    const short* a0 = Hs + (long)tok0 * HIDC + k0s * 8;
    const short* a1 = Hs + (long)tok1 * HIDC + k1s * 8;
    const short* b0 = Ws + (long)(bn + r0) * HIDC + k0s * 8;
    const short* b1 = Ws + (long)(bn + r1) * HIDC + k1s * 8;
    int fr = lane & 15, fq = lane >> 4;
    int aOff[4], bOff[4];
    #pragma unroll
    for (int i = 0; i < 4; i++) {
        int row = wm + i * 16 + fr;
        aOff[i] = row * 32 + ((fq ^ ((row >> 1) & 3)) * 8);
        int col = wn + i * 16 + fr;
        bOff[i] = col * 32 + ((fq ^ ((col >> 1) & 3)) * 8);
    }
    f32x4 acc[4][4] = {};
    bf16x8 va0 = *(const bf16x8*)(a0);
    bf16x8 va1 = *(const bf16x8*)(a1);
    bf16x8 vb0 = *(const bf16x8*)(b0);
    bf16x8 vb1 = *(const bf16x8*)(b1);
    int bufo = 0;
    for (int kk = 0; kk < HIDC; kk += 32) {
        *(bf16x8*)&As[bufo + p0 * 8] = va0;  *(bf16x8*)&As[bufo + p1 * 8] = va1;
        *(bf16x8*)&Bs[bufo + p0 * 8] = vb0;  *(bf16x8*)&Bs[bufo + p1 * 8] = vb1;
        __syncthreads();
        int kn = (kk + 32 < HIDC) ? kk + 32 : kk;
        bf16x8 na0 = *(const bf16x8*)(a0 + kn);
        bf16x8 na1 = *(const bf16x8*)(a1 + kn);
        bf16x8 nb0 = *(const bf16x8*)(b0 + kn);
        bf16x8 nb1 = *(const bf16x8*)(b1 + kn);
        bf16x8 aF[4], bF[4];
        #pragma unroll
        for (int i = 0; i < 4; i++) {
            aF[i] = *(const bf16x8*)&As[bufo + aOff[i]];
            bF[i] = *(const bf16x8*)&Bs[bufo + bOff[i]];
        }
        #pragma unroll
        for (int i = 0; i < 4; i++)
        #pragma unroll
        for (int j = 0; j < 4; j++)
            acc[i][j] = __builtin_amdgcn_mfma_f32_16x16x32_bf16(aF[i], bF[j], acc[i][j], 0, 0, 0);
        va0 = na0; va1 = na1; vb0 = nb0; vb1 = nb1;
        bufo ^= 4096;
    }
    const float* bb = e_b2 + (long)e * DIMC;
    #pragma unroll
    for (int i = 0; i < 4; i++)
    #pragma unroll
    for (int r = 0; r < 4; r++) {
        int tok = rowsS[wm + i * 16 + fq * 4 + r];
        if (tok < 0) continue;
        #pragma unroll
        for (int j = 0; j < 4; j++) {
            int col = bn + wn + j * 16 + fr;
            x_flat[(long)tok * DIMC + col] += acc[i][j][r] + bb[col];
        }
    }
}

// ---------------- LayerNorm: optional fp32 + bf16 hi/lo outputs ----------------
__global__ void ln_kernel(const float* __restrict__ x, const float* __restrict__ g,
                          const float* __restrict__ b, float* __restrict__ y,
                          bf16* __restrict__ yh, bf16* __restrict__ yl) {
    int tok = blockIdx.x;
    int t = threadIdx.x;
    const float* xr = x + (long)tok * DIMC;
    float v0 = xr[t], v1 = xr[t + 256];
    __shared__ float red[256];
    red[t] = v0 + v1; __syncthreads();
    for (int s = 128; s > 0; s >>= 1) { if (t < s) red[t] += red[t + s]; __syncthreads(); }
    float mu = red[0] * (1.f / DIMC);
    __syncthreads();
    float d0 = v0 - mu, d1 = v1 - mu;
    red[t] = d0 * d0 + d1 * d1; __syncthreads();
    for (int s = 128; s > 0; s >>= 1) { if (t < s) red[t] += red[t + s]; __syncthreads(); }
    float rs = rsqrtf(red[0] * (1.f / DIMC) + 1e-5f);
    float o0 = d0 * rs * g[t] + b[t];
    float o1 = d1 * rs * g[t + 256] + b[t + 256];
    if (y) { y[(long)tok * DIMC + t] = o0; y[(long)tok * DIMC + t + 256] = o1; }
    bf16 h, l;
    split2(o0, h, l); yh[(long)tok * DIMC + t] = h;       yl[(long)tok * DIMC + t] = l;
    split2(o1, h, l); yh[(long)tok * DIMC + t + 256] = h; yl[(long)tok * DIMC + t + 256] = l;
}

// ---------------- router text part ----------------
__global__ void textpart_kernel(const float* __restrict__ w, const float* __restrict__ r_text_mu,
                                const float* __restrict__ r_comb_mu, float* __restrict__ tp) {
    __shared__ float tw[4][128];
    int t = threadIdx.x;
    for (int j = 0; j < 2; j++) {
        int idx = t + j * 256; int b = idx >> 7, c = idx & 127;
        const float* wr = w + (long)b * LATC;
        float s = 0.f;
        for (int k = 0; k < LATC; k++) s += wr[k] * r_text_mu[(long)k * 128 + c];
        tw[b][c] = s;
    }
    __syncthreads();
    if (t < 32) {
        int b = t >> 3, e = t & 7;
        float s = 0.f;
        for (int c = 0; c < 128; c++) s += tw[b][c] * r_comb_mu[(long)(128 + c) * 8 + e];
        tp[t] = s;
    }
}

// ---------------- MoE meta ----------------
__global__ void moe_init_kernel(int* __restrict__ cnt, int* __restrict__ perm) {
    int g = blockIdx.x * blockDim.x + threadIdx.x;
    if (g < MAXT * 128) perm[g] = -1;
    if (g < NE) cnt[g] = 0;
}

__global__ void route_kernel(const float* __restrict__ feat, const float* __restrict__ tp,
                             const float* __restrict__ r_comb_mu, const float* __restrict__ r_temp,
                             float* __restrict__ onehot, int* __restrict__ idx, int* __restrict__ cnt) {
    int n = blockIdx.x * blockDim.x + threadIdx.x;
    if (n >= NTOK) return;
    int b = n >> 10;
    float tmp = fmaxf(r_temp[0], 0.1f);
    float invt = 1.f / tmp;
    const float* fr = feat + (long)n * 128;
    float lg[8];
    for (int e = 0; e < 8; e++) {
        float s = 0.f;
        for (int c = 0; c < 128; c++) s += fr[c] * r_comb_mu[(long)c * 8 + e];
        lg[e] = (s + tp[b * 8 + e]) * invt;
    }
    float best = lg[0]; int bi = 0;
    for (int e = 1; e < 8; e++) { if (lg[e] > best) { best = lg[e]; bi = e; } }
    for (int e = 0; e < 8; e++) onehot[(long)n * 8 + e] = (e == bi) ? 1.f : 0.f;
    idx[n] = bi;
    atomicAdd(&cnt[bi], 1);
}

__global__ void offsets_kernel(const int* __restrict__ cnt, int* __restrict__ cursor,
                               int* __restrict__ ntiles, int* __restrict__ table) {
    if (threadIdx.x != 0) return;
    int po = 0, nt = 0;
    for (int e = 0; e < NE; e++) {
        cursor[e] = po;
        int tiles = (cnt[e] + 127) >> 7;
        for (int j = 0; j < tiles; j++) { table[2 * nt] = e; table[2 * nt + 1] = po + j * 128; nt++; }
        po += tiles * 128;
    }
    ntiles[0] = nt;
}

__global__ void scatter_kernel(const int* __restrict__ idx, int* __restrict__ cursor,
                               int* __restrict__ perm) {
    int n = blockIdx.x * blockDim.x + threadIdx.x;
    if (n >= NTOK) return;
    int e = idx[n];
    int pos = atomicAdd(&cursor[e], 1);
    perm[pos] = n;
}

extern "C" void kernel_launch(void* const* d_in, const int* in_sizes, int n_in,
                              void* d_out, int out_size, void* d_ws, size_t ws_size,
                              hipStream_t stream) {
    const float* x        = (const float*)d_in[0];
    const float* w        = (const float*)d_in[1];
    const float* text     = (const float*)d_in[2];
    const float* pin_w    = (const float*)d_in[3];
    const float* pin_mw   = (const float*)d_in[4];
    const float* pin_mb   = (const float*)d_in[5];
    const float* pout_w   = (const float*)d_in[6];
    const float* pout_mw  = (const float*)d_in[7];
    const float* pout_mb  = (const float*)d_in[8];
    const float* ln1g     = (const float*)d_in[9];
    const float* ln1b     = (const float*)d_in[10];
    const float* ln2g     = (const float*)d_in[11];
    const float* ln2b     = (const float*)d_in[12];
    const float* ln3g     = (const float*)d_in[13];
    const float* ln3b     = (const float*)d_in[14];
    const float* sa_in_w  = (const float*)d_in[15];
    const float* sa_in_b  = (const float*)d_in[16];
    const float* sa_out_w = (const float*)d_in[17];
    const float* sa_out_b = (const float*)d_in[18];
    const float* ca_in_w  = (const float*)d_in[19];
    const float* ca_in_b  = (const float*)d_in[20];
    const float* ca_out_w = (const float*)d_in[21];
    const float* ca_out_b = (const float*)d_in[22];
    const float* r_feat   = (const float*)d_in[23];
    const float* r_text   = (const float*)d_in[24];
    const float* r_comb   = (const float*)d_in[25];
    const float* r_temp   = (const float*)d_in[26];
    const float* e_w1     = (const float*)d_in[27];
    const float* e_b1     = (const float*)d_in[28];
    const float* e_w2     = (const float*)d_in[29];
    const float* e_b2     = (const float*)d_in[30];

    float* out    = (float*)d_out;               // [B, DIM, H, W]
    float* onehot = out + (long)BB * DIMC * HWX; // [4096, 8]

    // ---------------- workspace: fp32 pool ----------------
    float* f32p = (float*)d_ws;
    float* style_in  = f32p;                 // 2048
    float* style_out = f32p + 2048;          // 2048
    float* tp        = f32p + 4096;          // 32
    int*   idx       = (int*)(f32p + 4128);  // 4096
    int*   cnt       = (int*)(f32p + 8224);  // 8
    int*   cursor    = (int*)(f32p + 8232);  // 8
    int*   ntiles    = (int*)(f32p + 8240);  // 8
    int*   table     = (int*)(f32p + 8248);  // 128
    int*   perm      = (int*)(f32p + 8376);  // 5120 -> ends 13496
    float* x_flat    = f32p + 13496;         // 2097152
    float* xn        = x_flat + 2097152;     // 2097152 (dead fp32; kept for layout stability)
    float* qkv       = xn + 2097152;         // 6291456 (SA q split / CA q split home)
    float* spill     = qkv + 6291456;        // 2097152 (e2T tail)

    // ---------------- bf16 pool (phase-aliased) ----------------
    bf16* bp = (bf16*)(f32p + 12596408);
    bf16* R1 = bp;                           // 6291456 elems, 3 phases
    bf16* xT_h  = R1;
    bf16* xT_l  = R1 + 2097152;
    bf16* wtA_h = R1 + 4194304;
    bf16* wtA_l = R1 + 5242880;
    bf16* obuf_h = R1;
    bf16* obuf_l = R1 + 2097152;
    bf16* kvt_h  = R1 + 4194304;                       // [308][1024] split
    bf16* kvt_l  = kvt_h + 315392;
    float* feat  = (float*)(kvt_l + 315392);           // 524288 fp32
    bf16* wtC_h = R1;
    bf16* wtC_l = R1 + 1048576;
    bf16* xn_h = R1 + 6291456;               // 2097152
    bf16* xn_l = xn_h + 2097152;             // 2097152
    bf16* WB   = xn_l + 2097152;             // 8388608: weights (early) / hid_b (late)
    bf16* text_h   = WB;
    bf16* text_l   = text_h + 157696;
    bf16* sawin_h  = text_l + 157696;
    bf16* sawin_l  = sawin_h + 786432;
    bf16* sawout_h = sawin_l + 786432;
    bf16* sawout_l = sawout_h + 262144;
    bf16* caw_h    = sawout_l + 262144;
    bf16* caw_l    = caw_h + 786432;
    bf16* cawout_h = caw_l + 786432;
    bf16* cawout_l = cawout_h + 262144;
    bf16* rfT_h    = cawout_l + 262144;      // [128][512] split r_feat^T
    bf16* rfT_l    = rfT_h + 65536;
    bf16* hid_b    = WB;                     // overlays weights after ca_out
    bf16* e1T = (bf16*)qkv;                  // [8][2048][512] in qkv+spill
    bf16* e2T = e1T + 8388608;
    bf16* xfl_h = xn_h;
    bf16* xfl_l = xn_l;
    bf16* q_h = (bf16*)qkv;                  // [4096][1536]
    bf16* q_l = q_h + 6291456;
    bf16* ca_qh = (bf16*)qkv;                // [4096][512]
    bf16* ca_ql = ca_qh + 2097152;
    (void)ws_size; (void)spill; (void)xn;

    auto mg = [&](const bf16* Ah, const bf16* Al, const bf16* Bh, const bf16* Bl,
                  const float* bias, const float* resid, float* C, bf16* Oh, bf16* Ol,
                  int M, int N, int K, long ab, long bb, long cb, int csm, int csn, int nb) {
        dim3 g(N / 64, (M + 63) / 64, nb);
        hipLaunchKernelGGL(mgemm64_kernel, g, dim3(256), 0, stream,
                           Ah, Al, Bh, Bl, bias, resid, C, Oh, Ol, M, N, K, ab, bb, cb, csm, csn);
    };
    auto cvt2 = [&](const float* in, bf16* h2, bf16* l2, int n) {
        hipLaunchKernelGGL(cvt2_kernel, dim3((n / 4 + 255) / 256), dim3(256), 0, stream, in, h2, l2, n);
    };

    // ---- input conversions (hi/lo) ----
    cvt2(sa_in_w, sawin_h, sawin_l, 1536 * 512);
    cvt2(sa_out_w, sawout_h, sawout_l, 512 * 512);
    cvt2(ca_in_w, caw_h, caw_l, 1536 * 512);
    cvt2(ca_out_w, cawout_h, cawout_l, 512 * 512);
    cvt2(text, text_h, text_l, BB * TXT * 512);
    hipLaunchKernelGGL(trcvt2_kernel, dim3(32, 16, BB), dim3(256), 0, stream,
                       x, xT_h, xT_l, 512, 1024, (long)512 * 1024, (long)1024 * 512);
    hipLaunchKernelGGL(trcvt2_kernel, dim3(4, 16, 1), dim3(256), 0, stream,
                       r_feat, rfT_h, rfT_l, 512, 128, 0L, 0L);

    // ---- modconv in ----
    hipLaunchKernelGGL(style_kernel, dim3(8), dim3(256), 0, stream, w, pin_mw, pin_mb, style_in);
    hipLaunchKernelGGL(wtmod_kernel, dim3(BB * DIMC), dim3(256), 0, stream, pin_w, style_in, wtA_h, wtA_l);
    mg(xT_h, xT_l, wtA_h, wtA_l, nullptr, nullptr, x_flat, nullptr, nullptr,
       HWX, DIMC, DIMC, (long)HWX * DIMC, (long)DIMC * DIMC, (long)HWX * DIMC, DIMC, 1, BB);

    // ---- LN1 + self-attention (split MFMA) ----
    hipLaunchKernelGGL(ln_kernel, dim3(NTOK), dim3(256), 0, stream, x_flat, ln1g, ln1b,
                       (float*)nullptr, xn_h, xn_l);
    mg(xn_h, xn_l, sawin_h, sawin_l, sa_in_b, nullptr, nullptr, q_h, q_l,
       NTOK, 1536, 512, 0, 0, 0, 1536, 1, 1);
    hipLaunchKernelGGL(sa_mfma_kernel, dim3(16, HEADS, BB), dim3(256), 0, stream,
                       q_h, q_l, obuf_h, obuf_l);
    mg(obuf_h, obuf_l, sawout_h, sawout_l, sa_out_b, x_flat, x_flat, nullptr, nullptr,
       NTOK, 512, 512, 0, 0, 0, 512, 1, 1);

    // ---- LN2 + cross-attention (split MFMA) ----
    hipLaunchKernelGGL(ln_kernel, dim3(NTOK), dim3(256), 0, stream, x_flat, ln2g, ln2b,
                       (float*)nullptr, xn_h, xn_l);
    mg(xn_h, xn_l, caw_h, caw_l, ca_in_b, nullptr, nullptr, ca_qh, ca_ql,
       NTOK, 512, 512, 0, 0, 0, 512, 1, 1);
    mg(text_h, text_l, caw_h + 512 * 512, caw_l + 512 * 512, ca_in_b + 512, nullptr, nullptr,
       kvt_h, kvt_l, BB * TXT, 1024, 512, 0, 0, 0, 1024, 1, 1);
    hipLaunchKernelGGL(ca_mfma_kernel, dim3(16, HEADS, BB), dim3(256), 0, stream,
                       ca_qh, ca_ql, kvt_h, kvt_l, obuf_h, obuf_l);
    hipLaunchKernelGGL(trcvt_kernel, dim3(64, 16, NE), dim3(256), 0, stream,
                       e_w1, e1T, 512, 2048, (long)512 * 2048, (long)2048 * 512);
    hipLaunchKernelGGL(trcvt_kernel, dim3(16, 64, NE), dim3(256), 0, stream,
                       e_w2, e2T, 2048, 512, (long)2048 * 512, (long)512 * 2048);
    mg(obuf_h, obuf_l, cawout_h, cawout_l, ca_out_b, x_flat, x_flat, nullptr, nullptr,
       NTOK, 512, 512, 0, 0, 0, 512, 1, 1);

    // ---- LN3 + router (feat via split MFMA) ----
    hipLaunchKernelGGL(ln_kernel, dim3(NTOK), dim3(256), 0, stream, x_flat, ln3g, ln3b,
                       (float*)nullptr, xn_h, xn_l);
    mg(xn_h, xn_l, rfT_h, rfT_l, nullptr, nullptr, feat, nullptr, nullptr,
       NTOK, 128, 512, 0, 0, 0, 128, 1, 1);
    hipLaunchKernelGGL(textpart_kernel, dim3(1), dim3(256), 0, stream, w, r_text, r_comb, tp);
    hipLaunchKernelGGL(moe_init_kernel, dim3((MAXT * 128 + 255) / 256), dim3(256), 0, stream, cnt, perm);
    hipLaunchKernelGGL(route_kernel, dim3(16), dim3(256), 0, stream, feat, tp, r_comb, r_temp, onehot, idx, cnt);
    hipLaunchKernelGGL(offsets_kernel, dim3(1), dim3(64), 0, stream, cnt, cursor, ntiles, table);
    hipLaunchKernelGGL(scatter_kernel, dim3(16), dim3(256), 0, stream, idx, cursor, perm);

    // ---- MoE grouped MFMA GEMMs ----
    hipLaunchKernelGGL(moe_mfma1_kernel, dim3(HIDC / 128, MAXT), dim3(256), 0, stream,
                       xn_h, e1T, e_b1, table, ntiles, perm, hid_b);
    hipLaunchKernelGGL(moe_mfma2_kernel, dim3(DIMC / 128, MAXT), dim3(256), 0, stream,
                       hid_b, e2T, e_b2, table, ntiles, perm, x_flat);

    // ---- modconv out (split both sides) ----
    cvt2(x_flat, xfl_h, xfl_l, NTOK * DIMC);
    hipLaunchKernelGGL(style_kernel, dim3(8), dim3(256), 0, stream, w, pout_mw, pout_mb, style_out);
    hipLaunchKernelGGL(wtmod_kernel, dim3(BB * DIMC), dim3(256), 0, stream, pout_w, style_out, wtC_h, wtC_l);
    mg(wtC_h, wtC_l, xfl_h, xfl_l, nullptr, nullptr, out, nullptr, nullptr,
       DIMC, HWX, DIMC, (long)DIMC * DIMC, (long)HWX * DIMC, (long)DIMC * HWX, HWX, 1, BB);
}

// Round 13
// 585.687 us; speedup vs baseline: 1.2297x; 1.0216x over previous
//
#include <hip/hip_runtime.h>
#include <hip/hip_bf16.h>
#include <math.h>

#define DIMC 512
#define HEADS 8
#define HD 64
#define BB 4
#define HWX 1024
#define TXT 77
#define LATC 512
#define NE 8
#define HIDC 2048
#define NTOK 4096
#define MAXT 72           // MoE tiles of 64: 4096/64 + 8

typedef __attribute__((ext_vector_type(8))) short bf16x8;
typedef __attribute__((ext_vector_type(4))) float f32x4;
typedef __hip_bfloat16 bf16;

__device__ __forceinline__ void split2(float v, bf16& h, bf16& l) {
    h = __float2bfloat16(v);
    l = __float2bfloat16(v - __bfloat162float(h));
}
__device__ __forceinline__ void split2s(float v, short& h, short& l) {
    bf16 hb, lb; split2(v, hb, lb);
    h = *(short*)&hb; l = *(short*)&lb;
}

// ---------------- style = w @ mod_w.T + mod_b ----------------
__global__ void style_kernel(const float* __restrict__ w, const float* __restrict__ mod_w,
                             const float* __restrict__ mod_b, float* __restrict__ style) {
    int t = blockIdx.x * blockDim.x + threadIdx.x;
    if (t >= BB * DIMC) return;
    int b = t / DIMC, i = t % DIMC;
    const float* wr = w + (long)b * LATC;
    const float* mr = mod_w + (long)i * LATC;
    float s = 0.f;
    #pragma unroll 8
    for (int l = 0; l < LATC; l++) s += wr[l] * mr[l];
    style[t] = s + mod_b[i];
}

// ------- wtmod[b,o,i] -> bf16 hi/lo (demodulated per-sample weight) -------
__global__ void wtmod_kernel(const float* __restrict__ weight, const float* __restrict__ style,
                             bf16* __restrict__ wh, bf16* __restrict__ wl) {
    int bo = blockIdx.x;
    int b = bo / DIMC, o = bo % DIMC;
    const float* wr = weight + (long)o * DIMC;
    const float* sr = style + (long)b * DIMC;
    int t = threadIdx.x;
    float vals[2]; float part = 0.f;
    for (int j = 0; j < 2; j++) {
        int i = t + j * 256;
        float v = wr[i] * sr[i];
        vals[j] = v; part += v * v;
    }
    __shared__ float red[256];
    red[t] = part; __syncthreads();
    for (int s = 128; s > 0; s >>= 1) { if (t < s) red[t] += red[t + s]; __syncthreads(); }
    float d = rsqrtf(red[0] + 1e-8f);
    for (int j = 0; j < 2; j++) {
        int i = t + j * 256;
        bf16 h, l; split2(vals[j] * d, h, l);
        wh[(long)bo * DIMC + i] = h; wl[(long)bo * DIMC + i] = l;
    }
}

// ---------------- fp32 -> bf16 hi/lo convert (flat) ----------------
__global__ void cvt2_kernel(const float* __restrict__ in, bf16* __restrict__ hi,
                            bf16* __restrict__ lo, int n) {
    int i = (blockIdx.x * blockDim.x + threadIdx.x) * 4;
    if (i >= n) return;
    float4 v = *(const float4*)(in + i);
    float a[4] = {v.x, v.y, v.z, v.w};
    #pragma unroll
    for (int j = 0; j < 4; j++) { bf16 h, l; split2(a[j], h, l); hi[i + j] = h; lo[i + j] = l; }
}

// ---------------- fp32 [R][C] -> bf16 [C][R] transpose hi/lo ----------------
__global__ void trcvt2_kernel(const float* __restrict__ in, bf16* __restrict__ hi,
                              bf16* __restrict__ lo, int R, int C, long in_bat, long out_bat) {
    __shared__ float tile[32][33];
    in += (long)blockIdx.z * in_bat; hi += (long)blockIdx.z * out_bat; lo += (long)blockIdx.z * out_bat;
    int c0 = blockIdx.x * 32, r0 = blockIdx.y * 32;
    int tc = threadIdx.x & 31, tr = threadIdx.x >> 5;
    #pragma unroll
    for (int i = 0; i < 4; i++) {
        int r = tr + i * 8;
        tile[r][tc] = in[(long)(r0 + r) * C + c0 + tc];
    }
    __syncthreads();
    #pragma unroll
    for (int i = 0; i < 4; i++) {
        int r = tr + i * 8;
        bf16 h, l; split2(tile[tc][r], h, l);
        hi[(long)(c0 + r) * R + r0 + tc] = h;
        lo[(long)(c0 + r) * R + r0 + tc] = l;
    }
}

// ---------------- fp32 [R][C] -> bf16 [C][R] transpose (single) ----------------
__global__ void trcvt_kernel(const float* __restrict__ in, bf16* __restrict__ out,
                             int R, int C, long in_bat, long out_bat) {
    __shared__ float tile[32][33];
    in += (long)blockIdx.z * in_bat; out += (long)blockIdx.z * out_bat;
    int c0 = blockIdx.x * 32, r0 = blockIdx.y * 32;
    int tc = threadIdx.x & 31, tr = threadIdx.x >> 5;
    #pragma unroll
    for (int i = 0; i < 4; i++) {
        int r = tr + i * 8;
        tile[r][tc] = in[(long)(r0 + r) * C + c0 + tc];
    }
    __syncthreads();
    #pragma unroll
    for (int i = 0; i < 4; i++) {
        int r = tr + i * 8;
        out[(long)(c0 + r) * R + r0 + tc] = __float2bfloat16(tile[tc][r]);
    }
}

// ---- split-precision bf16 MFMA GEMM, 64x64 tile (high machine fill) ----
__global__ __launch_bounds__(256) void mgemm64_kernel(
    const bf16* __restrict__ Ah, const bf16* __restrict__ Al,
    const bf16* __restrict__ Bh, const bf16* __restrict__ Bl,
    const float* __restrict__ bias, const float* __restrict__ resid, float* __restrict__ C,
    bf16* __restrict__ Oh, bf16* __restrict__ Ol,
    int M, int N, int K, long a_bat, long b_bat, long c_bat, int cs_m, int cs_n) {
    __shared__ short AsH[2 * 2048];
    __shared__ short AsL[2 * 2048];
    __shared__ short BsH[2 * 2048];
    __shared__ short BsL[2 * 2048];
    int bat = blockIdx.z;
    const short* AbH = (const short*)(Ah + (long)bat * a_bat);
    const short* AbL = (const short*)(Al + (long)bat * a_bat);
    const short* BbH = (const short*)(Bh + (long)bat * b_bat);
    const short* BbL = (const short*)(Bl + (long)bat * b_bat);
    float* Cb = C + (long)bat * c_bat;
    const float* Rb = resid ? resid + (long)bat * c_bat : nullptr;
    int bm = blockIdx.y * 64, bn = blockIdx.x * 64;
    int t = threadIdx.x, lane = t & 63, w = t >> 6;
    int wm = (w >> 1) * 32, wn = (w & 1) * 32;
    int r0 = t >> 2, k0s = (t & 3) ^ ((r0 >> 1) & 3);
    int ar0 = bm + r0; if (ar0 > M - 1) ar0 = M - 1;
    long aoff = (long)ar0 * K + k0s * 8;
    long boff = (long)(bn + r0) * K + k0s * 8;
    int fr = lane & 15, fq = lane >> 4;
    int aOff[2], bOff[2];
    #pragma unroll
    for (int i = 0; i < 2; i++) {
        int row = wm + i * 16 + fr;
        aOff[i] = row * 32 + ((fq ^ ((row >> 1) & 3)) * 8);
        int col = wn + i * 16 + fr;
        bOff[i] = col * 32 + ((fq ^ ((col >> 1) & 3)) * 8);
    }
    f32x4 acc[2][2] = {};
    bf16x8 vah = *(const bf16x8*)(AbH + aoff);
    bf16x8 val = *(const bf16x8*)(AbL + aoff);
    bf16x8 vbh = *(const bf16x8*)(BbH + boff);
    bf16x8 vbl = *(const bf16x8*)(BbL + boff);
    int bufo = 0;
    for (int kk = 0; kk < K; kk += 32) {
        *(bf16x8*)&AsH[bufo + t * 8] = vah;
        *(bf16x8*)&AsL[bufo + t * 8] = val;
        *(bf16x8*)&BsH[bufo + t * 8] = vbh;
        *(bf16x8*)&BsL[bufo + t * 8] = vbl;
        __syncthreads();
        int kn = (kk + 32 < K) ? kk + 32 : kk;
        bf16x8 nah = *(const bf16x8*)(AbH + aoff + kn);
        bf16x8 nal = *(const bf16x8*)(AbL + aoff + kn);
        bf16x8 nbh = *(const bf16x8*)(BbH + boff + kn);
        bf16x8 nbl = *(const bf16x8*)(BbL + boff + kn);
        bf16x8 aH[2], aL[2], bH[2], bL[2];
        #pragma unroll
        for (int i = 0; i < 2; i++) {
            aH[i] = *(const bf16x8*)&AsH[bufo + aOff[i]];
            aL[i] = *(const bf16x8*)&AsL[bufo + aOff[i]];
            bH[i] = *(const bf16x8*)&BsH[bufo + bOff[i]];
            bL[i] = *(const bf16x8*)&BsL[bufo + bOff[i]];
        }
        #pragma unroll
        for (int i = 0; i < 2; i++)
        #pragma unroll
        for (int j = 0; j < 2; j++) {
            acc[i][j] = __builtin_amdgcn_mfma_f32_16x16x32_bf16(aH[i], bH[j], acc[i][j], 0, 0, 0);
            acc[i][j] = __builtin_amdgcn_mfma_f32_16x16x32_bf16(aH[i], bL[j], acc[i][j], 0, 0, 0);
            acc[i][j] = __builtin_amdgcn_mfma_f32_16x16x32_bf16(aL[i], bH[j], acc[i][j], 0, 0, 0);
        }
        vah = nah; val = nal; vbh = nbh; vbl = nbl;
        bufo ^= 2048;
    }
    #pragma unroll
    for (int i = 0; i < 2; i++)
    #pragma unroll
    for (int j = 0; j < 2; j++)
    #pragma unroll
    for (int r = 0; r < 4; r++) {
        int row = bm + wm + i * 16 + fq * 4 + r;
        int col = bn + wn + j * 16 + fr;
        if (row < M) {
            long off = (long)row * cs_m + (long)col * cs_n;
            float v = acc[i][j][r];
            if (bias) v += bias[col];
            if (Oh) {
                bf16 hh, ll; split2(v, hh, ll);
                Oh[off] = hh; Ol[off] = ll;
            } else {
                if (Rb) v += Rb[off];
                Cb[off] = v;
            }
        }
    }
}

// ---- split-precision MFMA flash SA: dbuf + post-barrier prefetch + setprio ----
__global__ __launch_bounds__(256) void sa_mfma_kernel(
    const bf16* __restrict__ qh, const bf16* __restrict__ ql,
    bf16* __restrict__ oh, bf16* __restrict__ ol) {
    int qt = blockIdx.x, h = blockIdx.y, b = blockIdx.z;
    __shared__ short KsH[2 * 4096], KsL[2 * 4096];
    __shared__ short VtH[2 * 4096], VtL[2 * 4096];
    __shared__ short PHs[4][1024], PLs[4][1024];
    int t = threadIdx.x, lane = t & 63, w = t >> 6;
    int fr = lane & 15, fq = lane >> 4;
    const short* QH = (const short*)qh;
    const short* QL = (const short*)ql;
    long qrow = (long)(b * 1024 + qt * 64 + w * 16 + fr) * 1536 + h * 64;
    bf16x8 Qh2[2], Ql2[2];
    Qh2[0] = *(const bf16x8*)(QH + qrow + fq * 8);
    Qh2[1] = *(const bf16x8*)(QH + qrow + 32 + fq * 8);
    Ql2[0] = *(const bf16x8*)(QL + qrow + fq * 8);
    Ql2[1] = *(const bf16x8*)(QL + qrow + 32 + fq * 8);
    float m_i[4], l_i[4];
    f32x4 o_acc[4] = {};
    #pragma unroll
    for (int i = 0; i < 4; i++) { m_i[i] = -1e30f; l_i[i] = 0.f; }
    int c0 = t, c1 = t + 256;
    int r0 = c0 >> 3, g0 = c0 & 7;
    int r1 = c1 >> 3, g1 = c1 & 7;
    int kd0 = r0 * 64 + ((g0 * 8) ^ ((r0 & 7) << 3));
    int kd1 = r1 * 64 + ((g1 * 8) ^ ((r1 & 7) << 3));
    long kb = (long)(b * 1024) * 1536 + 512 + h * 64;
    long vb = kb + 512;
    long lo0 = (long)r0 * 1536 + g0 * 8, lo1 = (long)r1 * 1536 + g1 * 8;
    short* ph = PHs[w]; short* pl = PLs[w];
    bf16x8 kh0 = *(const bf16x8*)(QH + kb + lo0);
    bf16x8 kh1 = *(const bf16x8*)(QH + kb + lo1);
    bf16x8 kl0 = *(const bf16x8*)(QL + kb + lo0);
    bf16x8 kl1 = *(const bf16x8*)(QL + kb + lo1);
    bf16x8 vh0 = *(const bf16x8*)(QH + vb + lo0);
    bf16x8 vh1 = *(const bf16x8*)(QH + vb + lo1);
    bf16x8 vl0 = *(const bf16x8*)(QL + vb + lo0);
    bf16x8 vl1 = *(const bf16x8*)(QL + vb + lo1);
    int bufo = 0;
    for (int kt = 0; kt < 16; kt++) {
        *(bf16x8*)&KsH[bufo + kd0] = kh0;  *(bf16x8*)&KsH[bufo + kd1] = kh1;
        *(bf16x8*)&KsL[bufo + kd0] = kl0;  *(bf16x8*)&KsL[bufo + kd1] = kl1;
        #pragma unroll
        for (int j = 0; j < 8; j++) {
            int d0 = g0 * 8 + j;
            int i0 = bufo + d0 * 64 + (r0 ^ (((d0 >> 3) & 7) << 3));
            VtH[i0] = ((short*)&vh0)[j];  VtL[i0] = ((short*)&vl0)[j];
            int d1 = g1 * 8 + j;
            int i1 = bufo + d1 * 64 + (r1 ^ (((d1 >> 3) & 7) << 3));
            VtH[i1] = ((short*)&vh1)[j];  VtL[i1] = ((short*)&vl1)[j];
        }
        __syncthreads();
        int ktn = (kt + 1 < 16) ? kt + 1 : kt;
        long ko = kb + (long)(ktn * 64) * 1536;
        long vo = vb + (long)(ktn * 64) * 1536;
        bf16x8 nkh0 = *(const bf16x8*)(QH + ko + lo0);
        bf16x8 nkh1 = *(const bf16x8*)(QH + ko + lo1);
        bf16x8 nkl0 = *(const bf16x8*)(QL + ko + lo0);
        bf16x8 nkl1 = *(const bf16x8*)(QL + ko + lo1);
        bf16x8 nvh0 = *(const bf16x8*)(QH + vo + lo0);
        bf16x8 nvh1 = *(const bf16x8*)(QH + vo + lo1);
        bf16x8 nvl0 = *(const bf16x8*)(QL + vo + lo0);
        bf16x8 nvl1 = *(const bf16x8*)(QL + vo + lo1);
        __builtin_amdgcn_s_setprio(1);
        f32x4 s[4] = {};
        #pragma unroll
        for (int cf = 0; cf < 4; cf++) {
            int kvrow = cf * 16 + fr;
            #pragma unroll
            for (int kf = 0; kf < 2; kf++) {
                int idx = bufo + kvrow * 64 + ((kf * 32 + fq * 8) ^ ((kvrow & 7) << 3));
                bf16x8 Bh2 = *(const bf16x8*)&KsH[idx];
                bf16x8 Bl2 = *(const bf16x8*)&KsL[idx];
                s[cf] = __builtin_amdgcn_mfma_f32_16x16x32_bf16(Qh2[kf], Bh2, s[cf], 0, 0, 0);
                s[cf] = __builtin_amdgcn_mfma_f32_16x16x32_bf16(Qh2[kf], Bl2, s[cf], 0, 0, 0);
                s[cf] = __builtin_amdgcn_mfma_f32_16x16x32_bf16(Ql2[kf], Bh2, s[cf], 0, 0, 0);
            }
        }
        __builtin_amdgcn_s_setprio(0);
        #pragma unroll
        for (int cf = 0; cf < 4; cf++)
        #pragma unroll
        for (int reg = 0; reg < 4; reg++) s[cf][reg] *= 0.125f;
        float sc_[4];
        #pragma unroll
        for (int reg = 0; reg < 4; reg++) {
            float mx = fmaxf(fmaxf(s[0][reg], s[1][reg]), fmaxf(s[2][reg], s[3][reg]));
            mx = fmaxf(mx, __shfl_xor(mx, 1));
            mx = fmaxf(mx, __shfl_xor(mx, 2));
            mx = fmaxf(mx, __shfl_xor(mx, 4));
            mx = fmaxf(mx, __shfl_xor(mx, 8));
            float mn = fmaxf(m_i[reg], mx);
            sc_[reg] = __expf(m_i[reg] - mn);
            m_i[reg] = mn;
            float rs = 0.f;
            #pragma unroll
            for (int cf = 0; cf < 4; cf++) { s[cf][reg] = __expf(s[cf][reg] - mn); rs += s[cf][reg]; }
            rs += __shfl_xor(rs, 1);
            rs += __shfl_xor(rs, 2);
            rs += __shfl_xor(rs, 4);
            rs += __shfl_xor(rs, 8);
            l_i[reg] = l_i[reg] * sc_[reg] + rs;
        }
        #pragma unroll
        for (int cf = 0; cf < 4; cf++)
        #pragma unroll
        for (int reg = 0; reg < 4; reg++) o_acc[cf][reg] *= sc_[reg];
        #pragma unroll
        for (int cf = 0; cf < 4; cf++)
        #pragma unroll
        for (int reg = 0; reg < 4; reg++) {
            int q = fq * 4 + reg, kv = cf * 16 + fr;
            int idx = q * 64 + (kv ^ ((q & 7) << 3));
            split2s(s[cf][reg], ph[idx], pl[idx]);
        }
        asm volatile("s_waitcnt lgkmcnt(0)" ::: "memory");
        __builtin_amdgcn_sched_barrier(0);
        __builtin_amdgcn_s_setprio(1);
        bf16x8 Pf_h[2], Pf_l[2];
        #pragma unroll
        for (int kf = 0; kf < 2; kf++) {
            int idx = fr * 64 + ((kf * 32 + fq * 8) ^ ((fr & 7) << 3));
            Pf_h[kf] = *(const bf16x8*)&ph[idx];
            Pf_l[kf] = *(const bf16x8*)&pl[idx];
        }
        #pragma unroll
        for (int cf = 0; cf < 4; cf++) {
            int d = cf * 16 + fr;
            #pragma unroll
            for (int kf = 0; kf < 2; kf++) {
                int idx = bufo + d * 64 + ((kf * 32 + fq * 8) ^ (((d >> 3) & 7) << 3));
                bf16x8 Vh2 = *(const bf16x8*)&VtH[idx];
                bf16x8 Vl2 = *(const bf16x8*)&VtL[idx];
                o_acc[cf] = __builtin_amdgcn_mfma_f32_16x16x32_bf16(Pf_h[kf], Vh2, o_acc[cf], 0, 0, 0);
                o_acc[cf] = __builtin_amdgcn_mfma_f32_16x16x32_bf16(Pf_h[kf], Vl2, o_acc[cf], 0, 0, 0);
                o_acc[cf] = __builtin_amdgcn_mfma_f32_16x16x32_bf16(Pf_l[kf], Vh2, o_acc[cf], 0, 0, 0);
            }
        }
        __builtin_amdgcn_s_setprio(0);
        kh0 = nkh0; kh1 = nkh1; kl0 = nkl0; kl1 = nkl1;
        vh0 = nvh0; vh1 = nvh1; vl0 = nvl0; vl1 = nvl1;
        bufo ^= 4096;
    }
    #pragma unroll
    for (int reg = 0; reg < 4; reg++) {
        float inv = 1.f / l_i[reg];
        long m = (long)(b * 1024 + qt * 64 + w * 16 + fq * 4 + reg);
        #pragma unroll
        for (int cf = 0; cf < 4; cf++) {
            float v = o_acc[cf][reg] * inv;
            bf16 hh, ll; split2(v, hh, ll);
            long off = m * DIMC + h * 64 + cf * 16 + fr;
            oh[off] = hh; ol[off] = ll;
        }
    }
}

// ---- split-precision MFMA cross-attention: 77 keys padded to 96, single tile ----
__global__ __launch_bounds__(256) void ca_mfma_kernel(
    const bf16* __restrict__ qh, const bf16* __restrict__ ql,
    const bf16* __restrict__ kvh, const bf16* __restrict__ kvl,
    bf16* __restrict__ oh, bf16* __restrict__ ol) {
    int qt = blockIdx.x, h = blockIdx.y, b = blockIdx.z;
    __shared__ short UH[8192], UL[8192];
    __shared__ short PHs[4][2048], PLs[4][2048];
    int t = threadIdx.x, lane = t & 63, w = t >> 6;
    int fr = lane & 15, fq = lane >> 4;
    const short* QH = (const short*)qh;
    const short* QL = (const short*)ql;
    const short* KVH = (const short*)kvh;
    const short* KVL = (const short*)kvl;
    long qrow = (long)(b * 1024 + qt * 64 + w * 16 + fr) * DIMC + h * 64;
    bf16x8 Qh2[2], Ql2[2];
    Qh2[0] = *(const bf16x8*)(QH + qrow + fq * 8);
    Qh2[1] = *(const bf16x8*)(QH + qrow + 32 + fq * 8);
    Ql2[0] = *(const bf16x8*)(QL + qrow + fq * 8);
    Ql2[1] = *(const bf16x8*)(QL + qrow + 32 + fq * 8);
    for (int c = t; c < 768; c += 256) {
        int r = c >> 3, g = c & 7;
        int idx = r * 64 + ((g * 8) ^ ((r & 7) << 3));
        bf16x8 vh = {}, vl = {};
        if (r < 77) {
            long src = (long)(b * 77 + r) * 1024 + h * 64 + g * 8;
            vh = *(const bf16x8*)(KVH + src);
            vl = *(const bf16x8*)(KVL + src);
        }
        *(bf16x8*)&UH[idx] = vh;
        *(bf16x8*)&UL[idx] = vl;
    }
    __syncthreads();
    f32x4 s[5] = {};
    #pragma unroll
    for (int cf = 0; cf < 5; cf++) {
        int kvrow = cf * 16 + fr;
        #pragma unroll
        for (int kf = 0; kf < 2; kf++) {
            int idx = kvrow * 64 + ((kf * 32 + fq * 8) ^ ((kvrow & 7) << 3));
            bf16x8 Bh2 = *(const bf16x8*)&UH[idx];
            bf16x8 Bl2 = *(const bf16x8*)&UL[idx];
            s[cf] = __builtin_amdgcn_mfma_f32_16x16x32_bf16(Qh2[kf], Bh2, s[cf], 0, 0, 0);
            s[cf] = __builtin_amdgcn_mfma_f32_16x16x32_bf16(Qh2[kf], Bl2, s[cf], 0, 0, 0);
            s[cf] = __builtin_amdgcn_mfma_f32_16x16x32_bf16(Ql2[kf], Bh2, s[cf], 0, 0, 0);
        }
    }
    #pragma unroll
    for (int cf = 0; cf < 5; cf++) {
        int kv = cf * 16 + fr;
        #pragma unroll
        for (int reg = 0; reg < 4; reg++)
            s[cf][reg] = (kv < 77) ? s[cf][reg] * 0.125f : -1e30f;
    }
    float inv[4];
    #pragma unroll
    for (int reg = 0; reg < 4; reg++) {
        float mx = s[0][reg];
        #pragma unroll
        for (int cf = 1; cf < 5; cf++) mx = fmaxf(mx, s[cf][reg]);
        mx = fmaxf(mx, __shfl_xor(mx, 1));
        mx = fmaxf(mx, __shfl_xor(mx, 2));
        mx = fmaxf(mx, __shfl_xor(mx, 4));
        mx = fmaxf(mx, __shfl_xor(mx, 8));
        float rs = 0.f;
        #pragma unroll
        for (int cf = 0; cf < 5; cf++) { s[cf][reg] = __expf(s[cf][reg] - mx); rs += s[cf][reg]; }
        rs += __shfl_xor(rs, 1);
        rs += __shfl_xor(rs, 2);
        rs += __shfl_xor(rs, 4);
        rs += __shfl_xor(rs, 8);
        inv[reg] = 1.f / rs;
    }
    short* ph = PHs[w]; short* pl = PLs[w];
    #pragma unroll
    for (int cf = 0; cf < 6; cf++)
    #pragma unroll
    for (int reg = 0; reg < 4; reg++) {
        int q = fq * 4 + reg, kv = cf * 16 + fr;
        int idx = q * 128 + (kv ^ ((q & 7) << 3));
        float pv = (cf < 5) ? s[cf][reg] * inv[reg] : 0.f;
        split2s(pv, ph[idx], pl[idx]);
    }
    __syncthreads();
    for (int c = t; c < 768; c += 256) {
        int r = c >> 3, g = c & 7;
        bf16x8 vh = {}, vl = {};
        if (r < 77) {
            long src = (long)(b * 77 + r) * 1024 + 512 + h * 64 + g * 8;
            vh = *(const bf16x8*)(KVH + src);
            vl = *(const bf16x8*)(KVL + src);
        }
        #pragma unroll
        for (int j = 0; j < 8; j++) {
            int d = g * 8 + j;
            int idx = d * 128 + (r ^ (((d >> 3) & 7) << 3));
            UH[idx] = ((short*)&vh)[j];
            UL[idx] = ((short*)&vl)[j];
        }
    }
    __syncthreads();
    f32x4 o_acc[4] = {};
    bf16x8 Pf_h[3], Pf_l[3];
    #pragma unroll
    for (int kf = 0; kf < 3; kf++) {
        int idx = fr * 128 + ((kf * 32 + fq * 8) ^ ((fr & 7) << 3));
        Pf_h[kf] = *(const bf16x8*)&ph[idx];
        Pf_l[kf] = *(const bf16x8*)&pl[idx];
    }
    #pragma unroll
    for (int cf = 0; cf < 4; cf++) {
        int d = cf * 16 + fr;
        #pragma unroll
        for (int kf = 0; kf < 3; kf++) {
            int idx = d * 128 + ((kf * 32 + fq * 8) ^ (((d >> 3) & 7) << 3));
            bf16x8 Vh2 = *(const bf16x8*)&UH[idx];
            bf16x8 Vl2 = *(const bf16x8*)&UL[idx];
            o_acc[cf] = __builtin_amdgcn_mfma_f32_16x16x32_bf16(Pf_h[kf], Vh2, o_acc[cf], 0, 0, 0);
            o_acc[cf] = __builtin_amdgcn_mfma_f32_16x16x32_bf16(Pf_h[kf], Vl2, o_acc[cf], 0, 0, 0);
            o_acc[cf] = __builtin_amdgcn_mfma_f32_16x16x32_bf16(Pf_l[kf], Vh2, o_acc[cf], 0, 0, 0);
        }
    }
    #pragma unroll
    for (int reg = 0; reg < 4; reg++) {
        long m = (long)(b * 1024 + qt * 64 + w * 16 + fq * 4 + reg);
        #pragma unroll
        for (int cf = 0; cf < 4; cf++) {
            bf16 hh, ll; split2(o_acc[cf][reg], hh, ll);
            long off = m * DIMC + h * 64 + cf * 16 + fr;
            oh[off] = hh; ol[off] = ll;
        }
    }
}

// ---- MoE grouped MFMA GEMM1, 64x64 tile: hid = gelu(xn·w1 + b1), K=512 ----
__global__ __launch_bounds__(256) void moe64_1_kernel(
    const bf16* __restrict__ xn_b, const bf16* __restrict__ e1T, const float* __restrict__ e_b1,
    const int* __restrict__ table, const int* __restrict__ ntiles, const int* __restrict__ perm,
    bf16* __restrict__ hid_b) {
    if (blockIdx.y >= ntiles[0]) return;
    int e = table[2 * blockIdx.y], row0 = table[2 * blockIdx.y + 1];
    int bn = blockIdx.x * 64;
    __shared__ short As[2 * 2048];
    __shared__ short Bs[2 * 2048];
    __shared__ int rowsS[64];
    int t = threadIdx.x, lane = t & 63, w = t >> 6;
    if (t < 64) rowsS[t] = perm[row0 + t];
    __syncthreads();
    int wm = (w >> 1) * 32, wn = (w & 1) * 32;
    int r0 = t >> 2, k0s = (t & 3) ^ ((r0 >> 1) & 3);
    int tok0 = rowsS[r0]; if (tok0 < 0) tok0 = 0;
    const short* Xs = (const short*)xn_b;
    const short* Ws = (const short*)(e1T + (long)e * HIDC * DIMC);
    const short* a0 = Xs + (long)tok0 * DIMC + k0s * 8;
    const short* b0 = Ws + (long)(bn + r0) * DIMC + k0s * 8;
    int fr = lane & 15, fq = lane >> 4;
    int aOff[2], bOff[2];
    #pragma unroll
    for (int i = 0; i < 2; i++) {
        int row = wm + i * 16 + fr;
        aOff[i] = row * 32 + ((fq ^ ((row >> 1) & 3)) * 8);
        int col = wn + i * 16 + fr;
        bOff[i] = col * 32 + ((fq ^ ((col >> 1) & 3)) * 8);
    }
    f32x4 acc[2][2] = {};
    bf16x8 va = *(const bf16x8*)(a0);
    bf16x8 vb = *(const bf16x8*)(b0);
    int bufo = 0;
    for (int kk = 0; kk < DIMC; kk += 32) {
        *(bf16x8*)&As[bufo + t * 8] = va;
        *(bf16x8*)&Bs[bufo + t * 8] = vb;
        __syncthreads();
        int kn = (kk + 32 < DIMC) ? kk + 32 : kk;
        bf16x8 na = *(const bf16x8*)(a0 + kn);
        bf16x8 nb = *(const bf16x8*)(b0 + kn);
        bf16x8 aF[2], bF[2];
        #pragma unroll
        for (int i = 0; i < 2; i++) {
            aF[i] = *(const bf16x8*)&As[bufo + aOff[i]];
            bF[i] = *(const bf16x8*)&Bs[bufo + bOff[i]];
        }
        #pragma unroll
        for (int i = 0; i < 2; i++)
        #pragma unroll
        for (int j = 0; j < 2; j++)
            acc[i][j] = __builtin_amdgcn_mfma_f32_16x16x32_bf16(aF[i], bF[j], acc[i][j], 0, 0, 0);
        va = na; vb = nb;
        bufo ^= 2048;
    }
    const float* bb = e_b1 + (long)e * HIDC;
    #pragma unroll
    for (int i = 0; i < 2; i++)
    #pragma unroll
    for (int r = 0; r < 4; r++) {
        int tok = rowsS[wm + i * 16 + fq * 4 + r];
        if (tok < 0) continue;
        #pragma unroll
        for (int j = 0; j < 2; j++) {
            int col = bn + wn + j * 16 + fr;
            float v = acc[i][j][r] + bb[col];
            v = 0.5f * v * (1.f + erff(v * 0.70710678f));
            hid_b[(long)tok * HIDC + col] = __float2bfloat16(v);
        }
    }
}

// ---- MoE grouped MFMA GEMM2, 64x64 tile: x_flat += hid·w2 + b2, K=2048 ----
__global__ __launch_bounds__(256) void moe64_2_kernel(
    const bf16* __restrict__ hid_b, const bf16* __restrict__ e2T, const float* __restrict__ e_b2,
    const int* __restrict__ table, const int* __restrict__ ntiles, const int* __restrict__ perm,
    float* __restrict__ x_flat) {
    if (blockIdx.y >= ntiles[0]) return;
    int e = table[2 * blockIdx.y], row0 = table[2 * blockIdx.y + 1];
    int bn = blockIdx.x * 64;
    __shared__ short As[2 * 2048];
    __shared__ short Bs[2 * 2048];
    __shared__ int rowsS[64];
    int t = threadIdx.x, lane = t & 63, w = t >> 6;
    if (t < 64) rowsS[t] = perm[row0 + t];
    __syncthreads();
    int wm = (w >> 1) * 32, wn = (w & 1) * 32;
    int r0 = t >> 2, k0s = (t & 3) ^ ((r0 >> 1) & 3);
    int tok0 = rowsS[r0]; if (tok0 < 0) tok0 = 0;
    const short* Hs = (const short*)hid_b;
    const short* Ws = (const short*)(e2T + (long)e * DIMC * HIDC);
    const short* a0 = Hs + (long)tok0 * HIDC + k0s * 8;
    const short* b0 = Ws + (long)(bn + r0) * HIDC + k0s * 8;
    int fr = lane & 15, fq = lane >> 4;
    int aOff[2], bOff[2];
    #pragma unroll
    for (int i = 0; i < 2; i++) {
        int row = wm + i * 16 + fr;
        aOff[i] = row * 32 + ((fq ^ ((row >> 1) & 3)) * 8);
        int col = wn + i * 16 + fr;
        bOff[i] = col * 32 + ((fq ^ ((col >> 1) & 3)) * 8);
    }
    f32x4 acc[2][2] = {};
    bf16x8 va = *(const bf16x8*)(a0);
    bf16x8 vb = *(const bf16x8*)(b0);
    int bufo = 0;
    for (int kk = 0; kk < HIDC; kk += 32) {
        *(bf16x8*)&As[bufo + t * 8] = va;
        *(bf16x8*)&Bs[bufo + t * 8] = vb;
        __syncthreads();
        int kn = (kk + 32 < HIDC) ? kk + 32 : kk;
        bf16x8 na = *(const bf16x8*)(a0 + kn);
        bf16x8 nb = *(const bf16x8*)(b0 + kn);
        bf16x8 aF[2], bF[2];
        #pragma unroll
        for (int i = 0; i < 2; i++) {
            aF[i] = *(const bf16x8*)&As[bufo + aOff[i]];
            bF[i] = *(const bf16x8*)&Bs[bufo + bOff[i]];
        }
        #pragma unroll
        for (int i = 0; i < 2; i++)
        #pragma unroll
        for (int j = 0; j < 2; j++)
            acc[i][j] = __builtin_amdgcn_mfma_f32_16x16x32_bf16(aF[i], bF[j], acc[i][j], 0, 0, 0);
        va = na; vb = nb;
        bufo ^= 2048;
    }
    const float* bb = e_b2 + (long)e * DIMC;
    #pragma unroll
    for (int i = 0; i < 2; i++)
    #pragma unroll
    for (int r = 0; r < 4; r++) {
        int tok = rowsS[wm + i * 16 + fq * 4 + r];
        if (tok < 0) continue;
        #pragma unroll
        for (int j = 0; j < 2; j++) {
            int col = bn + wn + j * 16 + fr;
            x_flat[(long)tok * DIMC + col] += acc[i][j][r] + bb[col];
        }
    }
}

// ---------------- LayerNorm: optional fp32 + bf16 hi/lo outputs ----------------
__global__ void ln_kernel(const float* __restrict__ x, const float* __restrict__ g,
                          const float* __restrict__ b, float* __restrict__ y,
                          bf16* __restrict__ yh, bf16* __restrict__ yl) {
    int tok = blockIdx.x;
    int t = threadIdx.x;
    const float* xr = x + (long)tok * DIMC;
    float v0 = xr[t], v1 = xr[t + 256];
    __shared__ float red[256];
    red[t] = v0 + v1; __syncthreads();
    for (int s = 128; s > 0; s >>= 1) { if (t < s) red[t] += red[t + s]; __syncthreads(); }
    float mu = red[0] * (1.f / DIMC);
    __syncthreads();
    float d0 = v0 - mu, d1 = v1 - mu;
    red[t] = d0 * d0 + d1 * d1; __syncthreads();
    for (int s = 128; s > 0; s >>= 1) { if (t < s) red[t] += red[t + s]; __syncthreads(); }
    float rs = rsqrtf(red[0] * (1.f / DIMC) + 1e-5f);
    float o0 = d0 * rs * g[t] + b[t];
    float o1 = d1 * rs * g[t + 256] + b[t + 256];
    if (y) { y[(long)tok * DIMC + t] = o0; y[(long)tok * DIMC + t + 256] = o1; }
    bf16 h, l;
    split2(o0, h, l); yh[(long)tok * DIMC + t] = h;       yl[(long)tok * DIMC + t] = l;
    split2(o1, h, l); yh[(long)tok * DIMC + t + 256] = h; yl[(long)tok * DIMC + t + 256] = l;
}

// ---------------- router text part ----------------
__global__ void textpart_kernel(const float* __restrict__ w, const float* __restrict__ r_text_mu,
                                const float* __restrict__ r_comb_mu, float* __restrict__ tp) {
    __shared__ float tw[4][128];
    int t = threadIdx.x;
    for (int j = 0; j < 2; j++) {
        int idx = t + j * 256; int b = idx >> 7, c = idx & 127;
        const float* wr = w + (long)b * LATC;
        float s = 0.f;
        for (int k = 0; k < LATC; k++) s += wr[k] * r_text_mu[(long)k * 128 + c];
        tw[b][c] = s;
    }
    __syncthreads();
    if (t < 32) {
        int b = t >> 3, e = t & 7;
        float s = 0.f;
        for (int c = 0; c < 128; c++) s += tw[b][c] * r_comb_mu[(long)(128 + c) * 8 + e];
        tp[t] = s;
    }
}

// ---------------- MoE meta ----------------
__global__ void moe_init_kernel(int* __restrict__ cnt, int* __restrict__ perm) {
    int g = blockIdx.x * blockDim.x + threadIdx.x;
    if (g < MAXT * 64) perm[g] = -1;
    if (g < NE) cnt[g] = 0;
}

__global__ void route_kernel(const float* __restrict__ feat, const float* __restrict__ tp,
                             const float* __restrict__ r_comb_mu, const float* __restrict__ r_temp,
                             float* __restrict__ onehot, int* __restrict__ idx, int* __restrict__ cnt) {
    int n = blockIdx.x * blockDim.x + threadIdx.x;
    if (n >= NTOK) return;
    int b = n >> 10;
    float tmp = fmaxf(r_temp[0], 0.1f);
    float invt = 1.f / tmp;
    const float* fr = feat + (long)n * 128;
    float lg[8];
    for (int e = 0; e < 8; e++) {
        float s = 0.f;
        for (int c = 0; c < 128; c++) s += fr[c] * r_comb_mu[(long)c * 8 + e];
        lg[e] = (s + tp[b * 8 + e]) * invt;
    }
    float best = lg[0]; int bi = 0;
    for (int e = 1; e < 8; e++) { if (lg[e] > best) { best = lg[e]; bi = e; } }
    for (int e = 0; e < 8; e++) onehot[(long)n * 8 + e] = (e == bi) ? 1.f : 0.f;
    idx[n] = bi;
    atomicAdd(&cnt[bi], 1);
}

__global__ void offsets_kernel(const int* __restrict__ cnt, int* __restrict__ cursor,
                               int* __restrict__ ntiles, int* __restrict__ table) {
    if (threadIdx.x != 0) return;
    int po = 0, nt = 0;
    for (int e = 0; e < NE; e++) {
        cursor[e] = po;
        int tiles = (cnt[e] + 63) >> 6;
        for (int j = 0; j < tiles; j++) { table[2 * nt] = e; table[2 * nt + 1] = po + j * 64; nt++; }
        po += tiles * 64;
    }
    ntiles[0] = nt;
}

__global__ void scatter_kernel(const int* __restrict__ idx, int* __restrict__ cursor,
                               int* __restrict__ perm) {
    int n = blockIdx.x * blockDim.x + threadIdx.x;
    if (n >= NTOK) return;
    int e = idx[n];
    int pos = atomicAdd(&cursor[e], 1);
    perm[pos] = n;
}

extern "C" void kernel_launch(void* const* d_in, const int* in_sizes, int n_in,
                              void* d_out, int out_size, void* d_ws, size_t ws_size,
                              hipStream_t stream) {
    const float* x        = (const float*)d_in[0];
    const float* w        = (const float*)d_in[1];
    const float* text     = (const float*)d_in[2];
    const float* pin_w    = (const float*)d_in[3];
    const float* pin_mw   = (const float*)d_in[4];
    const float* pin_mb   = (const float*)d_in[5];
    const float* pout_w   = (const float*)d_in[6];
    const float* pout_mw  = (const float*)d_in[7];
    const float* pout_mb  = (const float*)d_in[8];
    const float* ln1g     = (const float*)d_in[9];
    const float* ln1b     = (const float*)d_in[10];
    const float* ln2g     = (const float*)d_in[11];
    const float* ln2b     = (const float*)d_in[12];
    const float* ln3g     = (const float*)d_in[13];
    const float* ln3b     = (const float*)d_in[14];
    const float* sa_in_w  = (const float*)d_in[15];
    const float* sa_in_b  = (const float*)d_in[16];
    const float* sa_out_w = (const float*)d_in[17];
    const float* sa_out_b = (const float*)d_in[18];
    const float* ca_in_w  = (const float*)d_in[19];
    const float* ca_in_b  = (const float*)d_in[20];
    const float* ca_out_w = (const float*)d_in[21];
    const float* ca_out_b = (const float*)d_in[22];
    const float* r_feat   = (const float*)d_in[23];
    const float* r_text   = (const float*)d_in[24];
    const float* r_comb   = (const float*)d_in[25];
    const float* r_temp   = (const float*)d_in[26];
    const float* e_w1     = (const float*)d_in[27];
    const float* e_b1     = (const float*)d_in[28];
    const float* e_w2     = (const float*)d_in[29];
    const float* e_b2     = (const float*)d_in[30];

    float* out    = (float*)d_out;               // [B, DIM, H, W]
    float* onehot = out + (long)BB * DIMC * HWX; // [4096, 8]

    // ---------------- workspace: fp32 pool ----------------
    float* f32p = (float*)d_ws;
    float* style_in  = f32p;                 // 2048
    float* style_out = f32p + 2048;          // 2048
    float* tp        = f32p + 4096;          // 32
    int*   idx       = (int*)(f32p + 4128);  // 4096
    int*   cnt       = (int*)(f32p + 8224);  // 8
    int*   cursor    = (int*)(f32p + 8232);  // 8
    int*   ntiles    = (int*)(f32p + 8240);  // 8
    int*   table     = (int*)(f32p + 8248);  // 256 (72 tiles * 2 + pad)
    int*   perm      = (int*)(f32p + 8504);  // 4608 -> ends 13112
    float* x_flat    = f32p + 13496;         // 2097152
    float* xn        = x_flat + 2097152;     // 2097152 (dead fp32; kept for layout stability)
    float* qkv       = xn + 2097152;         // 6291456 (SA q split / CA q split home)
    float* spill     = qkv + 6291456;        // 2097152 (e2T tail)

    // ---------------- bf16 pool (phase-aliased) ----------------
    bf16* bp = (bf16*)(f32p + 12596408);
    bf16* R1 = bp;                           // 6291456 elems, 3 phases
    bf16* xT_h  = R1;
    bf16* xT_l  = R1 + 2097152;
    bf16* wtA_h = R1 + 4194304;
    bf16* wtA_l = R1 + 5242880;
    bf16* obuf_h = R1;
    bf16* obuf_l = R1 + 2097152;
    bf16* kvt_h  = R1 + 4194304;                       // [308][1024] split
    bf16* kvt_l  = kvt_h + 315392;
    float* feat  = (float*)(kvt_l + 315392);           // 524288 fp32
    bf16* wtC_h = R1;
    bf16* wtC_l = R1 + 1048576;
    bf16* xn_h = R1 + 6291456;               // 2097152
    bf16* xn_l = xn_h + 2097152;             // 2097152
    bf16* WB   = xn_l + 2097152;             // 8388608: weights (early) / hid_b (late)
    bf16* text_h   = WB;
    bf16* text_l   = text_h + 157696;
    bf16* sawin_h  = text_l + 157696;
    bf16* sawin_l  = sawin_h + 786432;
    bf16* sawout_h = sawin_l + 786432;
    bf16* sawout_l = sawout_h + 262144;
    bf16* caw_h    = sawout_l + 262144;
    bf16* caw_l    = caw_h + 786432;
    bf16* cawout_h = caw_l + 786432;
    bf16* cawout_l = cawout_h + 262144;
    bf16* rfT_h    = cawout_l + 262144;      // [128][512] split r_feat^T
    bf16* rfT_l    = rfT_h + 65536;
    bf16* hid_b    = WB;                     // overlays weights after ca_out
    bf16* e1T = (bf16*)qkv;                  // [8][2048][512] in qkv+spill
    bf16* e2T = e1T + 8388608;
    bf16* xfl_h = xn_h;
    bf16* xfl_l = xn_l;
    bf16* q_h = (bf16*)qkv;                  // [4096][1536]
    bf16* q_l = q_h + 6291456;
    bf16* ca_qh = (bf16*)qkv;                // [4096][512]
    bf16* ca_ql = ca_qh + 2097152;
    (void)ws_size; (void)spill; (void)xn;

    auto mg = [&](const bf16* Ah, const bf16* Al, const bf16* Bh, const bf16* Bl,
                  const float* bias, const float* resid, float* C, bf16* Oh, bf16* Ol,
                  int M, int N, int K, long ab, long bb, long cb, int csm, int csn, int nb) {
        dim3 g(N / 64, (M + 63) / 64, nb);
        hipLaunchKernelGGL(mgemm64_kernel, g, dim3(256), 0, stream,
                           Ah, Al, Bh, Bl, bias, resid, C, Oh, Ol, M, N, K, ab, bb, cb, csm, csn);
    };
    auto cvt2 = [&](const float* in, bf16* h2, bf16* l2, int n) {
        hipLaunchKernelGGL(cvt2_kernel, dim3((n / 4 + 255) / 256), dim3(256), 0, stream, in, h2, l2, n);
    };

    // ---- input conversions (hi/lo) ----
    cvt2(sa_in_w, sawin_h, sawin_l, 1536 * 512);
    cvt2(sa_out_w, sawout_h, sawout_l, 512 * 512);
    cvt2(ca_in_w, caw_h, caw_l, 1536 * 512);
    cvt2(ca_out_w, cawout_h, cawout_l, 512 * 512);
    cvt2(text, text_h, text_l, BB * TXT * 512);
    hipLaunchKernelGGL(trcvt2_kernel, dim3(32, 16, BB), dim3(256), 0, stream,
                       x, xT_h, xT_l, 512, 1024, (long)512 * 1024, (long)1024 * 512);
    hipLaunchKernelGGL(trcvt2_kernel, dim3(4, 16, 1), dim3(256), 0, stream,
                       r_feat, rfT_h, rfT_l, 512, 128, 0L, 0L);

    // ---- modconv in ----
    hipLaunchKernelGGL(style_kernel, dim3(8), dim3(256), 0, stream, w, pin_mw, pin_mb, style_in);
    hipLaunchKernelGGL(wtmod_kernel, dim3(BB * DIMC), dim3(256), 0, stream, pin_w, style_in, wtA_h, wtA_l);
    mg(xT_h, xT_l, wtA_h, wtA_l, nullptr, nullptr, x_flat, nullptr, nullptr,
       HWX, DIMC, DIMC, (long)HWX * DIMC, (long)DIMC * DIMC, (long)HWX * DIMC, DIMC, 1, BB);

    // ---- LN1 + self-attention (split MFMA) ----
    hipLaunchKernelGGL(ln_kernel, dim3(NTOK), dim3(256), 0, stream, x_flat, ln1g, ln1b,
                       (float*)nullptr, xn_h, xn_l);
    mg(xn_h, xn_l, sawin_h, sawin_l, sa_in_b, nullptr, nullptr, q_h, q_l,
       NTOK, 1536, 512, 0, 0, 0, 1536, 1, 1);
    hipLaunchKernelGGL(sa_mfma_kernel, dim3(16, HEADS, BB), dim3(256), 0, stream,
                       q_h, q_l, obuf_h, obuf_l);
    mg(obuf_h, obuf_l, sawout_h, sawout_l, sa_out_b, x_flat, x_flat, nullptr, nullptr,
       NTOK, 512, 512, 0, 0, 0, 512, 1, 1);

    // ---- LN2 + cross-attention (split MFMA) ----
    hipLaunchKernelGGL(ln_kernel, dim3(NTOK), dim3(256), 0, stream, x_flat, ln2g, ln2b,
                       (float*)nullptr, xn_h, xn_l);
    mg(xn_h, xn_l, caw_h, caw_l, ca_in_b, nullptr, nullptr, ca_qh, ca_ql,
       NTOK, 512, 512, 0, 0, 0, 512, 1, 1);
    mg(text_h, text_l, caw_h + 512 * 512, caw_l + 512 * 512, ca_in_b + 512, nullptr, nullptr,
       kvt_h, kvt_l, BB * TXT, 1024, 512, 0, 0, 0, 1024, 1, 1);
    hipLaunchKernelGGL(ca_mfma_kernel, dim3(16, HEADS, BB), dim3(256), 0, stream,
                       ca_qh, ca_ql, kvt_h, kvt_l, obuf_h, obuf_l);
    hipLaunchKernelGGL(trcvt_kernel, dim3(64, 16, NE), dim3(256), 0, stream,
                       e_w1, e1T, 512, 2048, (long)512 * 2048, (long)2048 * 512);
    hipLaunchKernelGGL(trcvt_kernel, dim3(16, 64, NE), dim3(256), 0, stream,
                       e_w2, e2T, 2048, 512, (long)2048 * 512, (long)512 * 2048);
    mg(obuf_h, obuf_l, cawout_h, cawout_l, ca_out_b, x_flat, x_flat, nullptr, nullptr,
       NTOK, 512, 512, 0, 0, 0, 512, 1, 1);

    // ---- LN3 + router (feat via split MFMA) ----
    hipLaunchKernelGGL(ln_kernel, dim3(NTOK), dim3(256), 0, stream, x_flat, ln3g, ln3b,
                       (float*)nullptr, xn_h, xn_l);
    mg(xn_h, xn_l, rfT_h, rfT_l, nullptr, nullptr, feat, nullptr, nullptr,
       NTOK, 128, 512, 0, 0, 0, 128, 1, 1);
    hipLaunchKernelGGL(textpart_kernel, dim3(1), dim3(256), 0, stream, w, r_text, r_comb, tp);
    hipLaunchKernelGGL(moe_init_kernel, dim3((MAXT * 64 + 255) / 256), dim3(256), 0, stream, cnt, perm);
    hipLaunchKernelGGL(route_kernel, dim3(16), dim3(256), 0, stream, feat, tp, r_comb, r_temp, onehot, idx, cnt);
    hipLaunchKernelGGL(offsets_kernel, dim3(1), dim3(64), 0, stream, cnt, cursor, ntiles, table);
    hipLaunchKernelGGL(scatter_kernel, dim3(16), dim3(256), 0, stream, idx, cursor, perm);

    // ---- MoE grouped MFMA GEMMs (64x64 tiles, high fill) ----
    hipLaunchKernelGGL(moe64_1_kernel, dim3(HIDC / 64, MAXT), dim3(256), 0, stream,
                       xn_h, e1T, e_b1, table, ntiles, perm, hid_b);
    hipLaunchKernelGGL(moe64_2_kernel, dim3(DIMC / 64, MAXT), dim3(256), 0, stream,
                       hid_b, e2T, e_b2, table, ntiles, perm, x_flat);

    // ---- modconv out (split both sides) ----
    cvt2(x_flat, xfl_h, xfl_l, NTOK * DIMC);
    hipLaunchKernelGGL(style_kernel, dim3(8), dim3(256), 0, stream, w, pout_mw, pout_mb, style_out);
    hipLaunchKernelGGL(wtmod_kernel, dim3(BB * DIMC), dim3(256), 0, stream, pout_w, style_out, wtC_h, wtC_l);
    mg(wtC_h, wtC_l, xfl_h, xfl_l, nullptr, nullptr, out, nullptr, nullptr,
       DIMC, HWX, DIMC, (long)DIMC * DIMC, (long)HWX * DIMC, (long)DIMC * HWX, HWX, 1, BB);
}

// Round 14
// 554.439 us; speedup vs baseline: 1.2990x; 1.0564x over previous
//
#include <hip/hip_runtime.h>
#include <hip/hip_bf16.h>
#include <math.h>

#define DIMC 512
#define HEADS 8
#define HD 64
#define BB 4
#define HWX 1024
#define TXT 77
#define LATC 512
#define NE 8
#define HIDC 2048
#define NTOK 4096
#define MAXT 72           // MoE tiles of 64: 4096/64 + 8

typedef __attribute__((ext_vector_type(8))) short bf16x8;
typedef __attribute__((ext_vector_type(4))) float f32x4;
typedef __hip_bfloat16 bf16;

__device__ __forceinline__ void split2(float v, bf16& h, bf16& l) {
    h = __float2bfloat16(v);
    l = __float2bfloat16(v - __bfloat162float(h));
}
__device__ __forceinline__ void split2s(float v, short& h, short& l) {
    bf16 hb, lb; split2(v, hb, lb);
    h = *(short*)&hb; l = *(short*)&lb;
}

// ---------------- both styles in one launch: job 0 = in, job 1 = out ----------------
__global__ void style2_kernel(const float* __restrict__ w,
                              const float* __restrict__ mwA, const float* __restrict__ mbA,
                              const float* __restrict__ mwB, const float* __restrict__ mbB,
                              float* __restrict__ sA, float* __restrict__ sB) {
    int g = blockIdx.x * blockDim.x + threadIdx.x;
    int job = (g >= BB * DIMC) ? 1 : 0;
    int t = g - job * BB * DIMC;
    if (t >= BB * DIMC) return;
    const float* mw = job ? mwB : mwA;
    const float* mb = job ? mbB : mbA;
    float* st = job ? sB : sA;
    int b = t / DIMC, i = t % DIMC;
    const float* wr = w + (long)b * LATC;
    const float* mr = mw + (long)i * LATC;
    float s = 0.f;
    #pragma unroll 8
    for (int l = 0; l < LATC; l++) s += wr[l] * mr[l];
    st[t] = s + mb[i];
}

// ------- both wtmods in one launch -------
__global__ void wtmod2_kernel(const float* __restrict__ wA, const float* __restrict__ sA,
                              const float* __restrict__ wB, const float* __restrict__ sB,
                              bf16* __restrict__ whA, bf16* __restrict__ wlA,
                              bf16* __restrict__ whB, bf16* __restrict__ wlB) {
    int gb = blockIdx.x;
    int job = (gb >= BB * DIMC) ? 1 : 0;
    int bo = gb - job * BB * DIMC;
    const float* weight = job ? wB : wA;
    const float* style  = job ? sB : sA;
    bf16* wh = job ? whB : whA;
    bf16* wl = job ? wlB : wlA;
    int b = bo / DIMC, o = bo % DIMC;
    const float* wr = weight + (long)o * DIMC;
    const float* sr = style + (long)b * DIMC;
    int t = threadIdx.x;
    float vals[2]; float part = 0.f;
    for (int j = 0; j < 2; j++) {
        int i = t + j * 256;
        float v = wr[i] * sr[i];
        vals[j] = v; part += v * v;
    }
    __shared__ float red[256];
    red[t] = part; __syncthreads();
    for (int s = 128; s > 0; s >>= 1) { if (t < s) red[t] += red[t + s]; __syncthreads(); }
    float d = rsqrtf(red[0] + 1e-8f);
    for (int j = 0; j < 2; j++) {
        int i = t + j * 256;
        bf16 h, l; split2(vals[j] * d, h, l);
        wh[(long)bo * DIMC + i] = h; wl[(long)bo * DIMC + i] = l;
    }
}

// ---------------- fp32 -> bf16 hi/lo convert (flat) ----------------
__global__ void cvt2_kernel(const float* __restrict__ in, bf16* __restrict__ hi,
                            bf16* __restrict__ lo, int n) {
    int i = (blockIdx.x * blockDim.x + threadIdx.x) * 4;
    if (i >= n) return;
    float4 v = *(const float4*)(in + i);
    float a[4] = {v.x, v.y, v.z, v.w};
    #pragma unroll
    for (int j = 0; j < 4; j++) { bf16 h, l; split2(a[j], h, l); hi[i + j] = h; lo[i + j] = l; }
}

// ---------------- fp32 [R][C] -> bf16 [C][R] transpose hi/lo ----------------
__global__ void trcvt2_kernel(const float* __restrict__ in, bf16* __restrict__ hi,
                              bf16* __restrict__ lo, int R, int C, long in_bat, long out_bat) {
    __shared__ float tile[32][33];
    in += (long)blockIdx.z * in_bat; hi += (long)blockIdx.z * out_bat; lo += (long)blockIdx.z * out_bat;
    int c0 = blockIdx.x * 32, r0 = blockIdx.y * 32;
    int tc = threadIdx.x & 31, tr = threadIdx.x >> 5;
    #pragma unroll
    for (int i = 0; i < 4; i++) {
        int r = tr + i * 8;
        tile[r][tc] = in[(long)(r0 + r) * C + c0 + tc];
    }
    __syncthreads();
    #pragma unroll
    for (int i = 0; i < 4; i++) {
        int r = tr + i * 8;
        bf16 h, l; split2(tile[tc][r], h, l);
        hi[(long)(c0 + r) * R + r0 + tc] = h;
        lo[(long)(c0 + r) * R + r0 + tc] = l;
    }
}

// ---------------- fp32 [R][C] -> bf16 [C][R] transpose (single) ----------------
__global__ void trcvt_kernel(const float* __restrict__ in, bf16* __restrict__ out,
                             int R, int C, long in_bat, long out_bat) {
    __shared__ float tile[32][33];
    in += (long)blockIdx.z * in_bat; out += (long)blockIdx.z * out_bat;
    int c0 = blockIdx.x * 32, r0 = blockIdx.y * 32;
    int tc = threadIdx.x & 31, tr = threadIdx.x >> 5;
    #pragma unroll
    for (int i = 0; i < 4; i++) {
        int r = tr + i * 8;
        tile[r][tc] = in[(long)(r0 + r) * C + c0 + tc];
    }
    __syncthreads();
    #pragma unroll
    for (int i = 0; i < 4; i++) {
        int r = tr + i * 8;
        out[(long)(c0 + r) * R + r0 + tc] = __float2bfloat16(tile[tc][r]);
    }
}

// ---- split-precision bf16 MFMA GEMM, 64x64 tile (high machine fill) ----
__global__ __launch_bounds__(256) void mgemm64_kernel(
    const bf16* __restrict__ Ah, const bf16* __restrict__ Al,
    const bf16* __restrict__ Bh, const bf16* __restrict__ Bl,
    const float* __restrict__ bias, const float* __restrict__ resid, float* __restrict__ C,
    bf16* __restrict__ Oh, bf16* __restrict__ Ol,
    int M, int N, int K, long a_bat, long b_bat, long c_bat, int cs_m, int cs_n) {
    __shared__ short AsH[2 * 2048];
    __shared__ short AsL[2 * 2048];
    __shared__ short BsH[2 * 2048];
    __shared__ short BsL[2 * 2048];
    int bat = blockIdx.z;
    const short* AbH = (const short*)(Ah + (long)bat * a_bat);
    const short* AbL = (const short*)(Al + (long)bat * a_bat);
    const short* BbH = (const short*)(Bh + (long)bat * b_bat);
    const short* BbL = (const short*)(Bl + (long)bat * b_bat);
    float* Cb = C + (long)bat * c_bat;
    const float* Rb = resid ? resid + (long)bat * c_bat : nullptr;
    int bm = blockIdx.y * 64, bn = blockIdx.x * 64;
    int t = threadIdx.x, lane = t & 63, w = t >> 6;
    int wm = (w >> 1) * 32, wn = (w & 1) * 32;
    int r0 = t >> 2, k0s = (t & 3) ^ ((r0 >> 1) & 3);
    int ar0 = bm + r0; if (ar0 > M - 1) ar0 = M - 1;
    long aoff = (long)ar0 * K + k0s * 8;
    long boff = (long)(bn + r0) * K + k0s * 8;
    int fr = lane & 15, fq = lane >> 4;
    int aOff[2], bOff[2];
    #pragma unroll
    for (int i = 0; i < 2; i++) {
        int row = wm + i * 16 + fr;
        aOff[i] = row * 32 + ((fq ^ ((row >> 1) & 3)) * 8);
        int col = wn + i * 16 + fr;
        bOff[i] = col * 32 + ((fq ^ ((col >> 1) & 3)) * 8);
    }
    f32x4 acc[2][2] = {};
    bf16x8 vah = *(const bf16x8*)(AbH + aoff);
    bf16x8 val = *(const bf16x8*)(AbL + aoff);
    bf16x8 vbh = *(const bf16x8*)(BbH + boff);
    bf16x8 vbl = *(const bf16x8*)(BbL + boff);
    int bufo = 0;
    for (int kk = 0; kk < K; kk += 32) {
        *(bf16x8*)&AsH[bufo + t * 8] = vah;
        *(bf16x8*)&AsL[bufo + t * 8] = val;
        *(bf16x8*)&BsH[bufo + t * 8] = vbh;
        *(bf16x8*)&BsL[bufo + t * 8] = vbl;
        __syncthreads();
        int kn = (kk + 32 < K) ? kk + 32 : kk;
        bf16x8 nah = *(const bf16x8*)(AbH + aoff + kn);
        bf16x8 nal = *(const bf16x8*)(AbL + aoff + kn);
        bf16x8 nbh = *(const bf16x8*)(BbH + boff + kn);
        bf16x8 nbl = *(const bf16x8*)(BbL + boff + kn);
        bf16x8 aH[2], aL[2], bH[2], bL[2];
        #pragma unroll
        for (int i = 0; i < 2; i++) {
            aH[i] = *(const bf16x8*)&AsH[bufo + aOff[i]];
            aL[i] = *(const bf16x8*)&AsL[bufo + aOff[i]];
            bH[i] = *(const bf16x8*)&BsH[bufo + bOff[i]];
            bL[i] = *(const bf16x8*)&BsL[bufo + bOff[i]];
        }
        #pragma unroll
        for (int i = 0; i < 2; i++)
        #pragma unroll
        for (int j = 0; j < 2; j++) {
            acc[i][j] = __builtin_amdgcn_mfma_f32_16x16x32_bf16(aH[i], bH[j], acc[i][j], 0, 0, 0);
            acc[i][j] = __builtin_amdgcn_mfma_f32_16x16x32_bf16(aH[i], bL[j], acc[i][j], 0, 0, 0);
            acc[i][j] = __builtin_amdgcn_mfma_f32_16x16x32_bf16(aL[i], bH[j], acc[i][j], 0, 0, 0);
        }
        vah = nah; val = nal; vbh = nbh; vbl = nbl;
        bufo ^= 2048;
    }
    #pragma unroll
    for (int i = 0; i < 2; i++)
    #pragma unroll
    for (int j = 0; j < 2; j++)
    #pragma unroll
    for (int r = 0; r < 4; r++) {
        int row = bm + wm + i * 16 + fq * 4 + r;
        int col = bn + wn + j * 16 + fr;
        if (row < M) {
            long off = (long)row * cs_m + (long)col * cs_n;
            float v = acc[i][j][r];
            if (bias) v += bias[col];
            if (Oh) {
                bf16 hh, ll; split2(v, hh, ll);
                Oh[off] = hh; Ol[off] = ll;
            } else {
                if (Rb) v += Rb[off];
                Cb[off] = v;
            }
        }
    }
}

// ---- split-precision MFMA flash SA: dbuf + post-barrier prefetch + setprio ----
__global__ __launch_bounds__(256) void sa_mfma_kernel(
    const bf16* __restrict__ qh, const bf16* __restrict__ ql,
    bf16* __restrict__ oh, bf16* __restrict__ ol) {
    int qt = blockIdx.x, h = blockIdx.y, b = blockIdx.z;
    __shared__ short KsH[2 * 4096], KsL[2 * 4096];
    __shared__ short VtH[2 * 4096], VtL[2 * 4096];
    __shared__ short PHs[4][1024], PLs[4][1024];
    int t = threadIdx.x, lane = t & 63, w = t >> 6;
    int fr = lane & 15, fq = lane >> 4;
    const short* QH = (const short*)qh;
    const short* QL = (const short*)ql;
    long qrow = (long)(b * 1024 + qt * 64 + w * 16 + fr) * 1536 + h * 64;
    bf16x8 Qh2[2], Ql2[2];
    Qh2[0] = *(const bf16x8*)(QH + qrow + fq * 8);
    Qh2[1] = *(const bf16x8*)(QH + qrow + 32 + fq * 8);
    Ql2[0] = *(const bf16x8*)(QL + qrow + fq * 8);
    Ql2[1] = *(const bf16x8*)(QL + qrow + 32 + fq * 8);
    float m_i[4], l_i[4];
    f32x4 o_acc[4] = {};
    #pragma unroll
    for (int i = 0; i < 4; i++) { m_i[i] = -1e30f; l_i[i] = 0.f; }
    int c0 = t, c1 = t + 256;
    int r0 = c0 >> 3, g0 = c0 & 7;
    int r1 = c1 >> 3, g1 = c1 & 7;
    int kd0 = r0 * 64 + ((g0 * 8) ^ ((r0 & 7) << 3));
    int kd1 = r1 * 64 + ((g1 * 8) ^ ((r1 & 7) << 3));
    long kb = (long)(b * 1024) * 1536 + 512 + h * 64;
    long vb = kb + 512;
    long lo0 = (long)r0 * 1536 + g0 * 8, lo1 = (long)r1 * 1536 + g1 * 8;
    short* ph = PHs[w]; short* pl = PLs[w];
    bf16x8 kh0 = *(const bf16x8*)(QH + kb + lo0);
    bf16x8 kh1 = *(const bf16x8*)(QH + kb + lo1);
    bf16x8 kl0 = *(const bf16x8*)(QL + kb + lo0);
    bf16x8 kl1 = *(const bf16x8*)(QL + kb + lo1);
    bf16x8 vh0 = *(const bf16x8*)(QH + vb + lo0);
    bf16x8 vh1 = *(const bf16x8*)(QH + vb + lo1);
    bf16x8 vl0 = *(const bf16x8*)(QL + vb + lo0);
    bf16x8 vl1 = *(const bf16x8*)(QL + vb + lo1);
    int bufo = 0;
    for (int kt = 0; kt < 16; kt++) {
        *(bf16x8*)&KsH[bufo + kd0] = kh0;  *(bf16x8*)&KsH[bufo + kd1] = kh1;
        *(bf16x8*)&KsL[bufo + kd0] = kl0;  *(bf16x8*)&KsL[bufo + kd1] = kl1;
        #pragma unroll
        for (int j = 0; j < 8; j++) {
            int d0 = g0 * 8 + j;
            int i0 = bufo + d0 * 64 + (r0 ^ (((d0 >> 3) & 7) << 3));
            VtH[i0] = ((short*)&vh0)[j];  VtL[i0] = ((short*)&vl0)[j];
            int d1 = g1 * 8 + j;
            int i1 = bufo + d1 * 64 + (r1 ^ (((d1 >> 3) & 7) << 3));
            VtH[i1] = ((short*)&vh1)[j];  VtL[i1] = ((short*)&vl1)[j];
        }
        __syncthreads();
        int ktn = (kt + 1 < 16) ? kt + 1 : kt;
        long ko = kb + (long)(ktn * 64) * 1536;
        long vo = vb + (long)(ktn * 64) * 1536;
        bf16x8 nkh0 = *(const bf16x8*)(QH + ko + lo0);
        bf16x8 nkh1 = *(const bf16x8*)(QH + ko + lo1);
        bf16x8 nkl0 = *(const bf16x8*)(QL + ko + lo0);
        bf16x8 nkl1 = *(const bf16x8*)(QL + ko + lo1);
        bf16x8 nvh0 = *(const bf16x8*)(QH + vo + lo0);
        bf16x8 nvh1 = *(const bf16x8*)(QH + vo + lo1);
        bf16x8 nvl0 = *(const bf16x8*)(QL + vo + lo0);
        bf16x8 nvl1 = *(const bf16x8*)(QL + vo + lo1);
        __builtin_amdgcn_s_setprio(1);
        f32x4 s[4] = {};
        #pragma unroll
        for (int cf = 0; cf < 4; cf++) {
            int kvrow = cf * 16 + fr;
            #pragma unroll
            for (int kf = 0; kf < 2; kf++) {
                int idx = bufo + kvrow * 64 + ((kf * 32 + fq * 8) ^ ((kvrow & 7) << 3));
                bf16x8 Bh2 = *(const bf16x8*)&KsH[idx];
                bf16x8 Bl2 = *(const bf16x8*)&KsL[idx];
                s[cf] = __builtin_amdgcn_mfma_f32_16x16x32_bf16(Qh2[kf], Bh2, s[cf], 0, 0, 0);
                s[cf] = __builtin_amdgcn_mfma_f32_16x16x32_bf16(Qh2[kf], Bl2, s[cf], 0, 0, 0);
                s[cf] = __builtin_amdgcn_mfma_f32_16x16x32_bf16(Ql2[kf], Bh2, s[cf], 0, 0, 0);
            }
        }
        __builtin_amdgcn_s_setprio(0);
        #pragma unroll
        for (int cf = 0; cf < 4; cf++)
        #pragma unroll
        for (int reg = 0; reg < 4; reg++) s[cf][reg] *= 0.125f;
        float sc_[4];
        #pragma unroll
        for (int reg = 0; reg < 4; reg++) {
            float mx = fmaxf(fmaxf(s[0][reg], s[1][reg]), fmaxf(s[2][reg], s[3][reg]));
            mx = fmaxf(mx, __shfl_xor(mx, 1));
            mx = fmaxf(mx, __shfl_xor(mx, 2));
            mx = fmaxf(mx, __shfl_xor(mx, 4));
            mx = fmaxf(mx, __shfl_xor(mx, 8));
            float mn = fmaxf(m_i[reg], mx);
            sc_[reg] = __expf(m_i[reg] - mn);
            m_i[reg] = mn;
            float rs = 0.f;
            #pragma unroll
            for (int cf = 0; cf < 4; cf++) { s[cf][reg] = __expf(s[cf][reg] - mn); rs += s[cf][reg]; }
            rs += __shfl_xor(rs, 1);
            rs += __shfl_xor(rs, 2);
            rs += __shfl_xor(rs, 4);
            rs += __shfl_xor(rs, 8);
            l_i[reg] = l_i[reg] * sc_[reg] + rs;
        }
        #pragma unroll
        for (int cf = 0; cf < 4; cf++)
        #pragma unroll
        for (int reg = 0; reg < 4; reg++) o_acc[cf][reg] *= sc_[reg];
        #pragma unroll
        for (int cf = 0; cf < 4; cf++)
        #pragma unroll
        for (int reg = 0; reg < 4; reg++) {
            int q = fq * 4 + reg, kv = cf * 16 + fr;
            int idx = q * 64 + (kv ^ ((q & 7) << 3));
            split2s(s[cf][reg], ph[idx], pl[idx]);
        }
        asm volatile("s_waitcnt lgkmcnt(0)" ::: "memory");
        __builtin_amdgcn_sched_barrier(0);
        __builtin_amdgcn_s_setprio(1);
        bf16x8 Pf_h[2], Pf_l[2];
        #pragma unroll
        for (int kf = 0; kf < 2; kf++) {
            int idx = fr * 64 + ((kf * 32 + fq * 8) ^ ((fr & 7) << 3));
            Pf_h[kf] = *(const bf16x8*)&ph[idx];
            Pf_l[kf] = *(const bf16x8*)&pl[idx];
        }
        #pragma unroll
        for (int cf = 0; cf < 4; cf++) {
            int d = cf * 16 + fr;
            #pragma unroll
            for (int kf = 0; kf < 2; kf++) {
                int idx = bufo + d * 64 + ((kf * 32 + fq * 8) ^ (((d >> 3) & 7) << 3));
                bf16x8 Vh2 = *(const bf16x8*)&VtH[idx];
                bf16x8 Vl2 = *(const bf16x8*)&VtL[idx];
                o_acc[cf] = __builtin_amdgcn_mfma_f32_16x16x32_bf16(Pf_h[kf], Vh2, o_acc[cf], 0, 0, 0);
                o_acc[cf] = __builtin_amdgcn_mfma_f32_16x16x32_bf16(Pf_h[kf], Vl2, o_acc[cf], 0, 0, 0);
                o_acc[cf] = __builtin_amdgcn_mfma_f32_16x16x32_bf16(Pf_l[kf], Vh2, o_acc[cf], 0, 0, 0);
            }
        }
        __builtin_amdgcn_s_setprio(0);
        kh0 = nkh0; kh1 = nkh1; kl0 = nkl0; kl1 = nkl1;
        vh0 = nvh0; vh1 = nvh1; vl0 = nvl0; vl1 = nvl1;
        bufo ^= 4096;
    }
    #pragma unroll
    for (int reg = 0; reg < 4; reg++) {
        float inv = 1.f / l_i[reg];
        long m = (long)(b * 1024 + qt * 64 + w * 16 + fq * 4 + reg);
        #pragma unroll
        for (int cf = 0; cf < 4; cf++) {
            float v = o_acc[cf][reg] * inv;
            bf16 hh, ll; split2(v, hh, ll);
            long off = m * DIMC + h * 64 + cf * 16 + fr;
            oh[off] = hh; ol[off] = ll;
        }
    }
}

// ---- split-precision MFMA cross-attention: 77 keys padded to 96, single tile ----
__global__ __launch_bounds__(256) void ca_mfma_kernel(
    const bf16* __restrict__ qh, const bf16* __restrict__ ql,
    const bf16* __restrict__ kvh, const bf16* __restrict__ kvl,
    bf16* __restrict__ oh, bf16* __restrict__ ol) {
    int qt = blockIdx.x, h = blockIdx.y, b = blockIdx.z;
    __shared__ short UH[8192], UL[8192];
    __shared__ short PHs[4][2048], PLs[4][2048];
    int t = threadIdx.x, lane = t & 63, w = t >> 6;
    int fr = lane & 15, fq = lane >> 4;
    const short* QH = (const short*)qh;
    const short* QL = (const short*)ql;
    const short* KVH = (const short*)kvh;
    const short* KVL = (const short*)kvl;
    long qrow = (long)(b * 1024 + qt * 64 + w * 16 + fr) * DIMC + h * 64;
    bf16x8 Qh2[2], Ql2[2];
    Qh2[0] = *(const bf16x8*)(QH + qrow + fq * 8);
    Qh2[1] = *(const bf16x8*)(QH + qrow + 32 + fq * 8);
    Ql2[0] = *(const bf16x8*)(QL + qrow + fq * 8);
    Ql2[1] = *(const bf16x8*)(QL + qrow + 32 + fq * 8);
    for (int c = t; c < 768; c += 256) {
        int r = c >> 3, g = c & 7;
        int idx = r * 64 + ((g * 8) ^ ((r & 7) << 3));
        bf16x8 vh = {}, vl = {};
        if (r < 77) {
            long src = (long)(b * 77 + r) * 1024 + h * 64 + g * 8;
            vh = *(const bf16x8*)(KVH + src);
            vl = *(const bf16x8*)(KVL + src);
        }
        *(bf16x8*)&UH[idx] = vh;
        *(bf16x8*)&UL[idx] = vl;
    }
    __syncthreads();
    f32x4 s[5] = {};
    #pragma unroll
    for (int cf = 0; cf < 5; cf++) {
        int kvrow = cf * 16 + fr;
        #pragma unroll
        for (int kf = 0; kf < 2; kf++) {
            int idx = kvrow * 64 + ((kf * 32 + fq * 8) ^ ((kvrow & 7) << 3));
            bf16x8 Bh2 = *(const bf16x8*)&UH[idx];
            bf16x8 Bl2 = *(const bf16x8*)&UL[idx];
            s[cf] = __builtin_amdgcn_mfma_f32_16x16x32_bf16(Qh2[kf], Bh2, s[cf], 0, 0, 0);
            s[cf] = __builtin_amdgcn_mfma_f32_16x16x32_bf16(Qh2[kf], Bl2, s[cf], 0, 0, 0);
            s[cf] = __builtin_amdgcn_mfma_f32_16x16x32_bf16(Ql2[kf], Bh2, s[cf], 0, 0, 0);
        }
    }
    #pragma unroll
    for (int cf = 0; cf < 5; cf++) {
        int kv = cf * 16 + fr;
        #pragma unroll
        for (int reg = 0; reg < 4; reg++)
            s[cf][reg] = (kv < 77) ? s[cf][reg] * 0.125f : -1e30f;
    }
    float inv[4];
    #pragma unroll
    for (int reg = 0; reg < 4; reg++) {
        float mx = s[0][reg];
        #pragma unroll
        for (int cf = 1; cf < 5; cf++) mx = fmaxf(mx, s[cf][reg]);
        mx = fmaxf(mx, __shfl_xor(mx, 1));
        mx = fmaxf(mx, __shfl_xor(mx, 2));
        mx = fmaxf(mx, __shfl_xor(mx, 4));
        mx = fmaxf(mx, __shfl_xor(mx, 8));
        float rs = 0.f;
        #pragma unroll
        for (int cf = 0; cf < 5; cf++) { s[cf][reg] = __expf(s[cf][reg] - mx); rs += s[cf][reg]; }
        rs += __shfl_xor(rs, 1);
        rs += __shfl_xor(rs, 2);
        rs += __shfl_xor(rs, 4);
        rs += __shfl_xor(rs, 8);
        inv[reg] = 1.f / rs;
    }
    short* ph = PHs[w]; short* pl = PLs[w];
    #pragma unroll
    for (int cf = 0; cf < 6; cf++)
    #pragma unroll
    for (int reg = 0; reg < 4; reg++) {
        int q = fq * 4 + reg, kv = cf * 16 + fr;
        int idx = q * 128 + (kv ^ ((q & 7) << 3));
        float pv = (cf < 5) ? s[cf][reg] * inv[reg] : 0.f;
        split2s(pv, ph[idx], pl[idx]);
    }
    __syncthreads();
    for (int c = t; c < 768; c += 256) {
        int r = c >> 3, g = c & 7;
        bf16x8 vh = {}, vl = {};
        if (r < 77) {
            long src = (long)(b * 77 + r) * 1024 + 512 + h * 64 + g * 8;
            vh = *(const bf16x8*)(KVH + src);
            vl = *(const bf16x8*)(KVL + src);
        }
        #pragma unroll
        for (int j = 0; j < 8; j++) {
            int d = g * 8 + j;
            int idx = d * 128 + (r ^ (((d >> 3) & 7) << 3));
            UH[idx] = ((short*)&vh)[j];
            UL[idx] = ((short*)&vl)[j];
        }
    }
    __syncthreads();
    f32x4 o_acc[4] = {};
    bf16x8 Pf_h[3], Pf_l[3];
    #pragma unroll
    for (int kf = 0; kf < 3; kf++) {
        int idx = fr * 128 + ((kf * 32 + fq * 8) ^ ((fr & 7) << 3));
        Pf_h[kf] = *(const bf16x8*)&ph[idx];
        Pf_l[kf] = *(const bf16x8*)&pl[idx];
    }
    #pragma unroll
    for (int cf = 0; cf < 4; cf++) {
        int d = cf * 16 + fr;
        #pragma unroll
        for (int kf = 0; kf < 3; kf++) {
            int idx = d * 128 + ((kf * 32 + fq * 8) ^ (((d >> 3) & 7) << 3));
            bf16x8 Vh2 = *(const bf16x8*)&UH[idx];
            bf16x8 Vl2 = *(const bf16x8*)&UL[idx];
            o_acc[cf] = __builtin_amdgcn_mfma_f32_16x16x32_bf16(Pf_h[kf], Vh2, o_acc[cf], 0, 0, 0);
            o_acc[cf] = __builtin_amdgcn_mfma_f32_16x16x32_bf16(Pf_h[kf], Vl2, o_acc[cf], 0, 0, 0);
            o_acc[cf] = __builtin_amdgcn_mfma_f32_16x16x32_bf16(Pf_l[kf], Vh2, o_acc[cf], 0, 0, 0);
        }
    }
    #pragma unroll
    for (int reg = 0; reg < 4; reg++) {
        long m = (long)(b * 1024 + qt * 64 + w * 16 + fq * 4 + reg);
        #pragma unroll
        for (int cf = 0; cf < 4; cf++) {
            bf16 hh, ll; split2(o_acc[cf][reg], hh, ll);
            long off = m * DIMC + h * 64 + cf * 16 + fr;
            oh[off] = hh; ol[off] = ll;
        }
    }
}

// ---- MoE grouped MFMA GEMM1, 64x64 tile: hid = gelu(xn·w1 + b1), K=512 ----
__global__ __launch_bounds__(256) void moe64_1_kernel(
    const bf16* __restrict__ xn_b, const bf16* __restrict__ e1T, const float* __restrict__ e_b1,
    const int* __restrict__ table, const int* __restrict__ ntiles, const int* __restrict__ perm,
    bf16* __restrict__ hid_b) {
    if (blockIdx.y >= ntiles[0]) return;
    int e = table[2 * blockIdx.y], row0 = table[2 * blockIdx.y + 1];
    int bn = blockIdx.x * 64;
    __shared__ short As[2 * 2048];
    __shared__ short Bs[2 * 2048];
    __shared__ int rowsS[64];
    int t = threadIdx.x, lane = t & 63, w = t >> 6;
    if (t < 64) rowsS[t] = perm[row0 + t];
    __syncthreads();
    int wm = (w >> 1) * 32, wn = (w & 1) * 32;
    int r0 = t >> 2, k0s = (t & 3) ^ ((r0 >> 1) & 3);
    int tok0 = rowsS[r0]; if (tok0 < 0) tok0 = 0;
    const short* Xs = (const short*)xn_b;
    const short* Ws = (const short*)(e1T + (long)e * HIDC * DIMC);
    const short* a0 = Xs + (long)tok0 * DIMC + k0s * 8;
    const short* b0 = Ws + (long)(bn + r0) * DIMC + k0s * 8;
    int fr = lane & 15, fq = lane >> 4;
    int aOff[2], bOff[2];
    #pragma unroll
    for (int i = 0; i < 2; i++) {
        int row = wm + i * 16 + fr;
        aOff[i] = row * 32 + ((fq ^ ((row >> 1) & 3)) * 8);
        int col = wn + i * 16 + fr;
        bOff[i] = col * 32 + ((fq ^ ((col >> 1) & 3)) * 8);
    }
    f32x4 acc[2][2] = {};
    bf16x8 va = *(const bf16x8*)(a0);
    bf16x8 vb = *(const bf16x8*)(b0);
    int bufo = 0;
    for (int kk = 0; kk < DIMC; kk += 32) {
        *(bf16x8*)&As[bufo + t * 8] = va;
        *(bf16x8*)&Bs[bufo + t * 8] = vb;
        __syncthreads();
        int kn = (kk + 32 < DIMC) ? kk + 32 : kk;
        bf16x8 na = *(const bf16x8*)(a0 + kn);
        bf16x8 nb = *(const bf16x8*)(b0 + kn);
        bf16x8 aF[2], bF[2];
        #pragma unroll
        for (int i = 0; i < 2; i++) {
            aF[i] = *(const bf16x8*)&As[bufo + aOff[i]];
            bF[i] = *(const bf16x8*)&Bs[bufo + bOff[i]];
        }
        #pragma unroll
        for (int i = 0; i < 2; i++)
        #pragma unroll
        for (int j = 0; j < 2; j++)
            acc[i][j] = __builtin_amdgcn_mfma_f32_16x16x32_bf16(aF[i], bF[j], acc[i][j], 0, 0, 0);
        va = na; vb = nb;
        bufo ^= 2048;
    }
    const float* bb = e_b1 + (long)e * HIDC;
    #pragma unroll
    for (int i = 0; i < 2; i++)
    #pragma unroll
    for (int r = 0; r < 4; r++) {
        int tok = rowsS[wm + i * 16 + fq * 4 + r];
        if (tok < 0) continue;
        #pragma unroll
        for (int j = 0; j < 2; j++) {
            int col = bn + wn + j * 16 + fr;
            float v = acc[i][j][r] + bb[col];
            v = 0.5f * v * (1.f + erff(v * 0.70710678f));
            hid_b[(long)tok * HIDC + col] = __float2bfloat16(v);
        }
    }
}

// ---- MoE grouped MFMA GEMM2, 64x64 tile: out = resid + hid·w2 + b2 -> split bf16 ----
__global__ __launch_bounds__(256) void moe64_2_kernel(
    const bf16* __restrict__ hid_b, const bf16* __restrict__ e2T, const float* __restrict__ e_b2,
    const int* __restrict__ table, const int* __restrict__ ntiles, const int* __restrict__ perm,
    const float* __restrict__ resid, bf16* __restrict__ outh, bf16* __restrict__ outl) {
    if (blockIdx.y >= ntiles[0]) return;
    int e = table[2 * blockIdx.y], row0 = table[2 * blockIdx.y + 1];
    int bn = blockIdx.x * 64;
    __shared__ short As[2 * 2048];
    __shared__ short Bs[2 * 2048];
    __shared__ int rowsS[64];
    int t = threadIdx.x, lane = t & 63, w = t >> 6;
    if (t < 64) rowsS[t] = perm[row0 + t];
    __syncthreads();
    int wm = (w >> 1) * 32, wn = (w & 1) * 32;
    int r0 = t >> 2, k0s = (t & 3) ^ ((r0 >> 1) & 3);
    int tok0 = rowsS[r0]; if (tok0 < 0) tok0 = 0;
    const short* Hs = (const short*)hid_b;
    const short* Ws = (const short*)(e2T + (long)e * DIMC * HIDC);
    const short* a0 = Hs + (long)tok0 * HIDC + k0s * 8;
    const short* b0 = Ws + (long)(bn + r0) * HIDC + k0s * 8;
    int fr = lane & 15, fq = lane >> 4;
    int aOff[2], bOff[2];
    #pragma unroll
    for (int i = 0; i < 2; i++) {
        int row = wm + i * 16 + fr;
        aOff[i] = row * 32 + ((fq ^ ((row >> 1) & 3)) * 8);
        int col = wn + i * 16 + fr;
        bOff[i] = col * 32 + ((fq ^ ((col >> 1) & 3)) * 8);
    }
    f32x4 acc[2][2] = {};
    bf16x8 va = *(const bf16x8*)(a0);
    bf16x8 vb = *(const bf16x8*)(b0);
    int bufo = 0;
    for (int kk = 0; kk < HIDC; kk += 32) {
        *(bf16x8*)&As[bufo + t * 8] = va;
        *(bf16x8*)&Bs[bufo + t * 8] = vb;
        __syncthreads();
        int kn = (kk + 32 < HIDC) ? kk + 32 : kk;
        bf16x8 na = *(const bf16x8*)(a0 + kn);
        bf16x8 nb = *(const bf16x8*)(b0 + kn);
        bf16x8 aF[2], bF[2];
        #pragma unroll
        for (int i = 0; i < 2; i++) {
            aF[i] = *(const bf16x8*)&As[bufo + aOff[i]];
            bF[i] = *(const bf16x8*)&Bs[bufo + bOff[i]];
        }
        #pragma unroll
        for (int i = 0; i < 2; i++)
        #pragma unroll
        for (int j = 0; j < 2; j++)
            acc[i][j] = __builtin_amdgcn_mfma_f32_16x16x32_bf16(aF[i], bF[j], acc[i][j], 0, 0, 0);
        va = na; vb = nb;
        bufo ^= 2048;
    }
    const float* bb = e_b2 + (long)e * DIMC;
    #pragma unroll
    for (int i = 0; i < 2; i++)
    #pragma unroll
    for (int r = 0; r < 4; r++) {
        int tok = rowsS[wm + i * 16 + fq * 4 + r];
        if (tok < 0) continue;
        #pragma unroll
        for (int j = 0; j < 2; j++) {
            int col = bn + wn + j * 16 + fr;
            long off = (long)tok * DIMC + col;
            float v = resid[off] + acc[i][j][r] + bb[col];
            bf16 hh, ll; split2(v, hh, ll);
            outh[off] = hh; outl[off] = ll;
        }
    }
}

// ---------------- LayerNorm: optional fp32 + bf16 hi/lo outputs ----------------
__global__ void ln_kernel(const float* __restrict__ x, const float* __restrict__ g,
                          const float* __restrict__ b, float* __restrict__ y,
                          bf16* __restrict__ yh, bf16* __restrict__ yl) {
    int tok = blockIdx.x;
    int t = threadIdx.x;
    const float* xr = x + (long)tok * DIMC;
    float v0 = xr[t], v1 = xr[t + 256];
    __shared__ float red[256];
    red[t] = v0 + v1; __syncthreads();
    for (int s = 128; s > 0; s >>= 1) { if (t < s) red[t] += red[t + s]; __syncthreads(); }
    float mu = red[0] * (1.f / DIMC);
    __syncthreads();
    float d0 = v0 - mu, d1 = v1 - mu;
    red[t] = d0 * d0 + d1 * d1; __syncthreads();
    for (int s = 128; s > 0; s >>= 1) { if (t < s) red[t] += red[t + s]; __syncthreads(); }
    float rs = rsqrtf(red[0] * (1.f / DIMC) + 1e-5f);
    float o0 = d0 * rs * g[t] + b[t];
    float o1 = d1 * rs * g[t + 256] + b[t + 256];
    if (y) { y[(long)tok * DIMC + t] = o0; y[(long)tok * DIMC + t + 256] = o1; }
    bf16 h, l;
    split2(o0, h, l); yh[(long)tok * DIMC + t] = h;       yl[(long)tok * DIMC + t] = l;
    split2(o1, h, l); yh[(long)tok * DIMC + t + 256] = h; yl[(long)tok * DIMC + t + 256] = l;
}

// ---------------- router text part (+ cnt zeroing) ----------------
__global__ void textpart_kernel(const float* __restrict__ w, const float* __restrict__ r_text_mu,
                                const float* __restrict__ r_comb_mu, float* __restrict__ tp,
                                int* __restrict__ cnt) {
    __shared__ float tw[4][128];
    int t = threadIdx.x;
    if (t < NE) cnt[t] = 0;
    for (int j = 0; j < 2; j++) {
        int idx = t + j * 256; int b = idx >> 7, c = idx & 127;
        const float* wr = w + (long)b * LATC;
        float s = 0.f;
        for (int k = 0; k < LATC; k++) s += wr[k] * r_text_mu[(long)k * 128 + c];
        tw[b][c] = s;
    }
    __syncthreads();
    if (t < 32) {
        int b = t >> 3, e = t & 7;
        float s = 0.f;
        for (int c = 0; c < 128; c++) s += tw[b][c] * r_comb_mu[(long)(128 + c) * 8 + e];
        tp[t] = s;
    }
}

// ---------------- router: perm poison + logits + argmax ----------------
__global__ void route_kernel(const float* __restrict__ feat, const float* __restrict__ tp,
                             const float* __restrict__ r_comb_mu, const float* __restrict__ r_temp,
                             float* __restrict__ onehot, int* __restrict__ idx, int* __restrict__ cnt,
                             int* __restrict__ perm) {
    int n = blockIdx.x * blockDim.x + threadIdx.x;
    if (n < MAXT * 64) perm[n] = -1;
    if (n >= NTOK) return;
    int b = n >> 10;
    float tmp = fmaxf(r_temp[0], 0.1f);
    float invt = 1.f / tmp;
    const float* fr = feat + (long)n * 128;
    float lg[8];
    for (int e = 0; e < 8; e++) {
        float s = 0.f;
        for (int c = 0; c < 128; c++) s += fr[c] * r_comb_mu[(long)c * 8 + e];
        lg[e] = (s + tp[b * 8 + e]) * invt;
    }
    float best = lg[0]; int bi = 0;
    for (int e = 1; e < 8; e++) { if (lg[e] > best) { best = lg[e]; bi = e; } }
    for (int e = 0; e < 8; e++) onehot[(long)n * 8 + e] = (e == bi) ? 1.f : 0.f;
    idx[n] = bi;
    atomicAdd(&cnt[bi], 1);
}

__global__ void offsets_kernel(const int* __restrict__ cnt, int* __restrict__ cursor,
                               int* __restrict__ ntiles, int* __restrict__ table) {
    if (threadIdx.x != 0) return;
    int po = 0, nt = 0;
    for (int e = 0; e < NE; e++) {
        cursor[e] = po;
        int tiles = (cnt[e] + 63) >> 6;
        for (int j = 0; j < tiles; j++) { table[2 * nt] = e; table[2 * nt + 1] = po + j * 64; nt++; }
        po += tiles * 64;
    }
    ntiles[0] = nt;
}

__global__ void scatter_kernel(const int* __restrict__ idx, int* __restrict__ cursor,
                               int* __restrict__ perm) {
    int n = blockIdx.x * blockDim.x + threadIdx.x;
    if (n >= NTOK) return;
    int e = idx[n];
    int pos = atomicAdd(&cursor[e], 1);
    perm[pos] = n;
}

extern "C" void kernel_launch(void* const* d_in, const int* in_sizes, int n_in,
                              void* d_out, int out_size, void* d_ws, size_t ws_size,
                              hipStream_t stream) {
    const float* x        = (const float*)d_in[0];
    const float* w        = (const float*)d_in[1];
    const float* text     = (const float*)d_in[2];
    const float* pin_w    = (const float*)d_in[3];
    const float* pin_mw   = (const float*)d_in[4];
    const float* pin_mb   = (const float*)d_in[5];
    const float* pout_w   = (const float*)d_in[6];
    const float* pout_mw  = (const float*)d_in[7];
    const float* pout_mb  = (const float*)d_in[8];
    const float* ln1g     = (const float*)d_in[9];
    const float* ln1b     = (const float*)d_in[10];
    const float* ln2g     = (const float*)d_in[11];
    const float* ln2b     = (const float*)d_in[12];
    const float* ln3g     = (const float*)d_in[13];
    const float* ln3b     = (const float*)d_in[14];
    const float* sa_in_w  = (const float*)d_in[15];
    const float* sa_in_b  = (const float*)d_in[16];
    const float* sa_out_w = (const float*)d_in[17];
    const float* sa_out_b = (const float*)d_in[18];
    const float* ca_in_w  = (const float*)d_in[19];
    const float* ca_in_b  = (const float*)d_in[20];
    const float* ca_out_w = (const float*)d_in[21];
    const float* ca_out_b = (const float*)d_in[22];
    const float* r_feat   = (const float*)d_in[23];
    const float* r_text   = (const float*)d_in[24];
    const float* r_comb   = (const float*)d_in[25];
    const float* r_temp   = (const float*)d_in[26];
    const float* e_w1     = (const float*)d_in[27];
    const float* e_b1     = (const float*)d_in[28];
    const float* e_w2     = (const float*)d_in[29];
    const float* e_b2     = (const float*)d_in[30];

    float* out    = (float*)d_out;               // [B, DIM, H, W]
    float* onehot = out + (long)BB * DIMC * HWX; // [4096, 8]

    // ---------------- workspace: fp32 pool ----------------
    float* f32p = (float*)d_ws;
    float* style_in  = f32p;                 // 2048
    float* style_out = f32p + 2048;          // 2048
    float* tp        = f32p + 4096;          // 32
    int*   idx       = (int*)(f32p + 4128);  // 4096
    int*   cnt       = (int*)(f32p + 8224);  // 8
    int*   cursor    = (int*)(f32p + 8232);  // 8
    int*   ntiles    = (int*)(f32p + 8240);  // 8
    int*   table     = (int*)(f32p + 8248);  // 256
    int*   perm      = (int*)(f32p + 8504);  // 4608 -> ends 13112
    float* x_flat    = f32p + 13496;         // 2097152
    float* xn        = x_flat + 2097152;     // 2097152 (home of wtC split now)
    float* qkv       = xn + 2097152;         // 6291456 (SA q split / CA q split home)
    float* spill     = qkv + 6291456;        // 2097152 (e2T tail)

    // ---------------- bf16 pool (phase-aliased) ----------------
    bf16* bp = (bf16*)(f32p + 12596408);
    bf16* R1 = bp;                           // 6291456 elems, phases
    bf16* xT_h  = R1;
    bf16* xT_l  = R1 + 2097152;
    bf16* wtA_h = R1 + 4194304;
    bf16* wtA_l = R1 + 5242880;
    bf16* obuf_h = R1;
    bf16* obuf_l = R1 + 2097152;
    bf16* kvt_h  = R1 + 4194304;                       // [308][1024] split
    bf16* kvt_l  = kvt_h + 315392;
    float* feat  = (float*)(kvt_l + 315392);           // 524288 fp32
    bf16* xn_h = R1 + 6291456;               // 2097152
    bf16* xn_l = xn_h + 2097152;             // 2097152
    bf16* WB   = xn_l + 2097152;             // 8388608: weights (early) / hid_b (late)
    bf16* text_h   = WB;
    bf16* text_l   = text_h + 157696;
    bf16* sawin_h  = text_l + 157696;
    bf16* sawin_l  = sawin_h + 786432;
    bf16* sawout_h = sawin_l + 786432;
    bf16* sawout_l = sawout_h + 262144;
    bf16* caw_h    = sawout_l + 262144;
    bf16* caw_l    = caw_h + 786432;
    bf16* cawout_h = caw_l + 786432;
    bf16* cawout_l = cawout_h + 262144;
    bf16* rfT_h    = cawout_l + 262144;      // [128][512] split r_feat^T
    bf16* rfT_l    = rfT_h + 65536;
    bf16* hid_b    = WB;                     // overlays weights after ca_out
    bf16* e1T = (bf16*)qkv;                  // [8][2048][512] in qkv+spill
    bf16* e2T = e1T + 8388608;
    bf16* xfl_h = xn_h;                      // moe64_2 writes split output here
    bf16* xfl_l = xn_l;
    bf16* wtC_h = (bf16*)xn;                 // modconv-out weight (dead fp32 region)
    bf16* wtC_l = wtC_h + 1048576;
    bf16* q_h = (bf16*)qkv;                  // [4096][1536]
    bf16* q_l = q_h + 6291456;
    bf16* ca_qh = (bf16*)qkv;                // [4096][512]
    bf16* ca_ql = ca_qh + 2097152;
    (void)ws_size; (void)spill;

    auto mg = [&](const bf16* Ah, const bf16* Al, const bf16* Bh, const bf16* Bl,
                  const float* bias, const float* resid, float* C, bf16* Oh, bf16* Ol,
                  int M, int N, int K, long ab, long bb, long cb, int csm, int csn, int nb) {
        dim3 g(N / 64, (M + 63) / 64, nb);
        hipLaunchKernelGGL(mgemm64_kernel, g, dim3(256), 0, stream,
                           Ah, Al, Bh, Bl, bias, resid, C, Oh, Ol, M, N, K, ab, bb, cb, csm, csn);
    };
    auto cvt2 = [&](const float* in, bf16* h2, bf16* l2, int n) {
        hipLaunchKernelGGL(cvt2_kernel, dim3((n / 4 + 255) / 256), dim3(256), 0, stream, in, h2, l2, n);
    };

    // ---- input conversions (hi/lo) ----
    cvt2(sa_in_w, sawin_h, sawin_l, 1536 * 512);
    cvt2(sa_out_w, sawout_h, sawout_l, 512 * 512);
    cvt2(ca_in_w, caw_h, caw_l, 1536 * 512);
    cvt2(ca_out_w, cawout_h, cawout_l, 512 * 512);
    cvt2(text, text_h, text_l, BB * TXT * 512);
    hipLaunchKernelGGL(trcvt2_kernel, dim3(32, 16, BB), dim3(256), 0, stream,
                       x, xT_h, xT_l, 512, 1024, (long)512 * 1024, (long)1024 * 512);
    hipLaunchKernelGGL(trcvt2_kernel, dim3(4, 16, 1), dim3(256), 0, stream,
                       r_feat, rfT_h, rfT_l, 512, 128, 0L, 0L);

    // ---- both modconv styles + weights up front (wtC in dead xn region) ----
    hipLaunchKernelGGL(style2_kernel, dim3(16), dim3(256), 0, stream,
                       w, pin_mw, pin_mb, pout_mw, pout_mb, style_in, style_out);
    hipLaunchKernelGGL(wtmod2_kernel, dim3(2 * BB * DIMC), dim3(256), 0, stream,
                       pin_w, style_in, pout_w, style_out, wtA_h, wtA_l, wtC_h, wtC_l);

    // ---- modconv in ----
    mg(xT_h, xT_l, wtA_h, wtA_l, nullptr, nullptr, x_flat, nullptr, nullptr,
       HWX, DIMC, DIMC, (long)HWX * DIMC, (long)DIMC * DIMC, (long)HWX * DIMC, DIMC, 1, BB);

    // ---- LN1 + self-attention (split MFMA) ----
    hipLaunchKernelGGL(ln_kernel, dim3(NTOK), dim3(256), 0, stream, x_flat, ln1g, ln1b,
                       (float*)nullptr, xn_h, xn_l);
    mg(xn_h, xn_l, sawin_h, sawin_l, sa_in_b, nullptr, nullptr, q_h, q_l,
       NTOK, 1536, 512, 0, 0, 0, 1536, 1, 1);
    hipLaunchKernelGGL(sa_mfma_kernel, dim3(16, HEADS, BB), dim3(256), 0, stream,
                       q_h, q_l, obuf_h, obuf_l);
    mg(obuf_h, obuf_l, sawout_h, sawout_l, sa_out_b, x_flat, x_flat, nullptr, nullptr,
       NTOK, 512, 512, 0, 0, 0, 512, 1, 1);

    // ---- LN2 + cross-attention (split MFMA) ----
    hipLaunchKernelGGL(ln_kernel, dim3(NTOK), dim3(256), 0, stream, x_flat, ln2g, ln2b,
                       (float*)nullptr, xn_h, xn_l);
    mg(xn_h, xn_l, caw_h, caw_l, ca_in_b, nullptr, nullptr, ca_qh, ca_ql,
       NTOK, 512, 512, 0, 0, 0, 512, 1, 1);
    mg(text_h, text_l, caw_h + 512 * 512, caw_l + 512 * 512, ca_in_b + 512, nullptr, nullptr,
       kvt_h, kvt_l, BB * TXT, 1024, 512, 0, 0, 0, 1024, 1, 1);
    hipLaunchKernelGGL(ca_mfma_kernel, dim3(16, HEADS, BB), dim3(256), 0, stream,
                       ca_qh, ca_ql, kvt_h, kvt_l, obuf_h, obuf_l);
    hipLaunchKernelGGL(trcvt_kernel, dim3(64, 16, NE), dim3(256), 0, stream,
                       e_w1, e1T, 512, 2048, (long)512 * 2048, (long)2048 * 512);
    hipLaunchKernelGGL(trcvt_kernel, dim3(16, 64, NE), dim3(256), 0, stream,
                       e_w2, e2T, 2048, 512, (long)2048 * 512, (long)512 * 2048);
    mg(obuf_h, obuf_l, cawout_h, cawout_l, ca_out_b, x_flat, x_flat, nullptr, nullptr,
       NTOK, 512, 512, 0, 0, 0, 512, 1, 1);

    // ---- LN3 + router (feat via split MFMA) ----
    hipLaunchKernelGGL(ln_kernel, dim3(NTOK), dim3(256), 0, stream, x_flat, ln3g, ln3b,
                       (float*)nullptr, xn_h, xn_l);
    mg(xn_h, xn_l, rfT_h, rfT_l, nullptr, nullptr, feat, nullptr, nullptr,
       NTOK, 128, 512, 0, 0, 0, 128, 1, 1);
    hipLaunchKernelGGL(textpart_kernel, dim3(1), dim3(256), 0, stream, w, r_text, r_comb, tp, cnt);
    hipLaunchKernelGGL(route_kernel, dim3(18), dim3(256), 0, stream,
                       feat, tp, r_comb, r_temp, onehot, idx, cnt, perm);
    hipLaunchKernelGGL(offsets_kernel, dim3(1), dim3(64), 0, stream, cnt, cursor, ntiles, table);
    hipLaunchKernelGGL(scatter_kernel, dim3(16), dim3(256), 0, stream, idx, cursor, perm);

    // ---- MoE grouped MFMA GEMMs (64x64 tiles; gemm2 emits split bf16 directly) ----
    hipLaunchKernelGGL(moe64_1_kernel, dim3(HIDC / 64, MAXT), dim3(256), 0, stream,
                       xn_h, e1T, e_b1, table, ntiles, perm, hid_b);
    hipLaunchKernelGGL(moe64_2_kernel, dim3(DIMC / 64, MAXT), dim3(256), 0, stream,
                       hid_b, e2T, e_b2, table, ntiles, perm, x_flat, xfl_h, xfl_l);

    // ---- modconv out (weights already prepared) ----
    mg(wtC_h, wtC_l, xfl_h, xfl_l, nullptr, nullptr, out, nullptr, nullptr,
       DIMC, HWX, DIMC, (long)DIMC * DIMC, (long)HWX * DIMC, (long)DIMC * HWX, HWX, 1, BB);
}

// Round 15
// 522.909 us; speedup vs baseline: 1.3774x; 1.0603x over previous
//
#include <hip/hip_runtime.h>
#include <hip/hip_bf16.h>
#include <math.h>

#define DIMC 512
#define HEADS 8
#define HD 64
#define BB 4
#define HWX 1024
#define TXT 77
#define LATC 512
#define NE 8
#define HIDC 2048
#define NTOK 4096
#define MAXT 72           // MoE tiles of 64: 4096/64 + 8

typedef __attribute__((ext_vector_type(8))) short bf16x8;
typedef __attribute__((ext_vector_type(4))) float f32x4;
typedef __hip_bfloat16 bf16;

__device__ __forceinline__ void split2(float v, bf16& h, bf16& l) {
    h = __float2bfloat16(v);
    l = __float2bfloat16(v - __bfloat162float(h));
}
__device__ __forceinline__ void split2s(float v, short& h, short& l) {
    bf16 hb, lb; split2(v, hb, lb);
    h = *(short*)&hb; l = *(short*)&lb;
}

// ---------------- both styles in one launch: job 0 = in, job 1 = out ----------------
__global__ void style2_kernel(const float* __restrict__ w,
                              const float* __restrict__ mwA, const float* __restrict__ mbA,
                              const float* __restrict__ mwB, const float* __restrict__ mbB,
                              float* __restrict__ sA, float* __restrict__ sB) {
    int g = blockIdx.x * blockDim.x + threadIdx.x;
    int job = (g >= BB * DIMC) ? 1 : 0;
    int t = g - job * BB * DIMC;
    if (t >= BB * DIMC) return;
    const float* mw = job ? mwB : mwA;
    const float* mb = job ? mbB : mbA;
    float* st = job ? sB : sA;
    int b = t / DIMC, i = t % DIMC;
    const float* wr = w + (long)b * LATC;
    const float* mr = mw + (long)i * LATC;
    float s = 0.f;
    #pragma unroll 8
    for (int l = 0; l < LATC; l++) s += wr[l] * mr[l];
    st[t] = s + mb[i];
}

// ------- both wtmods in one launch -------
__global__ void wtmod2_kernel(const float* __restrict__ wA, const float* __restrict__ sA,
                              const float* __restrict__ wB, const float* __restrict__ sB,
                              bf16* __restrict__ whA, bf16* __restrict__ wlA,
                              bf16* __restrict__ whB, bf16* __restrict__ wlB) {
    int gb = blockIdx.x;
    int job = (gb >= BB * DIMC) ? 1 : 0;
    int bo = gb - job * BB * DIMC;
    const float* weight = job ? wB : wA;
    const float* style  = job ? sB : sA;
    bf16* wh = job ? whB : whA;
    bf16* wl = job ? wlB : wlA;
    int b = bo / DIMC, o = bo % DIMC;
    const float* wr = weight + (long)o * DIMC;
    const float* sr = style + (long)b * DIMC;
    int t = threadIdx.x;
    float vals[2]; float part = 0.f;
    for (int j = 0; j < 2; j++) {
        int i = t + j * 256;
        float v = wr[i] * sr[i];
        vals[j] = v; part += v * v;
    }
    __shared__ float red[256];
    red[t] = part; __syncthreads();
    for (int s = 128; s > 0; s >>= 1) { if (t < s) red[t] += red[t + s]; __syncthreads(); }
    float d = rsqrtf(red[0] + 1e-8f);
    for (int j = 0; j < 2; j++) {
        int i = t + j * 256;
        bf16 h, l; split2(vals[j] * d, h, l);
        wh[(long)bo * DIMC + i] = h; wl[(long)bo * DIMC + i] = l;
    }
}

// ---------------- fused segmented fp32 -> bf16 hi/lo convert (5 weight arrays) ----------------
__global__ void cvtall_kernel(
    const float* __restrict__ s0, bf16* __restrict__ h0, bf16* __restrict__ l0, int n0,
    const float* __restrict__ s1, bf16* __restrict__ h1, bf16* __restrict__ l1, int n1,
    const float* __restrict__ s2, bf16* __restrict__ h2, bf16* __restrict__ l2, int n2,
    const float* __restrict__ s3, bf16* __restrict__ h3, bf16* __restrict__ l3, int n3,
    const float* __restrict__ s4, bf16* __restrict__ h4, bf16* __restrict__ l4, int n4) {
    int i = (blockIdx.x * blockDim.x + threadIdx.x) * 4;
    const float* src; bf16 *hh, *ll;
    if (i < n0) { src = s0; hh = h0; ll = l0; }
    else if ((i -= n0) < n1) { src = s1; hh = h1; ll = l1; }
    else if ((i -= n1) < n2) { src = s2; hh = h2; ll = l2; }
    else if ((i -= n2) < n3) { src = s3; hh = h3; ll = l3; }
    else if ((i -= n3) < n4) { src = s4; hh = h4; ll = l4; }
    else return;
    float4 v = *(const float4*)(src + i);
    float a[4] = {v.x, v.y, v.z, v.w};
    #pragma unroll
    for (int j = 0; j < 4; j++) { bf16 h, l; split2(a[j], h, l); hh[i + j] = h; ll[i + j] = l; }
}

// ---------------- fp32 [R][C] -> bf16 [C][R] transpose hi/lo ----------------
__global__ void trcvt2_kernel(const float* __restrict__ in, bf16* __restrict__ hi,
                              bf16* __restrict__ lo, int R, int C, long in_bat, long out_bat) {
    __shared__ float tile[32][33];
    in += (long)blockIdx.z * in_bat; hi += (long)blockIdx.z * out_bat; lo += (long)blockIdx.z * out_bat;
    int c0 = blockIdx.x * 32, r0 = blockIdx.y * 32;
    int tc = threadIdx.x & 31, tr = threadIdx.x >> 5;
    #pragma unroll
    for (int i = 0; i < 4; i++) {
        int r = tr + i * 8;
        tile[r][tc] = in[(long)(r0 + r) * C + c0 + tc];
    }
    __syncthreads();
    #pragma unroll
    for (int i = 0; i < 4; i++) {
        int r = tr + i * 8;
        bf16 h, l; split2(tile[tc][r], h, l);
        hi[(long)(c0 + r) * R + r0 + tc] = h;
        lo[(long)(c0 + r) * R + r0 + tc] = l;
    }
}

// ---- fused expert-weight transposes: z<8 -> e_w1[z] (512x2048), z>=8 -> e_w2[z-8] (2048x512) ----
__global__ void tr2x_kernel(const float* __restrict__ w1, bf16* __restrict__ e1T,
                            const float* __restrict__ w2, bf16* __restrict__ e2T) {
    __shared__ float tile[32][33];
    int z = blockIdx.z;
    const float* in; bf16* out; int R, C, c0, r0;
    if (z < 8) {
        in = w1 + (long)z * 512 * 2048;  out = e1T + (long)z * 2048 * 512;
        R = 512; C = 2048;
        c0 = blockIdx.x * 32; r0 = blockIdx.y * 32;       // grid x=64, y=16
    } else {
        in = w2 + (long)(z - 8) * 2048 * 512;  out = e2T + (long)(z - 8) * 512 * 2048;
        R = 2048; C = 512;
        int lin = blockIdx.y * 64 + blockIdx.x;           // 0..1023 -> (16 x, 64 y)
        c0 = (lin & 15) * 32; r0 = (lin >> 4) * 32;
    }
    int tc = threadIdx.x & 31, tr = threadIdx.x >> 5;
    #pragma unroll
    for (int i = 0; i < 4; i++) {
        int r = tr + i * 8;
        tile[r][tc] = in[(long)(r0 + r) * C + c0 + tc];
    }
    __syncthreads();
    #pragma unroll
    for (int i = 0; i < 4; i++) {
        int r = tr + i * 8;
        out[(long)(c0 + r) * R + r0 + tc] = __float2bfloat16(tile[tc][r]);
    }
}

// ---- split-precision bf16 MFMA GEMM, 64x64 tile (high machine fill) ----
__global__ __launch_bounds__(256) void mgemm64_kernel(
    const bf16* __restrict__ Ah, const bf16* __restrict__ Al,
    const bf16* __restrict__ Bh, const bf16* __restrict__ Bl,
    const float* __restrict__ bias, const float* __restrict__ resid, float* __restrict__ C,
    bf16* __restrict__ Oh, bf16* __restrict__ Ol,
    int M, int N, int K, long a_bat, long b_bat, long c_bat, int cs_m, int cs_n) {
    __shared__ short AsH[2 * 2048];
    __shared__ short AsL[2 * 2048];
    __shared__ short BsH[2 * 2048];
    __shared__ short BsL[2 * 2048];
    int bat = blockIdx.z;
    const short* AbH = (const short*)(Ah + (long)bat * a_bat);
    const short* AbL = (const short*)(Al + (long)bat * a_bat);
    const short* BbH = (const short*)(Bh + (long)bat * b_bat);
    const short* BbL = (const short*)(Bl + (long)bat * b_bat);
    float* Cb = C + (long)bat * c_bat;
    const float* Rb = resid ? resid + (long)bat * c_bat : nullptr;
    int bm = blockIdx.y * 64, bn = blockIdx.x * 64;
    int t = threadIdx.x, lane = t & 63, w = t >> 6;
    int wm = (w >> 1) * 32, wn = (w & 1) * 32;
    int r0 = t >> 2, k0s = (t & 3) ^ ((r0 >> 1) & 3);
    int ar0 = bm + r0; if (ar0 > M - 1) ar0 = M - 1;
    long aoff = (long)ar0 * K + k0s * 8;
    long boff = (long)(bn + r0) * K + k0s * 8;
    int fr = lane & 15, fq = lane >> 4;
    int aOff[2], bOff[2];
    #pragma unroll
    for (int i = 0; i < 2; i++) {
        int row = wm + i * 16 + fr;
        aOff[i] = row * 32 + ((fq ^ ((row >> 1) & 3)) * 8);
        int col = wn + i * 16 + fr;
        bOff[i] = col * 32 + ((fq ^ ((col >> 1) & 3)) * 8);
    }
    f32x4 acc[2][2] = {};
    bf16x8 vah = *(const bf16x8*)(AbH + aoff);
    bf16x8 val = *(const bf16x8*)(AbL + aoff);
    bf16x8 vbh = *(const bf16x8*)(BbH + boff);
    bf16x8 vbl = *(const bf16x8*)(BbL + boff);
    int bufo = 0;
    for (int kk = 0; kk < K; kk += 32) {
        *(bf16x8*)&AsH[bufo + t * 8] = vah;
        *(bf16x8*)&AsL[bufo + t * 8] = val;
        *(bf16x8*)&BsH[bufo + t * 8] = vbh;
        *(bf16x8*)&BsL[bufo + t * 8] = vbl;
        __syncthreads();
        int kn = (kk + 32 < K) ? kk + 32 : kk;
        bf16x8 nah = *(const bf16x8*)(AbH + aoff + kn);
        bf16x8 nal = *(const bf16x8*)(AbL + aoff + kn);
        bf16x8 nbh = *(const bf16x8*)(BbH + boff + kn);
        bf16x8 nbl = *(const bf16x8*)(BbL + boff + kn);
        bf16x8 aH[2], aL[2], bH[2], bL[2];
        #pragma unroll
        for (int i = 0; i < 2; i++) {
            aH[i] = *(const bf16x8*)&AsH[bufo + aOff[i]];
            aL[i] = *(const bf16x8*)&AsL[bufo + aOff[i]];
            bH[i] = *(const bf16x8*)&BsH[bufo + bOff[i]];
            bL[i] = *(const bf16x8*)&BsL[bufo + bOff[i]];
        }
        #pragma unroll
        for (int i = 0; i < 2; i++)
        #pragma unroll
        for (int j = 0; j < 2; j++) {
            acc[i][j] = __builtin_amdgcn_mfma_f32_16x16x32_bf16(aH[i], bH[j], acc[i][j], 0, 0, 0);
            acc[i][j] = __builtin_amdgcn_mfma_f32_16x16x32_bf16(aH[i], bL[j], acc[i][j], 0, 0, 0);
            acc[i][j] = __builtin_amdgcn_mfma_f32_16x16x32_bf16(aL[i], bH[j], acc[i][j], 0, 0, 0);
        }
        vah = nah; val = nal; vbh = nbh; vbl = nbl;
        bufo ^= 2048;
    }
    #pragma unroll
    for (int i = 0; i < 2; i++)
    #pragma unroll
    for (int j = 0; j < 2; j++)
    #pragma unroll
    for (int r = 0; r < 4; r++) {
        int row = bm + wm + i * 16 + fq * 4 + r;
        int col = bn + wn + j * 16 + fr;
        if (row < M) {
            long off = (long)row * cs_m + (long)col * cs_n;
            float v = acc[i][j][r];
            if (bias) v += bias[col];
            if (Oh) {
                bf16 hh, ll; split2(v, hh, ll);
                Oh[off] = hh; Ol[off] = ll;
            } else {
                if (Rb) v += Rb[off];
                Cb[off] = v;
            }
        }
    }
}

// ---- split-precision MFMA flash SA: dbuf + post-barrier prefetch + setprio ----
__global__ __launch_bounds__(256) void sa_mfma_kernel(
    const bf16* __restrict__ qh, const bf16* __restrict__ ql,
    bf16* __restrict__ oh, bf16* __restrict__ ol) {
    int qt = blockIdx.x, h = blockIdx.y, b = blockIdx.z;
    __shared__ short KsH[2 * 4096], KsL[2 * 4096];
    __shared__ short VtH[2 * 4096], VtL[2 * 4096];
    __shared__ short PHs[4][1024], PLs[4][1024];
    int t = threadIdx.x, lane = t & 63, w = t >> 6;
    int fr = lane & 15, fq = lane >> 4;
    const short* QH = (const short*)qh;
    const short* QL = (const short*)ql;
    long qrow = (long)(b * 1024 + qt * 64 + w * 16 + fr) * 1536 + h * 64;
    bf16x8 Qh2[2], Ql2[2];
    Qh2[0] = *(const bf16x8*)(QH + qrow + fq * 8);
    Qh2[1] = *(const bf16x8*)(QH + qrow + 32 + fq * 8);
    Ql2[0] = *(const bf16x8*)(QL + qrow + fq * 8);
    Ql2[1] = *(const bf16x8*)(QL + qrow + 32 + fq * 8);
    float m_i[4], l_i[4];
    f32x4 o_acc[4] = {};
    #pragma unroll
    for (int i = 0; i < 4; i++) { m_i[i] = -1e30f; l_i[i] = 0.f; }
    int c0 = t, c1 = t + 256;
    int r0 = c0 >> 3, g0 = c0 & 7;
    int r1 = c1 >> 3, g1 = c1 & 7;
    int kd0 = r0 * 64 + ((g0 * 8) ^ ((r0 & 7) << 3));
    int kd1 = r1 * 64 + ((g1 * 8) ^ ((r1 & 7) << 3));
    long kb = (long)(b * 1024) * 1536 + 512 + h * 64;
    long vb = kb + 512;
    long lo0 = (long)r0 * 1536 + g0 * 8, lo1 = (long)r1 * 1536 + g1 * 8;
    short* ph = PHs[w]; short* pl = PLs[w];
    bf16x8 kh0 = *(const bf16x8*)(QH + kb + lo0);
    bf16x8 kh1 = *(const bf16x8*)(QH + kb + lo1);
    bf16x8 kl0 = *(const bf16x8*)(QL + kb + lo0);
    bf16x8 kl1 = *(const bf16x8*)(QL + kb + lo1);
    bf16x8 vh0 = *(const bf16x8*)(QH + vb + lo0);
    bf16x8 vh1 = *(const bf16x8*)(QH + vb + lo1);
    bf16x8 vl0 = *(const bf16x8*)(QL + vb + lo0);
    bf16x8 vl1 = *(const bf16x8*)(QL + vb + lo1);
    int bufo = 0;
    for (int kt = 0; kt < 16; kt++) {
        *(bf16x8*)&KsH[bufo + kd0] = kh0;  *(bf16x8*)&KsH[bufo + kd1] = kh1;
        *(bf16x8*)&KsL[bufo + kd0] = kl0;  *(bf16x8*)&KsL[bufo + kd1] = kl1;
        #pragma unroll
        for (int j = 0; j < 8; j++) {
            int d0 = g0 * 8 + j;
            int i0 = bufo + d0 * 64 + (r0 ^ (((d0 >> 3) & 7) << 3));
            VtH[i0] = ((short*)&vh0)[j];  VtL[i0] = ((short*)&vl0)[j];
            int d1 = g1 * 8 + j;
            int i1 = bufo + d1 * 64 + (r1 ^ (((d1 >> 3) & 7) << 3));
            VtH[i1] = ((short*)&vh1)[j];  VtL[i1] = ((short*)&vl1)[j];
        }
        __syncthreads();
        int ktn = (kt + 1 < 16) ? kt + 1 : kt;
        long ko = kb + (long)(ktn * 64) * 1536;
        long vo = vb + (long)(ktn * 64) * 1536;
        bf16x8 nkh0 = *(const bf16x8*)(QH + ko + lo0);
        bf16x8 nkh1 = *(const bf16x8*)(QH + ko + lo1);
        bf16x8 nkl0 = *(const bf16x8*)(QL + ko + lo0);
        bf16x8 nkl1 = *(const bf16x8*)(QL + ko + lo1);
        bf16x8 nvh0 = *(const bf16x8*)(QH + vo + lo0);
        bf16x8 nvh1 = *(const bf16x8*)(QH + vo + lo1);
        bf16x8 nvl0 = *(const bf16x8*)(QL + vo + lo0);
        bf16x8 nvl1 = *(const bf16x8*)(QL + vo + lo1);
        __builtin_amdgcn_s_setprio(1);
        f32x4 s[4] = {};
        #pragma unroll
        for (int cf = 0; cf < 4; cf++) {
            int kvrow = cf * 16 + fr;
            #pragma unroll
            for (int kf = 0; kf < 2; kf++) {
                int idx = bufo + kvrow * 64 + ((kf * 32 + fq * 8) ^ ((kvrow & 7) << 3));
                bf16x8 Bh2 = *(const bf16x8*)&KsH[idx];
                bf16x8 Bl2 = *(const bf16x8*)&KsL[idx];
                s[cf] = __builtin_amdgcn_mfma_f32_16x16x32_bf16(Qh2[kf], Bh2, s[cf], 0, 0, 0);
                s[cf] = __builtin_amdgcn_mfma_f32_16x16x32_bf16(Qh2[kf], Bl2, s[cf], 0, 0, 0);
                s[cf] = __builtin_amdgcn_mfma_f32_16x16x32_bf16(Ql2[kf], Bh2, s[cf], 0, 0, 0);
            }
        }
        __builtin_amdgcn_s_setprio(0);
        #pragma unroll
        for (int cf = 0; cf < 4; cf++)
        #pragma unroll
        for (int reg = 0; reg < 4; reg++) s[cf][reg] *= 0.125f;
        float sc_[4];
        #pragma unroll
        for (int reg = 0; reg < 4; reg++) {
            float mx = fmaxf(fmaxf(s[0][reg], s[1][reg]), fmaxf(s[2][reg], s[3][reg]));
            mx = fmaxf(mx, __shfl_xor(mx, 1));
            mx = fmaxf(mx, __shfl_xor(mx, 2));
            mx = fmaxf(mx, __shfl_xor(mx, 4));
            mx = fmaxf(mx, __shfl_xor(mx, 8));
            float mn = fmaxf(m_i[reg], mx);
            sc_[reg] = __expf(m_i[reg] - mn);
            m_i[reg] = mn;
            float rs = 0.f;
            #pragma unroll
            for (int cf = 0; cf < 4; cf++) { s[cf][reg] = __expf(s[cf][reg] - mn); rs += s[cf][reg]; }
            rs += __shfl_xor(rs, 1);
            rs += __shfl_xor(rs, 2);
            rs += __shfl_xor(rs, 4);
            rs += __shfl_xor(rs, 8);
            l_i[reg] = l_i[reg] * sc_[reg] + rs;
        }
        #pragma unroll
        for (int cf = 0; cf < 4; cf++)
        #pragma unroll
        for (int reg = 0; reg < 4; reg++) o_acc[cf][reg] *= sc_[reg];
        #pragma unroll
        for (int cf = 0; cf < 4; cf++)
        #pragma unroll
        for (int reg = 0; reg < 4; reg++) {
            int q = fq * 4 + reg, kv = cf * 16 + fr;
            int idx = q * 64 + (kv ^ ((q & 7) << 3));
            split2s(s[cf][reg], ph[idx], pl[idx]);
        }
        asm volatile("s_waitcnt lgkmcnt(0)" ::: "memory");
        __builtin_amdgcn_sched_barrier(0);
        __builtin_amdgcn_s_setprio(1);
        bf16x8 Pf_h[2], Pf_l[2];
        #pragma unroll
        for (int kf = 0; kf < 2; kf++) {
            int idx = fr * 64 + ((kf * 32 + fq * 8) ^ ((fr & 7) << 3));
            Pf_h[kf] = *(const bf16x8*)&ph[idx];
            Pf_l[kf] = *(const bf16x8*)&pl[idx];
        }
        #pragma unroll
        for (int cf = 0; cf < 4; cf++) {
            int d = cf * 16 + fr;
            #pragma unroll
            for (int kf = 0; kf < 2; kf++) {
                int idx = bufo + d * 64 + ((kf * 32 + fq * 8) ^ (((d >> 3) & 7) << 3));
                bf16x8 Vh2 = *(const bf16x8*)&VtH[idx];
                bf16x8 Vl2 = *(const bf16x8*)&VtL[idx];
                o_acc[cf] = __builtin_amdgcn_mfma_f32_16x16x32_bf16(Pf_h[kf], Vh2, o_acc[cf], 0, 0, 0);
                o_acc[cf] = __builtin_amdgcn_mfma_f32_16x16x32_bf16(Pf_h[kf], Vl2, o_acc[cf], 0, 0, 0);
                o_acc[cf] = __builtin_amdgcn_mfma_f32_16x16x32_bf16(Pf_l[kf], Vh2, o_acc[cf], 0, 0, 0);
            }
        }
        __builtin_amdgcn_s_setprio(0);
        kh0 = nkh0; kh1 = nkh1; kl0 = nkl0; kl1 = nkl1;
        vh0 = nvh0; vh1 = nvh1; vl0 = nvl0; vl1 = nvl1;
        bufo ^= 4096;
    }
    #pragma unroll
    for (int reg = 0; reg < 4; reg++) {
        float inv = 1.f / l_i[reg];
        long m = (long)(b * 1024 + qt * 64 + w * 16 + fq * 4 + reg);
        #pragma unroll
        for (int cf = 0; cf < 4; cf++) {
            float v = o_acc[cf][reg] * inv;
            bf16 hh, ll; split2(v, hh, ll);
            long off = m * DIMC + h * 64 + cf * 16 + fr;
            oh[off] = hh; ol[off] = ll;
        }
    }
}

// ---- split-precision MFMA cross-attention: 77 keys padded to 96, single tile ----
__global__ __launch_bounds__(256) void ca_mfma_kernel(
    const bf16* __restrict__ qh, const bf16* __restrict__ ql,
    const bf16* __restrict__ kvh, const bf16* __restrict__ kvl,
    bf16* __restrict__ oh, bf16* __restrict__ ol) {
    int qt = blockIdx.x, h = blockIdx.y, b = blockIdx.z;
    __shared__ short UH[8192], UL[8192];
    __shared__ short PHs[4][2048], PLs[4][2048];
    int t = threadIdx.x, lane = t & 63, w = t >> 6;
    int fr = lane & 15, fq = lane >> 4;
    const short* QH = (const short*)qh;
    const short* QL = (const short*)ql;
    const short* KVH = (const short*)kvh;
    const short* KVL = (const short*)kvl;
    long qrow = (long)(b * 1024 + qt * 64 + w * 16 + fr) * DIMC + h * 64;
    bf16x8 Qh2[2], Ql2[2];
    Qh2[0] = *(const bf16x8*)(QH + qrow + fq * 8);
    Qh2[1] = *(const bf16x8*)(QH + qrow + 32 + fq * 8);
    Ql2[0] = *(const bf16x8*)(QL + qrow + fq * 8);
    Ql2[1] = *(const bf16x8*)(QL + qrow + 32 + fq * 8);
    for (int c = t; c < 768; c += 256) {
        int r = c >> 3, g = c & 7;
        int idx = r * 64 + ((g * 8) ^ ((r & 7) << 3));
        bf16x8 vh = {}, vl = {};
        if (r < 77) {
            long src = (long)(b * 77 + r) * 1024 + h * 64 + g * 8;
            vh = *(const bf16x8*)(KVH + src);
            vl = *(const bf16x8*)(KVL + src);
        }
        *(bf16x8*)&UH[idx] = vh;
        *(bf16x8*)&UL[idx] = vl;
    }
    __syncthreads();
    f32x4 s[5] = {};
    #pragma unroll
    for (int cf = 0; cf < 5; cf++) {
        int kvrow = cf * 16 + fr;
        #pragma unroll
        for (int kf = 0; kf < 2; kf++) {
            int idx = kvrow * 64 + ((kf * 32 + fq * 8) ^ ((kvrow & 7) << 3));
            bf16x8 Bh2 = *(const bf16x8*)&UH[idx];
            bf16x8 Bl2 = *(const bf16x8*)&UL[idx];
            s[cf] = __builtin_amdgcn_mfma_f32_16x16x32_bf16(Qh2[kf], Bh2, s[cf], 0, 0, 0);
            s[cf] = __builtin_amdgcn_mfma_f32_16x16x32_bf16(Qh2[kf], Bl2, s[cf], 0, 0, 0);
            s[cf] = __builtin_amdgcn_mfma_f32_16x16x32_bf16(Ql2[kf], Bh2, s[cf], 0, 0, 0);
        }
    }
    #pragma unroll
    for (int cf = 0; cf < 5; cf++) {
        int kv = cf * 16 + fr;
        #pragma unroll
        for (int reg = 0; reg < 4; reg++)
            s[cf][reg] = (kv < 77) ? s[cf][reg] * 0.125f : -1e30f;
    }
    float inv[4];
    #pragma unroll
    for (int reg = 0; reg < 4; reg++) {
        float mx = s[0][reg];
        #pragma unroll
        for (int cf = 1; cf < 5; cf++) mx = fmaxf(mx, s[cf][reg]);
        mx = fmaxf(mx, __shfl_xor(mx, 1));
        mx = fmaxf(mx, __shfl_xor(mx, 2));
        mx = fmaxf(mx, __shfl_xor(mx, 4));
        mx = fmaxf(mx, __shfl_xor(mx, 8));
        float rs = 0.f;
        #pragma unroll
        for (int cf = 0; cf < 5; cf++) { s[cf][reg] = __expf(s[cf][reg] - mx); rs += s[cf][reg]; }
        rs += __shfl_xor(rs, 1);
        rs += __shfl_xor(rs, 2);
        rs += __shfl_xor(rs, 4);
        rs += __shfl_xor(rs, 8);
        inv[reg] = 1.f / rs;
    }
    short* ph = PHs[w]; short* pl = PLs[w];
    #pragma unroll
    for (int cf = 0; cf < 6; cf++)
    #pragma unroll
    for (int reg = 0; reg < 4; reg++) {
        int q = fq * 4 + reg, kv = cf * 16 + fr;
        int idx = q * 128 + (kv ^ ((q & 7) << 3));
        float pv = (cf < 5) ? s[cf][reg] * inv[reg] : 0.f;
        split2s(pv, ph[idx], pl[idx]);
    }
    __syncthreads();
    for (int c = t; c < 768; c += 256) {
        int r = c >> 3, g = c & 7;
        bf16x8 vh = {}, vl = {};
        if (r < 77) {
            long src = (long)(b * 77 + r) * 1024 + 512 + h * 64 + g * 8;
            vh = *(const bf16x8*)(KVH + src);
            vl = *(const bf16x8*)(KVL + src);
        }
        #pragma unroll
        for (int j = 0; j < 8; j++) {
            int d = g * 8 + j;
            int idx = d * 128 + (r ^ (((d >> 3) & 7) << 3));
            UH[idx] = ((short*)&vh)[j];
            UL[idx] = ((short*)&vl)[j];
        }
    }
    __syncthreads();
    f32x4 o_acc[4] = {};
    bf16x8 Pf_h[3], Pf_l[3];
    #pragma unroll
    for (int kf = 0; kf < 3; kf++) {
        int idx = fr * 128 + ((kf * 32 + fq * 8) ^ ((fr & 7) << 3));
        Pf_h[kf] = *(const bf16x8*)&ph[idx];
        Pf_l[kf] = *(const bf16x8*)&pl[idx];
    }
    #pragma unroll
    for (int cf = 0; cf < 4; cf++) {
        int d = cf * 16 + fr;
        #pragma unroll
        for (int kf = 0; kf < 3; kf++) {
            int idx = d * 128 + ((kf * 32 + fq * 8) ^ (((d >> 3) & 7) << 3));
            bf16x8 Vh2 = *(const bf16x8*)&UH[idx];
            bf16x8 Vl2 = *(const bf16x8*)&UL[idx];
            o_acc[cf] = __builtin_amdgcn_mfma_f32_16x16x32_bf16(Pf_h[kf], Vh2, o_acc[cf], 0, 0, 0);
            o_acc[cf] = __builtin_amdgcn_mfma_f32_16x16x32_bf16(Pf_h[kf], Vl2, o_acc[cf], 0, 0, 0);
            o_acc[cf] = __builtin_amdgcn_mfma_f32_16x16x32_bf16(Pf_l[kf], Vh2, o_acc[cf], 0, 0, 0);
        }
    }
    #pragma unroll
    for (int reg = 0; reg < 4; reg++) {
        long m = (long)(b * 1024 + qt * 64 + w * 16 + fq * 4 + reg);
        #pragma unroll
        for (int cf = 0; cf < 4; cf++) {
            bf16 hh, ll; split2(o_acc[cf][reg], hh, ll);
            long off = m * DIMC + h * 64 + cf * 16 + fr;
            oh[off] = hh; ol[off] = ll;
        }
    }
}

// ---- MoE grouped MFMA GEMM1, 64x64 tile: hid = gelu(xn·w1 + b1), K=512 ----
__global__ __launch_bounds__(256) void moe64_1_kernel(
    const bf16* __restrict__ xn_b, const bf16* __restrict__ e1T, const float* __restrict__ e_b1,
    const int* __restrict__ table, const int* __restrict__ ntiles, const int* __restrict__ perm,
    bf16* __restrict__ hid_b) {
    if (blockIdx.y >= ntiles[0]) return;
    int e = table[2 * blockIdx.y], row0 = table[2 * blockIdx.y + 1];
    int bn = blockIdx.x * 64;
    __shared__ short As[2 * 2048];
    __shared__ short Bs[2 * 2048];
    __shared__ int rowsS[64];
    int t = threadIdx.x, lane = t & 63, w = t >> 6;
    if (t < 64) rowsS[t] = perm[row0 + t];
    __syncthreads();
    int wm = (w >> 1) * 32, wn = (w & 1) * 32;
    int r0 = t >> 2, k0s = (t & 3) ^ ((r0 >> 1) & 3);
    int tok0 = rowsS[r0]; if (tok0 < 0) tok0 = 0;
    const short* Xs = (const short*)xn_b;
    const short* Ws = (const short*)(e1T + (long)e * HIDC * DIMC);
    const short* a0 = Xs + (long)tok0 * DIMC + k0s * 8;
    const short* b0 = Ws + (long)(bn + r0) * DIMC + k0s * 8;
    int fr = lane & 15, fq = lane >> 4;
    int aOff[2], bOff[2];
    #pragma unroll
    for (int i = 0; i < 2; i++) {
        int row = wm + i * 16 + fr;
        aOff[i] = row * 32 + ((fq ^ ((row >> 1) & 3)) * 8);
        int col = wn + i * 16 + fr;
        bOff[i] = col * 32 + ((fq ^ ((col >> 1) & 3)) * 8);
    }
    f32x4 acc[2][2] = {};
    bf16x8 va = *(const bf16x8*)(a0);
    bf16x8 vb = *(const bf16x8*)(b0);
    int bufo = 0;
    for (int kk = 0; kk < DIMC; kk += 32) {
        *(bf16x8*)&As[bufo + t * 8] = va;
        *(bf16x8*)&Bs[bufo + t * 8] = vb;
        __syncthreads();
        int kn = (kk + 32 < DIMC) ? kk + 32 : kk;
        bf16x8 na = *(const bf16x8*)(a0 + kn);
        bf16x8 nb = *(const bf16x8*)(b0 + kn);
        bf16x8 aF[2], bF[2];
        #pragma unroll
        for (int i = 0; i < 2; i++) {
            aF[i] = *(const bf16x8*)&As[bufo + aOff[i]];
            bF[i] = *(const bf16x8*)&Bs[bufo + bOff[i]];
        }
        #pragma unroll
        for (int i = 0; i < 2; i++)
        #pragma unroll
        for (int j = 0; j < 2; j++)
            acc[i][j] = __builtin_amdgcn_mfma_f32_16x16x32_bf16(aF[i], bF[j], acc[i][j], 0, 0, 0);
        va = na; vb = nb;
        bufo ^= 2048;
    }
    const float* bb = e_b1 + (long)e * HIDC;
    #pragma unroll
    for (int i = 0; i < 2; i++)
    #pragma unroll
    for (int r = 0; r < 4; r++) {
        int tok = rowsS[wm + i * 16 + fq * 4 + r];
        if (tok < 0) continue;
        #pragma unroll
        for (int j = 0; j < 2; j++) {
            int col = bn + wn + j * 16 + fr;
            float v = acc[i][j][r] + bb[col];
            v = 0.5f * v * (1.f + erff(v * 0.70710678f));
            hid_b[(long)tok * HIDC + col] = __float2bfloat16(v);
        }
    }
}

// ---- MoE grouped MFMA GEMM2, 64x64 tile: out = resid + hid·w2 + b2 -> split bf16 ----
__global__ __launch_bounds__(256) void moe64_2_kernel(
    const bf16* __restrict__ hid_b, const bf16* __restrict__ e2T, const float* __restrict__ e_b2,
    const int* __restrict__ table, const int* __restrict__ ntiles, const int* __restrict__ perm,
    const float* __restrict__ resid, bf16* __restrict__ outh, bf16* __restrict__ outl) {
    if (blockIdx.y >= ntiles[0]) return;
    int e = table[2 * blockIdx.y], row0 = table[2 * blockIdx.y + 1];
    int bn = blockIdx.x * 64;
    __shared__ short As[2 * 2048];
    __shared__ short Bs[2 * 2048];
    __shared__ int rowsS[64];
    int t = threadIdx.x, lane = t & 63, w = t >> 6;
    if (t < 64) rowsS[t] = perm[row0 + t];
    __syncthreads();
    int wm = (w >> 1) * 32, wn = (w & 1) * 32;
    int r0 = t >> 2, k0s = (t & 3) ^ ((r0 >> 1) & 3);
    int tok0 = rowsS[r0]; if (tok0 < 0) tok0 = 0;
    const short* Hs = (const short*)hid_b;
    const short* Ws = (const short*)(e2T + (long)e * DIMC * HIDC);
    const short* a0 = Hs + (long)tok0 * HIDC + k0s * 8;
    const short* b0 = Ws + (long)(bn + r0) * HIDC + k0s * 8;
    int fr = lane & 15, fq = lane >> 4;
    int aOff[2], bOff[2];
    #pragma unroll
    for (int i = 0; i < 2; i++) {
        int row = wm + i * 16 + fr;
        aOff[i] = row * 32 + ((fq ^ ((row >> 1) & 3)) * 8);
        int col = wn + i * 16 + fr;
        bOff[i] = col * 32 + ((fq ^ ((col >> 1) & 3)) * 8);
    }
    f32x4 acc[2][2] = {};
    bf16x8 va = *(const bf16x8*)(a0);
    bf16x8 vb = *(const bf16x8*)(b0);
    int bufo = 0;
    for (int kk = 0; kk < HIDC; kk += 32) {
        *(bf16x8*)&As[bufo + t * 8] = va;
        *(bf16x8*)&Bs[bufo + t * 8] = vb;
        __syncthreads();
        int kn = (kk + 32 < HIDC) ? kk + 32 : kk;
        bf16x8 na = *(const bf16x8*)(a0 + kn);
        bf16x8 nb = *(const bf16x8*)(b0 + kn);
        bf16x8 aF[2], bF[2];
        #pragma unroll
        for (int i = 0; i < 2; i++) {
            aF[i] = *(const bf16x8*)&As[bufo + aOff[i]];
            bF[i] = *(const bf16x8*)&Bs[bufo + bOff[i]];
        }
        #pragma unroll
        for (int i = 0; i < 2; i++)
        #pragma unroll
        for (int j = 0; j < 2; j++)
            acc[i][j] = __builtin_amdgcn_mfma_f32_16x16x32_bf16(aF[i], bF[j], acc[i][j], 0, 0, 0);
        va = na; vb = nb;
        bufo ^= 2048;
    }
    const float* bb = e_b2 + (long)e * DIMC;
    #pragma unroll
    for (int i = 0; i < 2; i++)
    #pragma unroll
    for (int r = 0; r < 4; r++) {
        int tok = rowsS[wm + i * 16 + fq * 4 + r];
        if (tok < 0) continue;
        #pragma unroll
        for (int j = 0; j < 2; j++) {
            int col = bn + wn + j * 16 + fr;
            long off = (long)tok * DIMC + col;
            float v = resid[off] + acc[i][j][r] + bb[col];
            bf16 hh, ll; split2(v, hh, ll);
            outh[off] = hh; outl[off] = ll;
        }
    }
}

// ---------------- LayerNorm: optional fp32 + bf16 hi/lo outputs ----------------
__global__ void ln_kernel(const float* __restrict__ x, const float* __restrict__ g,
                          const float* __restrict__ b, float* __restrict__ y,
                          bf16* __restrict__ yh, bf16* __restrict__ yl) {
    int tok = blockIdx.x;
    int t = threadIdx.x;
    const float* xr = x + (long)tok * DIMC;
    float v0 = xr[t], v1 = xr[t + 256];
    __shared__ float red[256];
    red[t] = v0 + v1; __syncthreads();
    for (int s = 128; s > 0; s >>= 1) { if (t < s) red[t] += red[t + s]; __syncthreads(); }
    float mu = red[0] * (1.f / DIMC);
    __syncthreads();
    float d0 = v0 - mu, d1 = v1 - mu;
    red[t] = d0 * d0 + d1 * d1; __syncthreads();
    for (int s = 128; s > 0; s >>= 1) { if (t < s) red[t] += red[t + s]; __syncthreads(); }
    float rs = rsqrtf(red[0] * (1.f / DIMC) + 1e-5f);
    float o0 = d0 * rs * g[t] + b[t];
    float o1 = d1 * rs * g[t + 256] + b[t + 256];
    if (y) { y[(long)tok * DIMC + t] = o0; y[(long)tok * DIMC + t + 256] = o1; }
    bf16 h, l;
    split2(o0, h, l); yh[(long)tok * DIMC + t] = h;       yl[(long)tok * DIMC + t] = l;
    split2(o1, h, l); yh[(long)tok * DIMC + t + 256] = h; yl[(long)tok * DIMC + t + 256] = l;
}

// ---------------- router text part (+ cnt zeroing) ----------------
__global__ void textpart_kernel(const float* __restrict__ w, const float* __restrict__ r_text_mu,
                                const float* __restrict__ r_comb_mu, float* __restrict__ tp,
                                int* __restrict__ cnt) {
    __shared__ float tw[4][128];
    int t = threadIdx.x;
    if (t < NE) cnt[t] = 0;
    for (int j = 0; j < 2; j++) {
        int idx = t + j * 256; int b = idx >> 7, c = idx & 127;
        const float* wr = w + (long)b * LATC;
        float s = 0.f;
        for (int k = 0; k < LATC; k++) s += wr[k] * r_text_mu[(long)k * 128 + c];
        tw[b][c] = s;
    }
    __syncthreads();
    if (t < 32) {
        int b = t >> 3, e = t & 7;
        float s = 0.f;
        for (int c = 0; c < 128; c++) s += tw[b][c] * r_comb_mu[(long)(128 + c) * 8 + e];
        tp[t] = s;
    }
}

// ---------------- router: perm poison + logits + argmax ----------------
__global__ void route_kernel(const float* __restrict__ feat, const float* __restrict__ tp,
                             const float* __restrict__ r_comb_mu, const float* __restrict__ r_temp,
                             float* __restrict__ onehot, int* __restrict__ idx, int* __restrict__ cnt,
                             int* __restrict__ perm) {
    int n = blockIdx.x * blockDim.x + threadIdx.x;
    if (n < MAXT * 64) perm[n] = -1;
    if (n >= NTOK) return;
    int b = n >> 10;
    float tmp = fmaxf(r_temp[0], 0.1f);
    float invt = 1.f / tmp;
    const float* fr = feat + (long)n * 128;
    float lg[8];
    for (int e = 0; e < 8; e++) {
        float s = 0.f;
        for (int c = 0; c < 128; c++) s += fr[c] * r_comb_mu[(long)c * 8 + e];
        lg[e] = (s + tp[b * 8 + e]) * invt;
    }
    float best = lg[0]; int bi = 0;
    for (int e = 1; e < 8; e++) { if (lg[e] > best) { best = lg[e]; bi = e; } }
    for (int e = 0; e < 8; e++) onehot[(long)n * 8 + e] = (e == bi) ? 1.f : 0.f;
    idx[n] = bi;
    atomicAdd(&cnt[bi], 1);
}

// ---------------- offsets + scatter fused (single block, LDS cursors) ----------------
__global__ void offscatter_kernel(const int* __restrict__ cnt, const int* __restrict__ idx,
                                  int* __restrict__ ntiles, int* __restrict__ table,
                                  int* __restrict__ perm) {
    __shared__ int cur[NE];
    int t = threadIdx.x;
    if (t == 0) {
        int po = 0, nt = 0;
        for (int e = 0; e < NE; e++) {
            cur[e] = po;
            int tiles = (cnt[e] + 63) >> 6;
            for (int j = 0; j < tiles; j++) { table[2 * nt] = e; table[2 * nt + 1] = po + j * 64; nt++; }
            po += tiles * 64;
        }
        ntiles[0] = nt;
    }
    __syncthreads();
    for (int n = t; n < NTOK; n += 256) {
        int e = idx[n];
        int pos = atomicAdd(&cur[e], 1);
        perm[pos] = n;
    }
}

extern "C" void kernel_launch(void* const* d_in, const int* in_sizes, int n_in,
                              void* d_out, int out_size, void* d_ws, size_t ws_size,
                              hipStream_t stream) {
    const float* x        = (const float*)d_in[0];
    const float* w        = (const float*)d_in[1];
    const float* text     = (const float*)d_in[2];
    const float* pin_w    = (const float*)d_in[3];
    const float* pin_mw   = (const float*)d_in[4];
    const float* pin_mb   = (const float*)d_in[5];
    const float* pout_w   = (const float*)d_in[6];
    const float* pout_mw  = (const float*)d_in[7];
    const float* pout_mb  = (const float*)d_in[8];
    const float* ln1g     = (const float*)d_in[9];
    const float* ln1b     = (const float*)d_in[10];
    const float* ln2g     = (const float*)d_in[11];
    const float* ln2b     = (const float*)d_in[12];
    const float* ln3g     = (const float*)d_in[13];
    const float* ln3b     = (const float*)d_in[14];
    const float* sa_in_w  = (const float*)d_in[15];
    const float* sa_in_b  = (const float*)d_in[16];
    const float* sa_out_w = (const float*)d_in[17];
    const float* sa_out_b = (const float*)d_in[18];
    const float* ca_in_w  = (const float*)d_in[19];
    const float* ca_in_b  = (const float*)d_in[20];
    const float* ca_out_w = (const float*)d_in[21];
    const float* ca_out_b = (const float*)d_in[22];
    const float* r_feat   = (const float*)d_in[23];
    const float* r_text   = (const float*)d_in[24];
    const float* r_comb   = (const float*)d_in[25];
    const float* r_temp   = (const float*)d_in[26];
    const float* e_w1     = (const float*)d_in[27];
    const float* e_b1     = (const float*)d_in[28];
    const float* e_w2     = (const float*)d_in[29];
    const float* e_b2     = (const float*)d_in[30];

    float* out    = (float*)d_out;               // [B, DIM, H, W]
    float* onehot = out + (long)BB * DIMC * HWX; // [4096, 8]

    // ---------------- workspace: fp32 pool ----------------
    float* f32p = (float*)d_ws;
    float* style_in  = f32p;                 // 2048
    float* style_out = f32p + 2048;          // 2048
    float* tp        = f32p + 4096;          // 32
    int*   idx       = (int*)(f32p + 4128);  // 4096
    int*   cnt       = (int*)(f32p + 8224);  // 8
    int*   ntiles    = (int*)(f32p + 8240);  // 8
    int*   table     = (int*)(f32p + 8248);  // 256
    int*   perm      = (int*)(f32p + 8504);  // 4608 -> ends 13112
    float* x_flat    = f32p + 13496;         // 2097152
    float* xn        = x_flat + 2097152;     // 2097152 (home of wtC split)
    float* qkv       = xn + 2097152;         // 6291456 (SA q split / CA q split home)
    float* spill     = qkv + 6291456;        // 2097152 (e2T tail)

    // ---------------- bf16 pool (phase-aliased) ----------------
    bf16* bp = (bf16*)(f32p + 12596408);
    bf16* R1 = bp;                           // 6291456 elems, phases
    bf16* xT_h  = R1;
    bf16* xT_l  = R1 + 2097152;
    bf16* wtA_h = R1 + 4194304;
    bf16* wtA_l = R1 + 5242880;
    bf16* obuf_h = R1;
    bf16* obuf_l = R1 + 2097152;
    bf16* kvt_h  = R1 + 4194304;                       // [308][1024] split
    bf16* kvt_l  = kvt_h + 315392;
    float* feat  = (float*)(kvt_l + 315392);           // 524288 fp32
    bf16* xn_h = R1 + 6291456;               // 2097152
    bf16* xn_l = xn_h + 2097152;             // 2097152
    bf16* WB   = xn_l + 2097152;             // 8388608: weights (early) / hid_b (late)
    bf16* text_h   = WB;
    bf16* text_l   = text_h + 157696;
    bf16* sawin_h  = text_l + 157696;
    bf16* sawin_l  = sawin_h + 786432;
    bf16* sawout_h = sawin_l + 786432;
    bf16* sawout_l = sawout_h + 262144;
    bf16* caw_h    = sawout_l + 262144;
    bf16* caw_l    = caw_h + 786432;
    bf16* cawout_h = caw_l + 786432;
    bf16* cawout_l = cawout_h + 262144;
    bf16* rfT_h    = cawout_l + 262144;      // [128][512] split r_feat^T
    bf16* rfT_l    = rfT_h + 65536;
    bf16* hid_b    = WB;                     // overlays weights after ca_out
    bf16* e1T = (bf16*)qkv;                  // [8][2048][512] in qkv+spill
    bf16* e2T = e1T + 8388608;
    bf16* xfl_h = xn_h;                      // moe64_2 writes split output here
    bf16* xfl_l = xn_l;
    bf16* wtC_h = (bf16*)xn;                 // modconv-out weight (dead fp32 region)
    bf16* wtC_l = wtC_h + 1048576;
    bf16* q_h = (bf16*)qkv;                  // [4096][1536]
    bf16* q_l = q_h + 6291456;
    bf16* ca_qh = (bf16*)qkv;                // [4096][512]
    bf16* ca_ql = ca_qh + 2097152;
    (void)ws_size; (void)spill;

    auto mg = [&](const bf16* Ah, const bf16* Al, const bf16* Bh, const bf16* Bl,
                  const float* bias, const float* resid, float* C, bf16* Oh, bf16* Ol,
                  int M, int N, int K, long ab, long bb, long cb, int csm, int csn, int nb) {
        dim3 g(N / 64, (M + 63) / 64, nb);
        hipLaunchKernelGGL(mgemm64_kernel, g, dim3(256), 0, stream,
                           Ah, Al, Bh, Bl, bias, resid, C, Oh, Ol, M, N, K, ab, bb, cb, csm, csn);
    };

    // ---- fused input conversions (hi/lo): one launch for all 5 flat arrays ----
    {
        int n0 = 1536 * 512, n1 = 512 * 512, n2 = 1536 * 512, n3 = 512 * 512, n4 = BB * TXT * 512;
        int total = n0 + n1 + n2 + n3 + n4;
        hipLaunchKernelGGL(cvtall_kernel, dim3((total / 4 + 255) / 256), dim3(256), 0, stream,
                           sa_in_w, sawin_h, sawin_l, n0,
                           sa_out_w, sawout_h, sawout_l, n1,
                           ca_in_w, caw_h, caw_l, n2,
                           ca_out_w, cawout_h, cawout_l, n3,
                           text, text_h, text_l, n4);
    }
    hipLaunchKernelGGL(trcvt2_kernel, dim3(32, 16, BB), dim3(256), 0, stream,
                       x, xT_h, xT_l, 512, 1024, (long)512 * 1024, (long)1024 * 512);
    hipLaunchKernelGGL(trcvt2_kernel, dim3(4, 16, 1), dim3(256), 0, stream,
                       r_feat, rfT_h, rfT_l, 512, 128, 0L, 0L);

    // ---- both modconv styles + weights up front (wtC in dead xn region) ----
    hipLaunchKernelGGL(style2_kernel, dim3(16), dim3(256), 0, stream,
                       w, pin_mw, pin_mb, pout_mw, pout_mb, style_in, style_out);
    hipLaunchKernelGGL(wtmod2_kernel, dim3(2 * BB * DIMC), dim3(256), 0, stream,
                       pin_w, style_in, pout_w, style_out, wtA_h, wtA_l, wtC_h, wtC_l);

    // ---- modconv in ----
    mg(xT_h, xT_l, wtA_h, wtA_l, nullptr, nullptr, x_flat, nullptr, nullptr,
       HWX, DIMC, DIMC, (long)HWX * DIMC, (long)DIMC * DIMC, (long)HWX * DIMC, DIMC, 1, BB);

    // ---- LN1 + self-attention (split MFMA) ----
    hipLaunchKernelGGL(ln_kernel, dim3(NTOK), dim3(256), 0, stream, x_flat, ln1g, ln1b,
                       (float*)nullptr, xn_h, xn_l);
    mg(xn_h, xn_l, sawin_h, sawin_l, sa_in_b, nullptr, nullptr, q_h, q_l,
       NTOK, 1536, 512, 0, 0, 0, 1536, 1, 1);
    hipLaunchKernelGGL(sa_mfma_kernel, dim3(16, HEADS, BB), dim3(256), 0, stream,
                       q_h, q_l, obuf_h, obuf_l);
    mg(obuf_h, obuf_l, sawout_h, sawout_l, sa_out_b, x_flat, x_flat, nullptr, nullptr,
       NTOK, 512, 512, 0, 0, 0, 512, 1, 1);

    // ---- LN2 + cross-attention (split MFMA) ----
    hipLaunchKernelGGL(ln_kernel, dim3(NTOK), dim3(256), 0, stream, x_flat, ln2g, ln2b,
                       (float*)nullptr, xn_h, xn_l);
    mg(xn_h, xn_l, caw_h, caw_l, ca_in_b, nullptr, nullptr, ca_qh, ca_ql,
       NTOK, 512, 512, 0, 0, 0, 512, 1, 1);
    mg(text_h, text_l, caw_h + 512 * 512, caw_l + 512 * 512, ca_in_b + 512, nullptr, nullptr,
       kvt_h, kvt_l, BB * TXT, 1024, 512, 0, 0, 0, 1024, 1, 1);
    hipLaunchKernelGGL(ca_mfma_kernel, dim3(16, HEADS, BB), dim3(256), 0, stream,
                       ca_qh, ca_ql, kvt_h, kvt_l, obuf_h, obuf_l);
    // expert weight transposes (qkv region dead after ca_mfma) — one fused launch
    hipLaunchKernelGGL(tr2x_kernel, dim3(64, 16, 16), dim3(256), 0, stream,
                       e_w1, e1T, e_w2, e2T);
    mg(obuf_h, obuf_l, cawout_h, cawout_l, ca_out_b, x_flat, x_flat, nullptr, nullptr,
       NTOK, 512, 512, 0, 0, 0, 512, 1, 1);

    // ---- LN3 + router (feat via split MFMA) ----
    hipLaunchKernelGGL(ln_kernel, dim3(NTOK), dim3(256), 0, stream, x_flat, ln3g, ln3b,
                       (float*)nullptr, xn_h, xn_l);
    mg(xn_h, xn_l, rfT_h, rfT_l, nullptr, nullptr, feat, nullptr, nullptr,
       NTOK, 128, 512, 0, 0, 0, 128, 1, 1);
    hipLaunchKernelGGL(textpart_kernel, dim3(1), dim3(256), 0, stream, w, r_text, r_comb, tp, cnt);
    hipLaunchKernelGGL(route_kernel, dim3(18), dim3(256), 0, stream,
                       feat, tp, r_comb, r_temp, onehot, idx, cnt, perm);
    hipLaunchKernelGGL(offscatter_kernel, dim3(1), dim3(256), 0, stream,
                       cnt, idx, ntiles, table, perm);

    // ---- MoE grouped MFMA GEMMs (64x64 tiles; gemm2 emits split bf16 directly) ----
    hipLaunchKernelGGL(moe64_1_kernel, dim3(HIDC / 64, MAXT), dim3(256), 0, stream,
                       xn_h, e1T, e_b1, table, ntiles, perm, hid_b);
    hipLaunchKernelGGL(moe64_2_kernel, dim3(DIMC / 64, MAXT), dim3(256), 0, stream,
                       hid_b, e2T, e_b2, table, ntiles, perm, x_flat, xfl_h, xfl_l);

    // ---- modconv out (weights already prepared) ----
    mg(wtC_h, wtC_l, xfl_h, xfl_l, nullptr, nullptr, out, nullptr, nullptr,
       DIMC, HWX, DIMC, (long)DIMC * DIMC, (long)HWX * DIMC, (long)DIMC * HWX, HWX, 1, BB);
}

// Round 16
// 508.817 us; speedup vs baseline: 1.4155x; 1.0277x over previous
//
#include <hip/hip_runtime.h>
#include <hip/hip_bf16.h>
#include <math.h>

#define DIMC 512
#define HEADS 8
#define HD 64
#define BB 4
#define HWX 1024
#define TXT 77
#define LATC 512
#define NE 8
#define HIDC 2048
#define NTOK 4096
#define MAXT 72           // MoE tiles of 64: 4096/64 + 8

typedef __attribute__((ext_vector_type(8))) short bf16x8;
typedef __attribute__((ext_vector_type(4))) float f32x4;
typedef __hip_bfloat16 bf16;

__device__ __forceinline__ void split2(float v, bf16& h, bf16& l) {
    h = __float2bfloat16(v);
    l = __float2bfloat16(v - __bfloat162float(h));
}
__device__ __forceinline__ void split2s(float v, short& h, short& l) {
    bf16 hb, lb; split2(v, hb, lb);
    h = *(short*)&hb; l = *(short*)&lb;
}

// ---------------- both styles in one launch: job 0 = in, job 1 = out ----------------
__global__ void style2_kernel(const float* __restrict__ w,
                              const float* __restrict__ mwA, const float* __restrict__ mbA,
                              const float* __restrict__ mwB, const float* __restrict__ mbB,
                              float* __restrict__ sA, float* __restrict__ sB) {
    int g = blockIdx.x * blockDim.x + threadIdx.x;
    int job = (g >= BB * DIMC) ? 1 : 0;
    int t = g - job * BB * DIMC;
    if (t >= BB * DIMC) return;
    const float* mw = job ? mwB : mwA;
    const float* mb = job ? mbB : mbA;
    float* st = job ? sB : sA;
    int b = t / DIMC, i = t % DIMC;
    const float* wr = w + (long)b * LATC;
    const float* mr = mw + (long)i * LATC;
    float s = 0.f;
    #pragma unroll 8
    for (int l = 0; l < LATC; l++) s += wr[l] * mr[l];
    st[t] = s + mb[i];
}

// ------- both wtmods in one launch -------
__global__ void wtmod2_kernel(const float* __restrict__ wA, const float* __restrict__ sA,
                              const float* __restrict__ wB, const float* __restrict__ sB,
                              bf16* __restrict__ whA, bf16* __restrict__ wlA,
                              bf16* __restrict__ whB, bf16* __restrict__ wlB) {
    int gb = blockIdx.x;
    int job = (gb >= BB * DIMC) ? 1 : 0;
    int bo = gb - job * BB * DIMC;
    const float* weight = job ? wB : wA;
    const float* style  = job ? sB : sA;
    bf16* wh = job ? whB : whA;
    bf16* wl = job ? wlB : wlA;
    int b = bo / DIMC, o = bo % DIMC;
    const float* wr = weight + (long)o * DIMC;
    const float* sr = style + (long)b * DIMC;
    int t = threadIdx.x;
    float vals[2]; float part = 0.f;
    for (int j = 0; j < 2; j++) {
        int i = t + j * 256;
        float v = wr[i] * sr[i];
        vals[j] = v; part += v * v;
    }
    __shared__ float red[256];
    red[t] = part; __syncthreads();
    for (int s = 128; s > 0; s >>= 1) { if (t < s) red[t] += red[t + s]; __syncthreads(); }
    float d = rsqrtf(red[0] + 1e-8f);
    for (int j = 0; j < 2; j++) {
        int i = t + j * 256;
        bf16 h, l; split2(vals[j] * d, h, l);
        wh[(long)bo * DIMC + i] = h; wl[(long)bo * DIMC + i] = l;
    }
}

// ---------------- fused segmented fp32 -> bf16 hi/lo convert (5 weight arrays) ----------------
__global__ void cvtall_kernel(
    const float* __restrict__ s0, bf16* __restrict__ h0, bf16* __restrict__ l0, int n0,
    const float* __restrict__ s1, bf16* __restrict__ h1, bf16* __restrict__ l1, int n1,
    const float* __restrict__ s2, bf16* __restrict__ h2, bf16* __restrict__ l2, int n2,
    const float* __restrict__ s3, bf16* __restrict__ h3, bf16* __restrict__ l3, int n3,
    const float* __restrict__ s4, bf16* __restrict__ h4, bf16* __restrict__ l4, int n4) {
    int i = (blockIdx.x * blockDim.x + threadIdx.x) * 4;
    const float* src; bf16 *hh, *ll;
    if (i < n0) { src = s0; hh = h0; ll = l0; }
    else if ((i -= n0) < n1) { src = s1; hh = h1; ll = l1; }
    else if ((i -= n1) < n2) { src = s2; hh = h2; ll = l2; }
    else if ((i -= n2) < n3) { src = s3; hh = h3; ll = l3; }
    else if ((i -= n3) < n4) { src = s4; hh = h4; ll = l4; }
    else return;
    float4 v = *(const float4*)(src + i);
    float a[4] = {v.x, v.y, v.z, v.w};
    #pragma unroll
    for (int j = 0; j < 4; j++) { bf16 h, l; split2(a[j], h, l); hh[i + j] = h; ll[i + j] = l; }
}

// ---- fused transpose hi/lo: z<4 -> x slice (512x1024), z==4 -> r_feat (512x128) ----
__global__ void trcvt2x_kernel(const float* __restrict__ x, bf16* __restrict__ xh,
                               bf16* __restrict__ xl, const float* __restrict__ rf,
                               bf16* __restrict__ rfh, bf16* __restrict__ rfl) {
    __shared__ float tile[32][33];
    int z = blockIdx.z;
    const float* in; bf16 *hi, *lo; int R, C;
    if (z < 4) {
        in = x + (long)z * 512 * 1024;
        hi = xh + (long)z * 1024 * 512; lo = xl + (long)z * 1024 * 512;
        R = 512; C = 1024;
    } else {
        if (blockIdx.x >= 4) return;
        in = rf; hi = rfh; lo = rfl;
        R = 512; C = 128;
    }
    int c0 = blockIdx.x * 32, r0 = blockIdx.y * 32;
    int tc = threadIdx.x & 31, tr = threadIdx.x >> 5;
    #pragma unroll
    for (int i = 0; i < 4; i++) {
        int r = tr + i * 8;
        tile[r][tc] = in[(long)(r0 + r) * C + c0 + tc];
    }
    __syncthreads();
    #pragma unroll
    for (int i = 0; i < 4; i++) {
        int r = tr + i * 8;
        bf16 h, l; split2(tile[tc][r], h, l);
        hi[(long)(c0 + r) * R + r0 + tc] = h;
        lo[(long)(c0 + r) * R + r0 + tc] = l;
    }
}

// ---- fused expert-weight transposes: z<8 -> e_w1[z] (512x2048), z>=8 -> e_w2[z-8] (2048x512) ----
__global__ void tr2x_kernel(const float* __restrict__ w1, bf16* __restrict__ e1T,
                            const float* __restrict__ w2, bf16* __restrict__ e2T) {
    __shared__ float tile[32][33];
    int z = blockIdx.z;
    const float* in; bf16* out; int R, C, c0, r0;
    if (z < 8) {
        in = w1 + (long)z * 512 * 2048;  out = e1T + (long)z * 2048 * 512;
        R = 512; C = 2048;
        c0 = blockIdx.x * 32; r0 = blockIdx.y * 32;       // grid x=64, y=16
    } else {
        in = w2 + (long)(z - 8) * 2048 * 512;  out = e2T + (long)(z - 8) * 512 * 2048;
        R = 2048; C = 512;
        int lin = blockIdx.y * 64 + blockIdx.x;           // 0..1023 -> (16 x, 64 y)
        c0 = (lin & 15) * 32; r0 = (lin >> 4) * 32;
    }
    int tc = threadIdx.x & 31, tr = threadIdx.x >> 5;
    #pragma unroll
    for (int i = 0; i < 4; i++) {
        int r = tr + i * 8;
        tile[r][tc] = in[(long)(r0 + r) * C + c0 + tc];
    }
    __syncthreads();
    #pragma unroll
    for (int i = 0; i < 4; i++) {
        int r = tr + i * 8;
        out[(long)(c0 + r) * R + r0 + tc] = __float2bfloat16(tile[tc][r]);
    }
}

// ---- split-precision bf16 MFMA GEMM, 64x64 tile (high machine fill) ----
__global__ __launch_bounds__(256) void mgemm64_kernel(
    const bf16* __restrict__ Ah, const bf16* __restrict__ Al,
    const bf16* __restrict__ Bh, const bf16* __restrict__ Bl,
    const float* __restrict__ bias, const float* __restrict__ resid, float* __restrict__ C,
    bf16* __restrict__ Oh, bf16* __restrict__ Ol,
    int M, int N, int K, long a_bat, long b_bat, long c_bat, int cs_m, int cs_n) {
    __shared__ short AsH[2 * 2048];
    __shared__ short AsL[2 * 2048];
    __shared__ short BsH[2 * 2048];
    __shared__ short BsL[2 * 2048];
    int bat = blockIdx.z;
    const short* AbH = (const short*)(Ah + (long)bat * a_bat);
    const short* AbL = (const short*)(Al + (long)bat * a_bat);
    const short* BbH = (const short*)(Bh + (long)bat * b_bat);
    const short* BbL = (const short*)(Bl + (long)bat * b_bat);
    float* Cb = C + (long)bat * c_bat;
    const float* Rb = resid ? resid + (long)bat * c_bat : nullptr;
    int bm = blockIdx.y * 64, bn = blockIdx.x * 64;
    int t = threadIdx.x, lane = t & 63, w = t >> 6;
    int wm = (w >> 1) * 32, wn = (w & 1) * 32;
    int r0 = t >> 2, k0s = (t & 3) ^ ((r0 >> 1) & 3);
    int ar0 = bm + r0; if (ar0 > M - 1) ar0 = M - 1;
    long aoff = (long)ar0 * K + k0s * 8;
    long boff = (long)(bn + r0) * K + k0s * 8;
    int fr = lane & 15, fq = lane >> 4;
    int aOff[2], bOff[2];
    #pragma unroll
    for (int i = 0; i < 2; i++) {
        int row = wm + i * 16 + fr;
        aOff[i] = row * 32 + ((fq ^ ((row >> 1) & 3)) * 8);
        int col = wn + i * 16 + fr;
        bOff[i] = col * 32 + ((fq ^ ((col >> 1) & 3)) * 8);
    }
    f32x4 acc[2][2] = {};
    bf16x8 vah = *(const bf16x8*)(AbH + aoff);
    bf16x8 val = *(const bf16x8*)(AbL + aoff);
    bf16x8 vbh = *(const bf16x8*)(BbH + boff);
    bf16x8 vbl = *(const bf16x8*)(BbL + boff);
    int bufo = 0;
    for (int kk = 0; kk < K; kk += 32) {
        *(bf16x8*)&AsH[bufo + t * 8] = vah;
        *(bf16x8*)&AsL[bufo + t * 8] = val;
        *(bf16x8*)&BsH[bufo + t * 8] = vbh;
        *(bf16x8*)&BsL[bufo + t * 8] = vbl;
        __syncthreads();
        int kn = (kk + 32 < K) ? kk + 32 : kk;
        bf16x8 nah = *(const bf16x8*)(AbH + aoff + kn);
        bf16x8 nal = *(const bf16x8*)(AbL + aoff + kn);
        bf16x8 nbh = *(const bf16x8*)(BbH + boff + kn);
        bf16x8 nbl = *(const bf16x8*)(BbL + boff + kn);
        bf16x8 aH[2], aL[2], bH[2], bL[2];
        #pragma unroll
        for (int i = 0; i < 2; i++) {
            aH[i] = *(const bf16x8*)&AsH[bufo + aOff[i]];
            aL[i] = *(const bf16x8*)&AsL[bufo + aOff[i]];
            bH[i] = *(const bf16x8*)&BsH[bufo + bOff[i]];
            bL[i] = *(const bf16x8*)&BsL[bufo + bOff[i]];
        }
        #pragma unroll
        for (int i = 0; i < 2; i++)
        #pragma unroll
        for (int j = 0; j < 2; j++) {
            acc[i][j] = __builtin_amdgcn_mfma_f32_16x16x32_bf16(aH[i], bH[j], acc[i][j], 0, 0, 0);
            acc[i][j] = __builtin_amdgcn_mfma_f32_16x16x32_bf16(aH[i], bL[j], acc[i][j], 0, 0, 0);
            acc[i][j] = __builtin_amdgcn_mfma_f32_16x16x32_bf16(aL[i], bH[j], acc[i][j], 0, 0, 0);
        }
        vah = nah; val = nal; vbh = nbh; vbl = nbl;
        bufo ^= 2048;
    }
    #pragma unroll
    for (int i = 0; i < 2; i++)
    #pragma unroll
    for (int j = 0; j < 2; j++)
    #pragma unroll
    for (int r = 0; r < 4; r++) {
        int row = bm + wm + i * 16 + fq * 4 + r;
        int col = bn + wn + j * 16 + fr;
        if (row < M) {
            long off = (long)row * cs_m + (long)col * cs_n;
            float v = acc[i][j][r];
            if (bias) v += bias[col];
            if (Oh) {
                bf16 hh, ll; split2(v, hh, ll);
                Oh[off] = hh; Ol[off] = ll;
            } else {
                if (Rb) v += Rb[off];
                Cb[off] = v;
            }
        }
    }
}

// ---- split-precision MFMA flash SA: no-max softmax (scores bounded), lane-local l ----
__global__ __launch_bounds__(256) void sa_mfma_kernel(
    const bf16* __restrict__ qh, const bf16* __restrict__ ql,
    bf16* __restrict__ oh, bf16* __restrict__ ol) {
    int qt = blockIdx.x, h = blockIdx.y, b = blockIdx.z;
    __shared__ short KsH[2 * 4096], KsL[2 * 4096];
    __shared__ short VtH[2 * 4096], VtL[2 * 4096];
    __shared__ short PHs[4][1024], PLs[4][1024];
    int t = threadIdx.x, lane = t & 63, w = t >> 6;
    int fr = lane & 15, fq = lane >> 4;
    const short* QH = (const short*)qh;
    const short* QL = (const short*)ql;
    long qrow = (long)(b * 1024 + qt * 64 + w * 16 + fr) * 1536 + h * 64;
    bf16x8 Qh2[2], Ql2[2];
    Qh2[0] = *(const bf16x8*)(QH + qrow + fq * 8);
    Qh2[1] = *(const bf16x8*)(QH + qrow + 32 + fq * 8);
    Ql2[0] = *(const bf16x8*)(QL + qrow + fq * 8);
    Ql2[1] = *(const bf16x8*)(QL + qrow + 32 + fq * 8);
    float l_i[4] = {0.f, 0.f, 0.f, 0.f};
    f32x4 o_acc[4] = {};
    int c0 = t, c1 = t + 256;
    int r0 = c0 >> 3, g0 = c0 & 7;
    int r1 = c1 >> 3, g1 = c1 & 7;
    int kd0 = r0 * 64 + ((g0 * 8) ^ ((r0 & 7) << 3));
    int kd1 = r1 * 64 + ((g1 * 8) ^ ((r1 & 7) << 3));
    long kb = (long)(b * 1024) * 1536 + 512 + h * 64;
    long vb = kb + 512;
    long lo0 = (long)r0 * 1536 + g0 * 8, lo1 = (long)r1 * 1536 + g1 * 8;
    short* ph = PHs[w]; short* pl = PLs[w];
    bf16x8 kh0 = *(const bf16x8*)(QH + kb + lo0);
    bf16x8 kh1 = *(const bf16x8*)(QH + kb + lo1);
    bf16x8 kl0 = *(const bf16x8*)(QL + kb + lo0);
    bf16x8 kl1 = *(const bf16x8*)(QL + kb + lo1);
    bf16x8 vh0 = *(const bf16x8*)(QH + vb + lo0);
    bf16x8 vh1 = *(const bf16x8*)(QH + vb + lo1);
    bf16x8 vl0 = *(const bf16x8*)(QL + vb + lo0);
    bf16x8 vl1 = *(const bf16x8*)(QL + vb + lo1);
    int bufo = 0;
    for (int kt = 0; kt < 16; kt++) {
        *(bf16x8*)&KsH[bufo + kd0] = kh0;  *(bf16x8*)&KsH[bufo + kd1] = kh1;
        *(bf16x8*)&KsL[bufo + kd0] = kl0;  *(bf16x8*)&KsL[bufo + kd1] = kl1;
        #pragma unroll
        for (int j = 0; j < 8; j++) {
            int d0 = g0 * 8 + j;
            int i0 = bufo + d0 * 64 + (r0 ^ (((d0 >> 3) & 7) << 3));
            VtH[i0] = ((short*)&vh0)[j];  VtL[i0] = ((short*)&vl0)[j];
            int d1 = g1 * 8 + j;
            int i1 = bufo + d1 * 64 + (r1 ^ (((d1 >> 3) & 7) << 3));
            VtH[i1] = ((short*)&vh1)[j];  VtL[i1] = ((short*)&vl1)[j];
        }
        __syncthreads();
        int ktn = (kt + 1 < 16) ? kt + 1 : kt;
        long ko = kb + (long)(ktn * 64) * 1536;
        long vo = vb + (long)(ktn * 64) * 1536;
        bf16x8 nkh0 = *(const bf16x8*)(QH + ko + lo0);
        bf16x8 nkh1 = *(const bf16x8*)(QH + ko + lo1);
        bf16x8 nkl0 = *(const bf16x8*)(QL + ko + lo0);
        bf16x8 nkl1 = *(const bf16x8*)(QL + ko + lo1);
        bf16x8 nvh0 = *(const bf16x8*)(QH + vo + lo0);
        bf16x8 nvh1 = *(const bf16x8*)(QH + vo + lo1);
        bf16x8 nvl0 = *(const bf16x8*)(QL + vo + lo0);
        bf16x8 nvl1 = *(const bf16x8*)(QL + vo + lo1);
        __builtin_amdgcn_s_setprio(1);
        f32x4 s[4] = {};
        #pragma unroll
        for (int cf = 0; cf < 4; cf++) {
            int kvrow = cf * 16 + fr;
            #pragma unroll
            for (int kf = 0; kf < 2; kf++) {
                int idx = bufo + kvrow * 64 + ((kf * 32 + fq * 8) ^ ((kvrow & 7) << 3));
                bf16x8 Bh2 = *(const bf16x8*)&KsH[idx];
                bf16x8 Bl2 = *(const bf16x8*)&KsL[idx];
                s[cf] = __builtin_amdgcn_mfma_f32_16x16x32_bf16(Qh2[kf], Bh2, s[cf], 0, 0, 0);
                s[cf] = __builtin_amdgcn_mfma_f32_16x16x32_bf16(Qh2[kf], Bl2, s[cf], 0, 0, 0);
                s[cf] = __builtin_amdgcn_mfma_f32_16x16x32_bf16(Ql2[kf], Bh2, s[cf], 0, 0, 0);
            }
        }
        __builtin_amdgcn_s_setprio(0);
        // ---- no-max softmax accumulation: P = exp(S/8), lane-local l partials ----
        #pragma unroll
        for (int cf = 0; cf < 4; cf++)
        #pragma unroll
        for (int reg = 0; reg < 4; reg++) {
            float e = __expf(s[cf][reg] * 0.125f);
            s[cf][reg] = e;
            l_i[reg] += e;
        }
        #pragma unroll
        for (int cf = 0; cf < 4; cf++)
        #pragma unroll
        for (int reg = 0; reg < 4; reg++) {
            int q = fq * 4 + reg, kv = cf * 16 + fr;
            int idx = q * 64 + (kv ^ ((q & 7) << 3));
            split2s(s[cf][reg], ph[idx], pl[idx]);
        }
        asm volatile("s_waitcnt lgkmcnt(0)" ::: "memory");
        __builtin_amdgcn_sched_barrier(0);
        __builtin_amdgcn_s_setprio(1);
        bf16x8 Pf_h[2], Pf_l[2];
        #pragma unroll
        for (int kf = 0; kf < 2; kf++) {
            int idx = fr * 64 + ((kf * 32 + fq * 8) ^ ((fr & 7) << 3));
            Pf_h[kf] = *(const bf16x8*)&ph[idx];
            Pf_l[kf] = *(const bf16x8*)&pl[idx];
        }
        #pragma unroll
        for (int cf = 0; cf < 4; cf++) {
            int d = cf * 16 + fr;
            #pragma unroll
            for (int kf = 0; kf < 2; kf++) {
                int idx = bufo + d * 64 + ((kf * 32 + fq * 8) ^ (((d >> 3) & 7) << 3));
                bf16x8 Vh2 = *(const bf16x8*)&VtH[idx];
                bf16x8 Vl2 = *(const bf16x8*)&VtL[idx];
                o_acc[cf] = __builtin_amdgcn_mfma_f32_16x16x32_bf16(Pf_h[kf], Vh2, o_acc[cf], 0, 0, 0);
                o_acc[cf] = __builtin_amdgcn_mfma_f32_16x16x32_bf16(Pf_h[kf], Vl2, o_acc[cf], 0, 0, 0);
                o_acc[cf] = __builtin_amdgcn_mfma_f32_16x16x32_bf16(Pf_l[kf], Vh2, o_acc[cf], 0, 0, 0);
            }
        }
        __builtin_amdgcn_s_setprio(0);
        kh0 = nkh0; kh1 = nkh1; kl0 = nkl0; kl1 = nkl1;
        vh0 = nvh0; vh1 = nvh1; vl0 = nvl0; vl1 = nvl1;
        bufo ^= 4096;
    }
    // ---- single final reduce of l across the 16 lanes sharing each row ----
    #pragma unroll
    for (int reg = 0; reg < 4; reg++) {
        float rs = l_i[reg];
        rs += __shfl_xor(rs, 1);
        rs += __shfl_xor(rs, 2);
        rs += __shfl_xor(rs, 4);
        rs += __shfl_xor(rs, 8);
        float inv = 1.f / rs;
        long m = (long)(b * 1024 + qt * 64 + w * 16 + fq * 4 + reg);
        #pragma unroll
        for (int cf = 0; cf < 4; cf++) {
            float v = o_acc[cf][reg] * inv;
            bf16 hh, ll; split2(v, hh, ll);
            long off = m * DIMC + h * 64 + cf * 16 + fr;
            oh[off] = hh; ol[off] = ll;
        }
    }
}

// ---- split-precision MFMA cross-attention: 77 keys padded to 96, no-max softmax ----
__global__ __launch_bounds__(256) void ca_mfma_kernel(
    const bf16* __restrict__ qh, const bf16* __restrict__ ql,
    const bf16* __restrict__ kvh, const bf16* __restrict__ kvl,
    bf16* __restrict__ oh, bf16* __restrict__ ol) {
    int qt = blockIdx.x, h = blockIdx.y, b = blockIdx.z;
    __shared__ short UH[8192], UL[8192];
    __shared__ short PHs[4][2048], PLs[4][2048];
    int t = threadIdx.x, lane = t & 63, w = t >> 6;
    int fr = lane & 15, fq = lane >> 4;
    const short* QH = (const short*)qh;
    const short* QL = (const short*)ql;
    const short* KVH = (const short*)kvh;
    const short* KVL = (const short*)kvl;
    long qrow = (long)(b * 1024 + qt * 64 + w * 16 + fr) * DIMC + h * 64;
    bf16x8 Qh2[2], Ql2[2];
    Qh2[0] = *(const bf16x8*)(QH + qrow + fq * 8);
    Qh2[1] = *(const bf16x8*)(QH + qrow + 32 + fq * 8);
    Ql2[0] = *(const bf16x8*)(QL + qrow + fq * 8);
    Ql2[1] = *(const bf16x8*)(QL + qrow + 32 + fq * 8);
    for (int c = t; c < 768; c += 256) {
        int r = c >> 3, g = c & 7;
        int idx = r * 64 + ((g * 8) ^ ((r & 7) << 3));
        bf16x8 vh = {}, vl = {};
        if (r < 77) {
            long src = (long)(b * 77 + r) * 1024 + h * 64 + g * 8;
            vh = *(const bf16x8*)(KVH + src);
            vl = *(const bf16x8*)(KVL + src);
        }
        *(bf16x8*)&UH[idx] = vh;
        *(bf16x8*)&UL[idx] = vl;
    }
    __syncthreads();
    f32x4 s[5] = {};
    #pragma unroll
    for (int cf = 0; cf < 5; cf++) {
        int kvrow = cf * 16 + fr;
        #pragma unroll
        for (int kf = 0; kf < 2; kf++) {
            int idx = kvrow * 64 + ((kf * 32 + fq * 8) ^ ((kvrow & 7) << 3));
            bf16x8 Bh2 = *(const bf16x8*)&UH[idx];
            bf16x8 Bl2 = *(const bf16x8*)&UL[idx];
            s[cf] = __builtin_amdgcn_mfma_f32_16x16x32_bf16(Qh2[kf], Bh2, s[cf], 0, 0, 0);
            s[cf] = __builtin_amdgcn_mfma_f32_16x16x32_bf16(Qh2[kf], Bl2, s[cf], 0, 0, 0);
            s[cf] = __builtin_amdgcn_mfma_f32_16x16x32_bf16(Ql2[kf], Bh2, s[cf], 0, 0, 0);
        }
    }
    // ---- no-max softmax: masked cols -> exp(-1e30) = 0 ----
    float inv[4];
    #pragma unroll
    for (int reg = 0; reg < 4; reg++) {
        float rs = 0.f;
        #pragma unroll
        for (int cf = 0; cf < 5; cf++) {
            int kv = cf * 16 + fr;
            float e = (kv < 77) ? __expf(s[cf][reg] * 0.125f) : 0.f;
            s[cf][reg] = e;
            rs += e;
        }
        rs += __shfl_xor(rs, 1);
        rs += __shfl_xor(rs, 2);
        rs += __shfl_xor(rs, 4);
        rs += __shfl_xor(rs, 8);
        inv[reg] = 1.f / rs;
    }
    short* ph = PHs[w]; short* pl = PLs[w];
    #pragma unroll
    for (int cf = 0; cf < 6; cf++)
    #pragma unroll
    for (int reg = 0; reg < 4; reg++) {
        int q = fq * 4 + reg, kv = cf * 16 + fr;
        int idx = q * 128 + (kv ^ ((q & 7) << 3));
        float pv = (cf < 5) ? s[cf][reg] * inv[reg] : 0.f;
        split2s(pv, ph[idx], pl[idx]);
    }
    __syncthreads();
    for (int c = t; c < 768; c += 256) {
        int r = c >> 3, g = c & 7;
        bf16x8 vh = {}, vl = {};
        if (r < 77) {
            long src = (long)(b * 77 + r) * 1024 + 512 + h * 64 + g * 8;
            vh = *(const bf16x8*)(KVH + src);
            vl = *(const bf16x8*)(KVL + src);
        }
        #pragma unroll
        for (int j = 0; j < 8; j++) {
            int d = g * 8 + j;
            int idx = d * 128 + (r ^ (((d >> 3) & 7) << 3));
            UH[idx] = ((short*)&vh)[j];
            UL[idx] = ((short*)&vl)[j];
        }
    }
    __syncthreads();
    f32x4 o_acc[4] = {};
    bf16x8 Pf_h[3], Pf_l[3];
    #pragma unroll
    for (int kf = 0; kf < 3; kf++) {
        int idx = fr * 128 + ((kf * 32 + fq * 8) ^ ((fr & 7) << 3));
        Pf_h[kf] = *(const bf16x8*)&ph[idx];
        Pf_l[kf] = *(const bf16x8*)&pl[idx];
    }
    #pragma unroll
    for (int cf = 0; cf < 4; cf++) {
        int d = cf * 16 + fr;
        #pragma unroll
        for (int kf = 0; kf < 3; kf++) {
            int idx = d * 128 + ((kf * 32 + fq * 8) ^ (((d >> 3) & 7) << 3));
            bf16x8 Vh2 = *(const bf16x8*)&UH[idx];
            bf16x8 Vl2 = *(const bf16x8*)&UL[idx];
            o_acc[cf] = __builtin_amdgcn_mfma_f32_16x16x32_bf16(Pf_h[kf], Vh2, o_acc[cf], 0, 0, 0);
            o_acc[cf] = __builtin_amdgcn_mfma_f32_16x16x32_bf16(Pf_h[kf], Vl2, o_acc[cf], 0, 0, 0);
            o_acc[cf] = __builtin_amdgcn_mfma_f32_16x16x32_bf16(Pf_l[kf], Vh2, o_acc[cf], 0, 0, 0);
        }
    }
    #pragma unroll
    for (int reg = 0; reg < 4; reg++) {
        long m = (long)(b * 1024 + qt * 64 + w * 16 + fq * 4 + reg);
        #pragma unroll
        for (int cf = 0; cf < 4; cf++) {
            bf16 hh, ll; split2(o_acc[cf][reg], hh, ll);
            long off = m * DIMC + h * 64 + cf * 16 + fr;
            oh[off] = hh; ol[off] = ll;
        }
    }
}

// ---- MoE grouped MFMA GEMM1, 64x64 tile: hid = gelu(xn·w1 + b1), K=512 ----
__global__ __launch_bounds__(256) void moe64_1_kernel(
    const bf16* __restrict__ xn_b, const bf16* __restrict__ e1T, const float* __restrict__ e_b1,
    const int* __restrict__ table, const int* __restrict__ ntiles, const int* __restrict__ perm,
    bf16* __restrict__ hid_b) {
    if (blockIdx.y >= ntiles[0]) return;
    int e = table[2 * blockIdx.y], row0 = table[2 * blockIdx.y + 1];
    int bn = blockIdx.x * 64;
    __shared__ short As[2 * 2048];
    __shared__ short Bs[2 * 2048];
    __shared__ int rowsS[64];
    int t = threadIdx.x, lane = t & 63, w = t >> 6;
    if (t < 64) rowsS[t] = perm[row0 + t];
    __syncthreads();
    int wm = (w >> 1) * 32, wn = (w & 1) * 32;
    int r0 = t >> 2, k0s = (t & 3) ^ ((r0 >> 1) & 3);
    int tok0 = rowsS[r0]; if (tok0 < 0) tok0 = 0;
    const short* Xs = (const short*)xn_b;
    const short* Ws = (const short*)(e1T + (long)e * HIDC * DIMC);
    const short* a0 = Xs + (long)tok0 * DIMC + k0s * 8;
    const short* b0 = Ws + (long)(bn + r0) * DIMC + k0s * 8;
    int fr = lane & 15, fq = lane >> 4;
    int aOff[2], bOff[2];
    #pragma unroll
    for (int i = 0; i < 2; i++) {
        int row = wm + i * 16 + fr;
        aOff[i] = row * 32 + ((fq ^ ((row >> 1) & 3)) * 8);
        int col = wn + i * 16 + fr;
        bOff[i] = col * 32 + ((fq ^ ((col >> 1) & 3)) * 8);
    }
    f32x4 acc[2][2] = {};
    bf16x8 va = *(const bf16x8*)(a0);
    bf16x8 vb = *(const bf16x8*)(b0);
    int bufo = 0;
    for (int kk = 0; kk < DIMC; kk += 32) {
        *(bf16x8*)&As[bufo + t * 8] = va;
        *(bf16x8*)&Bs[bufo + t * 8] = vb;
        __syncthreads();
        int kn = (kk + 32 < DIMC) ? kk + 32 : kk;
        bf16x8 na = *(const bf16x8*)(a0 + kn);
        bf16x8 nb = *(const bf16x8*)(b0 + kn);
        bf16x8 aF[2], bF[2];
        #pragma unroll
        for (int i = 0; i < 2; i++) {
            aF[i] = *(const bf16x8*)&As[bufo + aOff[i]];
            bF[i] = *(const bf16x8*)&Bs[bufo + bOff[i]];
        }
        #pragma unroll
        for (int i = 0; i < 2; i++)
        #pragma unroll
        for (int j = 0; j < 2; j++)
            acc[i][j] = __builtin_amdgcn_mfma_f32_16x16x32_bf16(aF[i], bF[j], acc[i][j], 0, 0, 0);
        va = na; vb = nb;
        bufo ^= 2048;
    }
    const float* bb = e_b1 + (long)e * HIDC;
    #pragma unroll
    for (int i = 0; i < 2; i++)
    #pragma unroll
    for (int r = 0; r < 4; r++) {
        int tok = rowsS[wm + i * 16 + fq * 4 + r];
        if (tok < 0) continue;
        #pragma unroll
        for (int j = 0; j < 2; j++) {
            int col = bn + wn + j * 16 + fr;
            float v = acc[i][j][r] + bb[col];
            v = 0.5f * v * (1.f + erff(v * 0.70710678f));
            hid_b[(long)tok * HIDC + col] = __float2bfloat16(v);
        }
    }
}

// ---- MoE grouped MFMA GEMM2, 64x64 tile: out = resid + hid·w2 + b2 -> split bf16 ----
__global__ __launch_bounds__(256) void moe64_2_kernel(
    const bf16* __restrict__ hid_b, const bf16* __restrict__ e2T, const float* __restrict__ e_b2,
    const int* __restrict__ table, const int* __restrict__ ntiles, const int* __restrict__ perm,
    const float* __restrict__ resid, bf16* __restrict__ outh, bf16* __restrict__ outl) {
    if (blockIdx.y >= ntiles[0]) return;
    int e = table[2 * blockIdx.y], row0 = table[2 * blockIdx.y + 1];
    int bn = blockIdx.x * 64;
    __shared__ short As[2 * 2048];
    __shared__ short Bs[2 * 2048];
    __shared__ int rowsS[64];
    int t = threadIdx.x, lane = t & 63, w = t >> 6;
    if (t < 64) rowsS[t] = perm[row0 + t];
    __syncthreads();
    int wm = (w >> 1) * 32, wn = (w & 1) * 32;
    int r0 = t >> 2, k0s = (t & 3) ^ ((r0 >> 1) & 3);
    int tok0 = rowsS[r0]; if (tok0 < 0) tok0 = 0;
    const short* Hs = (const short*)hid_b;
    const short* Ws = (const short*)(e2T + (long)e * DIMC * HIDC);
    const short* a0 = Hs + (long)tok0 * HIDC + k0s * 8;
    const short* b0 = Ws + (long)(bn + r0) * HIDC + k0s * 8;
    int fr = lane & 15, fq = lane >> 4;
    int aOff[2], bOff[2];
    #pragma unroll
    for (int i = 0; i < 2; i++) {
        int row = wm + i * 16 + fr;
        aOff[i] = row * 32 + ((fq ^ ((row >> 1) & 3)) * 8);
        int col = wn + i * 16 + fr;
        bOff[i] = col * 32 + ((fq ^ ((col >> 1) & 3)) * 8);
    }
    f32x4 acc[2][2] = {};
    bf16x8 va = *(const bf16x8*)(a0);
    bf16x8 vb = *(const bf16x8*)(b0);
    int bufo = 0;
    for (int kk = 0; kk < HIDC; kk += 32) {
        *(bf16x8*)&As[bufo + t * 8] = va;
        *(bf16x8*)&Bs[bufo + t * 8] = vb;
        __syncthreads();
        int kn = (kk + 32 < HIDC) ? kk + 32 : kk;
        bf16x8 na = *(const bf16x8*)(a0 + kn);
        bf16x8 nb = *(const bf16x8*)(b0 + kn);
        bf16x8 aF[2], bF[2];
        #pragma unroll
        for (int i = 0; i < 2; i++) {
            aF[i] = *(const bf16x8*)&As[bufo + aOff[i]];
            bF[i] = *(const bf16x8*)&Bs[bufo + bOff[i]];
        }
        #pragma unroll
        for (int i = 0; i < 2; i++)
        #pragma unroll
        for (int j = 0; j < 2; j++)
            acc[i][j] = __builtin_amdgcn_mfma_f32_16x16x32_bf16(aF[i], bF[j], acc[i][j], 0, 0, 0);
        va = na; vb = nb;
        bufo ^= 2048;
    }
    const float* bb = e_b2 + (long)e * DIMC;
    #pragma unroll
    for (int i = 0; i < 2; i++)
    #pragma unroll
    for (int r = 0; r < 4; r++) {
        int tok = rowsS[wm + i * 16 + fq * 4 + r];
        if (tok < 0) continue;
        #pragma unroll
        for (int j = 0; j < 2; j++) {
            int col = bn + wn + j * 16 + fr;
            long off = (long)tok * DIMC + col;
            float v = resid[off] + acc[i][j][r] + bb[col];
            bf16 hh, ll; split2(v, hh, ll);
            outh[off] = hh; outl[off] = ll;
        }
    }
}

// ---------------- LayerNorm: optional fp32 + bf16 hi/lo outputs ----------------
__global__ void ln_kernel(const float* __restrict__ x, const float* __restrict__ g,
                          const float* __restrict__ b, float* __restrict__ y,
                          bf16* __restrict__ yh, bf16* __restrict__ yl) {
    int tok = blockIdx.x;
    int t = threadIdx.x;
    const float* xr = x + (long)tok * DIMC;
    float v0 = xr[t], v1 = xr[t + 256];
    __shared__ float red[256];
    red[t] = v0 + v1; __syncthreads();
    for (int s = 128; s > 0; s >>= 1) { if (t < s) red[t] += red[t + s]; __syncthreads(); }
    float mu = red[0] * (1.f / DIMC);
    __syncthreads();
    float d0 = v0 - mu, d1 = v1 - mu;
    red[t] = d0 * d0 + d1 * d1; __syncthreads();
    for (int s = 128; s > 0; s >>= 1) { if (t < s) red[t] += red[t + s]; __syncthreads(); }
    float rs = rsqrtf(red[0] * (1.f / DIMC) + 1e-5f);
    float o0 = d0 * rs * g[t] + b[t];
    float o1 = d1 * rs * g[t + 256] + b[t + 256];
    if (y) { y[(long)tok * DIMC + t] = o0; y[(long)tok * DIMC + t + 256] = o1; }
    bf16 h, l;
    split2(o0, h, l); yh[(long)tok * DIMC + t] = h;       yl[(long)tok * DIMC + t] = l;
    split2(o1, h, l); yh[(long)tok * DIMC + t + 256] = h; yl[(long)tok * DIMC + t + 256] = l;
}

// ---------------- router text part (+ cnt zeroing) ----------------
__global__ void textpart_kernel(const float* __restrict__ w, const float* __restrict__ r_text_mu,
                                const float* __restrict__ r_comb_mu, float* __restrict__ tp,
                                int* __restrict__ cnt) {
    __shared__ float tw[4][128];
    int t = threadIdx.x;
    if (t < NE) cnt[t] = 0;
    for (int j = 0; j < 2; j++) {
        int idx = t + j * 256; int b = idx >> 7, c = idx & 127;
        const float* wr = w + (long)b * LATC;
        float s = 0.f;
        for (int k = 0; k < LATC; k++) s += wr[k] * r_text_mu[(long)k * 128 + c];
        tw[b][c] = s;
    }
    __syncthreads();
    if (t < 32) {
        int b = t >> 3, e = t & 7;
        float s = 0.f;
        for (int c = 0; c < 128; c++) s += tw[b][c] * r_comb_mu[(long)(128 + c) * 8 + e];
        tp[t] = s;
    }
}

// ---------------- router: perm poison + logits + argmax ----------------
__global__ void route_kernel(const float* __restrict__ feat, const float* __restrict__ tp,
                             const float* __restrict__ r_comb_mu, const float* __restrict__ r_temp,
                             float* __restrict__ onehot, int* __restrict__ idx, int* __restrict__ cnt,
                             int* __restrict__ perm) {
    int n = blockIdx.x * blockDim.x + threadIdx.x;
    if (n < MAXT * 64) perm[n] = -1;
    if (n >= NTOK) return;
    int b = n >> 10;
    float tmp = fmaxf(r_temp[0], 0.1f);
    float invt = 1.f / tmp;
    const float* fr = feat + (long)n * 128;
    float lg[8];
    for (int e = 0; e < 8; e++) {
        float s = 0.f;
        for (int c = 0; c < 128; c++) s += fr[c] * r_comb_mu[(long)c * 8 + e];
        lg[e] = (s + tp[b * 8 + e]) * invt;
    }
    float best = lg[0]; int bi = 0;
    for (int e = 1; e < 8; e++) { if (lg[e] > best) { best = lg[e]; bi = e; } }
    for (int e = 0; e < 8; e++) onehot[(long)n * 8 + e] = (e == bi) ? 1.f : 0.f;
    idx[n] = bi;
    atomicAdd(&cnt[bi], 1);
}

// ---------------- offsets + scatter fused (single block, LDS cursors) ----------------
__global__ void offscatter_kernel(const int* __restrict__ cnt, const int* __restrict__ idx,
                                  int* __restrict__ ntiles, int* __restrict__ table,
                                  int* __restrict__ perm) {
    __shared__ int cur[NE];
    int t = threadIdx.x;
    if (t == 0) {
        int po = 0, nt = 0;
        for (int e = 0; e < NE; e++) {
            cur[e] = po;
            int tiles = (cnt[e] + 63) >> 6;
            for (int j = 0; j < tiles; j++) { table[2 * nt] = e; table[2 * nt + 1] = po + j * 64; nt++; }
            po += tiles * 64;
        }
        ntiles[0] = nt;
    }
    __syncthreads();
    for (int n = t; n < NTOK; n += 256) {
        int e = idx[n];
        int pos = atomicAdd(&cur[e], 1);
        perm[pos] = n;
    }
}

extern "C" void kernel_launch(void* const* d_in, const int* in_sizes, int n_in,
                              void* d_out, int out_size, void* d_ws, size_t ws_size,
                              hipStream_t stream) {
    const float* x        = (const float*)d_in[0];
    const float* w        = (const float*)d_in[1];
    const float* text     = (const float*)d_in[2];
    const float* pin_w    = (const float*)d_in[3];
    const float* pin_mw   = (const float*)d_in[4];
    const float* pin_mb   = (const float*)d_in[5];
    const float* pout_w   = (const float*)d_in[6];
    const float* pout_mw  = (const float*)d_in[7];
    const float* pout_mb  = (const float*)d_in[8];
    const float* ln1g     = (const float*)d_in[9];
    const float* ln1b     = (const float*)d_in[10];
    const float* ln2g     = (const float*)d_in[11];
    const float* ln2b     = (const float*)d_in[12];
    const float* ln3g     = (const float*)d_in[13];
    const float* ln3b     = (const float*)d_in[14];
    const float* sa_in_w  = (const float*)d_in[15];
    const float* sa_in_b  = (const float*)d_in[16];
    const float* sa_out_w = (const float*)d_in[17];
    const float* sa_out_b = (const float*)d_in[18];
    const float* ca_in_w  = (const float*)d_in[19];
    const float* ca_in_b  = (const float*)d_in[20];
    const float* ca_out_w = (const float*)d_in[21];
    const float* ca_out_b = (const float*)d_in[22];
    const float* r_feat   = (const float*)d_in[23];
    const float* r_text   = (const float*)d_in[24];
    const float* r_comb   = (const float*)d_in[25];
    const float* r_temp   = (const float*)d_in[26];
    const float* e_w1     = (const float*)d_in[27];
    const float* e_b1     = (const float*)d_in[28];
    const float* e_w2     = (const float*)d_in[29];
    const float* e_b2     = (const float*)d_in[30];

    float* out    = (float*)d_out;               // [B, DIM, H, W]
    float* onehot = out + (long)BB * DIMC * HWX; // [4096, 8]

    // ---------------- workspace: fp32 pool ----------------
    float* f32p = (float*)d_ws;
    float* style_in  = f32p;                 // 2048
    float* style_out = f32p + 2048;          // 2048
    float* tp        = f32p + 4096;          // 32
    int*   idx       = (int*)(f32p + 4128);  // 4096
    int*   cnt       = (int*)(f32p + 8224);  // 8
    int*   ntiles    = (int*)(f32p + 8240);  // 8
    int*   table     = (int*)(f32p + 8248);  // 256
    int*   perm      = (int*)(f32p + 8504);  // 4608 -> ends 13112
    float* x_flat    = f32p + 13496;         // 2097152
    float* xn        = x_flat + 2097152;     // 2097152 (home of wtC split)
    float* qkv       = xn + 2097152;         // 6291456 (SA q split / CA q split home)
    float* spill     = qkv + 6291456;        // 2097152 (e2T tail)

    // ---------------- bf16 pool (phase-aliased) ----------------
    bf16* bp = (bf16*)(f32p + 12596408);
    bf16* R1 = bp;                           // 6291456 elems, phases
    bf16* xT_h  = R1;
    bf16* xT_l  = R1 + 2097152;
    bf16* wtA_h = R1 + 4194304;
    bf16* wtA_l = R1 + 5242880;
    bf16* obuf_h = R1;
    bf16* obuf_l = R1 + 2097152;
    bf16* kvt_h  = R1 + 4194304;                       // [308][1024] split
    bf16* kvt_l  = kvt_h + 315392;
    float* feat  = (float*)(kvt_l + 315392);           // 524288 fp32
    bf16* xn_h = R1 + 6291456;               // 2097152
    bf16* xn_l = xn_h + 2097152;             // 2097152
    bf16* WB   = xn_l + 2097152;             // 8388608: weights (early) / hid_b (late)
    bf16* text_h   = WB;
    bf16* text_l   = text_h + 157696;
    bf16* sawin_h  = text_l + 157696;
    bf16* sawin_l  = sawin_h + 786432;
    bf16* sawout_h = sawin_l + 786432;
    bf16* sawout_l = sawout_h + 262144;
    bf16* caw_h    = sawout_l + 262144;
    bf16* caw_l    = caw_h + 786432;
    bf16* cawout_h = caw_l + 786432;
    bf16* cawout_l = cawout_h + 262144;
    bf16* rfT_h    = cawout_l + 262144;      // [128][512] split r_feat^T
    bf16* rfT_l    = rfT_h + 65536;
    bf16* hid_b    = WB;                     // overlays weights after ca_out
    bf16* e1T = (bf16*)qkv;                  // [8][2048][512] in qkv+spill
    bf16* e2T = e1T + 8388608;
    bf16* xfl_h = xn_h;                      // moe64_2 writes split output here
    bf16* xfl_l = xn_l;
    bf16* wtC_h = (bf16*)xn;                 // modconv-out weight (dead fp32 region)
    bf16* wtC_l = wtC_h + 1048576;
    bf16* q_h = (bf16*)qkv;                  // [4096][1536]
    bf16* q_l = q_h + 6291456;
    bf16* ca_qh = (bf16*)qkv;                // [4096][512]
    bf16* ca_ql = ca_qh + 2097152;
    (void)ws_size; (void)spill;

    auto mg = [&](const bf16* Ah, const bf16* Al, const bf16* Bh, const bf16* Bl,
                  const float* bias, const float* resid, float* C, bf16* Oh, bf16* Ol,
                  int M, int N, int K, long ab, long bb, long cb, int csm, int csn, int nb) {
        dim3 g(N / 64, (M + 63) / 64, nb);
        hipLaunchKernelGGL(mgemm64_kernel, g, dim3(256), 0, stream,
                           Ah, Al, Bh, Bl, bias, resid, C, Oh, Ol, M, N, K, ab, bb, cb, csm, csn);
    };

    // ---- fused input conversions (hi/lo): one launch for all 5 flat arrays ----
    {
        int n0 = 1536 * 512, n1 = 512 * 512, n2 = 1536 * 512, n3 = 512 * 512, n4 = BB * TXT * 512;
        int total = n0 + n1 + n2 + n3 + n4;
        hipLaunchKernelGGL(cvtall_kernel, dim3((total / 4 + 255) / 256), dim3(256), 0, stream,
                           sa_in_w, sawin_h, sawin_l, n0,
                           sa_out_w, sawout_h, sawout_l, n1,
                           ca_in_w, caw_h, caw_l, n2,
                           ca_out_w, cawout_h, cawout_l, n3,
                           text, text_h, text_l, n4);
    }
    // ---- fused transposes: x (z<4) + r_feat (z==4) ----
    hipLaunchKernelGGL(trcvt2x_kernel, dim3(32, 16, 5), dim3(256), 0, stream,
                       x, xT_h, xT_l, r_feat, rfT_h, rfT_l);

    // ---- both modconv styles + weights up front (wtC in dead xn region) ----
    hipLaunchKernelGGL(style2_kernel, dim3(16), dim3(256), 0, stream,
                       w, pin_mw, pin_mb, pout_mw, pout_mb, style_in, style_out);
    hipLaunchKernelGGL(wtmod2_kernel, dim3(2 * BB * DIMC), dim3(256), 0, stream,
                       pin_w, style_in, pout_w, style_out, wtA_h, wtA_l, wtC_h, wtC_l);

    // ---- modconv in ----
    mg(xT_h, xT_l, wtA_h, wtA_l, nullptr, nullptr, x_flat, nullptr, nullptr,
       HWX, DIMC, DIMC, (long)HWX * DIMC, (long)DIMC * DIMC, (long)HWX * DIMC, DIMC, 1, BB);

    // ---- LN1 + self-attention (split MFMA) ----
    hipLaunchKernelGGL(ln_kernel, dim3(NTOK), dim3(256), 0, stream, x_flat, ln1g, ln1b,
                       (float*)nullptr, xn_h, xn_l);
    mg(xn_h, xn_l, sawin_h, sawin_l, sa_in_b, nullptr, nullptr, q_h, q_l,
       NTOK, 1536, 512, 0, 0, 0, 1536, 1, 1);
    hipLaunchKernelGGL(sa_mfma_kernel, dim3(16, HEADS, BB), dim3(256), 0, stream,
                       q_h, q_l, obuf_h, obuf_l);
    mg(obuf_h, obuf_l, sawout_h, sawout_l, sa_out_b, x_flat, x_flat, nullptr, nullptr,
       NTOK, 512, 512, 0, 0, 0, 512, 1, 1);

    // ---- LN2 + cross-attention (split MFMA) ----
    hipLaunchKernelGGL(ln_kernel, dim3(NTOK), dim3(256), 0, stream, x_flat, ln2g, ln2b,
                       (float*)nullptr, xn_h, xn_l);
    mg(xn_h, xn_l, caw_h, caw_l, ca_in_b, nullptr, nullptr, ca_qh, ca_ql,
       NTOK, 512, 512, 0, 0, 0, 512, 1, 1);
    mg(text_h, text_l, caw_h + 512 * 512, caw_l + 512 * 512, ca_in_b + 512, nullptr, nullptr,
       kvt_h, kvt_l, BB * TXT, 1024, 512, 0, 0, 0, 1024, 1, 1);
    hipLaunchKernelGGL(ca_mfma_kernel, dim3(16, HEADS, BB), dim3(256), 0, stream,
                       ca_qh, ca_ql, kvt_h, kvt_l, obuf_h, obuf_l);
    // expert weight transposes (qkv region dead after ca_mfma) — one fused launch
    hipLaunchKernelGGL(tr2x_kernel, dim3(64, 16, 16), dim3(256), 0, stream,
                       e_w1, e1T, e_w2, e2T);
    mg(obuf_h, obuf_l, cawout_h, cawout_l, ca_out_b, x_flat, x_flat, nullptr, nullptr,
       NTOK, 512, 512, 0, 0, 0, 512, 1, 1);

    // ---- LN3 + router (feat via split MFMA) ----
    hipLaunchKernelGGL(ln_kernel, dim3(NTOK), dim3(256), 0, stream, x_flat, ln3g, ln3b,
                       (float*)nullptr, xn_h, xn_l);
    mg(xn_h, xn_l, rfT_h, rfT_l, nullptr, nullptr, feat, nullptr, nullptr,
       NTOK, 128, 512, 0, 0, 0, 128, 1, 1);
    hipLaunchKernelGGL(textpart_kernel, dim3(1), dim3(256), 0, stream, w, r_text, r_comb, tp, cnt);
    hipLaunchKernelGGL(route_kernel, dim3(18), dim3(256), 0, stream,
                       feat, tp, r_comb, r_temp, onehot, idx, cnt, perm);
    hipLaunchKernelGGL(offscatter_kernel, dim3(1), dim3(256), 0, stream,
                       cnt, idx, ntiles, table, perm);

    // ---- MoE grouped MFMA GEMMs (64x64 tiles; gemm2 emits split bf16 directly) ----
    hipLaunchKernelGGL(moe64_1_kernel, dim3(HIDC / 64, MAXT), dim3(256), 0, stream,
                       xn_h, e1T, e_b1, table, ntiles, perm, hid_b);
    hipLaunchKernelGGL(moe64_2_kernel, dim3(DIMC / 64, MAXT), dim3(256), 0, stream,
                       hid_b, e2T, e_b2, table, ntiles, perm, x_flat, xfl_h, xfl_l);

    // ---- modconv out (weights already prepared) ----
    mg(wtC_h, wtC_l, xfl_h, xfl_l, nullptr, nullptr, out, nullptr, nullptr,
       DIMC, HWX, DIMC, (long)DIMC * DIMC, (long)HWX * DIMC, (long)DIMC * HWX, HWX, 1, BB);
}

// Round 17
// 505.046 us; speedup vs baseline: 1.4261x; 1.0075x over previous
//
#include <hip/hip_runtime.h>
#include <hip/hip_bf16.h>
#include <math.h>

#define DIMC 512
#define HEADS 8
#define HD 64
#define BB 4
#define HWX 1024
#define TXT 77
#define LATC 512
#define NE 8
#define HIDC 2048
#define NTOK 4096
#define MAXT 72           // MoE tiles of 64: 4096/64 + 8

typedef __attribute__((ext_vector_type(8))) short bf16x8;
typedef __attribute__((ext_vector_type(4))) float f32x4;
typedef __hip_bfloat16 bf16;

__device__ __forceinline__ void split2(float v, bf16& h, bf16& l) {
    h = __float2bfloat16(v);
    l = __float2bfloat16(v - __bfloat162float(h));
}
__device__ __forceinline__ void split2s(float v, short& h, short& l) {
    bf16 hb, lb; split2(v, hb, lb);
    h = *(short*)&hb; l = *(short*)&lb;
}

// ---------------- both styles in one launch: job 0 = in, job 1 = out ----------------
__global__ void style2_kernel(const float* __restrict__ w,
                              const float* __restrict__ mwA, const float* __restrict__ mbA,
                              const float* __restrict__ mwB, const float* __restrict__ mbB,
                              float* __restrict__ sA, float* __restrict__ sB) {
    int g = blockIdx.x * blockDim.x + threadIdx.x;
    int job = (g >= BB * DIMC) ? 1 : 0;
    int t = g - job * BB * DIMC;
    if (t >= BB * DIMC) return;
    const float* mw = job ? mwB : mwA;
    const float* mb = job ? mbB : mbA;
    float* st = job ? sB : sA;
    int b = t / DIMC, i = t % DIMC;
    const float* wr = w + (long)b * LATC;
    const float* mr = mw + (long)i * LATC;
    float s = 0.f;
    #pragma unroll 8
    for (int l = 0; l < LATC; l++) s += wr[l] * mr[l];
    st[t] = s + mb[i];
}

// ------- both wtmods in one launch -------
__global__ void wtmod2_kernel(const float* __restrict__ wA, const float* __restrict__ sA,
                              const float* __restrict__ wB, const float* __restrict__ sB,
                              bf16* __restrict__ whA, bf16* __restrict__ wlA,
                              bf16* __restrict__ whB, bf16* __restrict__ wlB) {
    int gb = blockIdx.x;
    int job = (gb >= BB * DIMC) ? 1 : 0;
    int bo = gb - job * BB * DIMC;
    const float* weight = job ? wB : wA;
    const float* style  = job ? sB : sA;
    bf16* wh = job ? whB : whA;
    bf16* wl = job ? wlB : wlA;
    int b = bo / DIMC, o = bo % DIMC;
    const float* wr = weight + (long)o * DIMC;
    const float* sr = style + (long)b * DIMC;
    int t = threadIdx.x;
    float vals[2]; float part = 0.f;
    for (int j = 0; j < 2; j++) {
        int i = t + j * 256;
        float v = wr[i] * sr[i];
        vals[j] = v; part += v * v;
    }
    __shared__ float red[256];
    red[t] = part; __syncthreads();
    for (int s = 128; s > 0; s >>= 1) { if (t < s) red[t] += red[t + s]; __syncthreads(); }
    float d = rsqrtf(red[0] + 1e-8f);
    for (int j = 0; j < 2; j++) {
        int i = t + j * 256;
        bf16 h, l; split2(vals[j] * d, h, l);
        wh[(long)bo * DIMC + i] = h; wl[(long)bo * DIMC + i] = l;
    }
}

// ---------------- fused segmented fp32 -> bf16 hi/lo convert (5 weight arrays) ----------------
__global__ void cvtall_kernel(
    const float* __restrict__ s0, bf16* __restrict__ h0, bf16* __restrict__ l0, int n0,
    const float* __restrict__ s1, bf16* __restrict__ h1, bf16* __restrict__ l1, int n1,
    const float* __restrict__ s2, bf16* __restrict__ h2, bf16* __restrict__ l2, int n2,
    const float* __restrict__ s3, bf16* __restrict__ h3, bf16* __restrict__ l3, int n3,
    const float* __restrict__ s4, bf16* __restrict__ h4, bf16* __restrict__ l4, int n4) {
    int i = (blockIdx.x * blockDim.x + threadIdx.x) * 4;
    const float* src; bf16 *hh, *ll;
    if (i < n0) { src = s0; hh = h0; ll = l0; }
    else if ((i -= n0) < n1) { src = s1; hh = h1; ll = l1; }
    else if ((i -= n1) < n2) { src = s2; hh = h2; ll = l2; }
    else if ((i -= n2) < n3) { src = s3; hh = h3; ll = l3; }
    else if ((i -= n3) < n4) { src = s4; hh = h4; ll = l4; }
    else return;
    float4 v = *(const float4*)(src + i);
    float a[4] = {v.x, v.y, v.z, v.w};
    #pragma unroll
    for (int j = 0; j < 4; j++) { bf16 h, l; split2(a[j], h, l); hh[i + j] = h; ll[i + j] = l; }
}

// ---- fused transpose hi/lo: z<4 -> x slice (512x1024), z==4 -> r_feat (512x128) ----
__global__ void trcvt2x_kernel(const float* __restrict__ x, bf16* __restrict__ xh,
                               bf16* __restrict__ xl, const float* __restrict__ rf,
                               bf16* __restrict__ rfh, bf16* __restrict__ rfl) {
    __shared__ float tile[32][33];
    int z = blockIdx.z;
    const float* in; bf16 *hi, *lo; int R, C;
    if (z < 4) {
        in = x + (long)z * 512 * 1024;
        hi = xh + (long)z * 1024 * 512; lo = xl + (long)z * 1024 * 512;
        R = 512; C = 1024;
    } else {
        if (blockIdx.x >= 4) return;
        in = rf; hi = rfh; lo = rfl;
        R = 512; C = 128;
    }
    int c0 = blockIdx.x * 32, r0 = blockIdx.y * 32;
    int tc = threadIdx.x & 31, tr = threadIdx.x >> 5;
    #pragma unroll
    for (int i = 0; i < 4; i++) {
        int r = tr + i * 8;
        tile[r][tc] = in[(long)(r0 + r) * C + c0 + tc];
    }
    __syncthreads();
    #pragma unroll
    for (int i = 0; i < 4; i++) {
        int r = tr + i * 8;
        bf16 h, l; split2(tile[tc][r], h, l);
        hi[(long)(c0 + r) * R + r0 + tc] = h;
        lo[(long)(c0 + r) * R + r0 + tc] = l;
    }
}

// ---- fused expert-weight transposes: z<8 -> e_w1[z] (512x2048), z>=8 -> e_w2[z-8] (2048x512) ----
__global__ void tr2x_kernel(const float* __restrict__ w1, bf16* __restrict__ e1T,
                            const float* __restrict__ w2, bf16* __restrict__ e2T) {
    __shared__ float tile[32][33];
    int z = blockIdx.z;
    const float* in; bf16* out; int R, C, c0, r0;
    if (z < 8) {
        in = w1 + (long)z * 512 * 2048;  out = e1T + (long)z * 2048 * 512;
        R = 512; C = 2048;
        c0 = blockIdx.x * 32; r0 = blockIdx.y * 32;       // grid x=64, y=16
    } else {
        in = w2 + (long)(z - 8) * 2048 * 512;  out = e2T + (long)(z - 8) * 512 * 2048;
        R = 2048; C = 512;
        int lin = blockIdx.y * 64 + blockIdx.x;           // 0..1023 -> (16 x, 64 y)
        c0 = (lin & 15) * 32; r0 = (lin >> 4) * 32;
    }
    int tc = threadIdx.x & 31, tr = threadIdx.x >> 5;
    #pragma unroll
    for (int i = 0; i < 4; i++) {
        int r = tr + i * 8;
        tile[r][tc] = in[(long)(r0 + r) * C + c0 + tc];
    }
    __syncthreads();
    #pragma unroll
    for (int i = 0; i < 4; i++) {
        int r = tr + i * 8;
        out[(long)(c0 + r) * R + r0 + tc] = __float2bfloat16(tile[tc][r]);
    }
}

// ---- split-precision bf16 MFMA GEMM, 64x64 tile (high machine fill) ----
__global__ __launch_bounds__(256) void mgemm64_kernel(
    const bf16* __restrict__ Ah, const bf16* __restrict__ Al,
    const bf16* __restrict__ Bh, const bf16* __restrict__ Bl,
    const float* __restrict__ bias, const float* __restrict__ resid, float* __restrict__ C,
    bf16* __restrict__ Oh, bf16* __restrict__ Ol,
    int M, int N, int K, long a_bat, long b_bat, long c_bat, int cs_m, int cs_n) {
    __shared__ short AsH[2 * 2048];
    __shared__ short AsL[2 * 2048];
    __shared__ short BsH[2 * 2048];
    __shared__ short BsL[2 * 2048];
    int bat = blockIdx.z;
    const short* AbH = (const short*)(Ah + (long)bat * a_bat);
    const short* AbL = (const short*)(Al + (long)bat * a_bat);
    const short* BbH = (const short*)(Bh + (long)bat * b_bat);
    const short* BbL = (const short*)(Bl + (long)bat * b_bat);
    float* Cb = C + (long)bat * c_bat;
    const float* Rb = resid ? resid + (long)bat * c_bat : nullptr;
    int bm = blockIdx.y * 64, bn = blockIdx.x * 64;
    int t = threadIdx.x, lane = t & 63, w = t >> 6;
    int wm = (w >> 1) * 32, wn = (w & 1) * 32;
    int r0 = t >> 2, k0s = (t & 3) ^ ((r0 >> 1) & 3);
    int ar0 = bm + r0; if (ar0 > M - 1) ar0 = M - 1;
    long aoff = (long)ar0 * K + k0s * 8;
    long boff = (long)(bn + r0) * K + k0s * 8;
    int fr = lane & 15, fq = lane >> 4;
    int aOff[2], bOff[2];
    #pragma unroll
    for (int i = 0; i < 2; i++) {
        int row = wm + i * 16 + fr;
        aOff[i] = row * 32 + ((fq ^ ((row >> 1) & 3)) * 8);
        int col = wn + i * 16 + fr;
        bOff[i] = col * 32 + ((fq ^ ((col >> 1) & 3)) * 8);
    }
    f32x4 acc[2][2] = {};
    bf16x8 vah = *(const bf16x8*)(AbH + aoff);
    bf16x8 val = *(const bf16x8*)(AbL + aoff);
    bf16x8 vbh = *(const bf16x8*)(BbH + boff);
    bf16x8 vbl = *(const bf16x8*)(BbL + boff);
    int bufo = 0;
    for (int kk = 0; kk < K; kk += 32) {
        *(bf16x8*)&AsH[bufo + t * 8] = vah;
        *(bf16x8*)&AsL[bufo + t * 8] = val;
        *(bf16x8*)&BsH[bufo + t * 8] = vbh;
        *(bf16x8*)&BsL[bufo + t * 8] = vbl;
        __syncthreads();
        int kn = (kk + 32 < K) ? kk + 32 : kk;
        bf16x8 nah = *(const bf16x8*)(AbH + aoff + kn);
        bf16x8 nal = *(const bf16x8*)(AbL + aoff + kn);
        bf16x8 nbh = *(const bf16x8*)(BbH + boff + kn);
        bf16x8 nbl = *(const bf16x8*)(BbL + boff + kn);
        bf16x8 aH[2], aL[2], bH[2], bL[2];
        #pragma unroll
        for (int i = 0; i < 2; i++) {
            aH[i] = *(const bf16x8*)&AsH[bufo + aOff[i]];
            aL[i] = *(const bf16x8*)&AsL[bufo + aOff[i]];
            bH[i] = *(const bf16x8*)&BsH[bufo + bOff[i]];
            bL[i] = *(const bf16x8*)&BsL[bufo + bOff[i]];
        }
        #pragma unroll
        for (int i = 0; i < 2; i++)
        #pragma unroll
        for (int j = 0; j < 2; j++) {
            acc[i][j] = __builtin_amdgcn_mfma_f32_16x16x32_bf16(aH[i], bH[j], acc[i][j], 0, 0, 0);
            acc[i][j] = __builtin_amdgcn_mfma_f32_16x16x32_bf16(aH[i], bL[j], acc[i][j], 0, 0, 0);
            acc[i][j] = __builtin_amdgcn_mfma_f32_16x16x32_bf16(aL[i], bH[j], acc[i][j], 0, 0, 0);
        }
        vah = nah; val = nal; vbh = nbh; vbl = nbl;
        bufo ^= 2048;
    }
    #pragma unroll
    for (int i = 0; i < 2; i++)
    #pragma unroll
    for (int j = 0; j < 2; j++)
    #pragma unroll
    for (int r = 0; r < 4; r++) {
        int row = bm + wm + i * 16 + fq * 4 + r;
        int col = bn + wn + j * 16 + fr;
        if (row < M) {
            long off = (long)row * cs_m + (long)col * cs_n;
            float v = acc[i][j][r];
            if (bias) v += bias[col];
            if (Oh) {
                bf16 hh, ll; split2(v, hh, ll);
                Oh[off] = hh; Ol[off] = ll;
            } else {
                if (Rb) v += Rb[off];
                Cb[off] = v;
            }
        }
    }
}

// ---- split-precision MFMA flash SA: no-max softmax, bank-conflict-free V (stride 72),
//      single-buffered K/V with 2 barriers/iter, post-barrier prefetch, setprio ----
__global__ __launch_bounds__(256) void sa_mfma_kernel(
    const bf16* __restrict__ qh, const bf16* __restrict__ ql,
    bf16* __restrict__ oh, bf16* __restrict__ ol) {
    int qt = blockIdx.x, h = blockIdx.y, b = blockIdx.z;
    __shared__ short KsH[4096], KsL[4096];       // [kv][64], swz: col ^ ((kv&7)<<3)
    __shared__ short VtH[4608], VtL[4608];       // [d][72], swz: col ^ (((d>>3)&7)<<3)
    __shared__ short PHs[4][1024], PLs[4][1024]; // per-wave P
    int t = threadIdx.x, lane = t & 63, w = t >> 6;
    int fr = lane & 15, fq = lane >> 4;
    const short* QH = (const short*)qh;
    const short* QL = (const short*)ql;
    long qrow = (long)(b * 1024 + qt * 64 + w * 16 + fr) * 1536 + h * 64;
    bf16x8 Qh2[2], Ql2[2];
    Qh2[0] = *(const bf16x8*)(QH + qrow + fq * 8);
    Qh2[1] = *(const bf16x8*)(QH + qrow + 32 + fq * 8);
    Ql2[0] = *(const bf16x8*)(QL + qrow + fq * 8);
    Ql2[1] = *(const bf16x8*)(QL + qrow + 32 + fq * 8);
    float l_i[4] = {0.f, 0.f, 0.f, 0.f};
    f32x4 o_acc[4] = {};
    int c0 = t, c1 = t + 256;
    int r0 = c0 >> 3, g0 = c0 & 7;               // r0 in 0..31
    int r1 = c1 >> 3, g1 = c1 & 7;               // r1 in 32..63
    int kd0 = r0 * 64 + ((g0 * 8) ^ ((r0 & 7) << 3));
    int kd1 = r1 * 64 + ((g1 * 8) ^ ((r1 & 7) << 3));
    long kb = (long)(b * 1024) * 1536 + 512 + h * 64;
    long vb = kb + 512;
    long lo0 = (long)r0 * 1536 + g0 * 8, lo1 = (long)r1 * 1536 + g1 * 8;
    short* ph = PHs[w]; short* pl = PLs[w];
    // prologue loads (kt = 0)
    bf16x8 kh0 = *(const bf16x8*)(QH + kb + lo0);
    bf16x8 kh1 = *(const bf16x8*)(QH + kb + lo1);
    bf16x8 kl0 = *(const bf16x8*)(QL + kb + lo0);
    bf16x8 kl1 = *(const bf16x8*)(QL + kb + lo1);
    bf16x8 vh0 = *(const bf16x8*)(QH + vb + lo0);
    bf16x8 vh1 = *(const bf16x8*)(QH + vb + lo1);
    bf16x8 vl0 = *(const bf16x8*)(QL + vb + lo0);
    bf16x8 vl1 = *(const bf16x8*)(QL + vb + lo1);
    for (int kt = 0; kt < 16; kt++) {
        __syncthreads();          // A: all waves finished reading Ks/Vt of prev iter
        *(bf16x8*)&KsH[kd0] = kh0;  *(bf16x8*)&KsH[kd1] = kh1;
        *(bf16x8*)&KsL[kd0] = kl0;  *(bf16x8*)&KsL[kd1] = kl1;
        #pragma unroll
        for (int j = 0; j < 8; j++) {
            int d0 = g0 * 8 + j;                       // (d0>>3)&7 == g0
            int i0 = d0 * 72 + (r0 ^ (g0 << 3));
            VtH[i0] = ((short*)&vh0)[j];  VtL[i0] = ((short*)&vl0)[j];
            int d1 = g1 * 8 + j;
            int i1 = d1 * 72 + (r1 ^ (g1 << 3));
            VtH[i1] = ((short*)&vh1)[j];  VtL[i1] = ((short*)&vl1)[j];
        }
        __syncthreads();          // B: staging visible
        // prefetch next KV tile AFTER the barrier (in flight across compute)
        int ktn = (kt + 1 < 16) ? kt + 1 : kt;
        long ko = kb + (long)(ktn * 64) * 1536;
        long vo = vb + (long)(ktn * 64) * 1536;
        bf16x8 nkh0 = *(const bf16x8*)(QH + ko + lo0);
        bf16x8 nkh1 = *(const bf16x8*)(QH + ko + lo1);
        bf16x8 nkl0 = *(const bf16x8*)(QL + ko + lo0);
        bf16x8 nkl1 = *(const bf16x8*)(QL + ko + lo1);
        bf16x8 nvh0 = *(const bf16x8*)(QH + vo + lo0);
        bf16x8 nvh1 = *(const bf16x8*)(QH + vo + lo1);
        bf16x8 nvl0 = *(const bf16x8*)(QL + vo + lo0);
        bf16x8 nvl1 = *(const bf16x8*)(QL + vo + lo1);
        __builtin_amdgcn_s_setprio(1);
        f32x4 s[4] = {};
        #pragma unroll
        for (int cf = 0; cf < 4; cf++) {
            int kvrow = cf * 16 + fr;
            #pragma unroll
            for (int kf = 0; kf < 2; kf++) {
                int idx = kvrow * 64 + ((kf * 32 + fq * 8) ^ ((kvrow & 7) << 3));
                bf16x8 Bh2 = *(const bf16x8*)&KsH[idx];
                bf16x8 Bl2 = *(const bf16x8*)&KsL[idx];
                s[cf] = __builtin_amdgcn_mfma_f32_16x16x32_bf16(Qh2[kf], Bh2, s[cf], 0, 0, 0);
                s[cf] = __builtin_amdgcn_mfma_f32_16x16x32_bf16(Qh2[kf], Bl2, s[cf], 0, 0, 0);
                s[cf] = __builtin_amdgcn_mfma_f32_16x16x32_bf16(Ql2[kf], Bh2, s[cf], 0, 0, 0);
            }
        }
        __builtin_amdgcn_s_setprio(0);
        // ---- no-max softmax accumulation: P = exp(S/8), lane-local l partials ----
        #pragma unroll
        for (int cf = 0; cf < 4; cf++)
        #pragma unroll
        for (int reg = 0; reg < 4; reg++) {
            float e = __expf(s[cf][reg] * 0.125f);
            s[cf][reg] = e;
            l_i[reg] += e;
        }
        #pragma unroll
        for (int cf = 0; cf < 4; cf++)
        #pragma unroll
        for (int reg = 0; reg < 4; reg++) {
            int q = fq * 4 + reg, kv = cf * 16 + fr;
            int idx = q * 64 + (kv ^ ((q & 7) << 3));
            split2s(s[cf][reg], ph[idx], pl[idx]);
        }
        asm volatile("s_waitcnt lgkmcnt(0)" ::: "memory");
        __builtin_amdgcn_sched_barrier(0);
        __builtin_amdgcn_s_setprio(1);
        bf16x8 Pf_h[2], Pf_l[2];
        #pragma unroll
        for (int kf = 0; kf < 2; kf++) {
            int idx = fr * 64 + ((kf * 32 + fq * 8) ^ ((fr & 7) << 3));
            Pf_h[kf] = *(const bf16x8*)&ph[idx];
            Pf_l[kf] = *(const bf16x8*)&pl[idx];
        }
        #pragma unroll
        for (int cf = 0; cf < 4; cf++) {
            int d = cf * 16 + fr;
            #pragma unroll
            for (int kf = 0; kf < 2; kf++) {
                int idx = d * 72 + ((kf * 32 + fq * 8) ^ (((d >> 3) & 7) << 3));
                bf16x8 Vh2 = *(const bf16x8*)&VtH[idx];
                bf16x8 Vl2 = *(const bf16x8*)&VtL[idx];
                o_acc[cf] = __builtin_amdgcn_mfma_f32_16x16x32_bf16(Pf_h[kf], Vh2, o_acc[cf], 0, 0, 0);
                o_acc[cf] = __builtin_amdgcn_mfma_f32_16x16x32_bf16(Pf_h[kf], Vl2, o_acc[cf], 0, 0, 0);
                o_acc[cf] = __builtin_amdgcn_mfma_f32_16x16x32_bf16(Pf_l[kf], Vh2, o_acc[cf], 0, 0, 0);
            }
        }
        __builtin_amdgcn_s_setprio(0);
        kh0 = nkh0; kh1 = nkh1; kl0 = nkl0; kl1 = nkl1;
        vh0 = nvh0; vh1 = nvh1; vl0 = nvl0; vl1 = nvl1;
    }
    // ---- single final reduce of l across the 16 lanes sharing each row ----
    #pragma unroll
    for (int reg = 0; reg < 4; reg++) {
        float rs = l_i[reg];
        rs += __shfl_xor(rs, 1);
        rs += __shfl_xor(rs, 2);
        rs += __shfl_xor(rs, 4);
        rs += __shfl_xor(rs, 8);
        float inv = 1.f / rs;
        long m = (long)(b * 1024 + qt * 64 + w * 16 + fq * 4 + reg);
        #pragma unroll
        for (int cf = 0; cf < 4; cf++) {
            float v = o_acc[cf][reg] * inv;
            bf16 hh, ll; split2(v, hh, ll);
            long off = m * DIMC + h * 64 + cf * 16 + fr;
            oh[off] = hh; ol[off] = ll;
        }
    }
}

// ---- split-precision MFMA cross-attention: 77 keys padded to 96, no-max softmax ----
__global__ __launch_bounds__(256) void ca_mfma_kernel(
    const bf16* __restrict__ qh, const bf16* __restrict__ ql,
    const bf16* __restrict__ kvh, const bf16* __restrict__ kvl,
    bf16* __restrict__ oh, bf16* __restrict__ ol) {
    int qt = blockIdx.x, h = blockIdx.y, b = blockIdx.z;
    __shared__ short UH[8192], UL[8192];
    __shared__ short PHs[4][2048], PLs[4][2048];
    int t = threadIdx.x, lane = t & 63, w = t >> 6;
    int fr = lane & 15, fq = lane >> 4;
    const short* QH = (const short*)qh;
    const short* QL = (const short*)ql;
    const short* KVH = (const short*)kvh;
    const short* KVL = (const short*)kvl;
    long qrow = (long)(b * 1024 + qt * 64 + w * 16 + fr) * DIMC + h * 64;
    bf16x8 Qh2[2], Ql2[2];
    Qh2[0] = *(const bf16x8*)(QH + qrow + fq * 8);
    Qh2[1] = *(const bf16x8*)(QH + qrow + 32 + fq * 8);
    Ql2[0] = *(const bf16x8*)(QL + qrow + fq * 8);
    Ql2[1] = *(const bf16x8*)(QL + qrow + 32 + fq * 8);
    for (int c = t; c < 768; c += 256) {
        int r = c >> 3, g = c & 7;
        int idx = r * 64 + ((g * 8) ^ ((r & 7) << 3));
        bf16x8 vh = {}, vl = {};
        if (r < 77) {
            long src = (long)(b * 77 + r) * 1024 + h * 64 + g * 8;
            vh = *(const bf16x8*)(KVH + src);
            vl = *(const bf16x8*)(KVL + src);
        }
        *(bf16x8*)&UH[idx] = vh;
        *(bf16x8*)&UL[idx] = vl;
    }
    __syncthreads();
    f32x4 s[5] = {};
    #pragma unroll
    for (int cf = 0; cf < 5; cf++) {
        int kvrow = cf * 16 + fr;
        #pragma unroll
        for (int kf = 0; kf < 2; kf++) {
            int idx = kvrow * 64 + ((kf * 32 + fq * 8) ^ ((kvrow & 7) << 3));
            bf16x8 Bh2 = *(const bf16x8*)&UH[idx];
            bf16x8 Bl2 = *(const bf16x8*)&UL[idx];
            s[cf] = __builtin_amdgcn_mfma_f32_16x16x32_bf16(Qh2[kf], Bh2, s[cf], 0, 0, 0);
            s[cf] = __builtin_amdgcn_mfma_f32_16x16x32_bf16(Qh2[kf], Bl2, s[cf], 0, 0, 0);
            s[cf] = __builtin_amdgcn_mfma_f32_16x16x32_bf16(Ql2[kf], Bh2, s[cf], 0, 0, 0);
        }
    }
    // ---- no-max softmax: masked cols contribute 0 ----
    float inv[4];
    #pragma unroll
    for (int reg = 0; reg < 4; reg++) {
        float rs = 0.f;
        #pragma unroll
        for (int cf = 0; cf < 5; cf++) {
            int kv = cf * 16 + fr;
            float e = (kv < 77) ? __expf(s[cf][reg] * 0.125f) : 0.f;
            s[cf][reg] = e;
            rs += e;
        }
        rs += __shfl_xor(rs, 1);
        rs += __shfl_xor(rs, 2);
        rs += __shfl_xor(rs, 4);
        rs += __shfl_xor(rs, 8);
        inv[reg] = 1.f / rs;
    }
    short* ph = PHs[w]; short* pl = PLs[w];
    #pragma unroll
    for (int cf = 0; cf < 6; cf++)
    #pragma unroll
    for (int reg = 0; reg < 4; reg++) {
        int q = fq * 4 + reg, kv = cf * 16 + fr;
        int idx = q * 128 + (kv ^ ((q & 7) << 3));
        float pv = (cf < 5) ? s[cf][reg] * inv[reg] : 0.f;
        split2s(pv, ph[idx], pl[idx]);
    }
    __syncthreads();
    for (int c = t; c < 768; c += 256) {
        int r = c >> 3, g = c & 7;
        bf16x8 vh = {}, vl = {};
        if (r < 77) {
            long src = (long)(b * 77 + r) * 1024 + 512 + h * 64 + g * 8;
            vh = *(const bf16x8*)(KVH + src);
            vl = *(const bf16x8*)(KVL + src);
        }
        #pragma unroll
        for (int j = 0; j < 8; j++) {
            int d = g * 8 + j;
            int idx = d * 128 + (r ^ (((d >> 3) & 7) << 3));
            UH[idx] = ((short*)&vh)[j];
            UL[idx] = ((short*)&vl)[j];
        }
    }
    __syncthreads();
    f32x4 o_acc[4] = {};
    bf16x8 Pf_h[3], Pf_l[3];
    #pragma unroll
    for (int kf = 0; kf < 3; kf++) {
        int idx = fr * 128 + ((kf * 32 + fq * 8) ^ ((fr & 7) << 3));
        Pf_h[kf] = *(const bf16x8*)&ph[idx];
        Pf_l[kf] = *(const bf16x8*)&pl[idx];
    }
    #pragma unroll
    for (int cf = 0; cf < 4; cf++) {
        int d = cf * 16 + fr;
        #pragma unroll
        for (int kf = 0; kf < 3; kf++) {
            int idx = d * 128 + ((kf * 32 + fq * 8) ^ (((d >> 3) & 7) << 3));
            bf16x8 Vh2 = *(const bf16x8*)&UH[idx];
            bf16x8 Vl2 = *(const bf16x8*)&UL[idx];
            o_acc[cf] = __builtin_amdgcn_mfma_f32_16x16x32_bf16(Pf_h[kf], Vh2, o_acc[cf], 0, 0, 0);
            o_acc[cf] = __builtin_amdgcn_mfma_f32_16x16x32_bf16(Pf_h[kf], Vl2, o_acc[cf], 0, 0, 0);
            o_acc[cf] = __builtin_amdgcn_mfma_f32_16x16x32_bf16(Pf_l[kf], Vh2, o_acc[cf], 0, 0, 0);
        }
    }
    #pragma unroll
    for (int reg = 0; reg < 4; reg++) {
        long m = (long)(b * 1024 + qt * 64 + w * 16 + fq * 4 + reg);
        #pragma unroll
        for (int cf = 0; cf < 4; cf++) {
            bf16 hh, ll; split2(o_acc[cf][reg], hh, ll);
            long off = m * DIMC + h * 64 + cf * 16 + fr;
            oh[off] = hh; ol[off] = ll;
        }
    }
}

// ---- MoE grouped MFMA GEMM1, 64x64 tile: hid = gelu(xn·w1 + b1), K=512 ----
__global__ __launch_bounds__(256) void moe64_1_kernel(
    const bf16* __restrict__ xn_b, const bf16* __restrict__ e1T, const float* __restrict__ e_b1,
    const int* __restrict__ table, const int* __restrict__ ntiles, const int* __restrict__ perm,
    bf16* __restrict__ hid_b) {
    if (blockIdx.y >= ntiles[0]) return;
    int e = table[2 * blockIdx.y], row0 = table[2 * blockIdx.y + 1];
    int bn = blockIdx.x * 64;
    __shared__ short As[2 * 2048];
    __shared__ short Bs[2 * 2048];
    __shared__ int rowsS[64];
    int t = threadIdx.x, lane = t & 63, w = t >> 6;
    if (t < 64) rowsS[t] = perm[row0 + t];
    __syncthreads();
    int wm = (w >> 1) * 32, wn = (w & 1) * 32;
    int r0 = t >> 2, k0s = (t & 3) ^ ((r0 >> 1) & 3);
    int tok0 = rowsS[r0]; if (tok0 < 0) tok0 = 0;
    const short* Xs = (const short*)xn_b;
    const short* Ws = (const short*)(e1T + (long)e * HIDC * DIMC);
    const short* a0 = Xs + (long)tok0 * DIMC + k0s * 8;
    const short* b0 = Ws + (long)(bn + r0) * DIMC + k0s * 8;
    int fr = lane & 15, fq = lane >> 4;
    int aOff[2], bOff[2];
    #pragma unroll
    for (int i = 0; i < 2; i++) {
        int row = wm + i * 16 + fr;
        aOff[i] = row * 32 + ((fq ^ ((row >> 1) & 3)) * 8);
        int col = wn + i * 16 + fr;
        bOff[i] = col * 32 + ((fq ^ ((col >> 1) & 3)) * 8);
    }
    f32x4 acc[2][2] = {};
    bf16x8 va = *(const bf16x8*)(a0);
    bf16x8 vb = *(const bf16x8*)(b0);
    int bufo = 0;
    for (int kk = 0; kk < DIMC; kk += 32) {
        *(bf16x8*)&As[bufo + t * 8] = va;
        *(bf16x8*)&Bs[bufo + t * 8] = vb;
        __syncthreads();
        int kn = (kk + 32 < DIMC) ? kk + 32 : kk;
        bf16x8 na = *(const bf16x8*)(a0 + kn);
        bf16x8 nb = *(const bf16x8*)(b0 + kn);
        bf16x8 aF[2], bF[2];
        #pragma unroll
        for (int i = 0; i < 2; i++) {
            aF[i] = *(const bf16x8*)&As[bufo + aOff[i]];
            bF[i] = *(const bf16x8*)&Bs[bufo + bOff[i]];
        }
        #pragma unroll
        for (int i = 0; i < 2; i++)
        #pragma unroll
        for (int j = 0; j < 2; j++)
            acc[i][j] = __builtin_amdgcn_mfma_f32_16x16x32_bf16(aF[i], bF[j], acc[i][j], 0, 0, 0);
        va = na; vb = nb;
        bufo ^= 2048;
    }
    const float* bb = e_b1 + (long)e * HIDC;
    #pragma unroll
    for (int i = 0; i < 2; i++)
    #pragma unroll
    for (int r = 0; r < 4; r++) {
        int tok = rowsS[wm + i * 16 + fq * 4 + r];
        if (tok < 0) continue;
        #pragma unroll
        for (int j = 0; j < 2; j++) {
            int col = bn + wn + j * 16 + fr;
            float v = acc[i][j][r] + bb[col];
            v = 0.5f * v * (1.f + erff(v * 0.70710678f));
            hid_b[(long)tok * HIDC + col] = __float2bfloat16(v);
        }
    }
}

// ---- MoE grouped MFMA GEMM2, 64x64 tile: out = resid + hid·w2 + b2 -> split bf16 ----
__global__ __launch_bounds__(256) void moe64_2_kernel(
    const bf16* __restrict__ hid_b, const bf16* __restrict__ e2T, const float* __restrict__ e_b2,
    const int* __restrict__ table, const int* __restrict__ ntiles, const int* __restrict__ perm,
    const float* __restrict__ resid, bf16* __restrict__ outh, bf16* __restrict__ outl) {
    if (blockIdx.y >= ntiles[0]) return;
    int e = table[2 * blockIdx.y], row0 = table[2 * blockIdx.y + 1];
    int bn = blockIdx.x * 64;
    __shared__ short As[2 * 2048];
    __shared__ short Bs[2 * 2048];
    __shared__ int rowsS[64];
    int t = threadIdx.x, lane = t & 63, w = t >> 6;
    if (t < 64) rowsS[t] = perm[row0 + t];
    __syncthreads();
    int wm = (w >> 1) * 32, wn = (w & 1) * 32;
    int r0 = t >> 2, k0s = (t & 3) ^ ((r0 >> 1) & 3);
    int tok0 = rowsS[r0]; if (tok0 < 0) tok0 = 0;
    const short* Hs = (const short*)hid_b;
    const short* Ws = (const short*)(e2T + (long)e * DIMC * HIDC);
    const short* a0 = Hs + (long)tok0 * HIDC + k0s * 8;
    const short* b0 = Ws + (long)(bn + r0) * HIDC + k0s * 8;
    int fr = lane & 15, fq = lane >> 4;
    int aOff[2], bOff[2];
    #pragma unroll
    for (int i = 0; i < 2; i++) {
        int row = wm + i * 16 + fr;
        aOff[i] = row * 32 + ((fq ^ ((row >> 1) & 3)) * 8);
        int col = wn + i * 16 + fr;
        bOff[i] = col * 32 + ((fq ^ ((col >> 1) & 3)) * 8);
    }
    f32x4 acc[2][2] = {};
    bf16x8 va = *(const bf16x8*)(a0);
    bf16x8 vb = *(const bf16x8*)(b0);
    int bufo = 0;
    for (int kk = 0; kk < HIDC; kk += 32) {
        *(bf16x8*)&As[bufo + t * 8] = va;
        *(bf16x8*)&Bs[bufo + t * 8] = vb;
        __syncthreads();
        int kn = (kk + 32 < HIDC) ? kk + 32 : kk;
        bf16x8 na = *(const bf16x8*)(a0 + kn);
        bf16x8 nb = *(const bf16x8*)(b0 + kn);
        bf16x8 aF[2], bF[2];
        #pragma unroll
        for (int i = 0; i < 2; i++) {
            aF[i] = *(const bf16x8*)&As[bufo + aOff[i]];
            bF[i] = *(const bf16x8*)&Bs[bufo + bOff[i]];
        }
        #pragma unroll
        for (int i = 0; i < 2; i++)
        #pragma unroll
        for (int j = 0; j < 2; j++)
            acc[i][j] = __builtin_amdgcn_mfma_f32_16x16x32_bf16(aF[i], bF[j], acc[i][j], 0, 0, 0);
        va = na; vb = nb;
        bufo ^= 2048;
    }
    const float* bb = e_b2 + (long)e * DIMC;
    #pragma unroll
    for (int i = 0; i < 2; i++)
    #pragma unroll
    for (int r = 0; r < 4; r++) {
        int tok = rowsS[wm + i * 16 + fq * 4 + r];
        if (tok < 0) continue;
        #pragma unroll
        for (int j = 0; j < 2; j++) {
            int col = bn + wn + j * 16 + fr;
            long off = (long)tok * DIMC + col;
            float v = resid[off] + acc[i][j][r] + bb[col];
            bf16 hh, ll; split2(v, hh, ll);
            outh[off] = hh; outl[off] = ll;
        }
    }
}

// ---------------- LayerNorm: optional fp32 + bf16 hi/lo outputs ----------------
__global__ void ln_kernel(const float* __restrict__ x, const float* __restrict__ g,
                          const float* __restrict__ b, float* __restrict__ y,
                          bf16* __restrict__ yh, bf16* __restrict__ yl) {
    int tok = blockIdx.x;
    int t = threadIdx.x;
    const float* xr = x + (long)tok * DIMC;
    float v0 = xr[t], v1 = xr[t + 256];
    __shared__ float red[256];
    red[t] = v0 + v1; __syncthreads();
    for (int s = 128; s > 0; s >>= 1) { if (t < s) red[t] += red[t + s]; __syncthreads(); }
    float mu = red[0] * (1.f / DIMC);
    __syncthreads();
    float d0 = v0 - mu, d1 = v1 - mu;
    red[t] = d0 * d0 + d1 * d1; __syncthreads();
    for (int s = 128; s > 0; s >>= 1) { if (t < s) red[t] += red[t + s]; __syncthreads(); }
    float rs = rsqrtf(red[0] * (1.f / DIMC) + 1e-5f);
    float o0 = d0 * rs * g[t] + b[t];
    float o1 = d1 * rs * g[t + 256] + b[t + 256];
    if (y) { y[(long)tok * DIMC + t] = o0; y[(long)tok * DIMC + t + 256] = o1; }
    bf16 h, l;
    split2(o0, h, l); yh[(long)tok * DIMC + t] = h;       yl[(long)tok * DIMC + t] = l;
    split2(o1, h, l); yh[(long)tok * DIMC + t + 256] = h; yl[(long)tok * DIMC + t + 256] = l;
}

// ---------------- router text part (+ cnt zeroing) ----------------
__global__ void textpart_kernel(const float* __restrict__ w, const float* __restrict__ r_text_mu,
                                const float* __restrict__ r_comb_mu, float* __restrict__ tp,
                                int* __restrict__ cnt) {
    __shared__ float tw[4][128];
    int t = threadIdx.x;
    if (t < NE) cnt[t] = 0;
    for (int j = 0; j < 2; j++) {
        int idx = t + j * 256; int b = idx >> 7, c = idx & 127;
        const float* wr = w + (long)b * LATC;
        float s = 0.f;
        for (int k = 0; k < LATC; k++) s += wr[k] * r_text_mu[(long)k * 128 + c];
        tw[b][c] = s;
    }
    __syncthreads();
    if (t < 32) {
        int b = t >> 3, e = t & 7;
        float s = 0.f;
        for (int c = 0; c < 128; c++) s += tw[b][c] * r_comb_mu[(long)(128 + c) * 8 + e];
        tp[t] = s;
    }
}

// ---------------- router: perm poison + logits + argmax ----------------
__global__ void route_kernel(const float* __restrict__ feat, const float* __restrict__ tp,
                             const float* __restrict__ r_comb_mu, const float* __restrict__ r_temp,
                             float* __restrict__ onehot, int* __restrict__ idx, int* __restrict__ cnt,
                             int* __restrict__ perm) {
    int n = blockIdx.x * blockDim.x + threadIdx.x;
    if (n < MAXT * 64) perm[n] = -1;
    if (n >= NTOK) return;
    int b = n >> 10;
    float tmp = fmaxf(r_temp[0], 0.1f);
    float invt = 1.f / tmp;
    const float* fr = feat + (long)n * 128;
    float lg[8];
    for (int e = 0; e < 8; e++) {
        float s = 0.f;
        for (int c = 0; c < 128; c++) s += fr[c] * r_comb_mu[(long)c * 8 + e];
        lg[e] = (s + tp[b * 8 + e]) * invt;
    }
    float best = lg[0]; int bi = 0;
    for (int e = 1; e < 8; e++) { if (lg[e] > best) { best = lg[e]; bi = e; } }
    for (int e = 0; e < 8; e++) onehot[(long)n * 8 + e] = (e == bi) ? 1.f : 0.f;
    idx[n] = bi;
    atomicAdd(&cnt[bi], 1);
}

// ---------------- offsets + scatter fused (single block, LDS cursors) ----------------
__global__ void offscatter_kernel(const int* __restrict__ cnt, const int* __restrict__ idx,
                                  int* __restrict__ ntiles, int* __restrict__ table,
                                  int* __restrict__ perm) {
    __shared__ int cur[NE];
    int t = threadIdx.x;
    if (t == 0) {
        int po = 0, nt = 0;
        for (int e = 0; e < NE; e++) {
            cur[e] = po;
            int tiles = (cnt[e] + 63) >> 6;
            for (int j = 0; j < tiles; j++) { table[2 * nt] = e; table[2 * nt + 1] = po + j * 64; nt++; }
            po += tiles * 64;
        }
        ntiles[0] = nt;
    }
    __syncthreads();
    for (int n = t; n < NTOK; n += 256) {
        int e = idx[n];
        int pos = atomicAdd(&cur[e], 1);
        perm[pos] = n;
    }
}

extern "C" void kernel_launch(void* const* d_in, const int* in_sizes, int n_in,
                              void* d_out, int out_size, void* d_ws, size_t ws_size,
                              hipStream_t stream) {
    const float* x        = (const float*)d_in[0];
    const float* w        = (const float*)d_in[1];
    const float* text     = (const float*)d_in[2];
    const float* pin_w    = (const float*)d_in[3];
    const float* pin_mw   = (const float*)d_in[4];
    const float* pin_mb   = (const float*)d_in[5];
    const float* pout_w   = (const float*)d_in[6];
    const float* pout_mw  = (const float*)d_in[7];
    const float* pout_mb  = (const float*)d_in[8];
    const float* ln1g     = (const float*)d_in[9];
    const float* ln1b     = (const float*)d_in[10];
    const float* ln2g     = (const float*)d_in[11];
    const float* ln2b     = (const float*)d_in[12];
    const float* ln3g     = (const float*)d_in[13];
    const float* ln3b     = (const float*)d_in[14];
    const float* sa_in_w  = (const float*)d_in[15];
    const float* sa_in_b  = (const float*)d_in[16];
    const float* sa_out_w = (const float*)d_in[17];
    const float* sa_out_b = (const float*)d_in[18];
    const float* ca_in_w  = (const float*)d_in[19];
    const float* ca_in_b  = (const float*)d_in[20];
    const float* ca_out_w = (const float*)d_in[21];
    const float* ca_out_b = (const float*)d_in[22];
    const float* r_feat   = (const float*)d_in[23];
    const float* r_text   = (const float*)d_in[24];
    const float* r_comb   = (const float*)d_in[25];
    const float* r_temp   = (const float*)d_in[26];
    const float* e_w1     = (const float*)d_in[27];
    const float* e_b1     = (const float*)d_in[28];
    const float* e_w2     = (const float*)d_in[29];
    const float* e_b2     = (const float*)d_in[30];

    float* out    = (float*)d_out;               // [B, DIM, H, W]
    float* onehot = out + (long)BB * DIMC * HWX; // [4096, 8]

    // ---------------- workspace: fp32 pool ----------------
    float* f32p = (float*)d_ws;
    float* style_in  = f32p;                 // 2048
    float* style_out = f32p + 2048;          // 2048
    float* tp        = f32p + 4096;          // 32
    int*   idx       = (int*)(f32p + 4128);  // 4096
    int*   cnt       = (int*)(f32p + 8224);  // 8
    int*   ntiles    = (int*)(f32p + 8240);  // 8
    int*   table     = (int*)(f32p + 8248);  // 256
    int*   perm      = (int*)(f32p + 8504);  // 4608 -> ends 13112
    float* x_flat    = f32p + 13496;         // 2097152
    float* xn        = x_flat + 2097152;     // 2097152 (home of wtC split)
    float* qkv       = xn + 2097152;         // 6291456 (SA q split / CA q split home)
    float* spill     = qkv + 6291456;        // 2097152 (e2T tail)

    // ---------------- bf16 pool (phase-aliased) ----------------
    bf16* bp = (bf16*)(f32p + 12596408);
    bf16* R1 = bp;                           // 6291456 elems, phases
    bf16* xT_h  = R1;
    bf16* xT_l  = R1 + 2097152;
    bf16* wtA_h = R1 + 4194304;
    bf16* wtA_l = R1 + 5242880;
    bf16* obuf_h = R1;
    bf16* obuf_l = R1 + 2097152;
    bf16* kvt_h  = R1 + 4194304;                       // [308][1024] split
    bf16* kvt_l  = kvt_h + 315392;
    float* feat  = (float*)(kvt_l + 315392);           // 524288 fp32
    bf16* xn_h = R1 + 6291456;               // 2097152
    bf16* xn_l = xn_h + 2097152;             // 2097152
    bf16* WB   = xn_l + 2097152;             // 8388608: weights (early) / hid_b (late)
    bf16* text_h   = WB;
    bf16* text_l   = text_h + 157696;
    bf16* sawin_h  = text_l + 157696;
    bf16* sawin_l  = sawin_h + 786432;
    bf16* sawout_h = sawin_l + 786432;
    bf16* sawout_l = sawout_h + 262144;
    bf16* caw_h    = sawout_l + 262144;
    bf16* caw_l    = caw_h + 786432;
    bf16* cawout_h = caw_l + 786432;
    bf16* cawout_l = cawout_h + 262144;
    bf16* rfT_h    = cawout_l + 262144;      // [128][512] split r_feat^T
    bf16* rfT_l    = rfT_h + 65536;
    bf16* hid_b    = WB;                     // overlays weights after ca_out
    bf16* e1T = (bf16*)qkv;                  // [8][2048][512] in qkv+spill
    bf16* e2T = e1T + 8388608;
    bf16* xfl_h = xn_h;                      // moe64_2 writes split output here
    bf16* xfl_l = xn_l;
    bf16* wtC_h = (bf16*)xn;                 // modconv-out weight (dead fp32 region)
    bf16* wtC_l = wtC_h + 1048576;
    bf16* q_h = (bf16*)qkv;                  // [4096][1536]
    bf16* q_l = q_h + 6291456;
    bf16* ca_qh = (bf16*)qkv;                // [4096][512]
    bf16* ca_ql = ca_qh + 2097152;
    (void)ws_size; (void)spill;

    auto mg = [&](const bf16* Ah, const bf16* Al, const bf16* Bh, const bf16* Bl,
                  const float* bias, const float* resid, float* C, bf16* Oh, bf16* Ol,
                  int M, int N, int K, long ab, long bb, long cb, int csm, int csn, int nb) {
        dim3 g(N / 64, (M + 63) / 64, nb);
        hipLaunchKernelGGL(mgemm64_kernel, g, dim3(256), 0, stream,
                           Ah, Al, Bh, Bl, bias, resid, C, Oh, Ol, M, N, K, ab, bb, cb, csm, csn);
    };

    // ---- fused input conversions (hi/lo): one launch for all 5 flat arrays ----
    {
        int n0 = 1536 * 512, n1 = 512 * 512, n2 = 1536 * 512, n3 = 512 * 512, n4 = BB * TXT * 512;
        int total = n0 + n1 + n2 + n3 + n4;
        hipLaunchKernelGGL(cvtall_kernel, dim3((total / 4 + 255) / 256), dim3(256), 0, stream,
                           sa_in_w, sawin_h, sawin_l, n0,
                           sa_out_w, sawout_h, sawout_l, n1,
                           ca_in_w, caw_h, caw_l, n2,
                           ca_out_w, cawout_h, cawout_l, n3,
                           text, text_h, text_l, n4);
    }
    // ---- fused transposes: x (z<4) + r_feat (z==4) ----
    hipLaunchKernelGGL(trcvt2x_kernel, dim3(32, 16, 5), dim3(256), 0, stream,
                       x, xT_h, xT_l, r_feat, rfT_h, rfT_l);

    // ---- both modconv styles + weights up front (wtC in dead xn region) ----
    hipLaunchKernelGGL(style2_kernel, dim3(16), dim3(256), 0, stream,
                       w, pin_mw, pin_mb, pout_mw, pout_mb, style_in, style_out);
    hipLaunchKernelGGL(wtmod2_kernel, dim3(2 * BB * DIMC), dim3(256), 0, stream,
                       pin_w, style_in, pout_w, style_out, wtA_h, wtA_l, wtC_h, wtC_l);

    // ---- modconv in ----
    mg(xT_h, xT_l, wtA_h, wtA_l, nullptr, nullptr, x_flat, nullptr, nullptr,
       HWX, DIMC, DIMC, (long)HWX * DIMC, (long)DIMC * DIMC, (long)HWX * DIMC, DIMC, 1, BB);

    // ---- LN1 + self-attention (split MFMA) ----
    hipLaunchKernelGGL(ln_kernel, dim3(NTOK), dim3(256), 0, stream, x_flat, ln1g, ln1b,
                       (float*)nullptr, xn_h, xn_l);
    mg(xn_h, xn_l, sawin_h, sawin_l, sa_in_b, nullptr, nullptr, q_h, q_l,
       NTOK, 1536, 512, 0, 0, 0, 1536, 1, 1);
    hipLaunchKernelGGL(sa_mfma_kernel, dim3(16, HEADS, BB), dim3(256), 0, stream,
                       q_h, q_l, obuf_h, obuf_l);
    mg(obuf_h, obuf_l, sawout_h, sawout_l, sa_out_b, x_flat, x_flat, nullptr, nullptr,
       NTOK, 512, 512, 0, 0, 0, 512, 1, 1);

    // ---- LN2 + cross-attention (split MFMA) ----
    hipLaunchKernelGGL(ln_kernel, dim3(NTOK), dim3(256), 0, stream, x_flat, ln2g, ln2b,
                       (float*)nullptr, xn_h, xn_l);
    mg(xn_h, xn_l, caw_h, caw_l, ca_in_b, nullptr, nullptr, ca_qh, ca_ql,
       NTOK, 512, 512, 0, 0, 0, 512, 1, 1);
    mg(text_h, text_l, caw_h + 512 * 512, caw_l + 512 * 512, ca_in_b + 512, nullptr, nullptr,
       kvt_h, kvt_l, BB * TXT, 1024, 512, 0, 0, 0, 1024, 1, 1);
    hipLaunchKernelGGL(ca_mfma_kernel, dim3(16, HEADS, BB), dim3(256), 0, stream,
                       ca_qh, ca_ql, kvt_h, kvt_l, obuf_h, obuf_l);
    // expert weight transposes (qkv region dead after ca_mfma) — one fused launch
    hipLaunchKernelGGL(tr2x_kernel, dim3(64, 16, 16), dim3(256), 0, stream,
                       e_w1, e1T, e_w2, e2T);
    mg(obuf_h, obuf_l, cawout_h, cawout_l, ca_out_b, x_flat, x_flat, nullptr, nullptr,
       NTOK, 512, 512, 0, 0, 0, 512, 1, 1);

    // ---- LN3 + router (feat via split MFMA) ----
    hipLaunchKernelGGL(ln_kernel, dim3(NTOK), dim3(256), 0, stream, x_flat, ln3g, ln3b,
                       (float*)nullptr, xn_h, xn_l);
    mg(xn_h, xn_l, rfT_h, rfT_l, nullptr, nullptr, feat, nullptr, nullptr,
       NTOK, 128, 512, 0, 0, 0, 128, 1, 1);
    hipLaunchKernelGGL(textpart_kernel, dim3(1), dim3(256), 0, stream, w, r_text, r_comb, tp, cnt);
    hipLaunchKernelGGL(route_kernel, dim3(18), dim3(256), 0, stream,
                       feat, tp, r_comb, r_temp, onehot, idx, cnt, perm);
    hipLaunchKernelGGL(offscatter_kernel, dim3(1), dim3(256), 0, stream,
                       cnt, idx, ntiles, table, perm);

    // ---- MoE grouped MFMA GEMMs (64x64 tiles; gemm2 emits split bf16 directly) ----
    hipLaunchKernelGGL(moe64_1_kernel, dim3(HIDC / 64, MAXT), dim3(256), 0, stream,
                       xn_h, e1T, e_b1, table, ntiles, perm, hid_b);
    hipLaunchKernelGGL(moe64_2_kernel, dim3(DIMC / 64, MAXT), dim3(256), 0, stream,
                       hid_b, e2T, e_b2, table, ntiles, perm, x_flat, xfl_h, xfl_l);

    // ---- modconv out (weights already prepared) ----
    mg(wtC_h, wtC_l, xfl_h, xfl_l, nullptr, nullptr, out, nullptr, nullptr,
       DIMC, HWX, DIMC, (long)DIMC * DIMC, (long)HWX * DIMC, (long)DIMC * HWX, HWX, 1, BB);
}

// Round 18
// 496.542 us; speedup vs baseline: 1.4505x; 1.0171x over previous
//
#include <hip/hip_runtime.h>
#include <hip/hip_bf16.h>
#include <math.h>

#define DIMC 512
#define HEADS 8
#define HD 64
#define BB 4
#define HWX 1024
#define TXT 77
#define LATC 512
#define NE 8
#define HIDC 2048
#define NTOK 4096
#define MAXT 72           // MoE tiles of 64: 4096/64 + 8

typedef __attribute__((ext_vector_type(8))) short bf16x8;
typedef __attribute__((ext_vector_type(4))) float f32x4;
typedef __hip_bfloat16 bf16;

__device__ __forceinline__ void split2(float v, bf16& h, bf16& l) {
    h = __float2bfloat16(v);
    l = __float2bfloat16(v - __bfloat162float(h));
}
__device__ __forceinline__ void split2s(float v, short& h, short& l) {
    bf16 hb, lb; split2(v, hb, lb);
    h = *(short*)&hb; l = *(short*)&lb;
}

// ---------------- both styles in one launch: job 0 = in, job 1 = out ----------------
__global__ void style2_kernel(const float* __restrict__ w,
                              const float* __restrict__ mwA, const float* __restrict__ mbA,
                              const float* __restrict__ mwB, const float* __restrict__ mbB,
                              float* __restrict__ sA, float* __restrict__ sB) {
    int g = blockIdx.x * blockDim.x + threadIdx.x;
    int job = (g >= BB * DIMC) ? 1 : 0;
    int t = g - job * BB * DIMC;
    if (t >= BB * DIMC) return;
    const float* mw = job ? mwB : mwA;
    const float* mb = job ? mbB : mbA;
    float* st = job ? sB : sA;
    int b = t / DIMC, i = t % DIMC;
    const float* wr = w + (long)b * LATC;
    const float* mr = mw + (long)i * LATC;
    float s = 0.f;
    #pragma unroll 8
    for (int l = 0; l < LATC; l++) s += wr[l] * mr[l];
    st[t] = s + mb[i];
}

// ------- both wtmods in one launch -------
__global__ void wtmod2_kernel(const float* __restrict__ wA, const float* __restrict__ sA,
                              const float* __restrict__ wB, const float* __restrict__ sB,
                              bf16* __restrict__ whA, bf16* __restrict__ wlA,
                              bf16* __restrict__ whB, bf16* __restrict__ wlB) {
    int gb = blockIdx.x;
    int job = (gb >= BB * DIMC) ? 1 : 0;
    int bo = gb - job * BB * DIMC;
    const float* weight = job ? wB : wA;
    const float* style  = job ? sB : sA;
    bf16* wh = job ? whB : whA;
    bf16* wl = job ? wlB : wlA;
    int b = bo / DIMC, o = bo % DIMC;
    const float* wr = weight + (long)o * DIMC;
    const float* sr = style + (long)b * DIMC;
    int t = threadIdx.x;
    float vals[2]; float part = 0.f;
    for (int j = 0; j < 2; j++) {
        int i = t + j * 256;
        float v = wr[i] * sr[i];
        vals[j] = v; part += v * v;
    }
    __shared__ float red[256];
    red[t] = part; __syncthreads();
    for (int s = 128; s > 0; s >>= 1) { if (t < s) red[t] += red[t + s]; __syncthreads(); }
    float d = rsqrtf(red[0] + 1e-8f);
    for (int j = 0; j < 2; j++) {
        int i = t + j * 256;
        bf16 h, l; split2(vals[j] * d, h, l);
        wh[(long)bo * DIMC + i] = h; wl[(long)bo * DIMC + i] = l;
    }
}

// ---------------- fused segmented fp32 -> bf16 hi/lo convert (5 weight arrays) ----------------
__global__ void cvtall_kernel(
    const float* __restrict__ s0, bf16* __restrict__ h0, bf16* __restrict__ l0, int n0,
    const float* __restrict__ s1, bf16* __restrict__ h1, bf16* __restrict__ l1, int n1,
    const float* __restrict__ s2, bf16* __restrict__ h2, bf16* __restrict__ l2, int n2,
    const float* __restrict__ s3, bf16* __restrict__ h3, bf16* __restrict__ l3, int n3,
    const float* __restrict__ s4, bf16* __restrict__ h4, bf16* __restrict__ l4, int n4) {
    int i = (blockIdx.x * blockDim.x + threadIdx.x) * 4;
    const float* src; bf16 *hh, *ll;
    if (i < n0) { src = s0; hh = h0; ll = l0; }
    else if ((i -= n0) < n1) { src = s1; hh = h1; ll = l1; }
    else if ((i -= n1) < n2) { src = s2; hh = h2; ll = l2; }
    else if ((i -= n2) < n3) { src = s3; hh = h3; ll = l3; }
    else if ((i -= n3) < n4) { src = s4; hh = h4; ll = l4; }
    else return;
    float4 v = *(const float4*)(src + i);
    float a[4] = {v.x, v.y, v.z, v.w};
    #pragma unroll
    for (int j = 0; j < 4; j++) { bf16 h, l; split2(a[j], h, l); hh[i + j] = h; ll[i + j] = l; }
}

// ---- fused transpose hi/lo: z<4 -> x slice (512x1024), z==4 -> r_feat (512x128) ----
__global__ void trcvt2x_kernel(const float* __restrict__ x, bf16* __restrict__ xh,
                               bf16* __restrict__ xl, const float* __restrict__ rf,
                               bf16* __restrict__ rfh, bf16* __restrict__ rfl) {
    __shared__ float tile[32][33];
    int z = blockIdx.z;
    const float* in; bf16 *hi, *lo; int R, C;
    if (z < 4) {
        in = x + (long)z * 512 * 1024;
        hi = xh + (long)z * 1024 * 512; lo = xl + (long)z * 1024 * 512;
        R = 512; C = 1024;
    } else {
        if (blockIdx.x >= 4) return;
        in = rf; hi = rfh; lo = rfl;
        R = 512; C = 128;
    }
    int c0 = blockIdx.x * 32, r0 = blockIdx.y * 32;
    int tc = threadIdx.x & 31, tr = threadIdx.x >> 5;
    #pragma unroll
    for (int i = 0; i < 4; i++) {
        int r = tr + i * 8;
        tile[r][tc] = in[(long)(r0 + r) * C + c0 + tc];
    }
    __syncthreads();
    #pragma unroll
    for (int i = 0; i < 4; i++) {
        int r = tr + i * 8;
        bf16 h, l; split2(tile[tc][r], h, l);
        hi[(long)(c0 + r) * R + r0 + tc] = h;
        lo[(long)(c0 + r) * R + r0 + tc] = l;
    }
}

// ---- fused expert-weight transposes: z<8 -> e_w1[z] (512x2048), z>=8 -> e_w2[z-8] (2048x512) ----
__global__ void tr2x_kernel(const float* __restrict__ w1, bf16* __restrict__ e1T,
                            const float* __restrict__ w2, bf16* __restrict__ e2T) {
    __shared__ float tile[32][33];
    int z = blockIdx.z;
    const float* in; bf16* out; int R, C, c0, r0;
    if (z < 8) {
        in = w1 + (long)z * 512 * 2048;  out = e1T + (long)z * 2048 * 512;
        R = 512; C = 2048;
        c0 = blockIdx.x * 32; r0 = blockIdx.y * 32;       // grid x=64, y=16
    } else {
        in = w2 + (long)(z - 8) * 2048 * 512;  out = e2T + (long)(z - 8) * 512 * 2048;
        R = 2048; C = 512;
        int lin = blockIdx.y * 64 + blockIdx.x;           // 0..1023 -> (16 x, 64 y)
        c0 = (lin & 15) * 32; r0 = (lin >> 4) * 32;
    }
    int tc = threadIdx.x & 31, tr = threadIdx.x >> 5;
    #pragma unroll
    for (int i = 0; i < 4; i++) {
        int r = tr + i * 8;
        tile[r][tc] = in[(long)(r0 + r) * C + c0 + tc];
    }
    __syncthreads();
    #pragma unroll
    for (int i = 0; i < 4; i++) {
        int r = tr + i * 8;
        out[(long)(c0 + r) * R + r0 + tc] = __float2bfloat16(tile[tc][r]);
    }
}

// ---- split-precision bf16 MFMA GEMM, 64x64 tile (high machine fill) ----
__global__ __launch_bounds__(256) void mgemm64_kernel(
    const bf16* __restrict__ Ah, const bf16* __restrict__ Al,
    const bf16* __restrict__ Bh, const bf16* __restrict__ Bl,
    const float* __restrict__ bias, const float* __restrict__ resid, float* __restrict__ C,
    bf16* __restrict__ Oh, bf16* __restrict__ Ol,
    int M, int N, int K, long a_bat, long b_bat, long c_bat, int cs_m, int cs_n) {
    __shared__ short AsH[2 * 2048];
    __shared__ short AsL[2 * 2048];
    __shared__ short BsH[2 * 2048];
    __shared__ short BsL[2 * 2048];
    int bat = blockIdx.z;
    const short* AbH = (const short*)(Ah + (long)bat * a_bat);
    const short* AbL = (const short*)(Al + (long)bat * a_bat);
    const short* BbH = (const short*)(Bh + (long)bat * b_bat);
    const short* BbL = (const short*)(Bl + (long)bat * b_bat);
    float* Cb = C + (long)bat * c_bat;
    const float* Rb = resid ? resid + (long)bat * c_bat : nullptr;
    int bm = blockIdx.y * 64, bn = blockIdx.x * 64;
    int t = threadIdx.x, lane = t & 63, w = t >> 6;
    int wm = (w >> 1) * 32, wn = (w & 1) * 32;
    int r0 = t >> 2, k0s = (t & 3) ^ ((r0 >> 1) & 3);
    int ar0 = bm + r0; if (ar0 > M - 1) ar0 = M - 1;
    long aoff = (long)ar0 * K + k0s * 8;
    long boff = (long)(bn + r0) * K + k0s * 8;
    int fr = lane & 15, fq = lane >> 4;
    int aOff[2], bOff[2];
    #pragma unroll
    for (int i = 0; i < 2; i++) {
        int row = wm + i * 16 + fr;
        aOff[i] = row * 32 + ((fq ^ ((row >> 1) & 3)) * 8);
        int col = wn + i * 16 + fr;
        bOff[i] = col * 32 + ((fq ^ ((col >> 1) & 3)) * 8);
    }
    f32x4 acc[2][2] = {};
    bf16x8 vah = *(const bf16x8*)(AbH + aoff);
    bf16x8 val = *(const bf16x8*)(AbL + aoff);
    bf16x8 vbh = *(const bf16x8*)(BbH + boff);
    bf16x8 vbl = *(const bf16x8*)(BbL + boff);
    int bufo = 0;
    for (int kk = 0; kk < K; kk += 32) {
        *(bf16x8*)&AsH[bufo + t * 8] = vah;
        *(bf16x8*)&AsL[bufo + t * 8] = val;
        *(bf16x8*)&BsH[bufo + t * 8] = vbh;
        *(bf16x8*)&BsL[bufo + t * 8] = vbl;
        __syncthreads();
        int kn = (kk + 32 < K) ? kk + 32 : kk;
        bf16x8 nah = *(const bf16x8*)(AbH + aoff + kn);
        bf16x8 nal = *(const bf16x8*)(AbL + aoff + kn);
        bf16x8 nbh = *(const bf16x8*)(BbH + boff + kn);
        bf16x8 nbl = *(const bf16x8*)(BbL + boff + kn);
        bf16x8 aH[2], aL[2], bH[2], bL[2];
        #pragma unroll
        for (int i = 0; i < 2; i++) {
            aH[i] = *(const bf16x8*)&AsH[bufo + aOff[i]];
            aL[i] = *(const bf16x8*)&AsL[bufo + aOff[i]];
            bH[i] = *(const bf16x8*)&BsH[bufo + bOff[i]];
            bL[i] = *(const bf16x8*)&BsL[bufo + bOff[i]];
        }
        #pragma unroll
        for (int i = 0; i < 2; i++)
        #pragma unroll
        for (int j = 0; j < 2; j++) {
            acc[i][j] = __builtin_amdgcn_mfma_f32_16x16x32_bf16(aH[i], bH[j], acc[i][j], 0, 0, 0);
            acc[i][j] = __builtin_amdgcn_mfma_f32_16x16x32_bf16(aH[i], bL[j], acc[i][j], 0, 0, 0);
            acc[i][j] = __builtin_amdgcn_mfma_f32_16x16x32_bf16(aL[i], bH[j], acc[i][j], 0, 0, 0);
        }
        vah = nah; val = nal; vbh = nbh; vbl = nbl;
        bufo ^= 2048;
    }
    #pragma unroll
    for (int i = 0; i < 2; i++)
    #pragma unroll
    for (int j = 0; j < 2; j++)
    #pragma unroll
    for (int r = 0; r < 4; r++) {
        int row = bm + wm + i * 16 + fq * 4 + r;
        int col = bn + wn + j * 16 + fr;
        if (row < M) {
            long off = (long)row * cs_m + (long)col * cs_n;
            float v = acc[i][j][r];
            if (bias) v += bias[col];
            if (Oh) {
                bf16 hh, ll; split2(v, hh, ll);
                Oh[off] = hh; Ol[off] = ll;
            } else {
                if (Rb) v += Rb[off];
                Cb[off] = v;
            }
        }
    }
}

// ---- split-precision bf16 MFMA GEMM, 128x64 tile (high reuse; for the big qkv GEMM) ----
// 4 waves in 2x2 quadrants of 64x32; per wave 4x2 frags -> 12 ds_reads per 24 MFMAs.
__global__ __launch_bounds__(256) void mgemm128x64_kernel(
    const bf16* __restrict__ Ah, const bf16* __restrict__ Al,
    const bf16* __restrict__ Bh, const bf16* __restrict__ Bl,
    const float* __restrict__ bias, bf16* __restrict__ Oh, bf16* __restrict__ Ol,
    int M, int N, int K) {
    __shared__ short AsH[2 * 4096];
    __shared__ short AsL[2 * 4096];
    __shared__ short BsH[2 * 2048];
    __shared__ short BsL[2 * 2048];
    const short* AbH = (const short*)Ah;
    const short* AbL = (const short*)Al;
    const short* BbH = (const short*)Bh;
    const short* BbL = (const short*)Bl;
    int bm = blockIdx.y * 128, bn = blockIdx.x * 64;
    int t = threadIdx.x, lane = t & 63, w = t >> 6;
    int wm = (w >> 1) * 64, wn = (w & 1) * 32;
    // A staging: 512 chunks (128 rows x 4 kslots), thread covers p0=t, p1=t+256
    int p0 = t, p1 = t + 256;
    int ra0 = p0 >> 2, ka0 = (p0 & 3) ^ ((ra0 >> 1) & 3);
    int ra1 = p1 >> 2, ka1 = (p1 & 3) ^ ((ra1 >> 1) & 3);
    int arow0 = bm + ra0; if (arow0 > M - 1) arow0 = M - 1;
    int arow1 = bm + ra1; if (arow1 > M - 1) arow1 = M - 1;
    long aoff0 = (long)arow0 * K + ka0 * 8;
    long aoff1 = (long)arow1 * K + ka1 * 8;
    // B staging: 256 chunks (64 rows x 4 kslots), one per thread
    int rb = t >> 2, kb2 = (t & 3) ^ ((rb >> 1) & 3);
    long boff = (long)(bn + rb) * K + kb2 * 8;
    int fr = lane & 15, fq = lane >> 4;
    int aOff[4], bOff[2];
    #pragma unroll
    for (int i = 0; i < 4; i++) {
        int row = wm + i * 16 + fr;
        aOff[i] = row * 32 + ((fq ^ ((row >> 1) & 3)) * 8);
    }
    #pragma unroll
    for (int j = 0; j < 2; j++) {
        int col = wn + j * 16 + fr;
        bOff[j] = col * 32 + ((fq ^ ((col >> 1) & 3)) * 8);
    }
    f32x4 acc[4][2] = {};
    // prologue loads (kk = 0)
    bf16x8 vah0 = *(const bf16x8*)(AbH + aoff0);
    bf16x8 vah1 = *(const bf16x8*)(AbH + aoff1);
    bf16x8 val0 = *(const bf16x8*)(AbL + aoff0);
    bf16x8 val1 = *(const bf16x8*)(AbL + aoff1);
    bf16x8 vbh  = *(const bf16x8*)(BbH + boff);
    bf16x8 vbl  = *(const bf16x8*)(BbL + boff);
    int bufA = 0, bufB = 0;
    for (int kk = 0; kk < K; kk += 32) {
        *(bf16x8*)&AsH[bufA + p0 * 8] = vah0;  *(bf16x8*)&AsH[bufA + p1 * 8] = vah1;
        *(bf16x8*)&AsL[bufA + p0 * 8] = val0;  *(bf16x8*)&AsL[bufA + p1 * 8] = val1;
        *(bf16x8*)&BsH[bufB + t * 8] = vbh;
        *(bf16x8*)&BsL[bufB + t * 8] = vbl;
        __syncthreads();
        int kn = (kk + 32 < K) ? kk + 32 : kk;
        bf16x8 nah0 = *(const bf16x8*)(AbH + aoff0 + kn);
        bf16x8 nah1 = *(const bf16x8*)(AbH + aoff1 + kn);
        bf16x8 nal0 = *(const bf16x8*)(AbL + aoff0 + kn);
        bf16x8 nal1 = *(const bf16x8*)(AbL + aoff1 + kn);
        bf16x8 nbh  = *(const bf16x8*)(BbH + boff + kn);
        bf16x8 nbl  = *(const bf16x8*)(BbL + boff + kn);
        bf16x8 aH[4], aL[4], bH[2], bL[2];
        #pragma unroll
        for (int i = 0; i < 4; i++) {
            aH[i] = *(const bf16x8*)&AsH[bufA + aOff[i]];
            aL[i] = *(const bf16x8*)&AsL[bufA + aOff[i]];
        }
        #pragma unroll
        for (int j = 0; j < 2; j++) {
            bH[j] = *(const bf16x8*)&BsH[bufB + bOff[j]];
            bL[j] = *(const bf16x8*)&BsL[bufB + bOff[j]];
        }
        #pragma unroll
        for (int i = 0; i < 4; i++)
        #pragma unroll
        for (int j = 0; j < 2; j++) {
            acc[i][j] = __builtin_amdgcn_mfma_f32_16x16x32_bf16(aH[i], bH[j], acc[i][j], 0, 0, 0);
            acc[i][j] = __builtin_amdgcn_mfma_f32_16x16x32_bf16(aH[i], bL[j], acc[i][j], 0, 0, 0);
            acc[i][j] = __builtin_amdgcn_mfma_f32_16x16x32_bf16(aL[i], bH[j], acc[i][j], 0, 0, 0);
        }
        vah0 = nah0; vah1 = nah1; val0 = nal0; val1 = nal1;
        vbh = nbh; vbl = nbl;
        bufA ^= 4096; bufB ^= 2048;
    }
    #pragma unroll
    for (int i = 0; i < 4; i++)
    #pragma unroll
    for (int j = 0; j < 2; j++)
    #pragma unroll
    for (int r = 0; r < 4; r++) {
        int row = bm + wm + i * 16 + fq * 4 + r;
        int col = bn + wn + j * 16 + fr;
        if (row < M) {
            long off = (long)row * N + col;
            float v = acc[i][j][r] + bias[col];
            bf16 hh, ll; split2(v, hh, ll);
            Oh[off] = hh; Ol[off] = ll;
        }
    }
}

// ---- split-precision MFMA flash SA: no-max softmax, bank-conflict-free V (stride 72),
//      single-buffered K/V with 2 barriers/iter, post-barrier prefetch, setprio ----
__global__ __launch_bounds__(256) void sa_mfma_kernel(
    const bf16* __restrict__ qh, const bf16* __restrict__ ql,
    bf16* __restrict__ oh, bf16* __restrict__ ol) {
    int qt = blockIdx.x, h = blockIdx.y, b = blockIdx.z;
    __shared__ short KsH[4096], KsL[4096];       // [kv][64], swz: col ^ ((kv&7)<<3)
    __shared__ short VtH[4608], VtL[4608];       // [d][72], swz: col ^ (((d>>3)&7)<<3)
    __shared__ short PHs[4][1024], PLs[4][1024]; // per-wave P
    int t = threadIdx.x, lane = t & 63, w = t >> 6;
    int fr = lane & 15, fq = lane >> 4;
    const short* QH = (const short*)qh;
    const short* QL = (const short*)ql;
    long qrow = (long)(b * 1024 + qt * 64 + w * 16 + fr) * 1536 + h * 64;
    bf16x8 Qh2[2], Ql2[2];
    Qh2[0] = *(const bf16x8*)(QH + qrow + fq * 8);
    Qh2[1] = *(const bf16x8*)(QH + qrow + 32 + fq * 8);
    Ql2[0] = *(const bf16x8*)(QL + qrow + fq * 8);
    Ql2[1] = *(const bf16x8*)(QL + qrow + 32 + fq * 8);
    float l_i[4] = {0.f, 0.f, 0.f, 0.f};
    f32x4 o_acc[4] = {};
    int c0 = t, c1 = t + 256;
    int r0 = c0 >> 3, g0 = c0 & 7;               // r0 in 0..31
    int r1 = c1 >> 3, g1 = c1 & 7;               // r1 in 32..63
    int kd0 = r0 * 64 + ((g0 * 8) ^ ((r0 & 7) << 3));
    int kd1 = r1 * 64 + ((g1 * 8) ^ ((r1 & 7) << 3));
    long kb = (long)(b * 1024) * 1536 + 512 + h * 64;
    long vb = kb + 512;
    long lo0 = (long)r0 * 1536 + g0 * 8, lo1 = (long)r1 * 1536 + g1 * 8;
    short* ph = PHs[w]; short* pl = PLs[w];
    bf16x8 kh0 = *(const bf16x8*)(QH + kb + lo0);
    bf16x8 kh1 = *(const bf16x8*)(QH + kb + lo1);
    bf16x8 kl0 = *(const bf16x8*)(QL + kb + lo0);
    bf16x8 kl1 = *(const bf16x8*)(QL + kb + lo1);
    bf16x8 vh0 = *(const bf16x8*)(QH + vb + lo0);
    bf16x8 vh1 = *(const bf16x8*)(QH + vb + lo1);
    bf16x8 vl0 = *(const bf16x8*)(QL + vb + lo0);
    bf16x8 vl1 = *(const bf16x8*)(QL + vb + lo1);
    for (int kt = 0; kt < 16; kt++) {
        __syncthreads();          // A: all waves finished reading Ks/Vt of prev iter
        *(bf16x8*)&KsH[kd0] = kh0;  *(bf16x8*)&KsH[kd1] = kh1;
        *(bf16x8*)&KsL[kd0] = kl0;  *(bf16x8*)&KsL[kd1] = kl1;
        #pragma unroll
        for (int j = 0; j < 8; j++) {
            int d0 = g0 * 8 + j;
            int i0 = d0 * 72 + (r0 ^ (g0 << 3));
            VtH[i0] = ((short*)&vh0)[j];  VtL[i0] = ((short*)&vl0)[j];
            int d1 = g1 * 8 + j;
            int i1 = d1 * 72 + (r1 ^ (g1 << 3));
            VtH[i1] = ((short*)&vh1)[j];  VtL[i1] = ((short*)&vl1)[j];
        }
        __syncthreads();          // B: staging visible
        int ktn = (kt + 1 < 16) ? kt + 1 : kt;
        long ko = kb + (long)(ktn * 64) * 1536;
        long vo = vb + (long)(ktn * 64) * 1536;
        bf16x8 nkh0 = *(const bf16x8*)(QH + ko + lo0);
        bf16x8 nkh1 = *(const bf16x8*)(QH + ko + lo1);
        bf16x8 nkl0 = *(const bf16x8*)(QL + ko + lo0);
        bf16x8 nkl1 = *(const bf16x8*)(QL + ko + lo1);
        bf16x8 nvh0 = *(const bf16x8*)(QH + vo + lo0);
        bf16x8 nvh1 = *(const bf16x8*)(QH + vo + lo1);
        bf16x8 nvl0 = *(const bf16x8*)(QL + vo + lo0);
        bf16x8 nvl1 = *(const bf16x8*)(QL + vo + lo1);
        __builtin_amdgcn_s_setprio(1);
        f32x4 s[4] = {};
        #pragma unroll
        for (int cf = 0; cf < 4; cf++) {
            int kvrow = cf * 16 + fr;
            #pragma unroll
            for (int kf = 0; kf < 2; kf++) {
                int idx = kvrow * 64 + ((kf * 32 + fq * 8) ^ ((kvrow & 7) << 3));
                bf16x8 Bh2 = *(const bf16x8*)&KsH[idx];
                bf16x8 Bl2 = *(const bf16x8*)&KsL[idx];
                s[cf] = __builtin_amdgcn_mfma_f32_16x16x32_bf16(Qh2[kf], Bh2, s[cf], 0, 0, 0);
                s[cf] = __builtin_amdgcn_mfma_f32_16x16x32_bf16(Qh2[kf], Bl2, s[cf], 0, 0, 0);
                s[cf] = __builtin_amdgcn_mfma_f32_16x16x32_bf16(Ql2[kf], Bh2, s[cf], 0, 0, 0);
            }
        }
        __builtin_amdgcn_s_setprio(0);
        #pragma unroll
        for (int cf = 0; cf < 4; cf++)
        #pragma unroll
        for (int reg = 0; reg < 4; reg++) {
            float e = __expf(s[cf][reg] * 0.125f);
            s[cf][reg] = e;
            l_i[reg] += e;
        }
        #pragma unroll
        for (int cf = 0; cf < 4; cf++)
        #pragma unroll
        for (int reg = 0; reg < 4; reg++) {
            int q = fq * 4 + reg, kv = cf * 16 + fr;
            int idx = q * 64 + (kv ^ ((q & 7) << 3));
            split2s(s[cf][reg], ph[idx], pl[idx]);
        }
        asm volatile("s_waitcnt lgkmcnt(0)" ::: "memory");
        __builtin_amdgcn_sched_barrier(0);
        __builtin_amdgcn_s_setprio(1);
        bf16x8 Pf_h[2], Pf_l[2];
        #pragma unroll
        for (int kf = 0; kf < 2; kf++) {
            int idx = fr * 64 + ((kf * 32 + fq * 8) ^ ((fr & 7) << 3));
            Pf_h[kf] = *(const bf16x8*)&ph[idx];
            Pf_l[kf] = *(const bf16x8*)&pl[idx];
        }
        #pragma unroll
        for (int cf = 0; cf < 4; cf++) {
            int d = cf * 16 + fr;
            #pragma unroll
            for (int kf = 0; kf < 2; kf++) {
                int idx = d * 72 + ((kf * 32 + fq * 8) ^ (((d >> 3) & 7) << 3));
                bf16x8 Vh2 = *(const bf16x8*)&VtH[idx];
                bf16x8 Vl2 = *(const bf16x8*)&VtL[idx];
                o_acc[cf] = __builtin_amdgcn_mfma_f32_16x16x32_bf16(Pf_h[kf], Vh2, o_acc[cf], 0, 0, 0);
                o_acc[cf] = __builtin_amdgcn_mfma_f32_16x16x32_bf16(Pf_h[kf], Vl2, o_acc[cf], 0, 0, 0);
                o_acc[cf] = __builtin_amdgcn_mfma_f32_16x16x32_bf16(Pf_l[kf], Vh2, o_acc[cf], 0, 0, 0);
            }
        }
        __builtin_amdgcn_s_setprio(0);
        kh0 = nkh0; kh1 = nkh1; kl0 = nkl0; kl1 = nkl1;
        vh0 = nvh0; vh1 = nvh1; vl0 = nvl0; vl1 = nvl1;
    }
    #pragma unroll
    for (int reg = 0; reg < 4; reg++) {
        float rs = l_i[reg];
        rs += __shfl_xor(rs, 1);
        rs += __shfl_xor(rs, 2);
        rs += __shfl_xor(rs, 4);
        rs += __shfl_xor(rs, 8);
        float inv = 1.f / rs;
        long m = (long)(b * 1024 + qt * 64 + w * 16 + fq * 4 + reg);
        #pragma unroll
        for (int cf = 0; cf < 4; cf++) {
            float v = o_acc[cf][reg] * inv;
            bf16 hh, ll; split2(v, hh, ll);
            long off = m * DIMC + h * 64 + cf * 16 + fr;
            oh[off] = hh; ol[off] = ll;
        }
    }
}

// ---- split-precision MFMA cross-attention: 77 keys padded to 96, no-max softmax ----
__global__ __launch_bounds__(256) void ca_mfma_kernel(
    const bf16* __restrict__ qh, const bf16* __restrict__ ql,
    const bf16* __restrict__ kvh, const bf16* __restrict__ kvl,
    bf16* __restrict__ oh, bf16* __restrict__ ol) {
    int qt = blockIdx.x, h = blockIdx.y, b = blockIdx.z;
    __shared__ short UH[8192], UL[8192];
    __shared__ short PHs[4][2048], PLs[4][2048];
    int t = threadIdx.x, lane = t & 63, w = t >> 6;
    int fr = lane & 15, fq = lane >> 4;
    const short* QH = (const short*)qh;
    const short* QL = (const short*)ql;
    const short* KVH = (const short*)kvh;
    const short* KVL = (const short*)kvl;
    long qrow = (long)(b * 1024 + qt * 64 + w * 16 + fr) * DIMC + h * 64;
    bf16x8 Qh2[2], Ql2[2];
    Qh2[0] = *(const bf16x8*)(QH + qrow + fq * 8);
    Qh2[1] = *(const bf16x8*)(QH + qrow + 32 + fq * 8);
    Ql2[0] = *(const bf16x8*)(QL + qrow + fq * 8);
    Ql2[1] = *(const bf16x8*)(QL + qrow + 32 + fq * 8);
    for (int c = t; c < 768; c += 256) {
        int r = c >> 3, g = c & 7;
        int idx = r * 64 + ((g * 8) ^ ((r & 7) << 3));
        bf16x8 vh = {}, vl = {};
        if (r < 77) {
            long src = (long)(b * 77 + r) * 1024 + h * 64 + g * 8;
            vh = *(const bf16x8*)(KVH + src);
            vl = *(const bf16x8*)(KVL + src);
        }
        *(bf16x8*)&UH[idx] = vh;
        *(bf16x8*)&UL[idx] = vl;
    }
    __syncthreads();
    f32x4 s[5] = {};
    #pragma unroll
    for (int cf = 0; cf < 5; cf++) {
        int kvrow = cf * 16 + fr;
        #pragma unroll
        for (int kf = 0; kf < 2; kf++) {
            int idx = kvrow * 64 + ((kf * 32 + fq * 8) ^ ((kvrow & 7) << 3));
            bf16x8 Bh2 = *(const bf16x8*)&UH[idx];
            bf16x8 Bl2 = *(const bf16x8*)&UL[idx];
            s[cf] = __builtin_amdgcn_mfma_f32_16x16x32_bf16(Qh2[kf], Bh2, s[cf], 0, 0, 0);
            s[cf] = __builtin_amdgcn_mfma_f32_16x16x32_bf16(Qh2[kf], Bl2, s[cf], 0, 0, 0);
            s[cf] = __builtin_amdgcn_mfma_f32_16x16x32_bf16(Ql2[kf], Bh2, s[cf], 0, 0, 0);
        }
    }
    float inv[4];
    #pragma unroll
    for (int reg = 0; reg < 4; reg++) {
        float rs = 0.f;
        #pragma unroll
        for (int cf = 0; cf < 5; cf++) {
            int kv = cf * 16 + fr;
            float e = (kv < 77) ? __expf(s[cf][reg] * 0.125f) : 0.f;
            s[cf][reg] = e;
            rs += e;
        }
        rs += __shfl_xor(rs, 1);
        rs += __shfl_xor(rs, 2);
        rs += __shfl_xor(rs, 4);
        rs += __shfl_xor(rs, 8);
        inv[reg] = 1.f / rs;
    }
    short* ph = PHs[w]; short* pl = PLs[w];
    #pragma unroll
    for (int cf = 0; cf < 6; cf++)
    #pragma unroll
    for (int reg = 0; reg < 4; reg++) {
        int q = fq * 4 + reg, kv = cf * 16 + fr;
        int idx = q * 128 + (kv ^ ((q & 7) << 3));
        float pv = (cf < 5) ? s[cf][reg] * inv[reg] : 0.f;
        split2s(pv, ph[idx], pl[idx]);
    }
    __syncthreads();
    for (int c = t; c < 768; c += 256) {
        int r = c >> 3, g = c & 7;
        bf16x8 vh = {}, vl = {};
        if (r < 77) {
            long src = (long)(b * 77 + r) * 1024 + 512 + h * 64 + g * 8;
            vh = *(const bf16x8*)(KVH + src);
            vl = *(const bf16x8*)(KVL + src);
        }
        #pragma unroll
        for (int j = 0; j < 8; j++) {
            int d = g * 8 + j;
            int idx = d * 128 + (r ^ (((d >> 3) & 7) << 3));
            UH[idx] = ((short*)&vh)[j];
            UL[idx] = ((short*)&vl)[j];
        }
    }
    __syncthreads();
    f32x4 o_acc[4] = {};
    bf16x8 Pf_h[3], Pf_l[3];
    #pragma unroll
    for (int kf = 0; kf < 3; kf++) {
        int idx = fr * 128 + ((kf * 32 + fq * 8) ^ ((fr & 7) << 3));
        Pf_h[kf] = *(const bf16x8*)&ph[idx];
        Pf_l[kf] = *(const bf16x8*)&pl[idx];
    }
    #pragma unroll
    for (int cf = 0; cf < 4; cf++) {
        int d = cf * 16 + fr;
        #pragma unroll
        for (int kf = 0; kf < 3; kf++) {
            int idx = d * 128 + ((kf * 32 + fq * 8) ^ (((d >> 3) & 7) << 3));
            bf16x8 Vh2 = *(const bf16x8*)&UH[idx];
            bf16x8 Vl2 = *(const bf16x8*)&UL[idx];
            o_acc[cf] = __builtin_amdgcn_mfma_f32_16x16x32_bf16(Pf_h[kf], Vh2, o_acc[cf], 0, 0, 0);
            o_acc[cf] = __builtin_amdgcn_mfma_f32_16x16x32_bf16(Pf_h[kf], Vl2, o_acc[cf], 0, 0, 0);
            o_acc[cf] = __builtin_amdgcn_mfma_f32_16x16x32_bf16(Pf_l[kf], Vh2, o_acc[cf], 0, 0, 0);
        }
    }
    #pragma unroll
    for (int reg = 0; reg < 4; reg++) {
        long m = (long)(b * 1024 + qt * 64 + w * 16 + fq * 4 + reg);
        #pragma unroll
        for (int cf = 0; cf < 4; cf++) {
            bf16 hh, ll; split2(o_acc[cf][reg], hh, ll);
            long off = m * DIMC + h * 64 + cf * 16 + fr;
            oh[off] = hh; ol[off] = ll;
        }
    }
}

// ---- MoE grouped MFMA GEMM1, 64x64 tile: hid = gelu(xn·w1 + b1), K=512 ----
__global__ __launch_bounds__(256) void moe64_1_kernel(
    const bf16* __restrict__ xn_b, const bf16* __restrict__ e1T, const float* __restrict__ e_b1,
    const int* __restrict__ table, const int* __restrict__ ntiles, const int* __restrict__ perm,
    bf16* __restrict__ hid_b) {
    if (blockIdx.y >= ntiles[0]) return;
    int e = table[2 * blockIdx.y], row0 = table[2 * blockIdx.y + 1];
    int bn = blockIdx.x * 64;
    __shared__ short As[2 * 2048];
    __shared__ short Bs[2 * 2048];
    __shared__ int rowsS[64];
    int t = threadIdx.x, lane = t & 63, w = t >> 6;
    if (t < 64) rowsS[t] = perm[row0 + t];
    __syncthreads();
    int wm = (w >> 1) * 32, wn = (w & 1) * 32;
    int r0 = t >> 2, k0s = (t & 3) ^ ((r0 >> 1) & 3);
    int tok0 = rowsS[r0]; if (tok0 < 0) tok0 = 0;
    const short* Xs = (const short*)xn_b;
    const short* Ws = (const short*)(e1T + (long)e * HIDC * DIMC);
    const short* a0 = Xs + (long)tok0 * DIMC + k0s * 8;
    const short* b0 = Ws + (long)(bn + r0) * DIMC + k0s * 8;
    int fr = lane & 15, fq = lane >> 4;
    int aOff[2], bOff[2];
    #pragma unroll
    for (int i = 0; i < 2; i++) {
        int row = wm + i * 16 + fr;
        aOff[i] = row * 32 + ((fq ^ ((row >> 1) & 3)) * 8);
        int col = wn + i * 16 + fr;
        bOff[i] = col * 32 + ((fq ^ ((col >> 1) & 3)) * 8);
    }
    f32x4 acc[2][2] = {};
    bf16x8 va = *(const bf16x8*)(a0);
    bf16x8 vb = *(const bf16x8*)(b0);
    int bufo = 0;
    for (int kk = 0; kk < DIMC; kk += 32) {
        *(bf16x8*)&As[bufo + t * 8] = va;
        *(bf16x8*)&Bs[bufo + t * 8] = vb;
        __syncthreads();
        int kn = (kk + 32 < DIMC) ? kk + 32 : kk;
        bf16x8 na = *(const bf16x8*)(a0 + kn);
        bf16x8 nb = *(const bf16x8*)(b0 + kn);
        bf16x8 aF[2], bF[2];
        #pragma unroll
        for (int i = 0; i < 2; i++) {
            aF[i] = *(const bf16x8*)&As[bufo + aOff[i]];
            bF[i] = *(const bf16x8*)&Bs[bufo + bOff[i]];
        }
        #pragma unroll
        for (int i = 0; i < 2; i++)
        #pragma unroll
        for (int j = 0; j < 2; j++)
            acc[i][j] = __builtin_amdgcn_mfma_f32_16x16x32_bf16(aF[i], bF[j], acc[i][j], 0, 0, 0);
        va = na; vb = nb;
        bufo ^= 2048;
    }
    const float* bb = e_b1 + (long)e * HIDC;
    #pragma unroll
    for (int i = 0; i < 2; i++)
    #pragma unroll
    for (int r = 0; r < 4; r++) {
        int tok = rowsS[wm + i * 16 + fq * 4 + r];
        if (tok < 0) continue;
        #pragma unroll
        for (int j = 0; j < 2; j++) {
            int col = bn + wn + j * 16 + fr;
            float v = acc[i][j][r] + bb[col];
            v = 0.5f * v * (1.f + erff(v * 0.70710678f));
            hid_b[(long)tok * HIDC + col] = __float2bfloat16(v);
        }
    }
}

// ---- MoE grouped MFMA GEMM2, 64x64 tile: out = resid + hid·w2 + b2 -> split bf16 ----
__global__ __launch_bounds__(256) void moe64_2_kernel(
    const bf16* __restrict__ hid_b, const bf16* __restrict__ e2T, const float* __restrict__ e_b2,
    const int* __restrict__ table, const int* __restrict__ ntiles, const int* __restrict__ perm,
    const float* __restrict__ resid, bf16* __restrict__ outh, bf16* __restrict__ outl) {
    if (blockIdx.y >= ntiles[0]) return;
    int e = table[2 * blockIdx.y], row0 = table[2 * blockIdx.y + 1];
    int bn = blockIdx.x * 64;
    __shared__ short As[2 * 2048];
    __shared__ short Bs[2 * 2048];
    __shared__ int rowsS[64];
    int t = threadIdx.x, lane = t & 63, w = t >> 6;
    if (t < 64) rowsS[t] = perm[row0 + t];
    __syncthreads();
    int wm = (w >> 1) * 32, wn = (w & 1) * 32;
    int r0 = t >> 2, k0s = (t & 3) ^ ((r0 >> 1) & 3);
    int tok0 = rowsS[r0]; if (tok0 < 0) tok0 = 0;
    const short* Hs = (const short*)hid_b;
    const short* Ws = (const short*)(e2T + (long)e * DIMC * HIDC);
    const short* a0 = Hs + (long)tok0 * HIDC + k0s * 8;
    const short* b0 = Ws + (long)(bn + r0) * HIDC + k0s * 8;
    int fr = lane & 15, fq = lane >> 4;
    int aOff[2], bOff[2];
    #pragma unroll
    for (int i = 0; i < 2; i++) {
        int row = wm + i * 16 + fr;
        aOff[i] = row * 32 + ((fq ^ ((row >> 1) & 3)) * 8);
        int col = wn + i * 16 + fr;
        bOff[i] = col * 32 + ((fq ^ ((col >> 1) & 3)) * 8);
    }
    f32x4 acc[2][2] = {};
    bf16x8 va = *(const bf16x8*)(a0);
    bf16x8 vb = *(const bf16x8*)(b0);
    int bufo = 0;
    for (int kk = 0; kk < HIDC; kk += 32) {
        *(bf16x8*)&As[bufo + t * 8] = va;
        *(bf16x8*)&Bs[bufo + t * 8] = vb;
        __syncthreads();
        int kn = (kk + 32 < HIDC) ? kk + 32 : kk;
        bf16x8 na = *(const bf16x8*)(a0 + kn);
        bf16x8 nb = *(const bf16x8*)(b0 + kn);
        bf16x8 aF[2], bF[2];
        #pragma unroll
        for (int i = 0; i < 2; i++) {
            aF[i] = *(const bf16x8*)&As[bufo + aOff[i]];
            bF[i] = *(const bf16x8*)&Bs[bufo + bOff[i]];
        }
        #pragma unroll
        for (int i = 0; i < 2; i++)
        #pragma unroll
        for (int j = 0; j < 2; j++)
            acc[i][j] = __builtin_amdgcn_mfma_f32_16x16x32_bf16(aF[i], bF[j], acc[i][j], 0, 0, 0);
        va = na; vb = nb;
        bufo ^= 2048;
    }
    const float* bb = e_b2 + (long)e * DIMC;
    #pragma unroll
    for (int i = 0; i < 2; i++)
    #pragma unroll
    for (int r = 0; r < 4; r++) {
        int tok = rowsS[wm + i * 16 + fq * 4 + r];
        if (tok < 0) continue;
        #pragma unroll
        for (int j = 0; j < 2; j++) {
            int col = bn + wn + j * 16 + fr;
            long off = (long)tok * DIMC + col;
            float v = resid[off] + acc[i][j][r] + bb[col];
            bf16 hh, ll; split2(v, hh, ll);
            outh[off] = hh; outl[off] = ll;
        }
    }
}

// ---------------- LayerNorm: optional fp32 + bf16 hi/lo outputs ----------------
__global__ void ln_kernel(const float* __restrict__ x, const float* __restrict__ g,
                          const float* __restrict__ b, float* __restrict__ y,
                          bf16* __restrict__ yh, bf16* __restrict__ yl) {
    int tok = blockIdx.x;
    int t = threadIdx.x;
    const float* xr = x + (long)tok * DIMC;
    float v0 = xr[t], v1 = xr[t + 256];
    __shared__ float red[256];
    red[t] = v0 + v1; __syncthreads();
    for (int s = 128; s > 0; s >>= 1) { if (t < s) red[t] += red[t + s]; __syncthreads(); }
    float mu = red[0] * (1.f / DIMC);
    __syncthreads();
    float d0 = v0 - mu, d1 = v1 - mu;
    red[t] = d0 * d0 + d1 * d1; __syncthreads();
    for (int s = 128; s > 0; s >>= 1) { if (t < s) red[t] += red[t + s]; __syncthreads(); }
    float rs = rsqrtf(red[0] * (1.f / DIMC) + 1e-5f);
    float o0 = d0 * rs * g[t] + b[t];
    float o1 = d1 * rs * g[t + 256] + b[t + 256];
    if (y) { y[(long)tok * DIMC + t] = o0; y[(long)tok * DIMC + t + 256] = o1; }
    bf16 h, l;
    split2(o0, h, l); yh[(long)tok * DIMC + t] = h;       yl[(long)tok * DIMC + t] = l;
    split2(o1, h, l); yh[(long)tok * DIMC + t + 256] = h; yl[(long)tok * DIMC + t + 256] = l;
}

// ---------------- router text part (+ cnt zeroing) ----------------
__global__ void textpart_kernel(const float* __restrict__ w, const float* __restrict__ r_text_mu,
                                const float* __restrict__ r_comb_mu, float* __restrict__ tp,
                                int* __restrict__ cnt) {
    __shared__ float tw[4][128];
    int t = threadIdx.x;
    if (t < NE) cnt[t] = 0;
    for (int j = 0; j < 2; j++) {
        int idx = t + j * 256; int b = idx >> 7, c = idx & 127;
        const float* wr = w + (long)b * LATC;
        float s = 0.f;
        for (int k = 0; k < LATC; k++) s += wr[k] * r_text_mu[(long)k * 128 + c];
        tw[b][c] = s;
    }
    __syncthreads();
    if (t < 32) {
        int b = t >> 3, e = t & 7;
        float s = 0.f;
        for (int c = 0; c < 128; c++) s += tw[b][c] * r_comb_mu[(long)(128 + c) * 8 + e];
        tp[t] = s;
    }
}

// ---------------- router: perm poison + logits + argmax ----------------
__global__ void route_kernel(const float* __restrict__ feat, const float* __restrict__ tp,
                             const float* __restrict__ r_comb_mu, const float* __restrict__ r_temp,
                             float* __restrict__ onehot, int* __restrict__ idx, int* __restrict__ cnt,
                             int* __restrict__ perm) {
    int n = blockIdx.x * blockDim.x + threadIdx.x;
    if (n < MAXT * 64) perm[n] = -1;
    if (n >= NTOK) return;
    int b = n >> 10;
    float tmp = fmaxf(r_temp[0], 0.1f);
    float invt = 1.f / tmp;
    const float* fr = feat + (long)n * 128;
    float lg[8];
    for (int e = 0; e < 8; e++) {
        float s = 0.f;
        for (int c = 0; c < 128; c++) s += fr[c] * r_comb_mu[(long)c * 8 + e];
        lg[e] = (s + tp[b * 8 + e]) * invt;
    }
    float best = lg[0]; int bi = 0;
    for (int e = 1; e < 8; e++) { if (lg[e] > best) { best = lg[e]; bi = e; } }
    for (int e = 0; e < 8; e++) onehot[(long)n * 8 + e] = (e == bi) ? 1.f : 0.f;
    idx[n] = bi;
    atomicAdd(&cnt[bi], 1);
}

// ---------------- offsets + scatter fused (single block, LDS cursors) ----------------
__global__ void offscatter_kernel(const int* __restrict__ cnt, const int* __restrict__ idx,
                                  int* __restrict__ ntiles, int* __restrict__ table,
                                  int* __restrict__ perm) {
    __shared__ int cur[NE];
    int t = threadIdx.x;
    if (t == 0) {
        int po = 0, nt = 0;
        for (int e = 0; e < NE; e++) {
            cur[e] = po;
            int tiles = (cnt[e] + 63) >> 6;
            for (int j = 0; j < tiles; j++) { table[2 * nt] = e; table[2 * nt + 1] = po + j * 64; nt++; }
            po += tiles * 64;
        }
        ntiles[0] = nt;
    }
    __syncthreads();
    for (int n = t; n < NTOK; n += 256) {
        int e = idx[n];
        int pos = atomicAdd(&cur[e], 1);
        perm[pos] = n;
    }
}

extern "C" void kernel_launch(void* const* d_in, const int* in_sizes, int n_in,
                              void* d_out, int out_size, void* d_ws, size_t ws_size,
                              hipStream_t stream) {
    const float* x        = (const float*)d_in[0];
    const float* w        = (const float*)d_in[1];
    const float* text     = (const float*)d_in[2];
    const float* pin_w    = (const float*)d_in[3];
    const float* pin_mw   = (const float*)d_in[4];
    const float* pin_mb   = (const float*)d_in[5];
    const float* pout_w   = (const float*)d_in[6];
    const float* pout_mw  = (const float*)d_in[7];
    const float* pout_mb  = (const float*)d_in[8];
    const float* ln1g     = (const float*)d_in[9];
    const float* ln1b     = (const float*)d_in[10];
    const float* ln2g     = (const float*)d_in[11];
    const float* ln2b     = (const float*)d_in[12];
    const float* ln3g     = (const float*)d_in[13];
    const float* ln3b     = (const float*)d_in[14];
    const float* sa_in_w  = (const float*)d_in[15];
    const float* sa_in_b  = (const float*)d_in[16];
    const float* sa_out_w = (const float*)d_in[17];
    const float* sa_out_b = (const float*)d_in[18];
    const float* ca_in_w  = (const float*)d_in[19];
    const float* ca_in_b  = (const float*)d_in[20];
    const float* ca_out_w = (const float*)d_in[21];
    const float* ca_out_b = (const float*)d_in[22];
    const float* r_feat   = (const float*)d_in[23];
    const float* r_text   = (const float*)d_in[24];
    const float* r_comb   = (const float*)d_in[25];
    const float* r_temp   = (const float*)d_in[26];
    const float* e_w1     = (const float*)d_in[27];
    const float* e_b1     = (const float*)d_in[28];
    const float* e_w2     = (const float*)d_in[29];
    const float* e_b2     = (const float*)d_in[30];

    float* out    = (float*)d_out;               // [B, DIM, H, W]
    float* onehot = out + (long)BB * DIMC * HWX; // [4096, 8]

    // ---------------- workspace: fp32 pool ----------------
    float* f32p = (float*)d_ws;
    float* style_in  = f32p;                 // 2048
    float* style_out = f32p + 2048;          // 2048
    float* tp        = f32p + 4096;          // 32
    int*   idx       = (int*)(f32p + 4128);  // 4096
    int*   cnt       = (int*)(f32p + 8224);  // 8
    int*   ntiles    = (int*)(f32p + 8240);  // 8
    int*   table     = (int*)(f32p + 8248);  // 256
    int*   perm      = (int*)(f32p + 8504);  // 4608 -> ends 13112
    float* x_flat    = f32p + 13496;         // 2097152
    float* xn        = x_flat + 2097152;     // 2097152 (home of wtC split)
    float* qkv       = xn + 2097152;         // 6291456 (SA q split / CA q split home)
    float* spill     = qkv + 6291456;        // 2097152 (e2T tail)

    // ---------------- bf16 pool (phase-aliased) ----------------
    bf16* bp = (bf16*)(f32p + 12596408);
    bf16* R1 = bp;                           // 6291456 elems, phases
    bf16* xT_h  = R1;
    bf16* xT_l  = R1 + 2097152;
    bf16* wtA_h = R1 + 4194304;
    bf16* wtA_l = R1 + 5242880;
    bf16* obuf_h = R1;
    bf16* obuf_l = R1 + 2097152;
    bf16* kvt_h  = R1 + 4194304;                       // [308][1024] split
    bf16* kvt_l  = kvt_h + 315392;
    float* feat  = (float*)(kvt_l + 315392);           // 524288 fp32
    bf16* xn_h = R1 + 6291456;               // 2097152
    bf16* xn_l = xn_h + 2097152;             // 2097152
    bf16* WB   = xn_l + 2097152;             // 8388608: weights (early) / hid_b (late)
    bf16* text_h   = WB;
    bf16* text_l   = text_h + 157696;
    bf16* sawin_h  = text_l + 157696;
    bf16* sawin_l  = sawin_h + 786432;
    bf16* sawout_h = sawin_l + 786432;
    bf16* sawout_l = sawout_h + 262144;
    bf16* caw_h    = sawout_l + 262144;
    bf16* caw_l    = caw_h + 786432;
    bf16* cawout_h = caw_l + 786432;
    bf16* cawout_l = cawout_h + 262144;
    bf16* rfT_h    = cawout_l + 262144;      // [128][512] split r_feat^T
    bf16* rfT_l    = rfT_h + 65536;
    bf16* hid_b    = WB;                     // overlays weights after ca_out
    bf16* e1T = (bf16*)qkv;                  // [8][2048][512] in qkv+spill
    bf16* e2T = e1T + 8388608;
    bf16* xfl_h = xn_h;                      // moe64_2 writes split output here
    bf16* xfl_l = xn_l;
    bf16* wtC_h = (bf16*)xn;                 // modconv-out weight (dead fp32 region)
    bf16* wtC_l = wtC_h + 1048576;
    bf16* q_h = (bf16*)qkv;                  // [4096][1536]
    bf16* q_l = q_h + 6291456;
    bf16* ca_qh = (bf16*)qkv;                // [4096][512]
    bf16* ca_ql = ca_qh + 2097152;
    (void)ws_size; (void)spill;

    auto mg = [&](const bf16* Ah, const bf16* Al, const bf16* Bh, const bf16* Bl,
                  const float* bias, const float* resid, float* C, bf16* Oh, bf16* Ol,
                  int M, int N, int K, long ab, long bb, long cb, int csm, int csn, int nb) {
        dim3 g(N / 64, (M + 63) / 64, nb);
        hipLaunchKernelGGL(mgemm64_kernel, g, dim3(256), 0, stream,
                           Ah, Al, Bh, Bl, bias, resid, C, Oh, Ol, M, N, K, ab, bb, cb, csm, csn);
    };

    // ---- fused input conversions (hi/lo): one launch for all 5 flat arrays ----
    {
        int n0 = 1536 * 512, n1 = 512 * 512, n2 = 1536 * 512, n3 = 512 * 512, n4 = BB * TXT * 512;
        int total = n0 + n1 + n2 + n3 + n4;
        hipLaunchKernelGGL(cvtall_kernel, dim3((total / 4 + 255) / 256), dim3(256), 0, stream,
                           sa_in_w, sawin_h, sawin_l, n0,
                           sa_out_w, sawout_h, sawout_l, n1,
                           ca_in_w, caw_h, caw_l, n2,
                           ca_out_w, cawout_h, cawout_l, n3,
                           text, text_h, text_l, n4);
    }
    // ---- fused transposes: x (z<4) + r_feat (z==4) ----
    hipLaunchKernelGGL(trcvt2x_kernel, dim3(32, 16, 5), dim3(256), 0, stream,
                       x, xT_h, xT_l, r_feat, rfT_h, rfT_l);

    // ---- both modconv styles + weights up front (wtC in dead xn region) ----
    hipLaunchKernelGGL(style2_kernel, dim3(16), dim3(256), 0, stream,
                       w, pin_mw, pin_mb, pout_mw, pout_mb, style_in, style_out);
    hipLaunchKernelGGL(wtmod2_kernel, dim3(2 * BB * DIMC), dim3(256), 0, stream,
                       pin_w, style_in, pout_w, style_out, wtA_h, wtA_l, wtC_h, wtC_l);

    // ---- modconv in ----
    mg(xT_h, xT_l, wtA_h, wtA_l, nullptr, nullptr, x_flat, nullptr, nullptr,
       HWX, DIMC, DIMC, (long)HWX * DIMC, (long)DIMC * DIMC, (long)HWX * DIMC, DIMC, 1, BB);

    // ---- LN1 + self-attention (split MFMA) ----
    hipLaunchKernelGGL(ln_kernel, dim3(NTOK), dim3(256), 0, stream, x_flat, ln1g, ln1b,
                       (float*)nullptr, xn_h, xn_l);
    // qkv projection via high-reuse 128x64 kernel
    hipLaunchKernelGGL(mgemm128x64_kernel, dim3(1536 / 64, NTOK / 128), dim3(256), 0, stream,
                       xn_h, xn_l, sawin_h, sawin_l, sa_in_b, q_h, q_l, NTOK, 1536, 512);
    hipLaunchKernelGGL(sa_mfma_kernel, dim3(16, HEADS, BB), dim3(256), 0, stream,
                       q_h, q_l, obuf_h, obuf_l);
    mg(obuf_h, obuf_l, sawout_h, sawout_l, sa_out_b, x_flat, x_flat, nullptr, nullptr,
       NTOK, 512, 512, 0, 0, 0, 512, 1, 1);

    // ---- LN2 + cross-attention (split MFMA) ----
    hipLaunchKernelGGL(ln_kernel, dim3(NTOK), dim3(256), 0, stream, x_flat, ln2g, ln2b,
                       (float*)nullptr, xn_h, xn_l);
    mg(xn_h, xn_l, caw_h, caw_l, ca_in_b, nullptr, nullptr, ca_qh, ca_ql,
       NTOK, 512, 512, 0, 0, 0, 512, 1, 1);
    mg(text_h, text_l, caw_h + 512 * 512, caw_l + 512 * 512, ca_in_b + 512, nullptr, nullptr,
       kvt_h, kvt_l, BB * TXT, 1024, 512, 0, 0, 0, 1024, 1, 1);
    hipLaunchKernelGGL(ca_mfma_kernel, dim3(16, HEADS, BB), dim3(256), 0, stream,
                       ca_qh, ca_ql, kvt_h, kvt_l, obuf_h, obuf_l);
    // expert weight transposes (qkv region dead after ca_mfma) — one fused launch
    hipLaunchKernelGGL(tr2x_kernel, dim3(64, 16, 16), dim3(256), 0, stream,
                       e_w1, e1T, e_w2, e2T);
    mg(obuf_h, obuf_l, cawout_h, cawout_l, ca_out_b, x_flat, x_flat, nullptr, nullptr,
       NTOK, 512, 512, 0, 0, 0, 512, 1, 1);

    // ---- LN3 + router (feat via split MFMA) ----
    hipLaunchKernelGGL(ln_kernel, dim3(NTOK), dim3(256), 0, stream, x_flat, ln3g, ln3b,
                       (float*)nullptr, xn_h, xn_l);
    mg(xn_h, xn_l, rfT_h, rfT_l, nullptr, nullptr, feat, nullptr, nullptr,
       NTOK, 128, 512, 0, 0, 0, 128, 1, 1);
    hipLaunchKernelGGL(textpart_kernel, dim3(1), dim3(256), 0, stream, w, r_text, r_comb, tp, cnt);
    hipLaunchKernelGGL(route_kernel, dim3(18), dim3(256), 0, stream,
                       feat, tp, r_comb, r_temp, onehot, idx, cnt, perm);
    hipLaunchKernelGGL(offscatter_kernel, dim3(1), dim3(256), 0, stream,
                       cnt, idx, ntiles, table, perm);

    // ---- MoE grouped MFMA GEMMs (64x64 tiles; gemm2 emits split bf16 directly) ----
    hipLaunchKernelGGL(moe64_1_kernel, dim3(HIDC / 64, MAXT), dim3(256), 0, stream,
                       xn_h, e1T, e_b1, table, ntiles, perm, hid_b);
    hipLaunchKernelGGL(moe64_2_kernel, dim3(DIMC / 64, MAXT), dim3(256), 0, stream,
                       hid_b, e2T, e_b2, table, ntiles, perm, x_flat, xfl_h, xfl_l);

    // ---- modconv out (weights already prepared) ----
    mg(wtC_h, wtC_l, xfl_h, xfl_l, nullptr, nullptr, out, nullptr, nullptr,
       DIMC, HWX, DIMC, (long)DIMC * DIMC, (long)HWX * DIMC, (long)DIMC * HWX, HWX, 1, BB);
}

// Round 19
// 488.506 us; speedup vs baseline: 1.4744x; 1.0165x over previous
//
#include <hip/hip_runtime.h>
#include <hip/hip_bf16.h>
#include <math.h>

#define DIMC 512
#define HEADS 8
#define HD 64
#define BB 4
#define HWX 1024
#define TXT 77
#define LATC 512
#define NE 8
#define HIDC 2048
#define NTOK 4096
#define MAXT 72           // MoE tiles of 64: 4096/64 + 8

typedef __attribute__((ext_vector_type(8))) short bf16x8;
typedef __attribute__((ext_vector_type(4))) float f32x4;
typedef __hip_bfloat16 bf16;

__device__ __forceinline__ void split2(float v, bf16& h, bf16& l) {
    h = __float2bfloat16(v);
    l = __float2bfloat16(v - __bfloat162float(h));
}
__device__ __forceinline__ void split2s(float v, short& h, short& l) {
    bf16 hb, lb; split2(v, hb, lb);
    h = *(short*)&hb; l = *(short*)&lb;
}

// ---------------- both styles in one launch: job 0 = in, job 1 = out ----------------
__global__ void style2_kernel(const float* __restrict__ w,
                              const float* __restrict__ mwA, const float* __restrict__ mbA,
                              const float* __restrict__ mwB, const float* __restrict__ mbB,
                              float* __restrict__ sA, float* __restrict__ sB) {
    int g = blockIdx.x * blockDim.x + threadIdx.x;
    int job = (g >= BB * DIMC) ? 1 : 0;
    int t = g - job * BB * DIMC;
    if (t >= BB * DIMC) return;
    const float* mw = job ? mwB : mwA;
    const float* mb = job ? mbB : mbA;
    float* st = job ? sB : sA;
    int b = t / DIMC, i = t % DIMC;
    const float* wr = w + (long)b * LATC;
    const float* mr = mw + (long)i * LATC;
    float s = 0.f;
    #pragma unroll 8
    for (int l = 0; l < LATC; l++) s += wr[l] * mr[l];
    st[t] = s + mb[i];
}

// ------- both wtmods in one launch -------
__global__ void wtmod2_kernel(const float* __restrict__ wA, const float* __restrict__ sA,
                              const float* __restrict__ wB, const float* __restrict__ sB,
                              bf16* __restrict__ whA, bf16* __restrict__ wlA,
                              bf16* __restrict__ whB, bf16* __restrict__ wlB) {
    int gb = blockIdx.x;
    int job = (gb >= BB * DIMC) ? 1 : 0;
    int bo = gb - job * BB * DIMC;
    const float* weight = job ? wB : wA;
    const float* style  = job ? sB : sA;
    bf16* wh = job ? whB : whA;
    bf16* wl = job ? wlB : wlA;
    int b = bo / DIMC, o = bo % DIMC;
    const float* wr = weight + (long)o * DIMC;
    const float* sr = style + (long)b * DIMC;
    int t = threadIdx.x;
    float vals[2]; float part = 0.f;
    for (int j = 0; j < 2; j++) {
        int i = t + j * 256;
        float v = wr[i] * sr[i];
        vals[j] = v; part += v * v;
    }
    __shared__ float red[256];
    red[t] = part; __syncthreads();
    for (int s = 128; s > 0; s >>= 1) { if (t < s) red[t] += red[t + s]; __syncthreads(); }
    float d = rsqrtf(red[0] + 1e-8f);
    for (int j = 0; j < 2; j++) {
        int i = t + j * 256;
        bf16 h, l; split2(vals[j] * d, h, l);
        wh[(long)bo * DIMC + i] = h; wl[(long)bo * DIMC + i] = l;
    }
}

// ---------------- fused segmented fp32 -> bf16 hi/lo convert (5 weight arrays) ----------------
__global__ void cvtall_kernel(
    const float* __restrict__ s0, bf16* __restrict__ h0, bf16* __restrict__ l0, int n0,
    const float* __restrict__ s1, bf16* __restrict__ h1, bf16* __restrict__ l1, int n1,
    const float* __restrict__ s2, bf16* __restrict__ h2, bf16* __restrict__ l2, int n2,
    const float* __restrict__ s3, bf16* __restrict__ h3, bf16* __restrict__ l3, int n3,
    const float* __restrict__ s4, bf16* __restrict__ h4, bf16* __restrict__ l4, int n4) {
    int i = (blockIdx.x * blockDim.x + threadIdx.x) * 4;
    const float* src; bf16 *hh, *ll;
    if (i < n0) { src = s0; hh = h0; ll = l0; }
    else if ((i -= n0) < n1) { src = s1; hh = h1; ll = l1; }
    else if ((i -= n1) < n2) { src = s2; hh = h2; ll = l2; }
    else if ((i -= n2) < n3) { src = s3; hh = h3; ll = l3; }
    else if ((i -= n3) < n4) { src = s4; hh = h4; ll = l4; }
    else return;
    float4 v = *(const float4*)(src + i);
    float a[4] = {v.x, v.y, v.z, v.w};
    #pragma unroll
    for (int j = 0; j < 4; j++) { bf16 h, l; split2(a[j], h, l); hh[i + j] = h; ll[i + j] = l; }
}

// ---- fused transpose hi/lo: z<4 -> x slice (512x1024), z==4 -> r_feat (512x128) ----
__global__ void trcvt2x_kernel(const float* __restrict__ x, bf16* __restrict__ xh,
                               bf16* __restrict__ xl, const float* __restrict__ rf,
                               bf16* __restrict__ rfh, bf16* __restrict__ rfl) {
    __shared__ float tile[32][33];
    int z = blockIdx.z;
    const float* in; bf16 *hi, *lo; int R, C;
    if (z < 4) {
        in = x + (long)z * 512 * 1024;
        hi = xh + (long)z * 1024 * 512; lo = xl + (long)z * 1024 * 512;
        R = 512; C = 1024;
    } else {
        if (blockIdx.x >= 4) return;
        in = rf; hi = rfh; lo = rfl;
        R = 512; C = 128;
    }
    int c0 = blockIdx.x * 32, r0 = blockIdx.y * 32;
    int tc = threadIdx.x & 31, tr = threadIdx.x >> 5;
    #pragma unroll
    for (int i = 0; i < 4; i++) {
        int r = tr + i * 8;
        tile[r][tc] = in[(long)(r0 + r) * C + c0 + tc];
    }
    __syncthreads();
    #pragma unroll
    for (int i = 0; i < 4; i++) {
        int r = tr + i * 8;
        bf16 h, l; split2(tile[tc][r], h, l);
        hi[(long)(c0 + r) * R + r0 + tc] = h;
        lo[(long)(c0 + r) * R + r0 + tc] = l;
    }
}

// ---- fused expert-weight transposes: z<8 -> e_w1[z] (512x2048), z>=8 -> e_w2[z-8] (2048x512) ----
__global__ void tr2x_kernel(const float* __restrict__ w1, bf16* __restrict__ e1T,
                            const float* __restrict__ w2, bf16* __restrict__ e2T) {
    __shared__ float tile[32][33];
    int z = blockIdx.z;
    const float* in; bf16* out; int R, C, c0, r0;
    if (z < 8) {
        in = w1 + (long)z * 512 * 2048;  out = e1T + (long)z * 2048 * 512;
        R = 512; C = 2048;
        c0 = blockIdx.x * 32; r0 = blockIdx.y * 32;       // grid x=64, y=16
    } else {
        in = w2 + (long)(z - 8) * 2048 * 512;  out = e2T + (long)(z - 8) * 512 * 2048;
        R = 2048; C = 512;
        int lin = blockIdx.y * 64 + blockIdx.x;           // 0..1023 -> (16 x, 64 y)
        c0 = (lin & 15) * 32; r0 = (lin >> 4) * 32;
    }
    int tc = threadIdx.x & 31, tr = threadIdx.x >> 5;
    #pragma unroll
    for (int i = 0; i < 4; i++) {
        int r = tr + i * 8;
        tile[r][tc] = in[(long)(r0 + r) * C + c0 + tc];
    }
    __syncthreads();
    #pragma unroll
    for (int i = 0; i < 4; i++) {
        int r = tr + i * 8;
        out[(long)(c0 + r) * R + r0 + tc] = __float2bfloat16(tile[tc][r]);
    }
}

// ---- split-precision bf16 MFMA GEMM, 64x64 tile (high machine fill) ----
__global__ __launch_bounds__(256) void mgemm64_kernel(
    const bf16* __restrict__ Ah, const bf16* __restrict__ Al,
    const bf16* __restrict__ Bh, const bf16* __restrict__ Bl,
    const float* __restrict__ bias, const float* __restrict__ resid, float* __restrict__ C,
    bf16* __restrict__ Oh, bf16* __restrict__ Ol,
    int M, int N, int K, long a_bat, long b_bat, long c_bat, int cs_m, int cs_n) {
    __shared__ short AsH[2 * 2048];
    __shared__ short AsL[2 * 2048];
    __shared__ short BsH[2 * 2048];
    __shared__ short BsL[2 * 2048];
    int bat = blockIdx.z;
    const short* AbH = (const short*)(Ah + (long)bat * a_bat);
    const short* AbL = (const short*)(Al + (long)bat * a_bat);
    const short* BbH = (const short*)(Bh + (long)bat * b_bat);
    const short* BbL = (const short*)(Bl + (long)bat * b_bat);
    float* Cb = C + (long)bat * c_bat;
    const float* Rb = resid ? resid + (long)bat * c_bat : nullptr;
    int bm = blockIdx.y * 64, bn = blockIdx.x * 64;
    int t = threadIdx.x, lane = t & 63, w = t >> 6;
    int wm = (w >> 1) * 32, wn = (w & 1) * 32;
    int r0 = t >> 2, k0s = (t & 3) ^ ((r0 >> 1) & 3);
    int ar0 = bm + r0; if (ar0 > M - 1) ar0 = M - 1;
    long aoff = (long)ar0 * K + k0s * 8;
    long boff = (long)(bn + r0) * K + k0s * 8;
    int fr = lane & 15, fq = lane >> 4;
    int aOff[2], bOff[2];
    #pragma unroll
    for (int i = 0; i < 2; i++) {
        int row = wm + i * 16 + fr;
        aOff[i] = row * 32 + ((fq ^ ((row >> 1) & 3)) * 8);
        int col = wn + i * 16 + fr;
        bOff[i] = col * 32 + ((fq ^ ((col >> 1) & 3)) * 8);
    }
    f32x4 acc[2][2] = {};
    bf16x8 vah = *(const bf16x8*)(AbH + aoff);
    bf16x8 val = *(const bf16x8*)(AbL + aoff);
    bf16x8 vbh = *(const bf16x8*)(BbH + boff);
    bf16x8 vbl = *(const bf16x8*)(BbL + boff);
    int bufo = 0;
    for (int kk = 0; kk < K; kk += 32) {
        *(bf16x8*)&AsH[bufo + t * 8] = vah;
        *(bf16x8*)&AsL[bufo + t * 8] = val;
        *(bf16x8*)&BsH[bufo + t * 8] = vbh;
        *(bf16x8*)&BsL[bufo + t * 8] = vbl;
        __syncthreads();
        int kn = (kk + 32 < K) ? kk + 32 : kk;
        bf16x8 nah = *(const bf16x8*)(AbH + aoff + kn);
        bf16x8 nal = *(const bf16x8*)(AbL + aoff + kn);
        bf16x8 nbh = *(const bf16x8*)(BbH + boff + kn);
        bf16x8 nbl = *(const bf16x8*)(BbL + boff + kn);
        bf16x8 aH[2], aL[2], bH[2], bL[2];
        #pragma unroll
        for (int i = 0; i < 2; i++) {
            aH[i] = *(const bf16x8*)&AsH[bufo + aOff[i]];
            aL[i] = *(const bf16x8*)&AsL[bufo + aOff[i]];
            bH[i] = *(const bf16x8*)&BsH[bufo + bOff[i]];
            bL[i] = *(const bf16x8*)&BsL[bufo + bOff[i]];
        }
        #pragma unroll
        for (int i = 0; i < 2; i++)
        #pragma unroll
        for (int j = 0; j < 2; j++) {
            acc[i][j] = __builtin_amdgcn_mfma_f32_16x16x32_bf16(aH[i], bH[j], acc[i][j], 0, 0, 0);
            acc[i][j] = __builtin_amdgcn_mfma_f32_16x16x32_bf16(aH[i], bL[j], acc[i][j], 0, 0, 0);
            acc[i][j] = __builtin_amdgcn_mfma_f32_16x16x32_bf16(aL[i], bH[j], acc[i][j], 0, 0, 0);
        }
        vah = nah; val = nal; vbh = nbh; vbl = nbl;
        bufo ^= 2048;
    }
    #pragma unroll
    for (int i = 0; i < 2; i++)
    #pragma unroll
    for (int j = 0; j < 2; j++)
    #pragma unroll
    for (int r = 0; r < 4; r++) {
        int row = bm + wm + i * 16 + fq * 4 + r;
        int col = bn + wn + j * 16 + fr;
        if (row < M) {
            long off = (long)row * cs_m + (long)col * cs_n;
            float v = acc[i][j][r];
            if (bias) v += bias[col];
            if (Oh) {
                bf16 hh, ll; split2(v, hh, ll);
                Oh[off] = hh; Ol[off] = ll;
            } else {
                if (Rb) v += Rb[off];
                Cb[off] = v;
            }
        }
    }
}

// ---- split-precision bf16 MFMA GEMM, 128x64 tile (high reuse; for the big qkv GEMM) ----
__global__ __launch_bounds__(256) void mgemm128x64_kernel(
    const bf16* __restrict__ Ah, const bf16* __restrict__ Al,
    const bf16* __restrict__ Bh, const bf16* __restrict__ Bl,
    const float* __restrict__ bias, bf16* __restrict__ Oh, bf16* __restrict__ Ol,
    int M, int N, int K) {
    __shared__ short AsH[2 * 4096];
    __shared__ short AsL[2 * 4096];
    __shared__ short BsH[2 * 2048];
    __shared__ short BsL[2 * 2048];
    const short* AbH = (const short*)Ah;
    const short* AbL = (const short*)Al;
    const short* BbH = (const short*)Bh;
    const short* BbL = (const short*)Bl;
    int bm = blockIdx.y * 128, bn = blockIdx.x * 64;
    int t = threadIdx.x, lane = t & 63, w = t >> 6;
    int wm = (w >> 1) * 64, wn = (w & 1) * 32;
    int p0 = t, p1 = t + 256;
    int ra0 = p0 >> 2, ka0 = (p0 & 3) ^ ((ra0 >> 1) & 3);
    int ra1 = p1 >> 2, ka1 = (p1 & 3) ^ ((ra1 >> 1) & 3);
    int arow0 = bm + ra0; if (arow0 > M - 1) arow0 = M - 1;
    int arow1 = bm + ra1; if (arow1 > M - 1) arow1 = M - 1;
    long aoff0 = (long)arow0 * K + ka0 * 8;
    long aoff1 = (long)arow1 * K + ka1 * 8;
    int rb = t >> 2, kb2 = (t & 3) ^ ((rb >> 1) & 3);
    long boff = (long)(bn + rb) * K + kb2 * 8;
    int fr = lane & 15, fq = lane >> 4;
    int aOff[4], bOff[2];
    #pragma unroll
    for (int i = 0; i < 4; i++) {
        int row = wm + i * 16 + fr;
        aOff[i] = row * 32 + ((fq ^ ((row >> 1) & 3)) * 8);
    }
    #pragma unroll
    for (int j = 0; j < 2; j++) {
        int col = wn + j * 16 + fr;
        bOff[j] = col * 32 + ((fq ^ ((col >> 1) & 3)) * 8);
    }
    f32x4 acc[4][2] = {};
    bf16x8 vah0 = *(const bf16x8*)(AbH + aoff0);
    bf16x8 vah1 = *(const bf16x8*)(AbH + aoff1);
    bf16x8 val0 = *(const bf16x8*)(AbL + aoff0);
    bf16x8 val1 = *(const bf16x8*)(AbL + aoff1);
    bf16x8 vbh  = *(const bf16x8*)(BbH + boff);
    bf16x8 vbl  = *(const bf16x8*)(BbL + boff);
    int bufA = 0, bufB = 0;
    for (int kk = 0; kk < K; kk += 32) {
        *(bf16x8*)&AsH[bufA + p0 * 8] = vah0;  *(bf16x8*)&AsH[bufA + p1 * 8] = vah1;
        *(bf16x8*)&AsL[bufA + p0 * 8] = val0;  *(bf16x8*)&AsL[bufA + p1 * 8] = val1;
        *(bf16x8*)&BsH[bufB + t * 8] = vbh;
        *(bf16x8*)&BsL[bufB + t * 8] = vbl;
        __syncthreads();
        int kn = (kk + 32 < K) ? kk + 32 : kk;
        bf16x8 nah0 = *(const bf16x8*)(AbH + aoff0 + kn);
        bf16x8 nah1 = *(const bf16x8*)(AbH + aoff1 + kn);
        bf16x8 nal0 = *(const bf16x8*)(AbL + aoff0 + kn);
        bf16x8 nal1 = *(const bf16x8*)(AbL + aoff1 + kn);
        bf16x8 nbh  = *(const bf16x8*)(BbH + boff + kn);
        bf16x8 nbl  = *(const bf16x8*)(BbL + boff + kn);
        bf16x8 aH[4], aL[4], bH[2], bL[2];
        #pragma unroll
        for (int i = 0; i < 4; i++) {
            aH[i] = *(const bf16x8*)&AsH[bufA + aOff[i]];
            aL[i] = *(const bf16x8*)&AsL[bufA + aOff[i]];
        }
        #pragma unroll
        for (int j = 0; j < 2; j++) {
            bH[j] = *(const bf16x8*)&BsH[bufB + bOff[j]];
            bL[j] = *(const bf16x8*)&BsL[bufB + bOff[j]];
        }
        #pragma unroll
        for (int i = 0; i < 4; i++)
        #pragma unroll
        for (int j = 0; j < 2; j++) {
            acc[i][j] = __builtin_amdgcn_mfma_f32_16x16x32_bf16(aH[i], bH[j], acc[i][j], 0, 0, 0);
            acc[i][j] = __builtin_amdgcn_mfma_f32_16x16x32_bf16(aH[i], bL[j], acc[i][j], 0, 0, 0);
            acc[i][j] = __builtin_amdgcn_mfma_f32_16x16x32_bf16(aL[i], bH[j], acc[i][j], 0, 0, 0);
        }
        vah0 = nah0; vah1 = nah1; val0 = nal0; val1 = nal1;
        vbh = nbh; vbl = nbl;
        bufA ^= 4096; bufB ^= 2048;
    }
    #pragma unroll
    for (int i = 0; i < 4; i++)
    #pragma unroll
    for (int j = 0; j < 2; j++)
    #pragma unroll
    for (int r = 0; r < 4; r++) {
        int row = bm + wm + i * 16 + fq * 4 + r;
        int col = bn + wn + j * 16 + fr;
        if (row < M) {
            long off = (long)row * N + col;
            float v = acc[i][j][r] + bias[col];
            bf16 hh, ll; split2(v, hh, ll);
            Oh[off] = hh; Ol[off] = ll;
        }
    }
}

// ---- split-precision MFMA flash SA: no-max softmax, single-bf16 P, V stride 72 ----
__global__ __launch_bounds__(256) void sa_mfma_kernel(
    const bf16* __restrict__ qh, const bf16* __restrict__ ql,
    bf16* __restrict__ oh, bf16* __restrict__ ol) {
    int qt = blockIdx.x, h = blockIdx.y, b = blockIdx.z;
    __shared__ short KsH[4096], KsL[4096];       // [kv][64], swz: col ^ ((kv&7)<<3)
    __shared__ short VtH[4608], VtL[4608];       // [d][72], swz: col ^ (((d>>3)&7)<<3)
    __shared__ short PHs[4][1024];               // per-wave P (single bf16)
    int t = threadIdx.x, lane = t & 63, w = t >> 6;
    int fr = lane & 15, fq = lane >> 4;
    const short* QH = (const short*)qh;
    const short* QL = (const short*)ql;
    long qrow = (long)(b * 1024 + qt * 64 + w * 16 + fr) * 1536 + h * 64;
    bf16x8 Qh2[2], Ql2[2];
    Qh2[0] = *(const bf16x8*)(QH + qrow + fq * 8);
    Qh2[1] = *(const bf16x8*)(QH + qrow + 32 + fq * 8);
    Ql2[0] = *(const bf16x8*)(QL + qrow + fq * 8);
    Ql2[1] = *(const bf16x8*)(QL + qrow + 32 + fq * 8);
    float l_i[4] = {0.f, 0.f, 0.f, 0.f};
    f32x4 o_acc[4] = {};
    int c0 = t, c1 = t + 256;
    int r0 = c0 >> 3, g0 = c0 & 7;               // r0 in 0..31
    int r1 = c1 >> 3, g1 = c1 & 7;               // r1 in 32..63
    int kd0 = r0 * 64 + ((g0 * 8) ^ ((r0 & 7) << 3));
    int kd1 = r1 * 64 + ((g1 * 8) ^ ((r1 & 7) << 3));
    long kb = (long)(b * 1024) * 1536 + 512 + h * 64;
    long vb = kb + 512;
    long lo0 = (long)r0 * 1536 + g0 * 8, lo1 = (long)r1 * 1536 + g1 * 8;
    short* ph = PHs[w];
    bf16x8 kh0 = *(const bf16x8*)(QH + kb + lo0);
    bf16x8 kh1 = *(const bf16x8*)(QH + kb + lo1);
    bf16x8 kl0 = *(const bf16x8*)(QL + kb + lo0);
    bf16x8 kl1 = *(const bf16x8*)(QL + kb + lo1);
    bf16x8 vh0 = *(const bf16x8*)(QH + vb + lo0);
    bf16x8 vh1 = *(const bf16x8*)(QH + vb + lo1);
    bf16x8 vl0 = *(const bf16x8*)(QL + vb + lo0);
    bf16x8 vl1 = *(const bf16x8*)(QL + vb + lo1);
    for (int kt = 0; kt < 16; kt++) {
        __syncthreads();          // A: all waves finished reading Ks/Vt of prev iter
        *(bf16x8*)&KsH[kd0] = kh0;  *(bf16x8*)&KsH[kd1] = kh1;
        *(bf16x8*)&KsL[kd0] = kl0;  *(bf16x8*)&KsL[kd1] = kl1;
        #pragma unroll
        for (int j = 0; j < 8; j++) {
            int d0 = g0 * 8 + j;
            int i0 = d0 * 72 + (r0 ^ (g0 << 3));
            VtH[i0] = ((short*)&vh0)[j];  VtL[i0] = ((short*)&vl0)[j];
            int d1 = g1 * 8 + j;
            int i1 = d1 * 72 + (r1 ^ (g1 << 3));
            VtH[i1] = ((short*)&vh1)[j];  VtL[i1] = ((short*)&vl1)[j];
        }
        __syncthreads();          // B: staging visible
        int ktn = (kt + 1 < 16) ? kt + 1 : kt;
        long ko = kb + (long)(ktn * 64) * 1536;
        long vo = vb + (long)(ktn * 64) * 1536;
        bf16x8 nkh0 = *(const bf16x8*)(QH + ko + lo0);
        bf16x8 nkh1 = *(const bf16x8*)(QH + ko + lo1);
        bf16x8 nkl0 = *(const bf16x8*)(QL + ko + lo0);
        bf16x8 nkl1 = *(const bf16x8*)(QL + ko + lo1);
        bf16x8 nvh0 = *(const bf16x8*)(QH + vo + lo0);
        bf16x8 nvh1 = *(const bf16x8*)(QH + vo + lo1);
        bf16x8 nvl0 = *(const bf16x8*)(QL + vo + lo0);
        bf16x8 nvl1 = *(const bf16x8*)(QL + vo + lo1);
        __builtin_amdgcn_s_setprio(1);
        f32x4 s[4] = {};
        #pragma unroll
        for (int cf = 0; cf < 4; cf++) {
            int kvrow = cf * 16 + fr;
            #pragma unroll
            for (int kf = 0; kf < 2; kf++) {
                int idx = kvrow * 64 + ((kf * 32 + fq * 8) ^ ((kvrow & 7) << 3));
                bf16x8 Bh2 = *(const bf16x8*)&KsH[idx];
                bf16x8 Bl2 = *(const bf16x8*)&KsL[idx];
                s[cf] = __builtin_amdgcn_mfma_f32_16x16x32_bf16(Qh2[kf], Bh2, s[cf], 0, 0, 0);
                s[cf] = __builtin_amdgcn_mfma_f32_16x16x32_bf16(Qh2[kf], Bl2, s[cf], 0, 0, 0);
                s[cf] = __builtin_amdgcn_mfma_f32_16x16x32_bf16(Ql2[kf], Bh2, s[cf], 0, 0, 0);
            }
        }
        __builtin_amdgcn_s_setprio(0);
        // ---- no-max softmax: P = exp(S/8) rounded to single bf16; l from rounded P ----
        #pragma unroll
        for (int cf = 0; cf < 4; cf++)
        #pragma unroll
        for (int reg = 0; reg < 4; reg++) {
            float e = __expf(s[cf][reg] * 0.125f);
            bf16 eb = __float2bfloat16(e);
            l_i[reg] += __bfloat162float(eb);
            int q = fq * 4 + reg, kv = cf * 16 + fr;
            int idx = q * 64 + (kv ^ ((q & 7) << 3));
            ph[idx] = *(short*)&eb;
        }
        asm volatile("s_waitcnt lgkmcnt(0)" ::: "memory");
        __builtin_amdgcn_sched_barrier(0);
        __builtin_amdgcn_s_setprio(1);
        bf16x8 Pf_h[2];
        #pragma unroll
        for (int kf = 0; kf < 2; kf++) {
            int idx = fr * 64 + ((kf * 32 + fq * 8) ^ ((fr & 7) << 3));
            Pf_h[kf] = *(const bf16x8*)&ph[idx];
        }
        #pragma unroll
        for (int cf = 0; cf < 4; cf++) {
            int d = cf * 16 + fr;
            #pragma unroll
            for (int kf = 0; kf < 2; kf++) {
                int idx = d * 72 + ((kf * 32 + fq * 8) ^ (((d >> 3) & 7) << 3));
                bf16x8 Vh2 = *(const bf16x8*)&VtH[idx];
                bf16x8 Vl2 = *(const bf16x8*)&VtL[idx];
                o_acc[cf] = __builtin_amdgcn_mfma_f32_16x16x32_bf16(Pf_h[kf], Vh2, o_acc[cf], 0, 0, 0);
                o_acc[cf] = __builtin_amdgcn_mfma_f32_16x16x32_bf16(Pf_h[kf], Vl2, o_acc[cf], 0, 0, 0);
            }
        }
        __builtin_amdgcn_s_setprio(0);
        kh0 = nkh0; kh1 = nkh1; kl0 = nkl0; kl1 = nkl1;
        vh0 = nvh0; vh1 = nvh1; vl0 = nvl0; vl1 = nvl1;
    }
    #pragma unroll
    for (int reg = 0; reg < 4; reg++) {
        float rs = l_i[reg];
        rs += __shfl_xor(rs, 1);
        rs += __shfl_xor(rs, 2);
        rs += __shfl_xor(rs, 4);
        rs += __shfl_xor(rs, 8);
        float inv = 1.f / rs;
        long m = (long)(b * 1024 + qt * 64 + w * 16 + fq * 4 + reg);
        #pragma unroll
        for (int cf = 0; cf < 4; cf++) {
            float v = o_acc[cf][reg] * inv;
            bf16 hh, ll; split2(v, hh, ll);
            long off = m * DIMC + h * 64 + cf * 16 + fr;
            oh[off] = hh; ol[off] = ll;
        }
    }
}

// ---- split-precision MFMA cross-attention: 77 keys padded to 96, single-bf16 P ----
__global__ __launch_bounds__(256) void ca_mfma_kernel(
    const bf16* __restrict__ qh, const bf16* __restrict__ ql,
    const bf16* __restrict__ kvh, const bf16* __restrict__ kvl,
    bf16* __restrict__ oh, bf16* __restrict__ ol) {
    int qt = blockIdx.x, h = blockIdx.y, b = blockIdx.z;
    __shared__ short UH[8192], UL[8192];
    __shared__ short PHs[4][2048];
    int t = threadIdx.x, lane = t & 63, w = t >> 6;
    int fr = lane & 15, fq = lane >> 4;
    const short* QH = (const short*)qh;
    const short* QL = (const short*)ql;
    const short* KVH = (const short*)kvh;
    const short* KVL = (const short*)kvl;
    long qrow = (long)(b * 1024 + qt * 64 + w * 16 + fr) * DIMC + h * 64;
    bf16x8 Qh2[2], Ql2[2];
    Qh2[0] = *(const bf16x8*)(QH + qrow + fq * 8);
    Qh2[1] = *(const bf16x8*)(QH + qrow + 32 + fq * 8);
    Ql2[0] = *(const bf16x8*)(QL + qrow + fq * 8);
    Ql2[1] = *(const bf16x8*)(QL + qrow + 32 + fq * 8);
    for (int c = t; c < 768; c += 256) {
        int r = c >> 3, g = c & 7;
        int idx = r * 64 + ((g * 8) ^ ((r & 7) << 3));
        bf16x8 vh = {}, vl = {};
        if (r < 77) {
            long src = (long)(b * 77 + r) * 1024 + h * 64 + g * 8;
            vh = *(const bf16x8*)(KVH + src);
            vl = *(const bf16x8*)(KVL + src);
        }
        *(bf16x8*)&UH[idx] = vh;
        *(bf16x8*)&UL[idx] = vl;
    }
    __syncthreads();
    f32x4 s[5] = {};
    #pragma unroll
    for (int cf = 0; cf < 5; cf++) {
        int kvrow = cf * 16 + fr;
        #pragma unroll
        for (int kf = 0; kf < 2; kf++) {
            int idx = kvrow * 64 + ((kf * 32 + fq * 8) ^ ((kvrow & 7) << 3));
            bf16x8 Bh2 = *(const bf16x8*)&UH[idx];
            bf16x8 Bl2 = *(const bf16x8*)&UL[idx];
            s[cf] = __builtin_amdgcn_mfma_f32_16x16x32_bf16(Qh2[kf], Bh2, s[cf], 0, 0, 0);
            s[cf] = __builtin_amdgcn_mfma_f32_16x16x32_bf16(Qh2[kf], Bl2, s[cf], 0, 0, 0);
            s[cf] = __builtin_amdgcn_mfma_f32_16x16x32_bf16(Ql2[kf], Bh2, s[cf], 0, 0, 0);
        }
    }
    float inv[4];
    #pragma unroll
    for (int reg = 0; reg < 4; reg++) {
        float rs = 0.f;
        #pragma unroll
        for (int cf = 0; cf < 5; cf++) {
            int kv = cf * 16 + fr;
            float e = (kv < 77) ? __expf(s[cf][reg] * 0.125f) : 0.f;
            s[cf][reg] = e;
            rs += e;
        }
        rs += __shfl_xor(rs, 1);
        rs += __shfl_xor(rs, 2);
        rs += __shfl_xor(rs, 4);
        rs += __shfl_xor(rs, 8);
        inv[reg] = 1.f / rs;
    }
    short* ph = PHs[w];
    #pragma unroll
    for (int cf = 0; cf < 6; cf++)
    #pragma unroll
    for (int reg = 0; reg < 4; reg++) {
        int q = fq * 4 + reg, kv = cf * 16 + fr;
        int idx = q * 128 + (kv ^ ((q & 7) << 3));
        float pv = (cf < 5) ? s[cf][reg] * inv[reg] : 0.f;
        bf16 pb = __float2bfloat16(pv);
        ph[idx] = *(short*)&pb;
    }
    __syncthreads();
    for (int c = t; c < 768; c += 256) {
        int r = c >> 3, g = c & 7;
        bf16x8 vh = {}, vl = {};
        if (r < 77) {
            long src = (long)(b * 77 + r) * 1024 + 512 + h * 64 + g * 8;
            vh = *(const bf16x8*)(KVH + src);
            vl = *(const bf16x8*)(KVL + src);
        }
        #pragma unroll
        for (int j = 0; j < 8; j++) {
            int d = g * 8 + j;
            int idx = d * 128 + (r ^ (((d >> 3) & 7) << 3));
            UH[idx] = ((short*)&vh)[j];
            UL[idx] = ((short*)&vl)[j];
        }
    }
    __syncthreads();
    f32x4 o_acc[4] = {};
    bf16x8 Pf_h[3];
    #pragma unroll
    for (int kf = 0; kf < 3; kf++) {
        int idx = fr * 128 + ((kf * 32 + fq * 8) ^ ((fr & 7) << 3));
        Pf_h[kf] = *(const bf16x8*)&ph[idx];
    }
    #pragma unroll
    for (int cf = 0; cf < 4; cf++) {
        int d = cf * 16 + fr;
        #pragma unroll
        for (int kf = 0; kf < 3; kf++) {
            int idx = d * 128 + ((kf * 32 + fq * 8) ^ (((d >> 3) & 7) << 3));
            bf16x8 Vh2 = *(const bf16x8*)&UH[idx];
            bf16x8 Vl2 = *(const bf16x8*)&UL[idx];
            o_acc[cf] = __builtin_amdgcn_mfma_f32_16x16x32_bf16(Pf_h[kf], Vh2, o_acc[cf], 0, 0, 0);
            o_acc[cf] = __builtin_amdgcn_mfma_f32_16x16x32_bf16(Pf_h[kf], Vl2, o_acc[cf], 0, 0, 0);
        }
    }
    #pragma unroll
    for (int reg = 0; reg < 4; reg++) {
        long m = (long)(b * 1024 + qt * 64 + w * 16 + fq * 4 + reg);
        #pragma unroll
        for (int cf = 0; cf < 4; cf++) {
            bf16 hh, ll; split2(o_acc[cf][reg], hh, ll);
            long off = m * DIMC + h * 64 + cf * 16 + fr;
            oh[off] = hh; ol[off] = ll;
        }
    }
}

// ---- MoE grouped MFMA GEMM1, 64x128 tile: hid = gelu(xn·w1 + b1), K=512 ----
__global__ __launch_bounds__(256) void moe128_1_kernel(
    const bf16* __restrict__ xn_b, const bf16* __restrict__ e1T, const float* __restrict__ e_b1,
    const int* __restrict__ table, const int* __restrict__ ntiles, const int* __restrict__ perm,
    bf16* __restrict__ hid_b) {
    if (blockIdx.y >= ntiles[0]) return;
    int e = table[2 * blockIdx.y], row0 = table[2 * blockIdx.y + 1];
    int bn = blockIdx.x * 128;
    __shared__ short As[2 * 2048];
    __shared__ short Bs[2 * 4096];
    __shared__ int rowsS[64];
    int t = threadIdx.x, lane = t & 63, w = t >> 6;
    if (t < 64) rowsS[t] = perm[row0 + t];
    __syncthreads();
    int wm = (w >> 1) * 32, wn = (w & 1) * 64;
    int ra = t >> 2, ka = (t & 3) ^ ((ra >> 1) & 3);
    int tok0 = rowsS[ra]; if (tok0 < 0) tok0 = 0;
    const short* Xs = (const short*)xn_b;
    const short* Ws = (const short*)(e1T + (long)e * HIDC * DIMC);
    const short* a0 = Xs + (long)tok0 * DIMC + ka * 8;
    int p0 = t, p1 = t + 256;
    int rb0 = p0 >> 2, kb0 = (p0 & 3) ^ ((rb0 >> 1) & 3);
    int rb1 = p1 >> 2, kb1 = (p1 & 3) ^ ((rb1 >> 1) & 3);
    const short* b0 = Ws + (long)(bn + rb0) * DIMC + kb0 * 8;
    const short* b1 = Ws + (long)(bn + rb1) * DIMC + kb1 * 8;
    int fr = lane & 15, fq = lane >> 4;
    int aOff[2], bOff[4];
    #pragma unroll
    for (int i = 0; i < 2; i++) {
        int row = wm + i * 16 + fr;
        aOff[i] = row * 32 + ((fq ^ ((row >> 1) & 3)) * 8);
    }
    #pragma unroll
    for (int j = 0; j < 4; j++) {
        int col = wn + j * 16 + fr;
        bOff[j] = col * 32 + ((fq ^ ((col >> 1) & 3)) * 8);
    }
    f32x4 acc[2][4] = {};
    bf16x8 va  = *(const bf16x8*)a0;
    bf16x8 vb0 = *(const bf16x8*)b0;
    bf16x8 vb1 = *(const bf16x8*)b1;
    int bufA = 0, bufB = 0;
    for (int kk = 0; kk < DIMC; kk += 32) {
        *(bf16x8*)&As[bufA + t * 8] = va;
        *(bf16x8*)&Bs[bufB + p0 * 8] = vb0;
        *(bf16x8*)&Bs[bufB + p1 * 8] = vb1;
        __syncthreads();
        int kn = (kk + 32 < DIMC) ? kk + 32 : kk;
        bf16x8 na  = *(const bf16x8*)(a0 + kn);
        bf16x8 nb0 = *(const bf16x8*)(b0 + kn);
        bf16x8 nb1 = *(const bf16x8*)(b1 + kn);
        bf16x8 aF[2], bF[4];
        #pragma unroll
        for (int i = 0; i < 2; i++) aF[i] = *(const bf16x8*)&As[bufA + aOff[i]];
        #pragma unroll
        for (int j = 0; j < 4; j++) bF[j] = *(const bf16x8*)&Bs[bufB + bOff[j]];
        #pragma unroll
        for (int i = 0; i < 2; i++)
        #pragma unroll
        for (int j = 0; j < 4; j++)
            acc[i][j] = __builtin_amdgcn_mfma_f32_16x16x32_bf16(aF[i], bF[j], acc[i][j], 0, 0, 0);
        va = na; vb0 = nb0; vb1 = nb1;
        bufA ^= 2048; bufB ^= 4096;
    }
    const float* bb = e_b1 + (long)e * HIDC;
    #pragma unroll
    for (int i = 0; i < 2; i++)
    #pragma unroll
    for (int r = 0; r < 4; r++) {
        int tok = rowsS[wm + i * 16 + fq * 4 + r];
        if (tok < 0) continue;
        #pragma unroll
        for (int j = 0; j < 4; j++) {
            int col = bn + wn + j * 16 + fr;
            float v = acc[i][j][r] + bb[col];
            v = 0.5f * v * (1.f + erff(v * 0.70710678f));
            hid_b[(long)tok * HIDC + col] = __float2bfloat16(v);
        }
    }
}

// ---- MoE grouped MFMA GEMM2, 64x128 tile: out = resid + hid·w2 + b2 -> split bf16 ----
__global__ __launch_bounds__(256) void moe128_2_kernel(
    const bf16* __restrict__ hid_b, const bf16* __restrict__ e2T, const float* __restrict__ e_b2,
    const int* __restrict__ table, const int* __restrict__ ntiles, const int* __restrict__ perm,
    const float* __restrict__ resid, bf16* __restrict__ outh, bf16* __restrict__ outl) {
    if (blockIdx.y >= ntiles[0]) return;
    int e = table[2 * blockIdx.y], row0 = table[2 * blockIdx.y + 1];
    int bn = blockIdx.x * 128;
    __shared__ short As[2 * 2048];
    __shared__ short Bs[2 * 4096];
    __shared__ int rowsS[64];
    int t = threadIdx.x, lane = t & 63, w = t >> 6;
    if (t < 64) rowsS[t] = perm[row0 + t];
    __syncthreads();
    int wm = (w >> 1) * 32, wn = (w & 1) * 64;
    int ra = t >> 2, ka = (t & 3) ^ ((ra >> 1) & 3);
    int tok0 = rowsS[ra]; if (tok0 < 0) tok0 = 0;
    const short* Hs = (const short*)hid_b;
    const short* Ws = (const short*)(e2T + (long)e * DIMC * HIDC);
    const short* a0 = Hs + (long)tok0 * HIDC + ka * 8;
    int p0 = t, p1 = t + 256;
    int rb0 = p0 >> 2, kb0 = (p0 & 3) ^ ((rb0 >> 1) & 3);
    int rb1 = p1 >> 2, kb1 = (p1 & 3) ^ ((rb1 >> 1) & 3);
    const short* b0 = Ws + (long)(bn + rb0) * HIDC + kb0 * 8;
    const short* b1 = Ws + (long)(bn + rb1) * HIDC + kb1 * 8;
    int fr = lane & 15, fq = lane >> 4;
    int aOff[2], bOff[4];
    #pragma unroll
    for (int i = 0; i < 2; i++) {
        int row = wm + i * 16 + fr;
        aOff[i] = row * 32 + ((fq ^ ((row >> 1) & 3)) * 8);
    }
    #pragma unroll
    for (int j = 0; j < 4; j++) {
        int col = wn + j * 16 + fr;
        bOff[j] = col * 32 + ((fq ^ ((col >> 1) & 3)) * 8);
    }
    f32x4 acc[2][4] = {};
    bf16x8 va  = *(const bf16x8*)a0;
    bf16x8 vb0 = *(const bf16x8*)b0;
    bf16x8 vb1 = *(const bf16x8*)b1;
    int bufA = 0, bufB = 0;
    for (int kk = 0; kk < HIDC; kk += 32) {
        *(bf16x8*)&As[bufA + t * 8] = va;
        *(bf16x8*)&Bs[bufB + p0 * 8] = vb0;
        *(bf16x8*)&Bs[bufB + p1 * 8] = vb1;
        __syncthreads();
        int kn = (kk + 32 < HIDC) ? kk + 32 : kk;
        bf16x8 na  = *(const bf16x8*)(a0 + kn);
        bf16x8 nb0 = *(const bf16x8*)(b0 + kn);
        bf16x8 nb1 = *(const bf16x8*)(b1 + kn);
        bf16x8 aF[2], bF[4];
        #pragma unroll
        for (int i = 0; i < 2; i++) aF[i] = *(const bf16x8*)&As[bufA + aOff[i]];
        #pragma unroll
        for (int j = 0; j < 4; j++) bF[j] = *(const bf16x8*)&Bs[bufB + bOff[j]];
        #pragma unroll
        for (int i = 0; i < 2; i++)
        #pragma unroll
        for (int j = 0; j < 4; j++)
            acc[i][j] = __builtin_amdgcn_mfma_f32_16x16x32_bf16(aF[i], bF[j], acc[i][j], 0, 0, 0);
        va = na; vb0 = nb0; vb1 = nb1;
        bufA ^= 2048; bufB ^= 4096;
    }
    const float* bb = e_b2 + (long)e * DIMC;
    #pragma unroll
    for (int i = 0; i < 2; i++)
    #pragma unroll
    for (int r = 0; r < 4; r++) {
        int tok = rowsS[wm + i * 16 + fq * 4 + r];
        if (tok < 0) continue;
        #pragma unroll
        for (int j = 0; j < 4; j++) {
            int col = bn + wn + j * 16 + fr;
            long off = (long)tok * DIMC + col;
            float v = resid[off] + acc[i][j][r] + bb[col];
            bf16 hh, ll; split2(v, hh, ll);
            outh[off] = hh; outl[off] = ll;
        }
    }
}

// ---------------- LayerNorm: optional fp32 + bf16 hi/lo outputs ----------------
__global__ void ln_kernel(const float* __restrict__ x, const float* __restrict__ g,
                          const float* __restrict__ b, float* __restrict__ y,
                          bf16* __restrict__ yh, bf16* __restrict__ yl) {
    int tok = blockIdx.x;
    int t = threadIdx.x;
    const float* xr = x + (long)tok * DIMC;
    float v0 = xr[t], v1 = xr[t + 256];
    __shared__ float red[256];
    red[t] = v0 + v1; __syncthreads();
    for (int s = 128; s > 0; s >>= 1) { if (t < s) red[t] += red[t + s]; __syncthreads(); }
    float mu = red[0] * (1.f / DIMC);
    __syncthreads();
    float d0 = v0 - mu, d1 = v1 - mu;
    red[t] = d0 * d0 + d1 * d1; __syncthreads();
    for (int s = 128; s > 0; s >>= 1) { if (t < s) red[t] += red[t + s]; __syncthreads(); }
    float rs = rsqrtf(red[0] * (1.f / DIMC) + 1e-5f);
    float o0 = d0 * rs * g[t] + b[t];
    float o1 = d1 * rs * g[t + 256] + b[t + 256];
    if (y) { y[(long)tok * DIMC + t] = o0; y[(long)tok * DIMC + t + 256] = o1; }
    bf16 h, l;
    split2(o0, h, l); yh[(long)tok * DIMC + t] = h;       yl[(long)tok * DIMC + t] = l;
    split2(o1, h, l); yh[(long)tok * DIMC + t + 256] = h; yl[(long)tok * DIMC + t + 256] = l;
}

// ---------------- router text part (+ cnt zeroing) ----------------
__global__ void textpart_kernel(const float* __restrict__ w, const float* __restrict__ r_text_mu,
                                const float* __restrict__ r_comb_mu, float* __restrict__ tp,
                                int* __restrict__ cnt) {
    __shared__ float tw[4][128];
    int t = threadIdx.x;
    if (t < NE) cnt[t] = 0;
    for (int j = 0; j < 2; j++) {
        int idx = t + j * 256; int b = idx >> 7, c = idx & 127;
        const float* wr = w + (long)b * LATC;
        float s = 0.f;
        for (int k = 0; k < LATC; k++) s += wr[k] * r_text_mu[(long)k * 128 + c];
        tw[b][c] = s;
    }
    __syncthreads();
    if (t < 32) {
        int b = t >> 3, e = t & 7;
        float s = 0.f;
        for (int c = 0; c < 128; c++) s += tw[b][c] * r_comb_mu[(long)(128 + c) * 8 + e];
        tp[t] = s;
    }
}

// ---------------- router: perm poison + logits + argmax ----------------
__global__ void route_kernel(const float* __restrict__ feat, const float* __restrict__ tp,
                             const float* __restrict__ r_comb_mu, const float* __restrict__ r_temp,
                             float* __restrict__ onehot, int* __restrict__ idx, int* __restrict__ cnt,
                             int* __restrict__ perm) {
    int n = blockIdx.x * blockDim.x + threadIdx.x;
    if (n < MAXT * 64) perm[n] = -1;
    if (n >= NTOK) return;
    int b = n >> 10;
    float tmp = fmaxf(r_temp[0], 0.1f);
    float invt = 1.f / tmp;
    const float* fr = feat + (long)n * 128;
    float lg[8];
    for (int e = 0; e < 8; e++) {
        float s = 0.f;
        for (int c = 0; c < 128; c++) s += fr[c] * r_comb_mu[(long)c * 8 + e];
        lg[e] = (s + tp[b * 8 + e]) * invt;
    }
    float best = lg[0]; int bi = 0;
    for (int e = 1; e < 8; e++) { if (lg[e] > best) { best = lg[e]; bi = e; } }
    for (int e = 0; e < 8; e++) onehot[(long)n * 8 + e] = (e == bi) ? 1.f : 0.f;
    idx[n] = bi;
    atomicAdd(&cnt[bi], 1);
}

// ---------------- offsets + scatter fused (single block, LDS cursors) ----------------
__global__ void offscatter_kernel(const int* __restrict__ cnt, const int* __restrict__ idx,
                                  int* __restrict__ ntiles, int* __restrict__ table,
                                  int* __restrict__ perm) {
    __shared__ int cur[NE];
    int t = threadIdx.x;
    if (t == 0) {
        int po = 0, nt = 0;
        for (int e = 0; e < NE; e++) {
            cur[e] = po;
            int tiles = (cnt[e] + 63) >> 6;
            for (int j = 0; j < tiles; j++) { table[2 * nt] = e; table[2 * nt + 1] = po + j * 64; nt++; }
            po += tiles * 64;
        }
        ntiles[0] = nt;
    }
    __syncthreads();
    for (int n = t; n < NTOK; n += 256) {
        int e = idx[n];
        int pos = atomicAdd(&cur[e], 1);
        perm[pos] = n;
    }
}

extern "C" void kernel_launch(void* const* d_in, const int* in_sizes, int n_in,
                              void* d_out, int out_size, void* d_ws, size_t ws_size,
                              hipStream_t stream) {
    const float* x        = (const float*)d_in[0];
    const float* w        = (const float*)d_in[1];
    const float* text     = (const float*)d_in[2];
    const float* pin_w    = (const float*)d_in[3];
    const float* pin_mw   = (const float*)d_in[4];
    const float* pin_mb   = (const float*)d_in[5];
    const float* pout_w   = (const float*)d_in[6];
    const float* pout_mw  = (const float*)d_in[7];
    const float* pout_mb  = (const float*)d_in[8];
    const float* ln1g     = (const float*)d_in[9];
    const float* ln1b     = (const float*)d_in[10];
    const float* ln2g     = (const float*)d_in[11];
    const float* ln2b     = (const float*)d_in[12];
    const float* ln3g     = (const float*)d_in[13];
    const float* ln3b     = (const float*)d_in[14];
    const float* sa_in_w  = (const float*)d_in[15];
    const float* sa_in_b  = (const float*)d_in[16];
    const float* sa_out_w = (const float*)d_in[17];
    const float* sa_out_b = (const float*)d_in[18];
    const float* ca_in_w  = (const float*)d_in[19];
    const float* ca_in_b  = (const float*)d_in[20];
    const float* ca_out_w = (const float*)d_in[21];
    const float* ca_out_b = (const float*)d_in[22];
    const float* r_feat   = (const float*)d_in[23];
    const float* r_text   = (const float*)d_in[24];
    const float* r_comb   = (const float*)d_in[25];
    const float* r_temp   = (const float*)d_in[26];
    const float* e_w1     = (const float*)d_in[27];
    const float* e_b1     = (const float*)d_in[28];
    const float* e_w2     = (const float*)d_in[29];
    const float* e_b2     = (const float*)d_in[30];

    float* out    = (float*)d_out;               // [B, DIM, H, W]
    float* onehot = out + (long)BB * DIMC * HWX; // [4096, 8]

    // ---------------- workspace: fp32 pool ----------------
    float* f32p = (float*)d_ws;
    float* style_in  = f32p;                 // 2048
    float* style_out = f32p + 2048;          // 2048
    float* tp        = f32p + 4096;          // 32
    int*   idx       = (int*)(f32p + 4128);  // 4096
    int*   cnt       = (int*)(f32p + 8224);  // 8
    int*   ntiles    = (int*)(f32p + 8240);  // 8
    int*   table     = (int*)(f32p + 8248);  // 256
    int*   perm      = (int*)(f32p + 8504);  // 4608 -> ends 13112
    float* x_flat    = f32p + 13496;         // 2097152
    float* xn        = x_flat + 2097152;     // 2097152 (home of wtC split)
    float* qkv       = xn + 2097152;         // 6291456 (SA q split / CA q split home)
    float* spill     = qkv + 6291456;        // 2097152 (e2T tail)

    // ---------------- bf16 pool (phase-aliased) ----------------
    bf16* bp = (bf16*)(f32p + 12596408);
    bf16* R1 = bp;                           // 6291456 elems, phases
    bf16* xT_h  = R1;
    bf16* xT_l  = R1 + 2097152;
    bf16* wtA_h = R1 + 4194304;
    bf16* wtA_l = R1 + 5242880;
    bf16* obuf_h = R1;
    bf16* obuf_l = R1 + 2097152;
    bf16* kvt_h  = R1 + 4194304;                       // [308][1024] split
    bf16* kvt_l  = kvt_h + 315392;
    float* feat  = (float*)(kvt_l + 315392);           // 524288 fp32
    bf16* xn_h = R1 + 6291456;               // 2097152
    bf16* xn_l = xn_h + 2097152;             // 2097152
    bf16* WB   = xn_l + 2097152;             // 8388608: weights (early) / hid_b (late)
    bf16* text_h   = WB;
    bf16* text_l   = text_h + 157696;
    bf16* sawin_h  = text_l + 157696;
    bf16* sawin_l  = sawin_h + 786432;
    bf16* sawout_h = sawin_l + 786432;
    bf16* sawout_l = sawout_h + 262144;
    bf16* caw_h    = sawout_l + 262144;
    bf16* caw_l    = caw_h + 786432;
    bf16* cawout_h = caw_l + 786432;
    bf16* cawout_l = cawout_h + 262144;
    bf16* rfT_h    = cawout_l + 262144;      // [128][512] split r_feat^T
    bf16* rfT_l    = rfT_h + 65536;
    bf16* hid_b    = WB;                     // overlays weights after ca_out
    bf16* e1T = (bf16*)qkv;                  // [8][2048][512] in qkv+spill
    bf16* e2T = e1T + 8388608;
    bf16* xfl_h = xn_h;                      // moe128_2 writes split output here
    bf16* xfl_l = xn_l;
    bf16* wtC_h = (bf16*)xn;                 // modconv-out weight (dead fp32 region)
    bf16* wtC_l = wtC_h + 1048576;
    bf16* q_h = (bf16*)qkv;                  // [4096][1536]
    bf16* q_l = q_h + 6291456;
    bf16* ca_qh = (bf16*)qkv;                // [4096][512]
    bf16* ca_ql = ca_qh + 2097152;
    (void)ws_size; (void)spill;

    auto mg = [&](const bf16* Ah, const bf16* Al, const bf16* Bh, const bf16* Bl,
                  const float* bias, const float* resid, float* C, bf16* Oh, bf16* Ol,
                  int M, int N, int K, long ab, long bb, long cb, int csm, int csn, int nb) {
        dim3 g(N / 64, (M + 63) / 64, nb);
        hipLaunchKernelGGL(mgemm64_kernel, g, dim3(256), 0, stream,
                           Ah, Al, Bh, Bl, bias, resid, C, Oh, Ol, M, N, K, ab, bb, cb, csm, csn);
    };

    // ---- fused input conversions (hi/lo): one launch for all 5 flat arrays ----
    {
        int n0 = 1536 * 512, n1 = 512 * 512, n2 = 1536 * 512, n3 = 512 * 512, n4 = BB * TXT * 512;
        int total = n0 + n1 + n2 + n3 + n4;
        hipLaunchKernelGGL(cvtall_kernel, dim3((total / 4 + 255) / 256), dim3(256), 0, stream,
                           sa_in_w, sawin_h, sawin_l, n0,
                           sa_out_w, sawout_h, sawout_l, n1,
                           ca_in_w, caw_h, caw_l, n2,
                           ca_out_w, cawout_h, cawout_l, n3,
                           text, text_h, text_l, n4);
    }
    // ---- fused transposes: x (z<4) + r_feat (z==4) ----
    hipLaunchKernelGGL(trcvt2x_kernel, dim3(32, 16, 5), dim3(256), 0, stream,
                       x, xT_h, xT_l, r_feat, rfT_h, rfT_l);

    // ---- both modconv styles + weights up front (wtC in dead xn region) ----
    hipLaunchKernelGGL(style2_kernel, dim3(16), dim3(256), 0, stream,
                       w, pin_mw, pin_mb, pout_mw, pout_mb, style_in, style_out);
    hipLaunchKernelGGL(wtmod2_kernel, dim3(2 * BB * DIMC), dim3(256), 0, stream,
                       pin_w, style_in, pout_w, style_out, wtA_h, wtA_l, wtC_h, wtC_l);

    // ---- modconv in ----
    mg(xT_h, xT_l, wtA_h, wtA_l, nullptr, nullptr, x_flat, nullptr, nullptr,
       HWX, DIMC, DIMC, (long)HWX * DIMC, (long)DIMC * DIMC, (long)HWX * DIMC, DIMC, 1, BB);

    // ---- LN1 + self-attention (split MFMA) ----
    hipLaunchKernelGGL(ln_kernel, dim3(NTOK), dim3(256), 0, stream, x_flat, ln1g, ln1b,
                       (float*)nullptr, xn_h, xn_l);
    // qkv projection via high-reuse 128x64 kernel
    hipLaunchKernelGGL(mgemm128x64_kernel, dim3(1536 / 64, NTOK / 128), dim3(256), 0, stream,
                       xn_h, xn_l, sawin_h, sawin_l, sa_in_b, q_h, q_l, NTOK, 1536, 512);
    hipLaunchKernelGGL(sa_mfma_kernel, dim3(16, HEADS, BB), dim3(256), 0, stream,
                       q_h, q_l, obuf_h, obuf_l);
    mg(obuf_h, obuf_l, sawout_h, sawout_l, sa_out_b, x_flat, x_flat, nullptr, nullptr,
       NTOK, 512, 512, 0, 0, 0, 512, 1, 1);

    // ---- LN2 + cross-attention (split MFMA) ----
    hipLaunchKernelGGL(ln_kernel, dim3(NTOK), dim3(256), 0, stream, x_flat, ln2g, ln2b,
                       (float*)nullptr, xn_h, xn_l);
    mg(xn_h, xn_l, caw_h, caw_l, ca_in_b, nullptr, nullptr, ca_qh, ca_ql,
       NTOK, 512, 512, 0, 0, 0, 512, 1, 1);
    mg(text_h, text_l, caw_h + 512 * 512, caw_l + 512 * 512, ca_in_b + 512, nullptr, nullptr,
       kvt_h, kvt_l, BB * TXT, 1024, 512, 0, 0, 0, 1024, 1, 1);
    hipLaunchKernelGGL(ca_mfma_kernel, dim3(16, HEADS, BB), dim3(256), 0, stream,
                       ca_qh, ca_ql, kvt_h, kvt_l, obuf_h, obuf_l);
    // expert weight transposes (qkv region dead after ca_mfma) — one fused launch
    hipLaunchKernelGGL(tr2x_kernel, dim3(64, 16, 16), dim3(256), 0, stream,
                       e_w1, e1T, e_w2, e2T);
    mg(obuf_h, obuf_l, cawout_h, cawout_l, ca_out_b, x_flat, x_flat, nullptr, nullptr,
       NTOK, 512, 512, 0, 0, 0, 512, 1, 1);

    // ---- LN3 + router (feat via split MFMA) ----
    hipLaunchKernelGGL(ln_kernel, dim3(NTOK), dim3(256), 0, stream, x_flat, ln3g, ln3b,
                       (float*)nullptr, xn_h, xn_l);
    mg(xn_h, xn_l, rfT_h, rfT_l, nullptr, nullptr, feat, nullptr, nullptr,
       NTOK, 128, 512, 0, 0, 0, 128, 1, 1);
    hipLaunchKernelGGL(textpart_kernel, dim3(1), dim3(256), 0, stream, w, r_text, r_comb, tp, cnt);
    hipLaunchKernelGGL(route_kernel, dim3(18), dim3(256), 0, stream,
                       feat, tp, r_comb, r_temp, onehot, idx, cnt, perm);
    hipLaunchKernelGGL(offscatter_kernel, dim3(1), dim3(256), 0, stream,
                       cnt, idx, ntiles, table, perm);

    // ---- MoE grouped MFMA GEMMs (64x128 tiles; gemm2 emits split bf16 directly) ----
    hipLaunchKernelGGL(moe128_1_kernel, dim3(HIDC / 128, MAXT), dim3(256), 0, stream,
                       xn_h, e1T, e_b1, table, ntiles, perm, hid_b);
    hipLaunchKernelGGL(moe128_2_kernel, dim3(DIMC / 128, MAXT), dim3(256), 0, stream,
                       hid_b, e2T, e_b2, table, ntiles, perm, x_flat, xfl_h, xfl_l);

    // ---- modconv out (weights already prepared) ----
    mg(wtC_h, wtC_l, xfl_h, xfl_l, nullptr, nullptr, out, nullptr, nullptr,
       DIMC, HWX, DIMC, (long)DIMC * DIMC, (long)HWX * DIMC, (long)DIMC * HWX, HWX, 1, BB);
}